// Round 3
// baseline (4959.258 us; speedup 1.0000x reference)
//
#include <hip/hip_runtime.h>
#include <hip/hip_bf16.h>
#include <math.h>
#include <stdio.h>

static constexpr int   kN  = 800;    // nodes
static constexpr int   kF  = 111;    // input features
static constexpr int   kE  = 32;     // embed dim
static constexpr int   kH  = 200;    // hidden
static constexpr int   kNC = 15;     // classes
static constexpr int   kNE = 8000;   // edges per type
static constexpr long  kNN = (long)kN*kN;   // 640000
static constexpr long  kNH = (long)kN*kH;   // 160000
static constexpr float kAl  = 0.5f;  // ALPHA
static constexpr float kEps = 1e-5f;
static constexpr int   kRB  = 512;   // reduction blocks

enum { EPI_NONE=0, EPI_BIAS=1, EPI_MASK=2, EPI_ACC=3 };

// ---------------------------------------------------------------- GEMM
// C[M,Ncl] = A(MxK or K,M if TRANSA) * B[K,Ncl]  (+ epilogue)
// TRIUA: A[m,k]==0 for k<m (exact)  -> start k at m0
// TRIUB: B[k,n]==0 for k>n (exact)  -> end   k at n0+TN
template<bool TRANSA, bool TRIUA, bool TRIUB, int EPI>
__global__ __launch_bounds__(256)
void gemm_kernel(const float* __restrict__ A, const float* __restrict__ B,
                 float* __restrict__ C, int M, int Ncl, int K,
                 long sA, long sB, long sC, float scale, const float* __restrict__ bias)
{
  constexpr int TM=64, TN=64, TK=16;
  A += (long)blockIdx.z * sA;
  B += (long)blockIdx.z * sB;
  C += (long)blockIdx.z * sC;
  __shared__ float As[TK][TM+4];
  __shared__ float Bs[TK][TN+4];
  const int tid = threadIdx.x;
  const int tn4 = (tid & 15)*4, tm4 = (tid >> 4)*4;
  const int m0 = blockIdx.x * TM, n0 = blockIdx.y * TN;
  float acc[4][4] = {};
  const bool skip = TRIUA && TRIUB && (m0 > n0 + TN - 1);
  int k0 = TRIUA ? m0 : 0;
  const int kEnd = TRIUB ? min(K, n0 + TN) : K;
  if (!skip) {
    for (; k0 < kEnd; k0 += TK) {
      #pragma unroll
      for (int u=0; u<4; ++u) {
        int idx = tid + 256*u;  // 0..1023
        if (!TRANSA) {
          int m = idx >> 4, ka = idx & 15;
          int gm = m0+m, gk = k0+ka;
          As[ka][m] = (gm < M && gk < K) ? A[(long)gm*K + gk] : 0.f;
        } else {
          int ka = idx >> 6, m = idx & 63;
          int gm = m0+m, gk = k0+ka;
          As[ka][m] = (gm < M && gk < K) ? A[(long)gk*M + gm] : 0.f;
        }
        int kb = idx >> 6, nb = idx & 63;
        int gk = k0+kb, gn = n0+nb;
        Bs[kb][nb] = (gk < K && gn < Ncl) ? B[(long)gk*Ncl + gn] : 0.f;
      }
      __syncthreads();
      #pragma unroll
      for (int kk=0; kk<TK; ++kk) {
        float a[4], b[4];
        #pragma unroll
        for (int u=0;u<4;++u){ a[u]=As[kk][tm4+u]; b[u]=Bs[kk][tn4+u]; }
        #pragma unroll
        for (int i=0;i<4;++i)
          #pragma unroll
          for (int j=0;j<4;++j)
            acc[i][j] = fmaf(a[i], b[j], acc[i][j]);
      }
      __syncthreads();
    }
  }
  #pragma unroll
  for (int i=0;i<4;++i) {
    int gm = m0 + tm4 + i;
    if (gm >= M) continue;
    #pragma unroll
    for (int j=0;j<4;++j) {
      int gn = n0 + tn4 + j;
      if (gn >= Ncl) continue;
      float v = acc[i][j];
      long off = (long)gm*Ncl + gn;
      if (EPI == EPI_BIAS)      C[off] = v + bias[gn];
      else if (EPI == EPI_MASK) C[off] = (v != 0.f) ? 1.f : 0.f;
      else if (EPI == EPI_ACC)  unsafeAtomicAdd(&C[off], scale*v);
      else                      C[off] = v;
    }
  }
}

template<bool TRANSA, bool TRIUA, bool TRIUB, int EPI>
static inline void launch_gemm(hipStream_t st, const float* A, const float* B, float* C,
                               int M, int Ncl, int K, int batch,
                               long sA, long sB, long sC, float scale, const float* bias)
{
  dim3 grid((M+63)/64, (Ncl+63)/64, batch);
  gemm_kernel<TRANSA,TRIUA,TRIUB,EPI><<<grid, 256, 0, st>>>(A,B,C,M,Ncl,K,sA,sB,sC,scale,bias);
}

// ---------------------------------------------------------------- small kernels
// t[n,f] = sum_e Y[(8+e)][n,f] + sum_e((1-a)*b0 + a*b1 + b2)[f]
__global__ void combine_root_kernel(const float* __restrict__ Y, const float* __restrict__ b,
                                    float* __restrict__ out){
  long idx = (long)blockIdx.x*256 + threadIdx.x;
  if (idx >= kNH) return;
  int f = (int)(idx % kH);
  float v = 0.f;
  #pragma unroll
  for (int e=0;e<4;++e) {
    v += Y[(long)(8+e)*kNH + idx];
    v += (1.f-kAl)*b[(0*4+e)*kH + f] + kAl*b[(1*4+e)*kH + f] + b[(2*4+e)*kH + f];
  }
  out[idx] = v;
}

// scatter messages: out[dst] += (1-a)*Min[src];  out[src] += a*Mout[dst]
__global__ __launch_bounds__(256)
void scatter_kernel(const int* __restrict__ e0, const int* __restrict__ e1,
                    const int* __restrict__ e2, const int* __restrict__ e3,
                    const float* __restrict__ Y, float* __restrict__ out){
  const int* eis[4] = {e0,e1,e2,e3};
  const int e = blockIdx.y;
  const int* ei = eis[e];
  long idx = (long)blockIdx.x*256 + threadIdx.x;
  if (idx >= (long)kNE*kH) return;
  int j = (int)(idx / kH), f = (int)(idx % kH);
  int s = ei[j], d = ei[kNE + j];
  float m_in  = Y[((long)e*kN + s)*kH + f];
  float m_out = Y[((long)(4+e)*kN + d)*kH + f];
  unsafeAtomicAdd(&out[(long)d*kH + f], (1.f-kAl)*m_in);
  unsafeAtomicAdd(&out[(long)s*kH + f], kAl*m_out);
}

__global__ void build_adj_kernel(const int* __restrict__ e0, const int* __restrict__ e1,
                                 const int* __restrict__ e2, const int* __restrict__ e3,
                                 float* __restrict__ A0){
  const int* eis[4] = {e0,e1,e2,e3};
  const int e = blockIdx.y;
  const int* ei = eis[e];
  int j = blockIdx.x*256 + threadIdx.x;
  if (j >= kNE) return;
  int s = ei[j], d = ei[kNE + j];
  A0[(long)e*kNN + (long)s*kN + d] = 1.0f;  // set (dup-safe), not add
}

// ---- deterministic two-stage (sum, sumsq) reduction: no atomics, no 64b shuffles
__global__ __launch_bounds__(256)
void reduce2_part_kernel(const float* __restrict__ x, long n, double* __restrict__ part){
  __shared__ double ss[256], qq[256];
  double s=0.0, q=0.0;
  for (long i = (long)blockIdx.x*256 + threadIdx.x; i < n; i += (long)gridDim.x*256){
    double v = x[i]; s += v; q += v*v;
  }
  ss[threadIdx.x]=s; qq[threadIdx.x]=q;
  __syncthreads();
  for (int h=128; h>0; h>>=1){
    if ((int)threadIdx.x < h){ ss[threadIdx.x]+=ss[threadIdx.x+h]; qq[threadIdx.x]+=qq[threadIdx.x+h]; }
    __syncthreads();
  }
  if (threadIdx.x==0){ part[2*blockIdx.x]=ss[0]; part[2*blockIdx.x+1]=qq[0]; }
}

__global__ __launch_bounds__(256)
void reduce2_fin_kernel(const double* __restrict__ part, int nb, double* __restrict__ out){
  __shared__ double ss[256], qq[256];
  double s=0.0, q=0.0;
  for (int i=threadIdx.x; i<nb; i+=256){ s += part[2*i]; q += part[2*i+1]; }
  ss[threadIdx.x]=s; qq[threadIdx.x]=q;
  __syncthreads();
  for (int h=128; h>0; h>>=1){
    if ((int)threadIdx.x < h){ ss[threadIdx.x]+=ss[threadIdx.x+h]; qq[threadIdx.x]+=qq[threadIdx.x+h]; }
    __syncthreads();
  }
  if (threadIdx.x==0){ out[0]=ss[0]; out[1]=qq[0]; }
}

// graph layernorm: y = (x-mu)*rsqrt(var+eps)*w[f] + b[f]   (mu/var over ALL N*H)
__global__ void apply_ln_kernel(const float* __restrict__ x, float* __restrict__ y,
                                const float* __restrict__ ln, const double* __restrict__ sc){
  long idx = (long)blockIdx.x*256 + threadIdx.x;
  if (idx >= kNH) return;
  int f = (int)(idx % kH);
  double mu  = sc[0] / (double)kNH;
  double var = sc[1] / (double)kNH - mu*mu;
  float rs = rsqrtf((float)var + kEps);
  y[idx] = (x[idx] - (float)mu) * rs * ln[f] + ln[kH + f];
}

// tri[i,j] = (i<=j) ? sigmoid(sum_k (z_i-z_j)^2 w_k + b) : 0
__global__ __launch_bounds__(256)
void pair_kernel(const float* __restrict__ z, const float* __restrict__ linW,
                 const float* __restrict__ linb, float* __restrict__ tri){
  __shared__ float zi[16][201], zj[16][201], w[208];
  const int i0 = blockIdx.y*16, j0 = blockIdx.x*16;
  const int tid = threadIdx.x;
  const int ti = tid >> 4, tj = tid & 15;
  const int i = i0+ti, j = j0+tj;
  if (i0 > j0 + 15) { tri[(long)i*kN + j] = 0.f; return; }  // fully lower block
  for (int idx = tid; idx < 16*kH; idx += 256){
    int r = idx / kH, c = idx % kH;
    zi[r][c] = z[(long)(i0+r)*kH + c];
    zj[r][c] = z[(long)(j0+r)*kH + c];
  }
  if (tid < kH) w[tid] = linW[tid];
  __syncthreads();
  float g = 0.f;
  if (i <= j){
    float s = linb[0];
    #pragma unroll 4
    for (int k=0;k<kH;++k){ float d = zi[ti][k]-zj[tj][k]; s = fmaf(d*d, w[k], s); }
    g = 1.f/(1.f + expf(-s));
  }
  tri[(long)i*kN + j] = g;
}

// papp = I - A/normA ; psq = P0*I + P1*papp ; qsq = Q0*I + Q1*papp
__global__ void init_pade_kernel(const float* __restrict__ tri, float* __restrict__ papp,
                                 float* __restrict__ psq, float* __restrict__ qsq,
                                 const double* __restrict__ frob2,
                                 float P0, float P1, float Q0, float Q1){
  int idx = blockIdx.x*256 + threadIdx.x;
  if (idx >= (int)kNN) return;
  int i = idx / kN, j = idx % kN;
  float rn = (float)(1.0 / sqrt(frob2[0]));
  float eye = (i==j) ? 1.f : 0.f;
  float pa = eye - tri[idx]*rn;
  papp[idx] = pa;
  psq[idx] = P0*eye + P1*pa;
  qsq[idx] = Q0*eye + Q1*pa;
}

__global__ void accpow_kernel(const float* __restrict__ pw, float* __restrict__ psq,
                              float* __restrict__ qsq, float pk, float qk){
  int idx = blockIdx.x*256 + threadIdx.x;
  if (idx >= (int)kNN) return;
  float v = pw[idx];
  psq[idx] += pk*v;
  qsq[idx] += qk*v;
}

// back-substitution U X = P, U & P exactly upper-triangular -> X upper-tri.
// one wave per column j; rows i>j are exactly 0. S = X * sqrt(normA).
__global__ __launch_bounds__(64)
void trsm_kernel(const float* __restrict__ U, const float* __restrict__ P,
                 float* __restrict__ S, float* __restrict__ Sout,
                 const double* __restrict__ frob2){
  const int j = blockIdx.x;
  const int lane = threadIdx.x;
  __shared__ float x[kN];
  const float fac = (float)sqrt(sqrt(frob2[0]));   // sqrt(normA), normA=sqrt(frob2)
  for (int i = j+1+lane; i < kN; i += 64){
    S[(long)i*kN + j] = 0.f;
    Sout[(long)i*kN + j] = 0.f;
  }
  for (int i = j; i >= 0; --i){
    const float* Ur = U + (long)i*kN;
    float s = 0.f;
    for (int k = i+1+lane; k <= j; k += 64) s = fmaf(Ur[k], x[k], s);
    #pragma unroll
    for (int off=32; off>0; off>>=1) s += __shfl_down(s, off, 64);
    if (lane == 0) x[i] = (P[(long)i*kN + j] - s) / Ur[i];
    __syncthreads();
  }
  for (int i = lane; i <= j; i += 64){
    float v = x[i]*fac;
    S[(long)i*kN + j] = v;
    Sout[(long)i*kN + j] = v;
  }
}

// global mean pool + classifier + log_softmax
__global__ __launch_bounds__(256)
void pool_head_kernel(const float* __restrict__ z2, const float* __restrict__ W,
                      const float* __restrict__ b, float* __restrict__ out){
  __shared__ float x2[kH];
  __shared__ float lg[kNC];
  int t = threadIdx.x;
  if (t < kH){
    float s = 0.f;
    for (int n = 0; n < kN; ++n) s += z2[(long)n*kH + t];
    float v = s * (1.f/(float)kN);
    x2[t] = v;
    out[t] = v;
  }
  __syncthreads();
  if (t < kNC){
    float s = b[t];
    for (int f = 0; f < kH; ++f) s = fmaf(x2[f], W[f*kNC + t], s);
    lg[t] = s;
  }
  __syncthreads();
  if (t == 0){
    float m = -1e30f;
    for (int c=0;c<kNC;++c) m = fmaxf(m, lg[c]);
    float se = 0.f;
    for (int c=0;c<kNC;++c) se += expf(lg[c]-m);
    float lse = m + logf(se);
    for (int c=0;c<kNC;++c) out[kH + c] = lg[c]-lse;
  }
}

// ---- NaN/Inf canary: prints stage id once if any non-finite found
__global__ void canary_kernel(const float* __restrict__ x, long n, int id, int* __restrict__ flag){
  for (long i = (long)blockIdx.x*256 + threadIdx.x; i < n; i += (long)gridDim.x*256){
    float v = x[i];
    if (!isfinite(v)){
      if (atomicExch(&flag[id], 1) == 0)
        printf("CANARY %d: bad %e at %ld\n", id, (double)v, i);
      return;
    }
  }
}
__global__ void canary_scal_kernel(const double* __restrict__ sc, int id, int* __restrict__ flag){
  if (threadIdx.x==0 && blockIdx.x==0){
    double v0=sc[0], v1=sc[1];
    if (!(isfinite(v0) && isfinite(v1)) || v1 <= 0.0){
      if (atomicExch(&flag[id], 1) == 0)
        printf("CANARY %d: scal %e %e\n", id, v0, v1);
    }
  }
}

// ---------------------------------------------------------------- host: Pade [5/5] of sqrt(1-x)
static void pade_coeffs(float* P, float* Q){
  double b[11]; b[0] = 1.0;
  for (int k=1;k<11;++k) b[k] = b[k-1]*(0.5-(k-1))/k;
  double c[11];
  for (int k=0;k<11;++k) c[k] = b[k]*((k&1)?-1.0:1.0);
  double A[5][5], rhs[5];
  for (int i=0;i<5;++i){ for (int j=0;j<5;++j) A[i][j] = c[5+i-j]; rhs[i] = -c[6+i]; }
  for (int col=0; col<5; ++col){
    int p = col;
    for (int r=col+1;r<5;++r) if (fabs(A[r][col]) > fabs(A[p][col])) p = r;
    if (p != col){
      for (int j=0;j<5;++j){ double t=A[col][j]; A[col][j]=A[p][j]; A[p][j]=t; }
      double t=rhs[col]; rhs[col]=rhs[p]; rhs[p]=t;
    }
    for (int r=col+1;r<5;++r){
      double f = A[r][col]/A[col][col];
      for (int j=col;j<5;++j) A[r][j] -= f*A[col][j];
      rhs[r] -= f*rhs[col];
    }
  }
  double q[6]; q[0] = 1.0;
  for (int r=4;r>=0;--r){
    double s = rhs[r];
    for (int j=r+1;j<5;++j) s -= A[r][j]*q[1+j];
    q[1+r] = s/A[r][r];
  }
  double p[6];
  for (int k=0;k<6;++k){
    double s = 0.0; int jm = k<5?k:5;
    for (int j=0;j<=jm;++j) s += q[j]*c[k-j];
    p[k] = s;
  }
  for (int k=0;k<6;++k){ P[k]=(float)p[k]; Q[k]=(float)q[k]; }
}

// ---------------------------------------------------------------- launch
extern "C" void kernel_launch(void* const* d_in, const int* in_sizes, int n_in,
                              void* d_out, int out_size, void* d_ws, size_t ws_size,
                              hipStream_t stream)
{
  const float* x_note = (const float*)d_in[0];
  const float* embW   = (const float*)d_in[1];
  const float* embB   = (const float*)d_in[2];
  const float* g1w1   = (const float*)d_in[3];
  const float* g1b1   = (const float*)d_in[4];
  const float* g1w2   = (const float*)d_in[5];
  const float* g1b2   = (const float*)d_in[6];
  const float* g1ln   = (const float*)d_in[7];
  const float* g2w1   = (const float*)d_in[8];
  const float* g2b1   = (const float*)d_in[9];
  const float* g2w2   = (const float*)d_in[10];
  const float* g2b2   = (const float*)d_in[11];
  const float* g2ln   = (const float*)d_in[12];
  const float* linW   = (const float*)d_in[13];
  const float* linb   = (const float*)d_in[14];
  const float* clfW   = (const float*)d_in[15];
  const float* clfb   = (const float*)d_in[16];
  const int*  e0     = (const int*)d_in[17];
  const int*  e1     = (const int*)d_in[18];
  const int*  e2     = (const int*)d_in[19];
  const int*  e3     = (const int*)d_in[20];
  float* out = (float*)d_out;

  // workspace layout:
  // bytes 0..31        : scald[0..3]  (LN pair, frob pair)
  // bytes 128..255     : canary flags (int[32])
  // bytes 512..8703    : reduction partials (kRB blocks x 2 doubles)
  // floats from o_h0   : tensors
  constexpr long o_h0   = 2176;
  constexpr long o_h1   = o_h0   + (long)kN*kE;
  constexpr long o_h2   = o_h1   + (long)kN*kE;
  constexpr long o_tnh  = o_h2   + (long)kN*kE;
  constexpr long o_zmid = o_tnh  + kNH;
  constexpr long o_z0   = o_zmid + kNH;
  constexpr long o_z1   = o_z0   + kNH;
  constexpr long o_z2   = o_z1   + kNH;
  constexpr long o_big  = o_z2   + kNH;             // union: Y (12*kNH) / T4 (4*kNN)
  constexpr long o_tri  = o_big  + 4*kNN;
  constexpr long o_papp = o_tri  + kNN;
  constexpr long o_pw1  = o_papp + kNN;
  constexpr long o_psq  = o_pw1  + kNN;
  constexpr long o_qsq  = o_psq  + kNN;
  constexpr long o_S1   = o_qsq  + kNN;
  constexpr long o_S2   = o_S1   + kNN;
  constexpr long o_A0   = o_S2   + kNN;             // 4*kNN; reused as mask2
  constexpr long o_M1   = o_A0   + 4*kNN;           // 4*kNN
  constexpr long o_end  = o_M1   + 4*kNN;

  if (ws_size < (size_t)o_end*sizeof(float) || out_size < 215 + 2*(int)kNN || n_in < 21){
    fprintf(stderr, "kernel_launch guard: ws=%zu need=%zu out=%d need=%d n_in=%d\n",
            ws_size, (size_t)o_end*sizeof(float), out_size, (int)(215+2*kNN), n_in);
    hipMemsetAsync(d_out, 0, (size_t)out_size*sizeof(float), stream);
    return;
  }

  float* ws = (float*)d_ws;
  double* scald = (double*)d_ws;
  int*    flags = (int*)((char*)d_ws + 128);
  double* partd = (double*)((char*)d_ws + 512);
  float *h0=ws+o_h0, *h1=ws+o_h1, *h2=ws+o_h2, *tnh=ws+o_tnh,
        *zmid=ws+o_zmid, *z0=ws+o_z0, *z1=ws+o_z1, *z2=ws+o_z2, *big=ws+o_big,
        *tri=ws+o_tri, *papp=ws+o_papp, *pw1=ws+o_pw1, *psq=ws+o_psq, *qsq=ws+o_qsq,
        *S1=ws+o_S1, *S2=ws+o_S2, *A0=ws+o_A0, *M1=ws+o_M1;
  float* pw0 = tri;  // tri buffer reused as a power buffer after init_pade

  float P[6], Q[6];
  pade_coeffs(P, Q);

  auto eg = [](long n){ return dim3((unsigned)((n+255)/256)); };

  hipMemsetAsync(flags, 0, 32*sizeof(int), stream);
  auto canary = [&](const float* buf, long n, int id){
    canary_kernel<<<256,256,0,stream>>>(buf, n, id, flags);
  };

  auto reduce2 = [&](const float* src, long n, double* dst){
    reduce2_part_kernel<<<kRB,256,0,stream>>>(src, n, partd);
    reduce2_fin_kernel<<<1,256,0,stream>>>(partd, kRB, dst);
  };
  auto do_ln = [&](const float* src, float* dst, const float* lnp){
    reduce2(src, kNH, scald);
    apply_ln_kernel<<<eg(kNH),256,0,stream>>>(src, dst, lnp, scald);
  };
  auto sparse_layer = [&](const float* hin, int K, const float* W, const float* b,
                          const float* lnp, float* zout){
    launch_gemm<false,false,false,EPI_NONE>(stream, hin, W, big, kN, kH, K, 12,
                                            0, (long)K*kH, kNH, 0.f, nullptr);
    combine_root_kernel<<<eg(kNH),256,0,stream>>>(big, b, tnh);
    scatter_kernel<<<dim3((unsigned)(((long)kNE*kH+255)/256),4),256,0,stream>>>(e0,e1,e2,e3, big, tnh);
    do_ln(tnh, zout, lnp);
  };
  auto dense_layer = [&](const float* hin, int K, const float* masks, const float* W,
                         const float* b, const float* lnp, float* zout){
    launch_gemm<false,false,false,EPI_NONE>(stream, hin, W, big, kN, kH, K, 12,
                                            0, (long)K*kH, kNH, 0.f, nullptr);
    combine_root_kernel<<<eg(kNH),256,0,stream>>>(big, b, tnh);
    // t += (1-a) * mask^T @ Y[(0,e)] ;  t += a * mask @ Y[(1,e)]   (batched over e, atomic acc)
    launch_gemm<true ,false,false,EPI_ACC>(stream, masks, big,       tnh, kN, kH, kN, 4,
                                           kNN, kNH, 0, 1.f-kAl, nullptr);
    launch_gemm<false,false,false,EPI_ACC>(stream, masks, big+4*kNH, tnh, kN, kH, kN, 4,
                                           kNN, kNH, 0, kAl,     nullptr);
    do_ln(tnh, zout, lnp);
  };

  // ---- embed
  launch_gemm<false,false,false,EPI_BIAS>(stream, x_note, embW, h0, kN, kE, kF, 1, 0,0,0, 0.f, embB);
  canary(h0, (long)kN*kE, 0);

  // ---- GNN1 (sparse)
  sparse_layer(h0,  kE, g1w1, g1b1, g1ln,        zmid);
  sparse_layer(zmid,kH, g1w2, g1b2, g1ln + 2*kH, z0);
  canary(z0, kNH, 1);

  // ---- S1  (canary ids 2..5)
  {
    pair_kernel<<<dim3(50,50),256,0,stream>>>(z0, linW, linb, tri);
    canary(tri, kNN, 2);
    reduce2(tri, kNN, scald+2);
    canary_scal_kernel<<<1,64,0,stream>>>(scald+2, 3, flags);
    init_pade_kernel<<<eg(kNN),256,0,stream>>>(tri, papp, psq, qsq, scald+3, P[0],P[1],Q[0],Q[1]);
    launch_gemm<false,true,true,EPI_NONE>(stream, papp, papp, pw0, kN,kN,kN, 1, 0,0,0, 0.f, nullptr);
    accpow_kernel<<<eg(kNN),256,0,stream>>>(pw0, psq, qsq, P[2],Q[2]);
    launch_gemm<false,true,true,EPI_NONE>(stream, pw0, papp, pw1, kN,kN,kN, 1, 0,0,0, 0.f, nullptr);
    accpow_kernel<<<eg(kNN),256,0,stream>>>(pw1, psq, qsq, P[3],Q[3]);
    launch_gemm<false,true,true,EPI_NONE>(stream, pw1, papp, pw0, kN,kN,kN, 1, 0,0,0, 0.f, nullptr);
    accpow_kernel<<<eg(kNN),256,0,stream>>>(pw0, psq, qsq, P[4],Q[4]);
    launch_gemm<false,true,true,EPI_NONE>(stream, pw0, papp, pw1, kN,kN,kN, 1, 0,0,0, 0.f, nullptr);
    accpow_kernel<<<eg(kNN),256,0,stream>>>(pw1, psq, qsq, P[5],Q[5]);
    canary(qsq, kNN, 4);
    trsm_kernel<<<dim3(kN),64,0,stream>>>(qsq, psq, S1, out + 215, scald+3);
    canary(S1, kNN, 5);
  }

  // ---- h1 = S1 @ h0
  launch_gemm<false,true,false,EPI_NONE>(stream, S1, h0, h1, kN, kE, kN, 1, 0,0,0, 0.f, nullptr);

  // ---- A0 adjacency + mask1 = (S1@A0)@S1 != 0
  hipMemsetAsync(A0, 0, (size_t)(4*kNN)*sizeof(float), stream);
  build_adj_kernel<<<dim3((kNE+255)/256,4),256,0,stream>>>(e0,e1,e2,e3, A0);
  launch_gemm<false,true ,false,EPI_NONE>(stream, S1, A0, big, kN,kN,kN, 4, 0,  kNN, kNN, 0.f, nullptr);
  launch_gemm<false,false,true ,EPI_MASK>(stream, big, S1, M1,  kN,kN,kN, 4, kNN, 0,  kNN, 0.f, nullptr);
  canary(M1, 4*kNN, 6);

  // ---- GNN2 #1 (dense, mask1)
  dense_layer(h1,  kE, M1, g2w1, g2b1, g2ln,        zmid);
  dense_layer(zmid,kH, M1, g2w2, g2b2, g2ln + 2*kH, z1);
  canary(z1, kNH, 7);

  // ---- S2  (canary ids 8..11)
  {
    pair_kernel<<<dim3(50,50),256,0,stream>>>(z1, linW, linb, tri);
    canary(tri, kNN, 8);
    reduce2(tri, kNN, scald+2);
    canary_scal_kernel<<<1,64,0,stream>>>(scald+2, 9, flags);
    init_pade_kernel<<<eg(kNN),256,0,stream>>>(tri, papp, psq, qsq, scald+3, P[0],P[1],Q[0],Q[1]);
    launch_gemm<false,true,true,EPI_NONE>(stream, papp, papp, pw0, kN,kN,kN, 1, 0,0,0, 0.f, nullptr);
    accpow_kernel<<<eg(kNN),256,0,stream>>>(pw0, psq, qsq, P[2],Q[2]);
    launch_gemm<false,true,true,EPI_NONE>(stream, pw0, papp, pw1, kN,kN,kN, 1, 0,0,0, 0.f, nullptr);
    accpow_kernel<<<eg(kNN),256,0,stream>>>(pw1, psq, qsq, P[3],Q[3]);
    launch_gemm<false,true,true,EPI_NONE>(stream, pw1, papp, pw0, kN,kN,kN, 1, 0,0,0, 0.f, nullptr);
    accpow_kernel<<<eg(kNN),256,0,stream>>>(pw0, psq, qsq, P[4],Q[4]);
    launch_gemm<false,true,true,EPI_NONE>(stream, pw0, papp, pw1, kN,kN,kN, 1, 0,0,0, 0.f, nullptr);
    accpow_kernel<<<eg(kNN),256,0,stream>>>(pw1, psq, qsq, P[5],Q[5]);
    canary(qsq, kNN, 10);
    trsm_kernel<<<dim3(kN),64,0,stream>>>(qsq, psq, S2, out + 215 + kNN, scald+3);
    canary(S2, kNN, 11);
  }

  // ---- h2 = S2 @ h1
  launch_gemm<false,true,false,EPI_NONE>(stream, S2, h1, h2, kN, kE, kN, 1, 0,0,0, 0.f, nullptr);

  // ---- mask2 = (S2@mask1)@S2 != 0  (into A0 region)
  launch_gemm<false,true ,false,EPI_NONE>(stream, S2, M1, big, kN,kN,kN, 4, 0,  kNN, kNN, 0.f, nullptr);
  launch_gemm<false,false,true ,EPI_MASK>(stream, big, S2, A0,  kN,kN,kN, 4, kNN, 0,  kNN, 0.f, nullptr);

  // ---- GNN2 #2 (dense, mask2)
  dense_layer(h2,  kE, A0, g2w1, g2b1, g2ln,        zmid);
  dense_layer(zmid,kH, A0, g2w2, g2b2, g2ln + 2*kH, z2);
  canary(z2, kNH, 12);

  // ---- pool + classifier + log_softmax
  pool_head_kernel<<<dim3(1),256,0,stream>>>(z2, clfW, clfb, out);
}

// Round 4
// 3842.496 us; speedup vs baseline: 1.2906x; 1.2906x over previous
//
#include <hip/hip_runtime.h>
#include <hip/hip_bf16.h>
#include <math.h>
#include <stdio.h>

static constexpr int   kN  = 800;    // nodes
static constexpr int   kF  = 111;    // input features
static constexpr int   kE  = 32;     // embed dim
static constexpr int   kH  = 200;    // hidden
static constexpr int   kNC = 15;     // classes
static constexpr int   kNE = 8000;   // edges per type
static constexpr long  kNN = (long)kN*kN;   // 640000
static constexpr long  kNH = (long)kN*kH;   // 160000
static constexpr float kAl  = 0.5f;  // ALPHA
static constexpr float kEps = 1e-5f;
static constexpr int   kRB  = 512;   // reduction blocks
static constexpr int   kDB  = 100;   // trsm diagonal block size (800 = 8 * 100)

enum { EPI_NONE=0, EPI_BIAS=1, EPI_MASK=2, EPI_ACC=3, EPI_SCALE=4, EPI_SMUL2=5 };

// ---------------------------------------------------------------- GEMM
// C[M,N] = A * B with row strides lda/ldb/ldc (A is K x M if TRANSA).
// TRIUA: A[m,k]==0 for k<m (exact, local coords)  -> start k at m0
// TRIUB: B[k,n]==0 for k>n (exact, local coords)  -> end   k at n0+TN
// EPI_ACC: atomic C += scale*v.  EPI_SCALE: C = scale*v.
// EPI_SMUL2: f=sqrt(sqrt(scalp[0])); C = v*f and C2 = v*f.
template<bool TRANSA, bool TRIUA, bool TRIUB, int EPI>
__global__ __launch_bounds__(256)
void gemm_kernel(const float* __restrict__ A, int lda,
                 const float* __restrict__ B, int ldb,
                 float* __restrict__ C, int ldc,
                 int M, int Ncl, int K,
                 long sA, long sB, long sC, float scale,
                 const float* __restrict__ bias,
                 float* __restrict__ C2, const double* __restrict__ scalp)
{
  constexpr int TM=64, TN=64, TK=16;
  A += (long)blockIdx.z * sA;
  B += (long)blockIdx.z * sB;
  C += (long)blockIdx.z * sC;
  __shared__ float As[TK][TM+4];
  __shared__ float Bs[TK][TN+4];
  const int tid = threadIdx.x;
  const int tn4 = (tid & 15)*4, tm4 = (tid >> 4)*4;
  const int m0 = blockIdx.x * TM, n0 = blockIdx.y * TN;
  float acc[4][4] = {};
  const bool skip = TRIUA && TRIUB && (m0 > n0 + TN - 1);
  int k0 = TRIUA ? m0 : 0;
  const int kEnd = TRIUB ? min(K, n0 + TN) : K;
  if (!skip) {
    for (; k0 < kEnd; k0 += TK) {
      #pragma unroll
      for (int u=0; u<4; ++u) {
        int idx = tid + 256*u;  // 0..1023
        if (!TRANSA) {
          int m = idx >> 4, ka = idx & 15;
          int gm = m0+m, gk = k0+ka;
          As[ka][m] = (gm < M && gk < K) ? A[(long)gm*lda + gk] : 0.f;
        } else {
          int ka = idx >> 6, m = idx & 63;
          int gm = m0+m, gk = k0+ka;
          As[ka][m] = (gm < M && gk < K) ? A[(long)gk*lda + gm] : 0.f;
        }
        int kb = idx >> 6, nb = idx & 63;
        int gk = k0+kb, gn = n0+nb;
        Bs[kb][nb] = (gk < K && gn < Ncl) ? B[(long)gk*ldb + gn] : 0.f;
      }
      __syncthreads();
      #pragma unroll
      for (int kk=0; kk<TK; ++kk) {
        float a[4], b[4];
        #pragma unroll
        for (int u=0;u<4;++u){ a[u]=As[kk][tm4+u]; b[u]=Bs[kk][tn4+u]; }
        #pragma unroll
        for (int i=0;i<4;++i)
          #pragma unroll
          for (int j=0;j<4;++j)
            acc[i][j] = fmaf(a[i], b[j], acc[i][j]);
      }
      __syncthreads();
    }
  }
  float f = 1.f;
  if (EPI == EPI_SMUL2) f = (float)sqrt(sqrt(scalp[0]));
  #pragma unroll
  for (int i=0;i<4;++i) {
    int gm = m0 + tm4 + i;
    if (gm >= M) continue;
    #pragma unroll
    for (int j=0;j<4;++j) {
      int gn = n0 + tn4 + j;
      if (gn >= Ncl) continue;
      float v = acc[i][j];
      long off = (long)gm*ldc + gn;
      if (EPI == EPI_BIAS)       C[off] = v + bias[gn];
      else if (EPI == EPI_MASK)  C[off] = (v != 0.f) ? 1.f : 0.f;
      else if (EPI == EPI_ACC)   unsafeAtomicAdd(&C[off], scale*v);
      else if (EPI == EPI_SCALE) C[off] = scale*v;
      else if (EPI == EPI_SMUL2){ C[off] = v*f; C2[off] = v*f; }
      else                       C[off] = v;
    }
  }
}

template<bool TRANSA, bool TRIUA, bool TRIUB, int EPI>
static inline void launch_gemm(hipStream_t st,
                               const float* A, int lda, const float* B, int ldb,
                               float* C, int ldc, int M, int Ncl, int K, int batch,
                               long sA, long sB, long sC, float scale,
                               const float* bias = nullptr,
                               float* C2 = nullptr, const double* scalp = nullptr)
{
  dim3 grid((M+63)/64, (Ncl+63)/64, batch);
  gemm_kernel<TRANSA,TRIUA,TRIUB,EPI><<<grid, 256, 0, st>>>(
      A,lda,B,ldb,C,ldc,M,Ncl,K,sA,sB,sC,scale,bias,C2,scalp);
}

// ---------------------------------------------------------------- small kernels
// t[n,f] = sum_e Y[(8+e)][n,f] + sum_e((1-a)*b0 + a*b1 + b2)[f]
__global__ void combine_root_kernel(const float* __restrict__ Y, const float* __restrict__ b,
                                    float* __restrict__ out){
  long idx = (long)blockIdx.x*256 + threadIdx.x;
  if (idx >= kNH) return;
  int f = (int)(idx % kH);
  float v = 0.f;
  #pragma unroll
  for (int e=0;e<4;++e) {
    v += Y[(long)(8+e)*kNH + idx];
    v += (1.f-kAl)*b[(0*4+e)*kH + f] + kAl*b[(1*4+e)*kH + f] + b[(2*4+e)*kH + f];
  }
  out[idx] = v;
}

// scatter messages: out[dst] += (1-a)*Min[src];  out[src] += a*Mout[dst]
__global__ __launch_bounds__(256)
void scatter_kernel(const int* __restrict__ e0, const int* __restrict__ e1,
                    const int* __restrict__ e2, const int* __restrict__ e3,
                    const float* __restrict__ Y, float* __restrict__ out){
  const int* eis[4] = {e0,e1,e2,e3};
  const int e = blockIdx.y;
  const int* ei = eis[e];
  long idx = (long)blockIdx.x*256 + threadIdx.x;
  if (idx >= (long)kNE*kH) return;
  int j = (int)(idx / kH), f = (int)(idx % kH);
  int s = ei[j], d = ei[kNE + j];
  float m_in  = Y[((long)e*kN + s)*kH + f];
  float m_out = Y[((long)(4+e)*kN + d)*kH + f];
  unsafeAtomicAdd(&out[(long)d*kH + f], (1.f-kAl)*m_in);
  unsafeAtomicAdd(&out[(long)s*kH + f], kAl*m_out);
}

__global__ void build_adj_kernel(const int* __restrict__ e0, const int* __restrict__ e1,
                                 const int* __restrict__ e2, const int* __restrict__ e3,
                                 float* __restrict__ A0){
  const int* eis[4] = {e0,e1,e2,e3};
  const int e = blockIdx.y;
  const int* ei = eis[e];
  int j = blockIdx.x*256 + threadIdx.x;
  if (j >= kNE) return;
  int s = ei[j], d = ei[kNE + j];
  A0[(long)e*kNN + (long)s*kN + d] = 1.0f;  // set (dup-safe), not add
}

// ---- deterministic two-stage (sum, sumsq) reduction
__global__ __launch_bounds__(256)
void reduce2_part_kernel(const float* __restrict__ x, long n, double* __restrict__ part){
  __shared__ double ss[256], qq[256];
  double s=0.0, q=0.0;
  for (long i = (long)blockIdx.x*256 + threadIdx.x; i < n; i += (long)gridDim.x*256){
    double v = x[i]; s += v; q += v*v;
  }
  ss[threadIdx.x]=s; qq[threadIdx.x]=q;
  __syncthreads();
  for (int h=128; h>0; h>>=1){
    if ((int)threadIdx.x < h){ ss[threadIdx.x]+=ss[threadIdx.x+h]; qq[threadIdx.x]+=qq[threadIdx.x+h]; }
    __syncthreads();
  }
  if (threadIdx.x==0){ part[2*blockIdx.x]=ss[0]; part[2*blockIdx.x+1]=qq[0]; }
}

__global__ __launch_bounds__(256)
void reduce2_fin_kernel(const double* __restrict__ part, int nb, double* __restrict__ out){
  __shared__ double ss[256], qq[256];
  double s=0.0, q=0.0;
  for (int i=threadIdx.x; i<nb; i+=256){ s += part[2*i]; q += part[2*i+1]; }
  ss[threadIdx.x]=s; qq[threadIdx.x]=q;
  __syncthreads();
  for (int h=128; h>0; h>>=1){
    if ((int)threadIdx.x < h){ ss[threadIdx.x]+=ss[threadIdx.x+h]; qq[threadIdx.x]+=qq[threadIdx.x+h]; }
    __syncthreads();
  }
  if (threadIdx.x==0){ out[0]=ss[0]; out[1]=qq[0]; }
}

// graph layernorm: y = (x-mu)*rsqrt(var+eps)*w[f] + b[f]   (mu/var over ALL N*H)
__global__ void apply_ln_kernel(const float* __restrict__ x, float* __restrict__ y,
                                const float* __restrict__ ln, const double* __restrict__ sc){
  long idx = (long)blockIdx.x*256 + threadIdx.x;
  if (idx >= kNH) return;
  int f = (int)(idx % kH);
  double mu  = sc[0] / (double)kNH;
  double var = sc[1] / (double)kNH - mu*mu;
  float rs = rsqrtf((float)var + kEps);
  y[idx] = (x[idx] - (float)mu) * rs * ln[f] + ln[kH + f];
}

// tri[i,j] = (i<=j) ? sigmoid(sum_k (z_i-z_j)^2 w_k + b) : 0
__global__ __launch_bounds__(256)
void pair_kernel(const float* __restrict__ z, const float* __restrict__ linW,
                 const float* __restrict__ linb, float* __restrict__ tri){
  __shared__ float zi[16][201], zj[16][201], w[208];
  const int i0 = blockIdx.y*16, j0 = blockIdx.x*16;
  const int tid = threadIdx.x;
  const int ti = tid >> 4, tj = tid & 15;
  const int i = i0+ti, j = j0+tj;
  if (i0 > j0 + 15) { tri[(long)i*kN + j] = 0.f; return; }  // fully lower block
  for (int idx = tid; idx < 16*kH; idx += 256){
    int r = idx / kH, c = idx % kH;
    zi[r][c] = z[(long)(i0+r)*kH + c];
    zj[r][c] = z[(long)(j0+r)*kH + c];
  }
  if (tid < kH) w[tid] = linW[tid];
  __syncthreads();
  float g = 0.f;
  if (i <= j){
    float s = linb[0];
    #pragma unroll 4
    for (int k=0;k<kH;++k){ float d = zi[ti][k]-zj[tj][k]; s = fmaf(d*d, w[k], s); }
    g = 1.f/(1.f + expf(-s));
  }
  tri[(long)i*kN + j] = g;
}

// papp = I - A/normA ; psq = P0*I + P1*papp ; qsq = Q0*I + Q1*papp
__global__ void init_pade_kernel(const float* __restrict__ tri, float* __restrict__ papp,
                                 float* __restrict__ psq, float* __restrict__ qsq,
                                 const double* __restrict__ frob2,
                                 float P0, float P1, float Q0, float Q1){
  int idx = blockIdx.x*256 + threadIdx.x;
  if (idx >= (int)kNN) return;
  int i = idx / kN, j = idx % kN;
  float rn = (float)(1.0 / sqrt(frob2[0]));
  float eye = (i==j) ? 1.f : 0.f;
  float pa = eye - tri[idx]*rn;
  papp[idx] = pa;
  psq[idx] = P0*eye + P1*pa;
  qsq[idx] = Q0*eye + Q1*pa;
}

__global__ void accpow_kernel(const float* __restrict__ pw, float* __restrict__ psq,
                              float* __restrict__ qsq, float pk, float qk){
  int idx = blockIdx.x*256 + threadIdx.x;
  if (idx >= (int)kNN) return;
  float v = pw[idx];
  psq[idx] += pk*v;
  qsq[idx] += qk*v;
}

// ---- invert the 8 diagonal 100x100 upper-tri blocks of U into W (W pre-zeroed)
__global__ __launch_bounds__(128)
void invdiag_kernel(const float* __restrict__ U, float* __restrict__ W){
  __shared__ float Us[kDB][kDB+1];
  __shared__ float Xs[kDB][kDB+1];
  const int base = blockIdx.x * kDB;
  const int tid = threadIdx.x;
  for (int idx = tid; idx < kDB*kDB; idx += 128){
    int r = idx / kDB, c = idx % kDB;
    Us[r][c] = U[(long)(base+r)*kN + base + c];
  }
  __syncthreads();
  const int c = tid;  // column of the inverse (active c < kDB)
  for (int i = kDB-1; i >= 0; --i){
    if (c < kDB){
      float x;
      if (c < i) x = 0.f;                 // inverse of upper-tri is upper-tri (exact)
      else {
        float s = 0.f;
        for (int k = i+1; k < kDB; ++k) s = fmaf(Us[i][k], Xs[k][c], s);
        x = (((c==i)?1.f:0.f) - s) / Us[i][i];
      }
      Xs[i][c] = x;
    }
    __syncthreads();
  }
  for (int idx = tid; idx < kDB*kDB; idx += 128){
    int r = idx / kDB, cc = idx % kDB;
    W[(long)(base+r)*kN + base + cc] = Xs[r][cc];
  }
}

// global mean pool + classifier + log_softmax
__global__ __launch_bounds__(256)
void pool_head_kernel(const float* __restrict__ z2, const float* __restrict__ W,
                      const float* __restrict__ b, float* __restrict__ out){
  __shared__ float x2[kH];
  __shared__ float lg[kNC];
  int t = threadIdx.x;
  if (t < kH){
    float s = 0.f;
    for (int n = 0; n < kN; ++n) s += z2[(long)n*kH + t];
    float v = s * (1.f/(float)kN);
    x2[t] = v;
    out[t] = v;
  }
  __syncthreads();
  if (t < kNC){
    float s = b[t];
    for (int f = 0; f < kH; ++f) s = fmaf(x2[f], W[f*kNC + t], s);
    lg[t] = s;
  }
  __syncthreads();
  if (t == 0){
    float m = -1e30f;
    for (int c=0;c<kNC;++c) m = fmaxf(m, lg[c]);
    float se = 0.f;
    for (int c=0;c<kNC;++c) se += expf(lg[c]-m);
    float lse = m + logf(se);
    for (int c=0;c<kNC;++c) out[kH + c] = lg[c]-lse;
  }
}

// ---------------------------------------------------------------- host: Pade [5/5] of sqrt(1-x)
static void pade_coeffs(float* P, float* Q){
  double b[11]; b[0] = 1.0;
  for (int k=1;k<11;++k) b[k] = b[k-1]*(0.5-(k-1))/k;
  double c[11];
  for (int k=0;k<11;++k) c[k] = b[k]*((k&1)?-1.0:1.0);
  double A[5][5], rhs[5];
  for (int i=0;i<5;++i){ for (int j=0;j<5;++j) A[i][j] = c[5+i-j]; rhs[i] = -c[6+i]; }
  for (int col=0; col<5; ++col){
    int p = col;
    for (int r=col+1;r<5;++r) if (fabs(A[r][col]) > fabs(A[p][col])) p = r;
    if (p != col){
      for (int j=0;j<5;++j){ double t=A[col][j]; A[col][j]=A[p][j]; A[p][j]=t; }
      double t=rhs[col]; rhs[col]=rhs[p]; rhs[p]=t;
    }
    for (int r=col+1;r<5;++r){
      double f = A[r][col]/A[col][col];
      for (int j=col;j<5;++j) A[r][j] -= f*A[col][j];
      rhs[r] -= f*rhs[col];
    }
  }
  double q[6]; q[0] = 1.0;
  for (int r=4;r>=0;--r){
    double s = rhs[r];
    for (int j=r+1;j<5;++j) s -= A[r][j]*q[1+j];
    q[1+r] = s/A[r][r];
  }
  double p[6];
  for (int k=0;k<6;++k){
    double s = 0.0; int jm = k<5?k:5;
    for (int j=0;j<=jm;++j) s += q[j]*c[k-j];
    p[k] = s;
  }
  for (int k=0;k<6;++k){ P[k]=(float)p[k]; Q[k]=(float)q[k]; }
}

// ---------------------------------------------------------------- launch
extern "C" void kernel_launch(void* const* d_in, const int* in_sizes, int n_in,
                              void* d_out, int out_size, void* d_ws, size_t ws_size,
                              hipStream_t stream)
{
  const float* x_note = (const float*)d_in[0];
  const float* embW   = (const float*)d_in[1];
  const float* embB   = (const float*)d_in[2];
  const float* g1w1   = (const float*)d_in[3];
  const float* g1b1   = (const float*)d_in[4];
  const float* g1w2   = (const float*)d_in[5];
  const float* g1b2   = (const float*)d_in[6];
  const float* g1ln   = (const float*)d_in[7];
  const float* g2w1   = (const float*)d_in[8];
  const float* g2b1   = (const float*)d_in[9];
  const float* g2w2   = (const float*)d_in[10];
  const float* g2b2   = (const float*)d_in[11];
  const float* g2ln   = (const float*)d_in[12];
  const float* linW   = (const float*)d_in[13];
  const float* linb   = (const float*)d_in[14];
  const float* clfW   = (const float*)d_in[15];
  const float* clfb   = (const float*)d_in[16];
  const int*  e0     = (const int*)d_in[17];
  const int*  e1     = (const int*)d_in[18];
  const int*  e2     = (const int*)d_in[19];
  const int*  e3     = (const int*)d_in[20];
  float* out = (float*)d_out;

  // workspace layout:
  // bytes 0..31        : scald[0..3]  (LN pair, frob pair)
  // bytes 512..8703    : reduction partials (kRB blocks x 2 doubles)
  // floats from o_h0   : tensors
  constexpr long o_h0   = 2176;
  constexpr long o_h1   = o_h0   + (long)kN*kE;
  constexpr long o_h2   = o_h1   + (long)kN*kE;
  constexpr long o_tnh  = o_h2   + (long)kN*kE;
  constexpr long o_zmid = o_tnh  + kNH;
  constexpr long o_z0   = o_zmid + kNH;
  constexpr long o_z1   = o_z0   + kNH;
  constexpr long o_z2   = o_z1   + kNH;
  constexpr long o_big  = o_z2   + kNH;             // union: Y (12*kNH) / T4 (4*kNN)
  constexpr long o_tri  = o_big  + 4*kNN;           // also: T scratch for trsm merges
  constexpr long o_papp = o_tri  + kNN;
  constexpr long o_pw1  = o_papp + kNN;             // also: W (triangular inverse)
  constexpr long o_psq  = o_pw1  + kNN;
  constexpr long o_qsq  = o_psq  + kNN;
  constexpr long o_S1   = o_qsq  + kNN;
  constexpr long o_S2   = o_S1   + kNN;
  constexpr long o_A0   = o_S2   + kNN;             // 4*kNN; reused as mask2
  constexpr long o_M1   = o_A0   + 4*kNN;           // 4*kNN
  constexpr long o_end  = o_M1   + 4*kNN;

  if (ws_size < (size_t)o_end*sizeof(float) || out_size < 215 + 2*(int)kNN || n_in < 21){
    fprintf(stderr, "kernel_launch guard: ws=%zu need=%zu out=%d need=%d n_in=%d\n",
            ws_size, (size_t)o_end*sizeof(float), out_size, (int)(215+2*kNN), n_in);
    hipMemsetAsync(d_out, 0, (size_t)out_size*sizeof(float), stream);
    return;
  }

  float* ws = (float*)d_ws;
  double* scald = (double*)d_ws;
  double* partd = (double*)((char*)d_ws + 512);
  float *h0=ws+o_h0, *h1=ws+o_h1, *h2=ws+o_h2, *tnh=ws+o_tnh,
        *zmid=ws+o_zmid, *z0=ws+o_z0, *z1=ws+o_z1, *z2=ws+o_z2, *big=ws+o_big,
        *tri=ws+o_tri, *papp=ws+o_papp, *pw1=ws+o_pw1, *psq=ws+o_psq, *qsq=ws+o_qsq,
        *S1=ws+o_S1, *S2=ws+o_S2, *A0=ws+o_A0, *M1=ws+o_M1;
  float* pw0 = tri;   // tri buffer reused as a power buffer after init_pade
  float* Winv = pw1;  // pw1 reused as triangular inverse after powers done
  float* Tm   = tri;  // merge scratch (free after powers done)

  float P[6], Q[6];
  pade_coeffs(P, Q);

  auto eg = [](long n){ return dim3((unsigned)((n+255)/256)); };

  auto reduce2 = [&](const float* src, long n, double* dst){
    reduce2_part_kernel<<<kRB,256,0,stream>>>(src, n, partd);
    reduce2_fin_kernel<<<1,256,0,stream>>>(partd, kRB, dst);
  };
  auto do_ln = [&](const float* src, float* dst, const float* lnp){
    reduce2(src, kNH, scald);
    apply_ln_kernel<<<eg(kNH),256,0,stream>>>(src, dst, lnp, scald);
  };
  auto sparse_layer = [&](const float* hin, int K, const float* W, const float* b,
                          const float* lnp, float* zout){
    launch_gemm<false,false,false,EPI_NONE>(stream, hin, K, W, kH, big, kH, kN, kH, K, 12,
                                            0, (long)K*kH, kNH, 0.f);
    combine_root_kernel<<<eg(kNH),256,0,stream>>>(big, b, tnh);
    scatter_kernel<<<dim3((unsigned)(((long)kNE*kH+255)/256),4),256,0,stream>>>(e0,e1,e2,e3, big, tnh);
    do_ln(tnh, zout, lnp);
  };
  auto dense_layer = [&](const float* hin, int K, const float* masks, const float* W,
                         const float* b, const float* lnp, float* zout){
    launch_gemm<false,false,false,EPI_NONE>(stream, hin, K, W, kH, big, kH, kN, kH, K, 12,
                                            0, (long)K*kH, kNH, 0.f);
    combine_root_kernel<<<eg(kNH),256,0,stream>>>(big, b, tnh);
    // t += (1-a) * mask^T @ Y[(0,e)] ;  t += a * mask @ Y[(1,e)]   (batched, atomic acc)
    launch_gemm<true ,false,false,EPI_ACC>(stream, masks, kN, big,       kH, tnh, kH, kN, kH, kN, 4,
                                           kNN, kNH, 0, 1.f-kAl);
    launch_gemm<false,false,false,EPI_ACC>(stream, masks, kN, big+4*kNH, kH, tnh, kH, kN, kH, kN, 4,
                                           kNN, kNH, 0, kAl);
    do_ln(tnh, zout, lnp);
  };
  // blocked triangular solve: S = (qsq^{-1} psq) * sqrt(normA), exactly upper-tri
  auto blocked_trsm = [&](float* Sdst, float* SoutDst){
    hipMemsetAsync(Winv, 0, (size_t)kNN*sizeof(float), stream);
    invdiag_kernel<<<dim3(kN/kDB),128,0,stream>>>(qsq, Winv);
    // recursive doubling: s = 100, 200, 400
    for (int s = kDB; s < kN; s *= 2){
      int npairs = kN / (2*s);
      long step = (long)2*s*kN + 2*s;          // diagonal advance between pairs
      // T_p = U[a:a+s, a+s:a+2s] @ Winv[a+s:, a+s:]   (B upper-tri)
      launch_gemm<false,false,true,EPI_NONE>(stream,
          qsq + (long)0*kN + s, kN, Winv + (long)s*kN + s, kN, Tm, s,
          s, s, s, npairs, step, step, (long)s*s, 0.f);
      // Winv[a:a+s, a+s:a+2s] = -Winv[a:,a:] @ T_p    (A upper-tri)
      launch_gemm<false,true,false,EPI_SCALE>(stream,
          Winv, kN, Tm, s, Winv + s, kN,
          s, s, s, npairs, step, (long)s*s, step, -1.f);
    }
    // S = Winv @ psq * fac ; also write to d_out region
    launch_gemm<false,true,true,EPI_SMUL2>(stream,
        Winv, kN, psq, kN, Sdst, kN, kN, kN, kN, 1, 0,0,0, 0.f,
        nullptr, SoutDst, scald+3);
  };
  auto run_pair_mpa = [&](const float* z, float* Sdst, float* SoutDst){
    pair_kernel<<<dim3(50,50),256,0,stream>>>(z, linW, linb, tri);
    reduce2(tri, kNN, scald+2);                                // scald[3] = ||A||_F^2
    init_pade_kernel<<<eg(kNN),256,0,stream>>>(tri, papp, psq, qsq, scald+3, P[0],P[1],Q[0],Q[1]);
    launch_gemm<false,true,true,EPI_NONE>(stream, papp, kN, papp, kN, pw0, kN, kN,kN,kN, 1, 0,0,0, 0.f);
    accpow_kernel<<<eg(kNN),256,0,stream>>>(pw0, psq, qsq, P[2],Q[2]);
    launch_gemm<false,true,true,EPI_NONE>(stream, pw0, kN, papp, kN, pw1, kN, kN,kN,kN, 1, 0,0,0, 0.f);
    accpow_kernel<<<eg(kNN),256,0,stream>>>(pw1, psq, qsq, P[3],Q[3]);
    launch_gemm<false,true,true,EPI_NONE>(stream, pw1, kN, papp, kN, pw0, kN, kN,kN,kN, 1, 0,0,0, 0.f);
    accpow_kernel<<<eg(kNN),256,0,stream>>>(pw0, psq, qsq, P[4],Q[4]);
    launch_gemm<false,true,true,EPI_NONE>(stream, pw0, kN, papp, kN, pw1, kN, kN,kN,kN, 1, 0,0,0, 0.f);
    accpow_kernel<<<eg(kNN),256,0,stream>>>(pw1, psq, qsq, P[5],Q[5]);
    blocked_trsm(Sdst, SoutDst);
  };

  // ---- embed
  launch_gemm<false,false,false,EPI_BIAS>(stream, x_note, kF, embW, kE, h0, kE, kN, kE, kF, 1,
                                          0,0,0, 0.f, embB);

  // ---- GNN1 (sparse)
  sparse_layer(h0,  kE, g1w1, g1b1, g1ln,        zmid);
  sparse_layer(zmid,kH, g1w2, g1b2, g1ln + 2*kH, z0);

  // ---- S1
  run_pair_mpa(z0, S1, out + 215);

  // ---- h1 = S1 @ h0
  launch_gemm<false,true,false,EPI_NONE>(stream, S1, kN, h0, kE, h1, kE, kN, kE, kN, 1, 0,0,0, 0.f);

  // ---- A0 adjacency + mask1 = (S1@A0)@S1 != 0
  hipMemsetAsync(A0, 0, (size_t)(4*kNN)*sizeof(float), stream);
  build_adj_kernel<<<dim3((kNE+255)/256,4),256,0,stream>>>(e0,e1,e2,e3, A0);
  launch_gemm<false,true ,false,EPI_NONE>(stream, S1, kN, A0, kN, big, kN, kN,kN,kN, 4, 0,  kNN, kNN, 0.f);
  launch_gemm<false,false,true ,EPI_MASK>(stream, big, kN, S1, kN, M1,  kN, kN,kN,kN, 4, kNN, 0,  kNN, 0.f);

  // ---- GNN2 #1 (dense, mask1)
  dense_layer(h1,  kE, M1, g2w1, g2b1, g2ln,        zmid);
  dense_layer(zmid,kH, M1, g2w2, g2b2, g2ln + 2*kH, z1);

  // ---- S2
  run_pair_mpa(z1, S2, out + 215 + kNN);

  // ---- h2 = S2 @ h1
  launch_gemm<false,true,false,EPI_NONE>(stream, S2, kN, h1, kE, h2, kE, kN, kE, kN, 1, 0,0,0, 0.f);

  // ---- mask2 = (S2@mask1)@S2 != 0  (into A0 region)
  launch_gemm<false,true ,false,EPI_NONE>(stream, S2, kN, M1, kN, big, kN, kN,kN,kN, 4, 0,  kNN, kNN, 0.f);
  launch_gemm<false,false,true ,EPI_MASK>(stream, big, kN, S2, kN, A0,  kN, kN,kN,kN, 4, kNN, 0,  kNN, 0.f);

  // ---- GNN2 #2 (dense, mask2)
  dense_layer(h2,  kE, A0, g2w1, g2b1, g2ln,        zmid);
  dense_layer(zmid,kH, A0, g2w2, g2b2, g2ln + 2*kH, z2);

  // ---- pool + classifier + log_softmax
  pool_head_kernel<<<dim3(1),256,0,stream>>>(z2, clfW, clfb, out);
}

// Round 6
// 2095.658 us; speedup vs baseline: 2.3664x; 1.8336x over previous
//
#include <hip/hip_runtime.h>
#include <hip/hip_bf16.h>
#include <math.h>
#include <stdio.h>

static constexpr int   kN  = 800;    // nodes
static constexpr int   kF  = 111;    // input features
static constexpr int   kE  = 32;     // embed dim
static constexpr int   kH  = 200;    // hidden
static constexpr int   kNC = 15;     // classes
static constexpr int   kNE = 8000;   // edges per type
static constexpr long  kNN = (long)kN*kN;   // 640000
static constexpr long  kNH = (long)kN*kH;   // 160000
static constexpr float kAl  = 0.5f;  // ALPHA
static constexpr float kEps = 1e-5f;
static constexpr int   kRB  = 512;   // reduction blocks
static constexpr int   kDB  = 100;   // trsm diagonal block size (800 = 8 * 100)

typedef unsigned short u16;
typedef __attribute__((ext_vector_type(8))) short short8;
typedef __attribute__((ext_vector_type(4))) float f32x4;

__device__ __forceinline__ u16 f2bf(float v){
  __hip_bfloat16 b = __float2bfloat16(v);
  return *reinterpret_cast<u16*>(&b);
}
__device__ __forceinline__ float bf2f(u16 h){
  unsigned int u = ((unsigned int)h) << 16;
  float f; __builtin_memcpy(&f, &u, 4);
  return f;
}

enum { EPI_NONE=0, EPI_BIAS=1, EPI_SCALE=4, EPI_SMUL2=5 };
enum { BEPI_NONE=0, BEPI_MASK=1, BEPI_ACC=2 };

// ---------------------------------------------------------------- fp32 GEMM
template<bool TRANSA, bool TRIUA, bool TRIUB, int EPI>
__global__ __launch_bounds__(256)
void gemm_kernel(const float* __restrict__ A, int lda,
                 const float* __restrict__ B, int ldb,
                 float* __restrict__ C, int ldc,
                 int M, int Ncl, int K,
                 long sA, long sB, long sC, float scale,
                 const float* __restrict__ bias,
                 u16* __restrict__ Cb, const double* __restrict__ scalp)
{
  constexpr int TM=64, TN=64, TK=16;
  A += (long)blockIdx.z * sA;
  B += (long)blockIdx.z * sB;
  C += (long)blockIdx.z * sC;
  __shared__ float As[TK][TM+4];
  __shared__ float Bs[TK][TN+4];
  const int tid = threadIdx.x;
  const int tn4 = (tid & 15)*4, tm4 = (tid >> 4)*4;
  const int m0 = blockIdx.x * TM, n0 = blockIdx.y * TN;
  float acc[4][4] = {};
  const bool skip = TRIUA && TRIUB && (m0 > n0 + TN - 1);
  int k0 = TRIUA ? m0 : 0;
  const int kEnd = TRIUB ? min(K, n0 + TN) : K;
  if (!skip) {
    for (; k0 < kEnd; k0 += TK) {
      #pragma unroll
      for (int u=0; u<4; ++u) {
        int idx = tid + 256*u;
        if (!TRANSA) {
          int m = idx >> 4, ka = idx & 15;
          int gm = m0+m, gk = k0+ka;
          As[ka][m] = (gm < M && gk < K) ? A[(long)gm*lda + gk] : 0.f;
        } else {
          int ka = idx >> 6, m = idx & 63;
          int gm = m0+m, gk = k0+ka;
          As[ka][m] = (gm < M && gk < K) ? A[(long)gk*lda + gm] : 0.f;
        }
        int kb = idx >> 6, nb = idx & 63;
        int gk = k0+kb, gn = n0+nb;
        Bs[kb][nb] = (gk < K && gn < Ncl) ? B[(long)gk*ldb + gn] : 0.f;
      }
      __syncthreads();
      #pragma unroll
      for (int kk=0; kk<TK; ++kk) {
        float a[4], b[4];
        #pragma unroll
        for (int u=0;u<4;++u){ a[u]=As[kk][tm4+u]; b[u]=Bs[kk][tn4+u]; }
        #pragma unroll
        for (int i=0;i<4;++i)
          #pragma unroll
          for (int j=0;j<4;++j)
            acc[i][j] = fmaf(a[i], b[j], acc[i][j]);
      }
      __syncthreads();
    }
  }
  float f = 1.f;
  if (EPI == EPI_SMUL2) f = (float)sqrt(sqrt(scalp[0]));
  #pragma unroll
  for (int i=0;i<4;++i) {
    int gm = m0 + tm4 + i;
    if (gm >= M) continue;
    #pragma unroll
    for (int j=0;j<4;++j) {
      int gn = n0 + tn4 + j;
      if (gn >= Ncl) continue;
      float v = acc[i][j];
      long off = (long)gm*ldc + gn;
      if (EPI == EPI_BIAS)       C[off] = v + bias[gn];
      else if (EPI == EPI_SCALE) C[off] = scale*v;
      else if (EPI == EPI_SMUL2){ float vf = v*f; C[off] = vf; Cb[off] = f2bf(vf); }
      else                       C[off] = v;
    }
  }
}

template<bool TRANSA, bool TRIUA, bool TRIUB, int EPI>
static inline void launch_gemm(hipStream_t st,
                               const float* A, int lda, const float* B, int ldb,
                               float* C, int ldc, int M, int Ncl, int K, int batch,
                               long sA, long sB, long sC, float scale,
                               const float* bias = nullptr,
                               u16* Cb = nullptr, const double* scalp = nullptr)
{
  dim3 grid((M+63)/64, (Ncl+63)/64, batch);
  gemm_kernel<TRANSA,TRIUA,TRIUB,EPI><<<grid, 256, 0, st>>>(
      A,lda,B,ldb,C,ldc,M,Ncl,K,sA,sB,sC,scale,bias,Cb,scalp);
}

// ---------------------------------------------------------------- bf16 MFMA GEMM (single)
// C[M,N] = A_bf[M,K] @ (Bt_bf[N,K])^T, fp32 accumulate.
template<bool TRIUA, bool TRIUB, int EPI>
__global__ __launch_bounds__(256)
void bgemm_kernel(const u16* __restrict__ A, int lda,
                  const u16* __restrict__ Bt, int ldb,
                  float* __restrict__ C, int ldc, u16* __restrict__ Cb,
                  int M, int N, int K,
                  long sA, long sB, long sC, float p0)
{
  constexpr int TM=64, TN=64, BK=32;
  A  += (long)blockIdx.z*sA;
  Bt += (long)blockIdx.z*sB;
  if (C)  C  += (long)blockIdx.z*sC;
  if (Cb) Cb += (long)blockIdx.z*sC;
  __shared__ u16 As[TM][40];
  __shared__ u16 Bs[TN][40];
  const int tid = threadIdx.x;
  const int m0 = blockIdx.x*TM, n0 = blockIdx.y*TN;
  const int w = tid>>6, lane = tid&63;
  const int wm = (w&1)*32, wn = (w>>1)*32;
  const int quad = lane>>4, lm = lane&15;
  f32x4 acc00={}, acc01={}, acc10={}, acc11={};
  const bool skip = TRIUA && TRIUB && (m0 > n0 + TN - 1);
  int k0 = TRIUA ? m0 : 0;
  const int kEnd = TRIUB ? min(K, n0+TN) : K;
  const int ar = tid>>2, ac = (tid&3)*8;
  if (!skip){
    for (; k0 < kEnd; k0 += BK){
      uint4 av = {0,0,0,0}, bv = {0,0,0,0};
      int gk = k0 + ac;
      if (m0+ar < M && gk < K) av = *(const uint4*)(A  + (long)(m0+ar)*lda + gk);
      if (n0+ar < N && gk < K) bv = *(const uint4*)(Bt + (long)(n0+ar)*ldb + gk);
      __syncthreads();
      *(uint4*)&As[ar][ac] = av;
      *(uint4*)&Bs[ar][ac] = bv;
      __syncthreads();
      short8 a0 = *(const short8*)&As[wm+lm][quad*8];
      short8 a1 = *(const short8*)&As[wm+16+lm][quad*8];
      short8 b0 = *(const short8*)&Bs[wn+lm][quad*8];
      short8 b1 = *(const short8*)&Bs[wn+16+lm][quad*8];
      acc00 = __builtin_amdgcn_mfma_f32_16x16x32_bf16(a0,b0,acc00,0,0,0);
      acc01 = __builtin_amdgcn_mfma_f32_16x16x32_bf16(a0,b1,acc01,0,0,0);
      acc10 = __builtin_amdgcn_mfma_f32_16x16x32_bf16(a1,b0,acc10,0,0,0);
      acc11 = __builtin_amdgcn_mfma_f32_16x16x32_bf16(a1,b1,acc11,0,0,0);
    }
  }
  f32x4 accs[2][2] = {{acc00, acc01},{acc10, acc11}};
  #pragma unroll
  for (int ti=0; ti<2; ++ti){
    #pragma unroll
    for (int tj=0; tj<2; ++tj){
      #pragma unroll
      for (int r=0; r<4; ++r){
        int gm = m0 + wm + ti*16 + quad*4 + r;
        int gn = n0 + wn + tj*16 + lm;
        if (gm >= M || gn >= N) continue;
        float v = accs[ti][tj][r];
        long off = (long)gm*ldc + gn;
        if (EPI == BEPI_MASK){ C[off] = (v!=0.f)?1.f:0.f; Cb[off] = (v!=0.f)?(u16)0x3F80:(u16)0; }
        else if (EPI == BEPI_ACC) unsafeAtomicAdd(&C[off], p0*v);
        else { if (C) C[off] = v; if (Cb) Cb[off] = f2bf(v); }
      }
    }
  }
}

template<bool TRIUA, bool TRIUB, int EPI>
static inline void launch_bgemm(hipStream_t st,
                                const u16* A, int lda, const u16* Bt, int ldb,
                                float* C, int ldc, u16* Cb,
                                int M, int N, int K, int batch,
                                long sA, long sB, long sC, float p0 = 0.f)
{
  dim3 grid((M+63)/64, (N+63)/64, batch);
  bgemm_kernel<TRIUA,TRIUB,EPI><<<grid, 256, 0, st>>>(
      A,lda,Bt,ldb,C,ldc,Cb,M,N,K,sA,sB,sC,p0);
}

// ---------------------------------------------------------------- split-bf16 MFMA GEMM (powers)
// v = (Ah+Al)[M,K] @ ((Bth+Btl)[N,K])^T dropping lo*lo  (~fp32 accuracy)
// psq += p0*v; qsq += p1*v; Oh/Ol = hi/lo split of v.   All matrices kN x kN,
// A and B^T upper-triangular (exact); lower blocks write exact zeros.
__global__ __launch_bounds__(256)
void bgemm2_kernel(const u16* __restrict__ Ah, const u16* __restrict__ Al,
                   const u16* __restrict__ Bh, const u16* __restrict__ Bl,
                   float* __restrict__ C, float* __restrict__ C2,
                   u16* __restrict__ Oh, u16* __restrict__ Ol,
                   float p0, float p1)
{
  constexpr int TM=64, TN=64, BK=32;
  __shared__ u16 Ash[TM][40], Asl[TM][40], Bsh[TN][40], Bsl[TN][40];
  const int tid = threadIdx.x;
  const int m0 = blockIdx.x*TM, n0 = blockIdx.y*TN;
  const int w = tid>>6, lane = tid&63;
  const int wm = (w&1)*32, wn = (w>>1)*32;
  const int quad = lane>>4, lm = lane&15;
  f32x4 acc00={}, acc01={}, acc10={}, acc11={};
  const bool skip = (m0 > n0 + TN - 1);
  int k0 = m0;
  const int kEnd = min(kN, n0+TN);
  const int ar = tid>>2, ac = (tid&3)*8;
  if (!skip){
    for (; k0 < kEnd; k0 += BK){
      uint4 avh={0,0,0,0}, avl={0,0,0,0}, bvh={0,0,0,0}, bvl={0,0,0,0};
      int gk = k0 + ac;
      if (m0+ar < kN && gk < kN){
        avh = *(const uint4*)(Ah + (long)(m0+ar)*kN + gk);
        avl = *(const uint4*)(Al + (long)(m0+ar)*kN + gk);
      }
      if (n0+ar < kN && gk < kN){
        bvh = *(const uint4*)(Bh + (long)(n0+ar)*kN + gk);
        bvl = *(const uint4*)(Bl + (long)(n0+ar)*kN + gk);
      }
      __syncthreads();
      *(uint4*)&Ash[ar][ac] = avh; *(uint4*)&Asl[ar][ac] = avl;
      *(uint4*)&Bsh[ar][ac] = bvh; *(uint4*)&Bsl[ar][ac] = bvl;
      __syncthreads();
      short8 a0h = *(const short8*)&Ash[wm+lm][quad*8];
      short8 a1h = *(const short8*)&Ash[wm+16+lm][quad*8];
      short8 a0l = *(const short8*)&Asl[wm+lm][quad*8];
      short8 a1l = *(const short8*)&Asl[wm+16+lm][quad*8];
      short8 b0h = *(const short8*)&Bsh[wn+lm][quad*8];
      short8 b1h = *(const short8*)&Bsh[wn+16+lm][quad*8];
      short8 b0l = *(const short8*)&Bsl[wn+lm][quad*8];
      short8 b1l = *(const short8*)&Bsl[wn+16+lm][quad*8];
      acc00 = __builtin_amdgcn_mfma_f32_16x16x32_bf16(a0h,b0h,acc00,0,0,0);
      acc00 = __builtin_amdgcn_mfma_f32_16x16x32_bf16(a0h,b0l,acc00,0,0,0);
      acc00 = __builtin_amdgcn_mfma_f32_16x16x32_bf16(a0l,b0h,acc00,0,0,0);
      acc01 = __builtin_amdgcn_mfma_f32_16x16x32_bf16(a0h,b1h,acc01,0,0,0);
      acc01 = __builtin_amdgcn_mfma_f32_16x16x32_bf16(a0h,b1l,acc01,0,0,0);
      acc01 = __builtin_amdgcn_mfma_f32_16x16x32_bf16(a0l,b1h,acc01,0,0,0);
      acc10 = __builtin_amdgcn_mfma_f32_16x16x32_bf16(a1h,b0h,acc10,0,0,0);
      acc10 = __builtin_amdgcn_mfma_f32_16x16x32_bf16(a1h,b0l,acc10,0,0,0);
      acc10 = __builtin_amdgcn_mfma_f32_16x16x32_bf16(a1l,b0h,acc10,0,0,0);
      acc11 = __builtin_amdgcn_mfma_f32_16x16x32_bf16(a1h,b1h,acc11,0,0,0);
      acc11 = __builtin_amdgcn_mfma_f32_16x16x32_bf16(a1h,b1l,acc11,0,0,0);
      acc11 = __builtin_amdgcn_mfma_f32_16x16x32_bf16(a1l,b1h,acc11,0,0,0);
    }
  }
  f32x4 accs[2][2] = {{acc00, acc01},{acc10, acc11}};
  #pragma unroll
  for (int ti=0; ti<2; ++ti){
    #pragma unroll
    for (int tj=0; tj<2; ++tj){
      #pragma unroll
      for (int r=0; r<4; ++r){
        int gm = m0 + wm + ti*16 + quad*4 + r;
        int gn = n0 + wn + tj*16 + lm;
        if (gm >= kN || gn >= kN) continue;
        float v = accs[ti][tj][r];
        long off = (long)gm*kN + gn;
        C[off]  += p0*v;
        C2[off] += p1*v;
        u16 h = f2bf(v);
        Oh[off] = h;
        Ol[off] = f2bf(v - bf2f(h));
      }
    }
  }
}

// ---- transpose fp32 -> bf16 (hi, optional lo): dst[c][r]; dst row length R
__global__ __launch_bounds__(256)
void transpose_bf_kernel(const float* __restrict__ src, int R, int Cc, long sS,
                         u16* __restrict__ dh, u16* __restrict__ dl, long sD)
{
  __shared__ float t[32][33];
  src += (long)blockIdx.z*sS;
  dh  += (long)blockIdx.z*sD;
  if (dl) dl += (long)blockIdx.z*sD;
  int r0 = blockIdx.y*32, c0 = blockIdx.x*32;
  int tr = threadIdx.x>>5, tc = threadIdx.x&31;
  for (int i=tr; i<32; i+=8){
    int r = r0+i, c = c0+tc;
    t[i][tc] = (r<R && c<Cc) ? src[(long)r*Cc + c] : 0.f;
  }
  __syncthreads();
  for (int i=tr; i<32; i+=8){
    int c = c0+i, r = r0+tc;
    if (c<Cc && r<R){
      float v = t[tc][i];
      u16 h = f2bf(v);
      dh[(long)c*R + r] = h;
      if (dl) dl[(long)c*R + r] = f2bf(v - bf2f(h));
    }
  }
}
static inline void launch_transpose(hipStream_t st, const float* src, int R, int Cc,
                                    long sS, u16* dh, u16* dl, long sD, int batch){
  dim3 grid((Cc+31)/32, (R+31)/32, batch);
  transpose_bf_kernel<<<grid, 256, 0, st>>>(src, R, Cc, sS, dh, dl, sD);
}

// ---------------------------------------------------------------- small kernels
__global__ void combine_root_kernel(const float* __restrict__ Y, const float* __restrict__ b,
                                    float* __restrict__ out){
  long idx = (long)blockIdx.x*256 + threadIdx.x;
  if (idx >= kNH) return;
  int f = (int)(idx % kH);
  float v = 0.f;
  #pragma unroll
  for (int e=0;e<4;++e) {
    v += Y[(long)(8+e)*kNH + idx];
    v += (1.f-kAl)*b[(0*4+e)*kH + f] + kAl*b[(1*4+e)*kH + f] + b[(2*4+e)*kH + f];
  }
  out[idx] = v;
}

__global__ __launch_bounds__(256)
void scatter_kernel(const int* __restrict__ e0, const int* __restrict__ e1,
                    const int* __restrict__ e2, const int* __restrict__ e3,
                    const float* __restrict__ Y, float* __restrict__ out){
  const int* eis[4] = {e0,e1,e2,e3};
  const int e = blockIdx.y;
  const int* ei = eis[e];
  long idx = (long)blockIdx.x*256 + threadIdx.x;
  if (idx >= (long)kNE*kH) return;
  int j = (int)(idx / kH), f = (int)(idx % kH);
  int s = ei[j], d = ei[kNE + j];
  float m_in  = Y[((long)e*kN + s)*kH + f];
  float m_out = Y[((long)(4+e)*kN + d)*kH + f];
  unsafeAtomicAdd(&out[(long)d*kH + f], (1.f-kAl)*m_in);
  unsafeAtomicAdd(&out[(long)s*kH + f], kAl*m_out);
}

// builds A0^T directly in bf16: A0t[e][d][s] = 1
__global__ void build_adj_kernel(const int* __restrict__ e0, const int* __restrict__ e1,
                                 const int* __restrict__ e2, const int* __restrict__ e3,
                                 u16* __restrict__ A0t){
  const int* eis[4] = {e0,e1,e2,e3};
  const int e = blockIdx.y;
  const int* ei = eis[e];
  int j = blockIdx.x*256 + threadIdx.x;
  if (j >= kNE) return;
  int s = ei[j], d = ei[kNE + j];
  A0t[(long)e*kNN + (long)d*kN + s] = (u16)0x3F80;
}

__global__ __launch_bounds__(256)
void reduce2_part_kernel(const float* __restrict__ x, long n, double* __restrict__ part){
  __shared__ double ss[256], qq[256];
  double s=0.0, q=0.0;
  for (long i = (long)blockIdx.x*256 + threadIdx.x; i < n; i += (long)gridDim.x*256){
    double v = x[i]; s += v; q += v*v;
  }
  ss[threadIdx.x]=s; qq[threadIdx.x]=q;
  __syncthreads();
  for (int h=128; h>0; h>>=1){
    if ((int)threadIdx.x < h){ ss[threadIdx.x]+=ss[threadIdx.x+h]; qq[threadIdx.x]+=qq[threadIdx.x+h]; }
    __syncthreads();
  }
  if (threadIdx.x==0){ part[2*blockIdx.x]=ss[0]; part[2*blockIdx.x+1]=qq[0]; }
}

__global__ __launch_bounds__(256)
void reduce2_fin_kernel(const double* __restrict__ part, int nb, double* __restrict__ out){
  __shared__ double ss[256], qq[256];
  double s=0.0, q=0.0;
  for (int i=threadIdx.x; i<nb; i+=256){ s += part[2*i]; q += part[2*i+1]; }
  ss[threadIdx.x]=s; qq[threadIdx.x]=q;
  __syncthreads();
  for (int h=128; h>0; h>>=1){
    if ((int)threadIdx.x < h){ ss[threadIdx.x]+=ss[threadIdx.x+h]; qq[threadIdx.x]+=qq[threadIdx.x+h]; }
    __syncthreads();
  }
  if (threadIdx.x==0){ out[0]=ss[0]; out[1]=qq[0]; }
}

__global__ void apply_ln_kernel(const float* __restrict__ x, float* __restrict__ y,
                                const float* __restrict__ ln, const double* __restrict__ sc){
  long idx = (long)blockIdx.x*256 + threadIdx.x;
  if (idx >= kNH) return;
  int f = (int)(idx % kH);
  double mu  = sc[0] / (double)kNH;
  double var = sc[1] / (double)kNH - mu*mu;
  float rs = rsqrtf((float)var + kEps);
  y[idx] = (x[idx] - (float)mu) * rs * ln[f] + ln[kH + f];
}

__global__ __launch_bounds__(256)
void pair_kernel(const float* __restrict__ z, const float* __restrict__ linW,
                 const float* __restrict__ linb, float* __restrict__ tri){
  __shared__ float zi[16][201], zj[16][201], w[208];
  const int i0 = blockIdx.y*16, j0 = blockIdx.x*16;
  const int tid = threadIdx.x;
  const int ti = tid >> 4, tj = tid & 15;
  const int i = i0+ti, j = j0+tj;
  if (i0 > j0 + 15) { tri[(long)i*kN + j] = 0.f; return; }
  for (int idx = tid; idx < 16*kH; idx += 256){
    int r = idx / kH, c = idx % kH;
    zi[r][c] = z[(long)(i0+r)*kH + c];
    zj[r][c] = z[(long)(j0+r)*kH + c];
  }
  if (tid < kH) w[tid] = linW[tid];
  __syncthreads();
  float g = 0.f;
  if (i <= j){
    float s = linb[0];
    #pragma unroll 4
    for (int k=0;k<kH;++k){ float d = zi[ti][k]-zj[tj][k]; s = fmaf(d*d, w[k], s); }
    g = 1.f/(1.f + expf(-s));
  }
  tri[(long)i*kN + j] = g;
}

__global__ void init_pade_kernel(const float* __restrict__ tri, float* __restrict__ papp,
                                 u16* __restrict__ papp_h, u16* __restrict__ papp_l,
                                 float* __restrict__ psq, float* __restrict__ qsq,
                                 const double* __restrict__ frob2,
                                 float P0, float P1, float Q0, float Q1){
  int idx = blockIdx.x*256 + threadIdx.x;
  if (idx >= (int)kNN) return;
  int i = idx / kN, j = idx % kN;
  float rn = (float)(1.0 / sqrt(frob2[0]));
  float eye = (i==j) ? 1.f : 0.f;
  float pa = eye - tri[idx]*rn;
  papp[idx] = pa;
  u16 h = f2bf(pa);
  papp_h[idx] = h;
  papp_l[idx] = f2bf(pa - bf2f(h));
  psq[idx] = P0*eye + P1*pa;
  qsq[idx] = Q0*eye + Q1*pa;
}

// ---- invert the 8 diagonal 100x100 upper-tri blocks of U into W (W pre-zeroed)
__global__ __launch_bounds__(128)
void invdiag_kernel(const float* __restrict__ U, float* __restrict__ W){
  __shared__ float Us[kDB][kDB+1];
  __shared__ float Xs[kDB][kDB+1];
  const int base = blockIdx.x * kDB;
  const int tid = threadIdx.x;
  for (int idx = tid; idx < kDB*kDB; idx += 128){
    int r = idx / kDB, c = idx % kDB;
    Us[r][c] = U[(long)(base+r)*kN + base + c];
  }
  __syncthreads();
  const int c = tid;
  for (int i = kDB-1; i >= 0; --i){
    if (c < kDB){
      float x;
      if (c < i) x = 0.f;
      else {
        float s = 0.f;
        for (int k = i+1; k < kDB; ++k) s = fmaf(Us[i][k], Xs[k][c], s);
        x = (((c==i)?1.f:0.f) - s) / Us[i][i];
      }
      Xs[i][c] = x;
    }
    __syncthreads();
  }
  for (int idx = tid; idx < kDB*kDB; idx += 128){
    int r = idx / kDB, cc = idx % kDB;
    W[(long)(base+r)*kN + base + cc] = Xs[r][cc];
  }
}

__global__ __launch_bounds__(256)
void pool_head_kernel(const float* __restrict__ z2, const float* __restrict__ W,
                      const float* __restrict__ b, float* __restrict__ out){
  __shared__ float x2[kH];
  __shared__ float lg[kNC];
  int t = threadIdx.x;
  if (t < kH){
    float s = 0.f;
    for (int n = 0; n < kN; ++n) s += z2[(long)n*kH + t];
    float v = s * (1.f/(float)kN);
    x2[t] = v;
    out[t] = v;
  }
  __syncthreads();
  if (t < kNC){
    float s = b[t];
    for (int f = 0; f < kH; ++f) s = fmaf(x2[f], W[f*kNC + t], s);
    lg[t] = s;
  }
  __syncthreads();
  if (t == 0){
    float m = -1e30f;
    for (int c=0;c<kNC;++c) m = fmaxf(m, lg[c]);
    float se = 0.f;
    for (int c=0;c<kNC;++c) se += expf(lg[c]-m);
    float lse = m + logf(se);
    for (int c=0;c<kNC;++c) out[kH + c] = lg[c]-lse;
  }
}

// ---------------------------------------------------------------- host: Pade [5/5] of sqrt(1-x)
static void pade_coeffs(float* P, float* Q){
  double b[11]; b[0] = 1.0;
  for (int k=1;k<11;++k) b[k] = b[k-1]*(0.5-(k-1))/k;
  double c[11];
  for (int k=0;k<11;++k) c[k] = b[k]*((k&1)?-1.0:1.0);
  double A[5][5], rhs[5];
  for (int i=0;i<5;++i){ for (int j=0;j<5;++j) A[i][j] = c[5+i-j]; rhs[i] = -c[6+i]; }
  for (int col=0; col<5; ++col){
    int p = col;
    for (int r=col+1;r<5;++r) if (fabs(A[r][col]) > fabs(A[p][col])) p = r;
    if (p != col){
      for (int j=0;j<5;++j){ double t=A[col][j]; A[col][j]=A[p][j]; A[p][j]=t; }
      double t=rhs[col]; rhs[col]=rhs[p]; rhs[p]=t;
    }
    for (int r=col+1;r<5;++r){
      double f = A[r][col]/A[col][col];
      for (int j=col;j<5;++j) A[r][j] -= f*A[col][j];
      rhs[r] -= f*rhs[col];
    }
  }
  double q[6]; q[0] = 1.0;
  for (int r=4;r>=0;--r){
    double s = rhs[r];
    for (int j=r+1;j<5;++j) s -= A[r][j]*q[1+j];
    q[1+r] = s/A[r][r];
  }
  double p[6];
  for (int k=0;k<6;++k){
    double s = 0.0; int jm = k<5?k:5;
    for (int j=0;j<=jm;++j) s += q[j]*c[k-j];
    p[k] = s;
  }
  for (int k=0;k<6;++k){ P[k]=(float)p[k]; Q[k]=(float)q[k]; }
}

// ---------------------------------------------------------------- launch
extern "C" void kernel_launch(void* const* d_in, const int* in_sizes, int n_in,
                              void* d_out, int out_size, void* d_ws, size_t ws_size,
                              hipStream_t stream)
{
  const float* x_note = (const float*)d_in[0];
  const float* embW   = (const float*)d_in[1];
  const float* embB   = (const float*)d_in[2];
  const float* g1w1   = (const float*)d_in[3];
  const float* g1b1   = (const float*)d_in[4];
  const float* g1w2   = (const float*)d_in[5];
  const float* g1b2   = (const float*)d_in[6];
  const float* g1ln   = (const float*)d_in[7];
  const float* g2w1   = (const float*)d_in[8];
  const float* g2b1   = (const float*)d_in[9];
  const float* g2w2   = (const float*)d_in[10];
  const float* g2b2   = (const float*)d_in[11];
  const float* g2ln   = (const float*)d_in[12];
  const float* linW   = (const float*)d_in[13];
  const float* linb   = (const float*)d_in[14];
  const float* clfW   = (const float*)d_in[15];
  const float* clfb   = (const float*)d_in[16];
  const int*  e0     = (const int*)d_in[17];
  const int*  e1     = (const int*)d_in[18];
  const int*  e2     = (const int*)d_in[19];
  const int*  e3     = (const int*)d_in[20];
  float* out = (float*)d_out;

  // fp32 region (float offsets)
  constexpr long o_h0   = 2176;
  constexpr long o_h1   = o_h0   + (long)kN*kE;
  constexpr long o_h2   = o_h1   + (long)kN*kE;
  constexpr long o_tnh  = o_h2   + (long)kN*kE;
  constexpr long o_zmid = o_tnh  + kNH;
  constexpr long o_z0   = o_zmid + kNH;
  constexpr long o_z1   = o_z0   + kNH;
  constexpr long o_z2   = o_z1   + kNH;
  constexpr long o_big  = o_z2   + kNH;             // 4*kNN floats, multi-purpose
  constexpr long o_tri  = o_big  + 4*kNN;           // tri / maskF (4*kNN span) / merge scratch
  constexpr long o_papp = o_tri  + kNN;
  constexpr long o_winv = o_papp + kNN;
  constexpr long o_psq  = o_winv + kNN;
  constexpr long o_qsq  = o_psq  + kNN;
  constexpr long o_us   = o_qsq  + kNN;
  // ushort offsets (u16 units)
  constexpr long u_S1b = 0;
  constexpr long u_S1t = u_S1b + kNN;
  constexpr long u_S2b = u_S1t + kNN;
  constexpr long u_S2t = u_S2b + kNN;
  constexpr long u_A0t = u_S2t + kNN;      // 4*kNN; reused as M2b
  constexpr long u_Tb  = u_A0t + 4*kNN;    // 4*kNN; reused as Yt_lo in dense phase
  constexpr long u_M1b = u_Tb  + 4*kNN;    // 4*kNN; reused as M2t
  constexpr long u_M1t = u_M1b + 4*kNN;    // 4*kNN
  constexpr long u_end = u_M1t + 4*kNN;
  constexpr long o_end = o_us + (u_end+1)/2;

  if (ws_size < (size_t)o_end*sizeof(float) || out_size < 215 + 2*(int)kNN || n_in < 21){
    fprintf(stderr, "kernel_launch guard: ws=%zu need=%zu out=%d need=%d n_in=%d\n",
            ws_size, (size_t)o_end*sizeof(float), out_size, (int)(215+2*kNN), n_in);
    hipMemsetAsync(d_out, 0, (size_t)out_size*sizeof(float), stream);
    return;
  }

  float* ws = (float*)d_ws;
  double* scald = (double*)d_ws;
  double* partd = (double*)((char*)d_ws + 512);
  float *h0=ws+o_h0, *h1=ws+o_h1, *h2=ws+o_h2, *tnh=ws+o_tnh,
        *zmid=ws+o_zmid, *z0=ws+o_z0, *z1=ws+o_z1, *z2=ws+o_z2, *big=ws+o_big,
        *tri=ws+o_tri, *papp=ws+o_papp, *winv=ws+o_winv, *psq=ws+o_psq, *qsq=ws+o_qsq;
  float* maskF = ws + o_tri;                  // 4*kNN span (tri..psq), dead at mask time
  u16* ub   = (u16*)(ws + o_us);
  u16* S1b  = ub + u_S1b;  u16* S1t = ub + u_S1t;
  u16* S2b  = ub + u_S2b;  u16* S2t = ub + u_S2t;
  u16* A0t  = ub + u_A0t;  u16* Tb  = ub + u_Tb;
  u16* M1b  = ub + u_M1b;  u16* M1t = ub + u_M1t;
  u16* M2b  = A0t;         u16* M2t = M1b;    // slot reuse
  // power-phase split scratch aliased inside big (8 planes x kNN u16 = 4*kNN floats)
  u16* papp_h = (u16*)big;
  u16* papp_l = papp_h + kNN;
  u16* pT_h   = papp_l + kNN;
  u16* pT_l   = pT_h + kNN;
  u16* pwA_h  = pT_l + kNN;
  u16* pwA_l  = pwA_h + kNN;
  u16* pwB_h  = pwA_l + kNN;
  u16* pwB_l  = pwB_h + kNN;
  // dense-phase: Y fp32 = big[0..12*kNH); Yt_hi in remaining 4*kNH floats; Yt_lo in Tb slot
  u16* Yt_h = (u16*)(big + 12*kNH);
  u16* Yt_l = Tb;

  float P[6], Q[6];
  pade_coeffs(P, Q);

  auto eg = [](long n){ return dim3((unsigned)((n+255)/256)); };

  auto reduce2 = [&](const float* src, long n, double* dst){
    reduce2_part_kernel<<<kRB,256,0,stream>>>(src, n, partd);
    reduce2_fin_kernel<<<1,256,0,stream>>>(partd, kRB, dst);
  };
  auto do_ln = [&](const float* src, float* dst, const float* lnp){
    reduce2(src, kNH, scald);
    apply_ln_kernel<<<eg(kNH),256,0,stream>>>(src, dst, lnp, scald);
  };
  auto sparse_layer = [&](const float* hin, int K, const float* W, const float* b,
                          const float* lnp, float* zout){
    launch_gemm<false,false,false,EPI_NONE>(stream, hin, K, W, kH, big, kH, kN, kH, K, 12,
                                            0, (long)K*kH, kNH, 0.f);
    combine_root_kernel<<<eg(kNH),256,0,stream>>>(big, b, tnh);
    scatter_kernel<<<dim3((unsigned)(((long)kNE*kH+255)/256),4),256,0,stream>>>(e0,e1,e2,e3, big, tnh);
    do_ln(tnh, zout, lnp);
  };
  auto dense_layer = [&](const float* hin, int K, const u16* mb, const u16* mtb,
                         const float* W, const float* b, const float* lnp, float* zout){
    launch_gemm<false,false,false,EPI_NONE>(stream, hin, K, W, kH, big, kH, kN, kH, K, 12,
                                            0, (long)K*kH, kNH, 0.f);
    combine_root_kernel<<<eg(kNH),256,0,stream>>>(big, b, tnh);
    launch_transpose(stream, big, kN, kH, kNH, Yt_h, Yt_l, kNH, 8);  // Yt[e][feat][node] hi/lo
    // x_in: tnh += 0.5 * mask^T @ (Y_hi + Y_lo)[e=0..3]
    launch_bgemm<false,false,BEPI_ACC>(stream, mtb, kN, Yt_h, kN, tnh, kH, nullptr,
                                       kN, kH, kN, 4, kNN, kNH, 0, 0.5f);
    launch_bgemm<false,false,BEPI_ACC>(stream, mtb, kN, Yt_l, kN, tnh, kH, nullptr,
                                       kN, kH, kN, 4, kNN, kNH, 0, 0.5f);
    // x_out: tnh += 0.5 * mask @ (Y_hi + Y_lo)[e=4..7]
    launch_bgemm<false,false,BEPI_ACC>(stream, mb, kN, Yt_h + 4*kNH, kN, tnh, kH, nullptr,
                                       kN, kH, kN, 4, kNN, kNH, 0, 0.5f);
    launch_bgemm<false,false,BEPI_ACC>(stream, mb, kN, Yt_l + 4*kNH, kN, tnh, kH, nullptr,
                                       kN, kH, kN, 4, kNN, kNH, 0, 0.5f);
    do_ln(tnh, zout, lnp);
  };
  auto blocked_trsm = [&](float* SoutDst, u16* Sb){
    hipMemsetAsync(winv, 0, (size_t)kNN*sizeof(float), stream);
    invdiag_kernel<<<dim3(kN/kDB),128,0,stream>>>(qsq, winv);
    for (int s = kDB; s < kN; s *= 2){
      int npairs = kN / (2*s);
      long step = (long)2*s*kN + 2*s;
      launch_gemm<false,false,true,EPI_NONE>(stream,
          qsq + s, kN, winv + (long)s*kN + s, kN, tri, s,
          s, s, s, npairs, step, step, (long)s*s, 0.f);
      launch_gemm<false,true,false,EPI_SCALE>(stream,
          winv, kN, tri, s, winv + s, kN,
          s, s, s, npairs, step, (long)s*s, step, -1.f);
    }
    launch_gemm<false,true,true,EPI_SMUL2>(stream,
        winv, kN, psq, kN, SoutDst, kN, kN, kN, kN, 1, 0,0,0, 0.f,
        nullptr, Sb, scald+3);
  };
  auto run_pair_mpa = [&](const float* z, float* SoutDst, u16* Sb, u16* St){
    pair_kernel<<<dim3(50,50),256,0,stream>>>(z, linW, linb, tri);
    reduce2(tri, kNN, scald+2);                                // scald[3] = ||A||_F^2
    init_pade_kernel<<<eg(kNN),256,0,stream>>>(tri, papp, papp_h, papp_l, psq, qsq, scald+3,
                                               P[0],P[1],Q[0],Q[1]);
    launch_transpose(stream, papp, kN, kN, 0, pT_h, pT_l, 0, 1);
    dim3 g13(13,13,1);
    bgemm2_kernel<<<g13,256,0,stream>>>(papp_h,papp_l, pT_h,pT_l, psq,qsq, pwA_h,pwA_l, P[2],Q[2]);
    bgemm2_kernel<<<g13,256,0,stream>>>(pwA_h,pwA_l,  pT_h,pT_l, psq,qsq, pwB_h,pwB_l, P[3],Q[3]);
    bgemm2_kernel<<<g13,256,0,stream>>>(pwB_h,pwB_l,  pT_h,pT_l, psq,qsq, pwA_h,pwA_l, P[4],Q[4]);
    bgemm2_kernel<<<g13,256,0,stream>>>(pwA_h,pwA_l,  pT_h,pT_l, psq,qsq, pwB_h,pwB_l, P[5],Q[5]);
    blocked_trsm(SoutDst, Sb);
    launch_transpose(stream, SoutDst, kN, kN, 0, St, nullptr, 0, 1);
  };

  // ---- embed
  launch_gemm<false,false,false,EPI_BIAS>(stream, x_note, kF, embW, kE, h0, kE, kN, kE, kF, 1,
                                          0,0,0, 0.f, embB);

  // ---- GNN1 (sparse)
  sparse_layer(h0,  kE, g1w1, g1b1, g1ln,        zmid);
  sparse_layer(zmid,kH, g1w2, g1b2, g1ln + 2*kH, z0);

  // ---- S1 (fp32 written into d_out region)
  float* S1f = out + 215;
  float* S2f = out + 215 + kNN;
  run_pair_mpa(z0, S1f, S1b, S1t);

  // ---- h1 = S1 @ h0  (fp32)
  launch_gemm<false,true,false,EPI_NONE>(stream, S1f, kN, h0, kE, h1, kE, kN, kE, kN, 1, 0,0,0, 0.f);

  // ---- mask1 = (S1@A0)@S1 != 0   (bf16 MFMA, pattern-exact)
  hipMemsetAsync(A0t, 0, (size_t)(4*kNN)*sizeof(u16), stream);
  build_adj_kernel<<<dim3((kNE+255)/256,4),256,0,stream>>>(e0,e1,e2,e3, A0t);
  launch_bgemm<true,false,BEPI_NONE>(stream, S1b, kN, A0t, kN, nullptr, kN, Tb,
                                     kN,kN,kN, 4, 0, kNN, kNN);
  launch_bgemm<false,true,BEPI_MASK>(stream, Tb, kN, S1t, kN, maskF, kN, M1b,
                                     kN,kN,kN, 4, kNN, 0, kNN);
  launch_transpose(stream, maskF, kN, kN, kNN, M1t, nullptr, kNN, 4);

  // ---- GNN2 #1 (dense, mask1)
  dense_layer(h1,  kE, M1b, M1t, g2w1, g2b1, g2ln,        zmid);
  dense_layer(zmid,kH, M1b, M1t, g2w2, g2b2, g2ln + 2*kH, z1);

  // ---- S2
  run_pair_mpa(z1, S2f, S2b, S2t);

  // ---- h2 = S2 @ h1  (fp32)
  launch_gemm<false,true,false,EPI_NONE>(stream, S2f, kN, h1, kE, h2, kE, kN, kE, kN, 1, 0,0,0, 0.f);

  // ---- mask2 = (S2@mask1)@S2 != 0
  launch_bgemm<true,false,BEPI_NONE>(stream, S2b, kN, M1t, kN, nullptr, kN, Tb,
                                     kN,kN,kN, 4, 0, kNN, kNN);
  launch_bgemm<false,true,BEPI_MASK>(stream, Tb, kN, S2t, kN, maskF, kN, M2b,
                                     kN,kN,kN, 4, kNN, 0, kNN);
  launch_transpose(stream, maskF, kN, kN, kNN, M2t, nullptr, kNN, 4);

  // ---- GNN2 #2 (dense, mask2)
  dense_layer(h2,  kE, M2b, M2t, g2w1, g2b1, g2ln,        zmid);
  dense_layer(zmid,kH, M2b, M2t, g2w2, g2b2, g2ln + 2*kH, z2);

  // ---- pool + classifier + log_softmax
  pool_head_kernel<<<dim3(1),256,0,stream>>>(z2, clfW, clfb, out);
}

// Round 7
// 1737.876 us; speedup vs baseline: 2.8536x; 1.2059x over previous
//
#include <hip/hip_runtime.h>
#include <hip/hip_bf16.h>
#include <math.h>
#include <stdio.h>

static constexpr int   kN  = 800;    // nodes
static constexpr int   kF  = 111;    // input features
static constexpr int   kE  = 32;     // embed dim
static constexpr int   kH  = 200;    // hidden
static constexpr int   kNC = 15;     // classes
static constexpr int   kNE = 8000;   // edges per type
static constexpr long  kNN = (long)kN*kN;   // 640000
static constexpr long  kNH = (long)kN*kH;   // 160000
static constexpr float kAl  = 0.5f;  // ALPHA
static constexpr float kEps = 1e-5f;
static constexpr int   kRB  = 512;   // reduction blocks
static constexpr int   kDB  = 100;   // trsm diagonal block size (800 = 8 * 100)

typedef unsigned short u16;
typedef __attribute__((ext_vector_type(8))) short short8;
typedef __attribute__((ext_vector_type(4))) float f32x4;

__device__ __forceinline__ u16 f2bf(float v){
  __hip_bfloat16 b = __float2bfloat16(v);
  return *reinterpret_cast<u16*>(&b);
}
__device__ __forceinline__ float bf2f(u16 h){
  unsigned int u = ((unsigned int)h) << 16;
  float f; __builtin_memcpy(&f, &u, 4);
  return f;
}

enum { EPI_NONE=0, EPI_BIAS=1, EPI_SCALE=4, EPI_ACC=6 };
enum { BEPI_NONE=0, BEPI_MASK=1, BEPI_ACC=2 };

// ---------------------------------------------------------------- fp32 GEMM
// C[M,N] = A * B, row strides lda/ldb/ldc.
// TRIUA: A[m,kglob]==0 for kglob<m (exact); TRIUB: B[kglob,n]==0 for kglob>n.
// kstep!=0: K-split mode — blockIdx.z selects a K-chunk; kbase=z*kstep is the
// global k offset of this chunk (A/B pre-offset via sA/sB); triangular clips
// use global coords. EPI_ACC: atomic C += scale*v (skip blocks return).
template<bool TRANSA, bool TRIUA, bool TRIUB, int EPI>
__global__ __launch_bounds__(256)
void gemm_kernel(const float* __restrict__ A, int lda,
                 const float* __restrict__ B, int ldb,
                 float* __restrict__ C, int ldc,
                 int M, int Ncl, int K,
                 long sA, long sB, long sC, float scale,
                 const float* __restrict__ bias, int kstep)
{
  constexpr int TM=64, TN=64, TK=16;
  A += (long)blockIdx.z * sA;
  B += (long)blockIdx.z * sB;
  C += (long)blockIdx.z * sC;
  __shared__ float As[TK][TM+4];
  __shared__ float Bs[TK][TN+4];
  const int tid = threadIdx.x;
  const int tn4 = (tid & 15)*4, tm4 = (tid >> 4)*4;
  const int m0 = blockIdx.x * TM, n0 = blockIdx.y * TN;
  float acc[4][4] = {};
  const int kbase = kstep ? (int)blockIdx.z * kstep : 0;
  int k0 = TRIUA ? max(m0 - kbase, 0) : 0;
  int kEnd = TRIUB ? min(K, n0 + TN - kbase) : K;
  const bool skip = (k0 >= kEnd);
  if (skip && EPI == EPI_ACC) return;
  if (!skip) {
    for (; k0 < kEnd; k0 += TK) {
      #pragma unroll
      for (int u=0; u<4; ++u) {
        int idx = tid + 256*u;
        if (!TRANSA) {
          int m = idx >> 4, ka = idx & 15;
          int gm = m0+m, gk = k0+ka;
          As[ka][m] = (gm < M && gk < K) ? A[(long)gm*lda + gk] : 0.f;
        } else {
          int ka = idx >> 6, m = idx & 63;
          int gm = m0+m, gk = k0+ka;
          As[ka][m] = (gm < M && gk < K) ? A[(long)gk*lda + gm] : 0.f;
        }
        int kb = idx >> 6, nb = idx & 63;
        int gk = k0+kb, gn = n0+nb;
        Bs[kb][nb] = (gk < K && gn < Ncl) ? B[(long)gk*ldb + gn] : 0.f;
      }
      __syncthreads();
      #pragma unroll
      for (int kk=0; kk<TK; ++kk) {
        float a[4], b[4];
        #pragma unroll
        for (int u=0;u<4;++u){ a[u]=As[kk][tm4+u]; b[u]=Bs[kk][tn4+u]; }
        #pragma unroll
        for (int i=0;i<4;++i)
          #pragma unroll
          for (int j=0;j<4;++j)
            acc[i][j] = fmaf(a[i], b[j], acc[i][j]);
      }
      __syncthreads();
    }
  }
  #pragma unroll
  for (int i=0;i<4;++i) {
    int gm = m0 + tm4 + i;
    if (gm >= M) continue;
    #pragma unroll
    for (int j=0;j<4;++j) {
      int gn = n0 + tn4 + j;
      if (gn >= Ncl) continue;
      float v = acc[i][j];
      long off = (long)gm*ldc + gn;
      if (EPI == EPI_BIAS)       C[off] = v + bias[gn];
      else if (EPI == EPI_SCALE) C[off] = scale*v;
      else if (EPI == EPI_ACC)   unsafeAtomicAdd(&C[off], scale*v);
      else                       C[off] = v;
    }
  }
}

template<bool TRANSA, bool TRIUA, bool TRIUB, int EPI>
static inline void launch_gemm(hipStream_t st,
                               const float* A, int lda, const float* B, int ldb,
                               float* C, int ldc, int M, int Ncl, int K, int batch,
                               long sA, long sB, long sC, float scale,
                               const float* bias = nullptr, int kstep = 0)
{
  dim3 grid((M+63)/64, (Ncl+63)/64, batch);
  gemm_kernel<TRANSA,TRIUA,TRIUB,EPI><<<grid, 256, 0, st>>>(
      A,lda,B,ldb,C,ldc,M,Ncl,K,sA,sB,sC,scale,bias,kstep);
}

// ---------------------------------------------------------------- bf16 MFMA GEMM (single)
template<bool TRIUA, bool TRIUB, int EPI>
__global__ __launch_bounds__(256)
void bgemm_kernel(const u16* __restrict__ A, int lda,
                  const u16* __restrict__ Bt, int ldb,
                  float* __restrict__ C, int ldc, u16* __restrict__ Cb,
                  int M, int N, int K,
                  long sA, long sB, long sC, float p0)
{
  constexpr int TM=64, TN=64, BK=32;
  A  += (long)blockIdx.z*sA;
  Bt += (long)blockIdx.z*sB;
  if (C)  C  += (long)blockIdx.z*sC;
  if (Cb) Cb += (long)blockIdx.z*sC;
  __shared__ u16 As[TM][40];
  __shared__ u16 Bs[TN][40];
  const int tid = threadIdx.x;
  const int m0 = blockIdx.x*TM, n0 = blockIdx.y*TN;
  const int w = tid>>6, lane = tid&63;
  const int wm = (w&1)*32, wn = (w>>1)*32;
  const int quad = lane>>4, lm = lane&15;
  f32x4 acc00={}, acc01={}, acc10={}, acc11={};
  const bool skip = TRIUA && TRIUB && (m0 > n0 + TN - 1);
  int k0 = TRIUA ? m0 : 0;
  const int kEnd = TRIUB ? min(K, n0+TN) : K;
  const int ar = tid>>2, ac = (tid&3)*8;
  if (!skip){
    for (; k0 < kEnd; k0 += BK){
      uint4 av = {0,0,0,0}, bv = {0,0,0,0};
      int gk = k0 + ac;
      if (m0+ar < M && gk < K) av = *(const uint4*)(A  + (long)(m0+ar)*lda + gk);
      if (n0+ar < N && gk < K) bv = *(const uint4*)(Bt + (long)(n0+ar)*ldb + gk);
      __syncthreads();
      *(uint4*)&As[ar][ac] = av;
      *(uint4*)&Bs[ar][ac] = bv;
      __syncthreads();
      short8 a0 = *(const short8*)&As[wm+lm][quad*8];
      short8 a1 = *(const short8*)&As[wm+16+lm][quad*8];
      short8 b0 = *(const short8*)&Bs[wn+lm][quad*8];
      short8 b1 = *(const short8*)&Bs[wn+16+lm][quad*8];
      acc00 = __builtin_amdgcn_mfma_f32_16x16x32_bf16(a0,b0,acc00,0,0,0);
      acc01 = __builtin_amdgcn_mfma_f32_16x16x32_bf16(a0,b1,acc01,0,0,0);
      acc10 = __builtin_amdgcn_mfma_f32_16x16x32_bf16(a1,b0,acc10,0,0,0);
      acc11 = __builtin_amdgcn_mfma_f32_16x16x32_bf16(a1,b1,acc11,0,0,0);
    }
  }
  f32x4 accs[2][2] = {{acc00, acc01},{acc10, acc11}};
  #pragma unroll
  for (int ti=0; ti<2; ++ti){
    #pragma unroll
    for (int tj=0; tj<2; ++tj){
      #pragma unroll
      for (int r=0; r<4; ++r){
        int gm = m0 + wm + ti*16 + quad*4 + r;
        int gn = n0 + wn + tj*16 + lm;
        if (gm >= M || gn >= N) continue;
        float v = accs[ti][tj][r];
        long off = (long)gm*ldc + gn;
        if (EPI == BEPI_MASK){ C[off] = (v!=0.f)?1.f:0.f; Cb[off] = (v!=0.f)?(u16)0x3F80:(u16)0; }
        else if (EPI == BEPI_ACC) unsafeAtomicAdd(&C[off], p0*v);
        else { if (C) C[off] = v; if (Cb) Cb[off] = f2bf(v); }
      }
    }
  }
}

template<bool TRIUA, bool TRIUB, int EPI>
static inline void launch_bgemm(hipStream_t st,
                                const u16* A, int lda, const u16* Bt, int ldb,
                                float* C, int ldc, u16* Cb,
                                int M, int N, int K, int batch,
                                long sA, long sB, long sC, float p0 = 0.f)
{
  dim3 grid((M+63)/64, (N+63)/64, batch);
  bgemm_kernel<TRIUA,TRIUB,EPI><<<grid, 256, 0, st>>>(
      A,lda,Bt,ldb,C,ldc,Cb,M,N,K,sA,sB,sC,p0);
}

// ---------------------------------------------------------------- bf16 MFMA, A exact, B split hi/lo, atomic ACC
// C += p0 * A[M,K] @ ((Bh+Bl)[N,K])^T
__global__ __launch_bounds__(256)
void bgemm_accs_kernel(const u16* __restrict__ A, int lda,
                       const u16* __restrict__ Bh, const u16* __restrict__ Bl, int ldb,
                       float* __restrict__ C, int ldc,
                       int M, int N, int K, long sA, long sB, float p0)
{
  constexpr int TM=64, TN=64, BK=32;
  A  += (long)blockIdx.z*sA;
  Bh += (long)blockIdx.z*sB;
  Bl += (long)blockIdx.z*sB;
  __shared__ u16 As[TM][40], Bsh[TN][40], Bsl[TN][40];
  const int tid = threadIdx.x;
  const int m0 = blockIdx.x*TM, n0 = blockIdx.y*TN;
  const int w = tid>>6, lane = tid&63;
  const int wm = (w&1)*32, wn = (w>>1)*32;
  const int quad = lane>>4, lm = lane&15;
  f32x4 acc00={}, acc01={}, acc10={}, acc11={};
  const int ar = tid>>2, ac = (tid&3)*8;
  for (int k0 = 0; k0 < K; k0 += BK){
    uint4 av={0,0,0,0}, bvh={0,0,0,0}, bvl={0,0,0,0};
    int gk = k0 + ac;
    if (m0+ar < M && gk < K) av = *(const uint4*)(A + (long)(m0+ar)*lda + gk);
    if (n0+ar < N && gk < K){
      bvh = *(const uint4*)(Bh + (long)(n0+ar)*ldb + gk);
      bvl = *(const uint4*)(Bl + (long)(n0+ar)*ldb + gk);
    }
    __syncthreads();
    *(uint4*)&As[ar][ac] = av;
    *(uint4*)&Bsh[ar][ac] = bvh;
    *(uint4*)&Bsl[ar][ac] = bvl;
    __syncthreads();
    short8 a0 = *(const short8*)&As[wm+lm][quad*8];
    short8 a1 = *(const short8*)&As[wm+16+lm][quad*8];
    short8 b0h = *(const short8*)&Bsh[wn+lm][quad*8];
    short8 b1h = *(const short8*)&Bsh[wn+16+lm][quad*8];
    short8 b0l = *(const short8*)&Bsl[wn+lm][quad*8];
    short8 b1l = *(const short8*)&Bsl[wn+16+lm][quad*8];
    acc00 = __builtin_amdgcn_mfma_f32_16x16x32_bf16(a0,b0h,acc00,0,0,0);
    acc00 = __builtin_amdgcn_mfma_f32_16x16x32_bf16(a0,b0l,acc00,0,0,0);
    acc01 = __builtin_amdgcn_mfma_f32_16x16x32_bf16(a0,b1h,acc01,0,0,0);
    acc01 = __builtin_amdgcn_mfma_f32_16x16x32_bf16(a0,b1l,acc01,0,0,0);
    acc10 = __builtin_amdgcn_mfma_f32_16x16x32_bf16(a1,b0h,acc10,0,0,0);
    acc10 = __builtin_amdgcn_mfma_f32_16x16x32_bf16(a1,b0l,acc10,0,0,0);
    acc11 = __builtin_amdgcn_mfma_f32_16x16x32_bf16(a1,b1h,acc11,0,0,0);
    acc11 = __builtin_amdgcn_mfma_f32_16x16x32_bf16(a1,b1l,acc11,0,0,0);
  }
  f32x4 accs[2][2] = {{acc00, acc01},{acc10, acc11}};
  #pragma unroll
  for (int ti=0; ti<2; ++ti){
    #pragma unroll
    for (int tj=0; tj<2; ++tj){
      #pragma unroll
      for (int r=0; r<4; ++r){
        int gm = m0 + wm + ti*16 + quad*4 + r;
        int gn = n0 + wn + tj*16 + lm;
        if (gm >= M || gn >= N) continue;
        unsafeAtomicAdd(&C[(long)gm*ldc + gn], p0*accs[ti][tj][r]);
      }
    }
  }
}

// ---------------------------------------------------------------- split-bf16 MFMA GEMM (powers)
__global__ __launch_bounds__(256)
void bgemm2_kernel(const u16* __restrict__ Ah, const u16* __restrict__ Al,
                   const u16* __restrict__ Bh, const u16* __restrict__ Bl,
                   float* __restrict__ C, float* __restrict__ C2,
                   u16* __restrict__ Oh, u16* __restrict__ Ol,
                   float p0, float p1)
{
  constexpr int TM=64, TN=64, BK=32;
  __shared__ u16 Ash[TM][40], Asl[TM][40], Bsh[TN][40], Bsl[TN][40];
  const int tid = threadIdx.x;
  const int m0 = blockIdx.x*TM, n0 = blockIdx.y*TN;
  const int w = tid>>6, lane = tid&63;
  const int wm = (w&1)*32, wn = (w>>1)*32;
  const int quad = lane>>4, lm = lane&15;
  f32x4 acc00={}, acc01={}, acc10={}, acc11={};
  const bool skip = (m0 > n0 + TN - 1);
  int k0 = m0;
  const int kEnd = min(kN, n0+TN);
  const int ar = tid>>2, ac = (tid&3)*8;
  if (!skip){
    for (; k0 < kEnd; k0 += BK){
      uint4 avh={0,0,0,0}, avl={0,0,0,0}, bvh={0,0,0,0}, bvl={0,0,0,0};
      int gk = k0 + ac;
      if (m0+ar < kN && gk < kN){
        avh = *(const uint4*)(Ah + (long)(m0+ar)*kN + gk);
        avl = *(const uint4*)(Al + (long)(m0+ar)*kN + gk);
      }
      if (n0+ar < kN && gk < kN){
        bvh = *(const uint4*)(Bh + (long)(n0+ar)*kN + gk);
        bvl = *(const uint4*)(Bl + (long)(n0+ar)*kN + gk);
      }
      __syncthreads();
      *(uint4*)&Ash[ar][ac] = avh; *(uint4*)&Asl[ar][ac] = avl;
      *(uint4*)&Bsh[ar][ac] = bvh; *(uint4*)&Bsl[ar][ac] = bvl;
      __syncthreads();
      short8 a0h = *(const short8*)&Ash[wm+lm][quad*8];
      short8 a1h = *(const short8*)&Ash[wm+16+lm][quad*8];
      short8 a0l = *(const short8*)&Asl[wm+lm][quad*8];
      short8 a1l = *(const short8*)&Asl[wm+16+lm][quad*8];
      short8 b0h = *(const short8*)&Bsh[wn+lm][quad*8];
      short8 b1h = *(const short8*)&Bsh[wn+16+lm][quad*8];
      short8 b0l = *(const short8*)&Bsl[wn+lm][quad*8];
      short8 b1l = *(const short8*)&Bsl[wn+16+lm][quad*8];
      acc00 = __builtin_amdgcn_mfma_f32_16x16x32_bf16(a0h,b0h,acc00,0,0,0);
      acc00 = __builtin_amdgcn_mfma_f32_16x16x32_bf16(a0h,b0l,acc00,0,0,0);
      acc00 = __builtin_amdgcn_mfma_f32_16x16x32_bf16(a0l,b0h,acc00,0,0,0);
      acc01 = __builtin_amdgcn_mfma_f32_16x16x32_bf16(a0h,b1h,acc01,0,0,0);
      acc01 = __builtin_amdgcn_mfma_f32_16x16x32_bf16(a0h,b1l,acc01,0,0,0);
      acc01 = __builtin_amdgcn_mfma_f32_16x16x32_bf16(a0l,b1h,acc01,0,0,0);
      acc10 = __builtin_amdgcn_mfma_f32_16x16x32_bf16(a1h,b0h,acc10,0,0,0);
      acc10 = __builtin_amdgcn_mfma_f32_16x16x32_bf16(a1h,b0l,acc10,0,0,0);
      acc10 = __builtin_amdgcn_mfma_f32_16x16x32_bf16(a1l,b0h,acc10,0,0,0);
      acc11 = __builtin_amdgcn_mfma_f32_16x16x32_bf16(a1h,b1h,acc11,0,0,0);
      acc11 = __builtin_amdgcn_mfma_f32_16x16x32_bf16(a1h,b1l,acc11,0,0,0);
      acc11 = __builtin_amdgcn_mfma_f32_16x16x32_bf16(a1l,b1h,acc11,0,0,0);
    }
  }
  f32x4 accs[2][2] = {{acc00, acc01},{acc10, acc11}};
  #pragma unroll
  for (int ti=0; ti<2; ++ti){
    #pragma unroll
    for (int tj=0; tj<2; ++tj){
      #pragma unroll
      for (int r=0; r<4; ++r){
        int gm = m0 + wm + ti*16 + quad*4 + r;
        int gn = n0 + wn + tj*16 + lm;
        if (gm >= kN || gn >= kN) continue;
        float v = accs[ti][tj][r];
        long off = (long)gm*kN + gn;
        C[off]  += p0*v;
        C2[off] += p1*v;
        u16 h = f2bf(v);
        Oh[off] = h;
        Ol[off] = f2bf(v - bf2f(h));
      }
    }
  }
}

// ---- transpose fp32 -> bf16 (hi, optional lo): dst[c][r]; dst row length R
__global__ __launch_bounds__(256)
void transpose_bf_kernel(const float* __restrict__ src, int R, int Cc, long sS,
                         u16* __restrict__ dh, u16* __restrict__ dl, long sD)
{
  __shared__ float t[32][33];
  src += (long)blockIdx.z*sS;
  dh  += (long)blockIdx.z*sD;
  if (dl) dl += (long)blockIdx.z*sD;
  int r0 = blockIdx.y*32, c0 = blockIdx.x*32;
  int tr = threadIdx.x>>5, tc = threadIdx.x&31;
  for (int i=tr; i<32; i+=8){
    int r = r0+i, c = c0+tc;
    t[i][tc] = (r<R && c<Cc) ? src[(long)r*Cc + c] : 0.f;
  }
  __syncthreads();
  for (int i=tr; i<32; i+=8){
    int c = c0+i, r = r0+tc;
    if (c<Cc && r<R){
      float v = t[tc][i];
      u16 h = f2bf(v);
      dh[(long)c*R + r] = h;
      if (dl) dl[(long)c*R + r] = f2bf(v - bf2f(h));
    }
  }
}
static inline void launch_transpose(hipStream_t st, const float* src, int R, int Cc,
                                    long sS, u16* dh, u16* dl, long sD, int batch){
  dim3 grid((Cc+31)/32, (R+31)/32, batch);
  transpose_bf_kernel<<<grid, 256, 0, st>>>(src, R, Cc, sS, dh, dl, sD);
}

// ---- final S epilogue: S = acc*fac -> out fp32, Sb bf16, St bf16-transposed
__global__ __launch_bounds__(256)
void s_final_kernel(const float* __restrict__ acc, const double* __restrict__ frob2,
                    float* __restrict__ outf, u16* __restrict__ Sb, u16* __restrict__ St)
{
  __shared__ float t[32][33];
  const float fac = (float)sqrt(sqrt(frob2[0]));
  int r0 = blockIdx.y*32, c0 = blockIdx.x*32;
  int tr = threadIdx.x>>5, tc = threadIdx.x&31;
  for (int i=tr; i<32; i+=8){
    int r = r0+i, c = c0+tc;
    float v = acc[(long)r*kN + c] * fac;
    t[i][tc] = v;
    outf[(long)r*kN + c] = v;
    Sb[(long)r*kN + c] = f2bf(v);
  }
  __syncthreads();
  for (int i=tr; i<32; i+=8){
    int c = c0+i, r = r0+tc;
    St[(long)c*kN + r] = f2bf(t[tc][i]);
  }
}

// ---------------------------------------------------------------- small kernels
__global__ void combine_root_kernel(const float* __restrict__ Y, const float* __restrict__ b,
                                    float* __restrict__ out){
  long idx = (long)blockIdx.x*256 + threadIdx.x;
  if (idx >= kNH) return;
  int f = (int)(idx % kH);
  float v = 0.f;
  #pragma unroll
  for (int e=0;e<4;++e) {
    v += Y[(long)(8+e)*kNH + idx];
    v += (1.f-kAl)*b[(0*4+e)*kH + f] + kAl*b[(1*4+e)*kH + f] + b[(2*4+e)*kH + f];
  }
  out[idx] = v;
}

__global__ __launch_bounds__(256)
void scatter_kernel(const int* __restrict__ e0, const int* __restrict__ e1,
                    const int* __restrict__ e2, const int* __restrict__ e3,
                    const float* __restrict__ Y, float* __restrict__ out){
  const int* eis[4] = {e0,e1,e2,e3};
  const int e = blockIdx.y;
  const int* ei = eis[e];
  long idx = (long)blockIdx.x*256 + threadIdx.x;
  if (idx >= (long)kNE*kH) return;
  int j = (int)(idx / kH), f = (int)(idx % kH);
  int s = ei[j], d = ei[kNE + j];
  float m_in  = Y[((long)e*kN + s)*kH + f];
  float m_out = Y[((long)(4+e)*kN + d)*kH + f];
  unsafeAtomicAdd(&out[(long)d*kH + f], (1.f-kAl)*m_in);
  unsafeAtomicAdd(&out[(long)s*kH + f], kAl*m_out);
}

// builds A0^T directly in bf16: A0t[e][d][s] = 1
__global__ void build_adj_kernel(const int* __restrict__ e0, const int* __restrict__ e1,
                                 const int* __restrict__ e2, const int* __restrict__ e3,
                                 u16* __restrict__ A0t){
  const int* eis[4] = {e0,e1,e2,e3};
  const int e = blockIdx.y;
  const int* ei = eis[e];
  int j = blockIdx.x*256 + threadIdx.x;
  if (j >= kNE) return;
  int s = ei[j], d = ei[kNE + j];
  A0t[(long)e*kNN + (long)d*kN + s] = (u16)0x3F80;
}

__global__ __launch_bounds__(256)
void reduce2_part_kernel(const float* __restrict__ x, long n, double* __restrict__ part){
  __shared__ double ss[256], qq[256];
  double s=0.0, q=0.0;
  for (long i = (long)blockIdx.x*256 + threadIdx.x; i < n; i += (long)gridDim.x*256){
    double v = x[i]; s += v; q += v*v;
  }
  ss[threadIdx.x]=s; qq[threadIdx.x]=q;
  __syncthreads();
  for (int h=128; h>0; h>>=1){
    if ((int)threadIdx.x < h){ ss[threadIdx.x]+=ss[threadIdx.x+h]; qq[threadIdx.x]+=qq[threadIdx.x+h]; }
    __syncthreads();
  }
  if (threadIdx.x==0){ part[2*blockIdx.x]=ss[0]; part[2*blockIdx.x+1]=qq[0]; }
}

__global__ __launch_bounds__(256)
void reduce2_fin_kernel(const double* __restrict__ part, int nb, double* __restrict__ out){
  __shared__ double ss[256], qq[256];
  double s=0.0, q=0.0;
  for (int i=threadIdx.x; i<nb; i+=256){ s += part[2*i]; q += part[2*i+1]; }
  ss[threadIdx.x]=s; qq[threadIdx.x]=q;
  __syncthreads();
  for (int h=128; h>0; h>>=1){
    if ((int)threadIdx.x < h){ ss[threadIdx.x]+=ss[threadIdx.x+h]; qq[threadIdx.x]+=qq[threadIdx.x+h]; }
    __syncthreads();
  }
  if (threadIdx.x==0){ out[0]=ss[0]; out[1]=qq[0]; }
}

__global__ void apply_ln_kernel(const float* __restrict__ x, float* __restrict__ y,
                                const float* __restrict__ ln, const double* __restrict__ sc){
  long idx = (long)blockIdx.x*256 + threadIdx.x;
  if (idx >= kNH) return;
  int f = (int)(idx % kH);
  double mu  = sc[0] / (double)kNH;
  double var = sc[1] / (double)kNH - mu*mu;
  float rs = rsqrtf((float)var + kEps);
  y[idx] = (x[idx] - (float)mu) * rs * ln[f] + ln[kH + f];
}

__global__ __launch_bounds__(256)
void pair_kernel(const float* __restrict__ z, const float* __restrict__ linW,
                 const float* __restrict__ linb, float* __restrict__ tri){
  __shared__ float zi[16][201], zj[16][201], w[208];
  const int i0 = blockIdx.y*16, j0 = blockIdx.x*16;
  const int tid = threadIdx.x;
  const int ti = tid >> 4, tj = tid & 15;
  const int i = i0+ti, j = j0+tj;
  if (i0 > j0 + 15) { tri[(long)i*kN + j] = 0.f; return; }
  for (int idx = tid; idx < 16*kH; idx += 256){
    int r = idx / kH, c = idx % kH;
    zi[r][c] = z[(long)(i0+r)*kH + c];
    zj[r][c] = z[(long)(j0+r)*kH + c];
  }
  if (tid < kH) w[tid] = linW[tid];
  __syncthreads();
  float g = 0.f;
  if (i <= j){
    float s = linb[0];
    #pragma unroll 4
    for (int k=0;k<kH;++k){ float d = zi[ti][k]-zj[tj][k]; s = fmaf(d*d, w[k], s); }
    g = 1.f/(1.f + expf(-s));
  }
  tri[(long)i*kN + j] = g;
}

__global__ void init_pade_kernel(const float* __restrict__ tri, float* __restrict__ papp,
                                 u16* __restrict__ papp_h, u16* __restrict__ papp_l,
                                 float* __restrict__ psq, float* __restrict__ qsq,
                                 const double* __restrict__ frob2,
                                 float P0, float P1, float Q0, float Q1){
  int idx = blockIdx.x*256 + threadIdx.x;
  if (idx >= (int)kNN) return;
  int i = idx / kN, j = idx % kN;
  float rn = (float)(1.0 / sqrt(frob2[0]));
  float eye = (i==j) ? 1.f : 0.f;
  float pa = eye - tri[idx]*rn;
  papp[idx] = pa;
  u16 h = f2bf(pa);
  papp_h[idx] = h;
  papp_l[idx] = f2bf(pa - bf2f(h));
  psq[idx] = P0*eye + P1*pa;
  qsq[idx] = Q0*eye + Q1*pa;
}

// ---- invert the 8 diagonal 100x100 upper-tri blocks of U into W (W pre-zeroed)
__global__ __launch_bounds__(128)
void invdiag_kernel(const float* __restrict__ U, float* __restrict__ W){
  __shared__ float Us[kDB][kDB+1];
  __shared__ float Xs[kDB][kDB+1];
  const int base = blockIdx.x * kDB;
  const int tid = threadIdx.x;
  for (int idx = tid; idx < kDB*kDB; idx += 128){
    int r = idx / kDB, c = idx % kDB;
    Us[r][c] = U[(long)(base+r)*kN + base + c];
  }
  __syncthreads();
  const int c = tid;
  for (int i = kDB-1; i >= 0; --i){
    if (c < kDB){
      float x;
      if (c < i) x = 0.f;
      else {
        float s = 0.f;
        for (int k = i+1; k < kDB; ++k) s = fmaf(Us[i][k], Xs[k][c], s);
        x = (((c==i)?1.f:0.f) - s) / Us[i][i];
      }
      Xs[i][c] = x;
    }
    __syncthreads();
  }
  for (int idx = tid; idx < kDB*kDB; idx += 128){
    int r = idx / kDB, cc = idx % kDB;
    W[(long)(base+r)*kN + base + cc] = Xs[r][cc];
  }
}

__global__ __launch_bounds__(256)
void pool_head_kernel(const float* __restrict__ z2, const float* __restrict__ W,
                      const float* __restrict__ b, float* __restrict__ out){
  __shared__ float x2[kH];
  __shared__ float lg[kNC];
  int t = threadIdx.x;
  if (t < kH){
    float s = 0.f;
    for (int n = 0; n < kN; ++n) s += z2[(long)n*kH + t];
    float v = s * (1.f/(float)kN);
    x2[t] = v;
    out[t] = v;
  }
  __syncthreads();
  if (t < kNC){
    float s = b[t];
    for (int f = 0; f < kH; ++f) s = fmaf(x2[f], W[f*kNC + t], s);
    lg[t] = s;
  }
  __syncthreads();
  if (t == 0){
    float m = -1e30f;
    for (int c=0;c<kNC;++c) m = fmaxf(m, lg[c]);
    float se = 0.f;
    for (int c=0;c<kNC;++c) se += expf(lg[c]-m);
    float lse = m + logf(se);
    for (int c=0;c<kNC;++c) out[kH + c] = lg[c]-lse;
  }
}

// ---------------------------------------------------------------- host: Pade [5/5] of sqrt(1-x)
static void pade_coeffs(float* P, float* Q){
  double b[11]; b[0] = 1.0;
  for (int k=1;k<11;++k) b[k] = b[k-1]*(0.5-(k-1))/k;
  double c[11];
  for (int k=0;k<11;++k) c[k] = b[k]*((k&1)?-1.0:1.0);
  double A[5][5], rhs[5];
  for (int i=0;i<5;++i){ for (int j=0;j<5;++j) A[i][j] = c[5+i-j]; rhs[i] = -c[6+i]; }
  for (int col=0; col<5; ++col){
    int p = col;
    for (int r=col+1;r<5;++r) if (fabs(A[r][col]) > fabs(A[p][col])) p = r;
    if (p != col){
      for (int j=0;j<5;++j){ double t=A[col][j]; A[col][j]=A[p][j]; A[p][j]=t; }
      double t=rhs[col]; rhs[col]=rhs[p]; rhs[p]=t;
    }
    for (int r=col+1;r<5;++r){
      double f = A[r][col]/A[col][col];
      for (int j=col;j<5;++j) A[r][j] -= f*A[col][j];
      rhs[r] -= f*rhs[col];
    }
  }
  double q[6]; q[0] = 1.0;
  for (int r=4;r>=0;--r){
    double s = rhs[r];
    for (int j=r+1;j<5;++j) s -= A[r][j]*q[1+j];
    q[1+r] = s/A[r][r];
  }
  double p[6];
  for (int k=0;k<6;++k){
    double s = 0.0; int jm = k<5?k:5;
    for (int j=0;j<=jm;++j) s += q[j]*c[k-j];
    p[k] = s;
  }
  for (int k=0;k<6;++k){ P[k]=(float)p[k]; Q[k]=(float)q[k]; }
}

// ---------------------------------------------------------------- launch
extern "C" void kernel_launch(void* const* d_in, const int* in_sizes, int n_in,
                              void* d_out, int out_size, void* d_ws, size_t ws_size,
                              hipStream_t stream)
{
  const float* x_note = (const float*)d_in[0];
  const float* embW   = (const float*)d_in[1];
  const float* embB   = (const float*)d_in[2];
  const float* g1w1   = (const float*)d_in[3];
  const float* g1b1   = (const float*)d_in[4];
  const float* g1w2   = (const float*)d_in[5];
  const float* g1b2   = (const float*)d_in[6];
  const float* g1ln   = (const float*)d_in[7];
  const float* g2w1   = (const float*)d_in[8];
  const float* g2b1   = (const float*)d_in[9];
  const float* g2w2   = (const float*)d_in[10];
  const float* g2b2   = (const float*)d_in[11];
  const float* g2ln   = (const float*)d_in[12];
  const float* linW   = (const float*)d_in[13];
  const float* linb   = (const float*)d_in[14];
  const float* clfW   = (const float*)d_in[15];
  const float* clfb   = (const float*)d_in[16];
  const int*  e0     = (const int*)d_in[17];
  const int*  e1     = (const int*)d_in[18];
  const int*  e2     = (const int*)d_in[19];
  const int*  e3     = (const int*)d_in[20];
  float* out = (float*)d_out;

  // fp32 region (float offsets)
  constexpr long o_h0   = 2176;
  constexpr long o_h1   = o_h0   + (long)kN*kE;
  constexpr long o_h2   = o_h1   + (long)kN*kE;
  constexpr long o_tnh  = o_h2   + (long)kN*kE;
  constexpr long o_zmid = o_tnh  + kNH;
  constexpr long o_z0   = o_zmid + kNH;
  constexpr long o_z1   = o_z0   + kNH;
  constexpr long o_z2   = o_z1   + kNH;
  constexpr long o_big  = o_z2   + kNH;             // 4*kNN floats, multi-purpose
  constexpr long o_tri  = o_big  + 4*kNN;           // tri / maskF (4*kNN span) / merge scratch
  constexpr long o_papp = o_tri  + kNN;             // also: S accumulator in blocked_trsm
  constexpr long o_winv = o_papp + kNN;
  constexpr long o_psq  = o_winv + kNN;
  constexpr long o_qsq  = o_psq  + kNN;
  constexpr long o_us   = o_qsq  + kNN;
  // ushort offsets (u16 units)
  constexpr long u_S1b = 0;
  constexpr long u_S1t = u_S1b + kNN;
  constexpr long u_S2b = u_S1t + kNN;
  constexpr long u_S2t = u_S2b + kNN;
  constexpr long u_A0t = u_S2t + kNN;      // 4*kNN; reused as M2b
  constexpr long u_Tb  = u_A0t + 4*kNN;    // 4*kNN; reused as Yt_lo in dense phase
  constexpr long u_M1b = u_Tb  + 4*kNN;    // 4*kNN; reused as M2t
  constexpr long u_M1t = u_M1b + 4*kNN;    // 4*kNN
  constexpr long u_end = u_M1t + 4*kNN;
  constexpr long o_end = o_us + (u_end+1)/2;

  if (ws_size < (size_t)o_end*sizeof(float) || out_size < 215 + 2*(int)kNN || n_in < 21){
    fprintf(stderr, "kernel_launch guard: ws=%zu need=%zu out=%d need=%d n_in=%d\n",
            ws_size, (size_t)o_end*sizeof(float), out_size, (int)(215+2*kNN), n_in);
    hipMemsetAsync(d_out, 0, (size_t)out_size*sizeof(float), stream);
    return;
  }

  float* ws = (float*)d_ws;
  double* scald = (double*)d_ws;
  double* partd = (double*)((char*)d_ws + 512);
  float *h0=ws+o_h0, *h1=ws+o_h1, *h2=ws+o_h2, *tnh=ws+o_tnh,
        *zmid=ws+o_zmid, *z0=ws+o_z0, *z1=ws+o_z1, *z2=ws+o_z2, *big=ws+o_big,
        *tri=ws+o_tri, *papp=ws+o_papp, *winv=ws+o_winv, *psq=ws+o_psq, *qsq=ws+o_qsq;
  float* maskF = ws + o_tri;                  // 4*kNN span (tri..psq), dead at mask time
  float* Sacc  = papp;                        // papp fp32 is dead after pT transpose
  u16* ub   = (u16*)(ws + o_us);
  u16* S1b  = ub + u_S1b;  u16* S1t = ub + u_S1t;
  u16* S2b  = ub + u_S2b;  u16* S2t = ub + u_S2t;
  u16* A0t  = ub + u_A0t;  u16* Tb  = ub + u_Tb;
  u16* M1b  = ub + u_M1b;  u16* M1t = ub + u_M1t;
  u16* M2b  = A0t;         u16* M2t = M1b;    // slot reuse
  // power-phase split scratch aliased inside big (8 planes x kNN u16 = 4*kNN floats)
  u16* papp_h = (u16*)big;
  u16* papp_l = papp_h + kNN;
  u16* pT_h   = papp_l + kNN;
  u16* pT_l   = pT_h + kNN;
  u16* pwA_h  = pT_l + kNN;
  u16* pwA_l  = pwA_h + kNN;
  u16* pwB_h  = pwA_l + kNN;
  u16* pwB_l  = pwB_h + kNN;
  // dense-phase: Y fp32 = big[0..12*kNH); Yt_hi in remaining 4*kNH floats; Yt_lo in Tb slot
  u16* Yt_h = (u16*)(big + 12*kNH);
  u16* Yt_l = Tb;

  float P[6], Q[6];
  pade_coeffs(P, Q);

  auto eg = [](long n){ return dim3((unsigned)((n+255)/256)); };

  auto reduce2 = [&](const float* src, long n, double* dst){
    reduce2_part_kernel<<<kRB,256,0,stream>>>(src, n, partd);
    reduce2_fin_kernel<<<1,256,0,stream>>>(partd, kRB, dst);
  };
  auto do_ln = [&](const float* src, float* dst, const float* lnp){
    reduce2(src, kNH, scald);
    apply_ln_kernel<<<eg(kNH),256,0,stream>>>(src, dst, lnp, scald);
  };
  auto sparse_layer = [&](const float* hin, int K, const float* W, const float* b,
                          const float* lnp, float* zout){
    launch_gemm<false,false,false,EPI_NONE>(stream, hin, K, W, kH, big, kH, kN, kH, K, 12,
                                            0, (long)K*kH, kNH, 0.f);
    combine_root_kernel<<<eg(kNH),256,0,stream>>>(big, b, tnh);
    scatter_kernel<<<dim3((unsigned)(((long)kNE*kH+255)/256),4),256,0,stream>>>(e0,e1,e2,e3, big, tnh);
    do_ln(tnh, zout, lnp);
  };
  auto dense_layer = [&](const float* hin, int K, const u16* mb, const u16* mtb,
                         const float* W, const float* b, const float* lnp, float* zout){
    launch_gemm<false,false,false,EPI_NONE>(stream, hin, K, W, kH, big, kH, kN, kH, K, 12,
                                            0, (long)K*kH, kNH, 0.f);
    combine_root_kernel<<<eg(kNH),256,0,stream>>>(big, b, tnh);
    launch_transpose(stream, big, kN, kH, kNH, Yt_h, Yt_l, kNH, 8);  // Yt[e][feat][node] hi/lo
    dim3 gacc((kN+63)/64, (kH+63)/64, 4);
    // x_in: tnh += 0.5 * mask^T @ (Y_hi + Y_lo)[e=0..3]
    bgemm_accs_kernel<<<gacc,256,0,stream>>>(mtb, kN, Yt_h, Yt_l, kN, tnh, kH,
                                             kN, kH, kN, kNN, kNH, 0.5f);
    // x_out: tnh += 0.5 * mask @ (Y_hi + Y_lo)[e=4..7]
    bgemm_accs_kernel<<<gacc,256,0,stream>>>(mb, kN, Yt_h + 4*kNH, Yt_l + 4*kNH, kN, tnh, kH,
                                             kN, kH, kN, kNN, kNH, 0.5f);
    do_ln(tnh, zout, lnp);
  };
  auto blocked_trsm = [&](float* SoutDst, u16* Sb, u16* St){
    hipMemsetAsync(winv, 0, (size_t)kNN*sizeof(float), stream);
    invdiag_kernel<<<dim3(kN/kDB),128,0,stream>>>(qsq, winv);
    for (int s = kDB; s < kN; s *= 2){
      int npairs = kN / (2*s);
      long step = (long)2*s*kN + 2*s;
      launch_gemm<false,false,true,EPI_NONE>(stream,
          qsq + s, kN, winv + (long)s*kN + s, kN, tri, s,
          s, s, s, npairs, step, step, (long)s*s, 0.f);
      launch_gemm<false,true,false,EPI_SCALE>(stream,
          winv, kN, tri, s, winv + s, kN,
          s, s, s, npairs, step, (long)s*s, step, -1.f);
    }
    // S_acc = winv @ psq, K-split into 4 chunks of 200 (atomic fp32 accumulate)
    hipMemsetAsync(Sacc, 0, (size_t)kNN*sizeof(float), stream);
    launch_gemm<false,true,true,EPI_ACC>(stream,
        winv, kN, psq, kN, Sacc, kN, kN, kN, 200, 4,
        200 /*sA: col offset*/, (long)200*kN /*sB: row offset*/, 0, 1.f,
        nullptr, 200 /*kstep*/);
    // fused: out fp32 + Sb bf16 + St bf16-transposed, scaled by sqrt(normA)
    s_final_kernel<<<dim3(25,25),256,0,stream>>>(Sacc, scald+3, SoutDst, Sb, St);
  };
  auto run_pair_mpa = [&](const float* z, float* SoutDst, u16* Sb, u16* St){
    pair_kernel<<<dim3(50,50),256,0,stream>>>(z, linW, linb, tri);
    reduce2(tri, kNN, scald+2);                                // scald[3] = ||A||_F^2
    init_pade_kernel<<<eg(kNN),256,0,stream>>>(tri, papp, papp_h, papp_l, psq, qsq, scald+3,
                                               P[0],P[1],Q[0],Q[1]);
    launch_transpose(stream, papp, kN, kN, 0, pT_h, pT_l, 0, 1);   // papp fp32 dead after this
    dim3 g13(13,13,1);
    bgemm2_kernel<<<g13,256,0,stream>>>(papp_h,papp_l, pT_h,pT_l, psq,qsq, pwA_h,pwA_l, P[2],Q[2]);
    bgemm2_kernel<<<g13,256,0,stream>>>(pwA_h,pwA_l,  pT_h,pT_l, psq,qsq, pwB_h,pwB_l, P[3],Q[3]);
    bgemm2_kernel<<<g13,256,0,stream>>>(pwB_h,pwB_l,  pT_h,pT_l, psq,qsq, pwA_h,pwA_l, P[4],Q[4]);
    bgemm2_kernel<<<g13,256,0,stream>>>(pwA_h,pwA_l,  pT_h,pT_l, psq,qsq, pwB_h,pwB_l, P[5],Q[5]);
    blocked_trsm(SoutDst, Sb, St);
  };
  // h_out = S @ h_in, K-split into 4 chunks (S upper-tri, fp32, atomic acc)
  auto s_times_h = [&](const float* Sf, const float* hin, float* hout){
    hipMemsetAsync(hout, 0, (size_t)kN*kE*sizeof(float), stream);
    launch_gemm<false,true,false,EPI_ACC>(stream,
        Sf, kN, hin, kE, hout, kE, kN, kE, 200, 4,
        200 /*sA*/, (long)200*kE /*sB*/, 0, 1.f, nullptr, 200 /*kstep*/);
  };

  // ---- embed
  launch_gemm<false,false,false,EPI_BIAS>(stream, x_note, kF, embW, kE, h0, kE, kN, kE, kF, 1,
                                          0,0,0, 0.f, embB);

  // ---- GNN1 (sparse)
  sparse_layer(h0,  kE, g1w1, g1b1, g1ln,        zmid);
  sparse_layer(zmid,kH, g1w2, g1b2, g1ln + 2*kH, z0);

  // ---- S1 (fp32 written into d_out region)
  float* S1f = out + 215;
  float* S2f = out + 215 + kNN;
  run_pair_mpa(z0, S1f, S1b, S1t);

  // ---- h1 = S1 @ h0
  s_times_h(S1f, h0, h1);

  // ---- mask1 = (S1@A0)@S1 != 0   (bf16 MFMA, pattern-exact)
  hipMemsetAsync(A0t, 0, (size_t)(4*kNN)*sizeof(u16), stream);
  build_adj_kernel<<<dim3((kNE+255)/256,4),256,0,stream>>>(e0,e1,e2,e3, A0t);
  launch_bgemm<true,false,BEPI_NONE>(stream, S1b, kN, A0t, kN, nullptr, kN, Tb,
                                     kN,kN,kN, 4, 0, kNN, kNN);
  launch_bgemm<false,true,BEPI_MASK>(stream, Tb, kN, S1t, kN, maskF, kN, M1b,
                                     kN,kN,kN, 4, kNN, 0, kNN);
  launch_transpose(stream, maskF, kN, kN, kNN, M1t, nullptr, kNN, 4);

  // ---- GNN2 #1 (dense, mask1)
  dense_layer(h1,  kE, M1b, M1t, g2w1, g2b1, g2ln,        zmid);
  dense_layer(zmid,kH, M1b, M1t, g2w2, g2b2, g2ln + 2*kH, z1);

  // ---- S2
  run_pair_mpa(z1, S2f, S2b, S2t);

  // ---- h2 = S2 @ h1
  s_times_h(S2f, h1, h2);

  // ---- mask2 = (S2@mask1)@S2 != 0
  launch_bgemm<true,false,BEPI_NONE>(stream, S2b, kN, M1t, kN, nullptr, kN, Tb,
                                     kN,kN,kN, 4, 0, kNN, kNN);
  launch_bgemm<false,true,BEPI_MASK>(stream, Tb, kN, S2t, kN, maskF, kN, M2b,
                                     kN,kN,kN, 4, kNN, 0, kNN);
  launch_transpose(stream, maskF, kN, kN, kNN, M2t, nullptr, kNN, 4);

  // ---- GNN2 #2 (dense, mask2)
  dense_layer(h2,  kE, M2b, M2t, g2w1, g2b1, g2ln,        zmid);
  dense_layer(zmid,kH, M2b, M2t, g2w2, g2b2, g2ln + 2*kH, z2);

  // ---- pool + classifier + log_softmax
  pool_head_kernel<<<dim3(1),256,0,stream>>>(z2, clfW, clfb, out);
}

// Round 8
// 1596.877 us; speedup vs baseline: 3.1056x; 1.0883x over previous
//
#include <hip/hip_runtime.h>
#include <hip/hip_bf16.h>
#include <math.h>
#include <stdio.h>

static constexpr int   kN  = 800;    // nodes
static constexpr int   kF  = 111;    // input features
static constexpr int   kE  = 32;     // embed dim
static constexpr int   kH  = 200;    // hidden
static constexpr int   kNC = 15;     // classes
static constexpr int   kNE = 8000;   // edges per type
static constexpr long  kNN = (long)kN*kN;   // 640000
static constexpr long  kNH = (long)kN*kH;   // 160000
static constexpr float kAl  = 0.5f;  // ALPHA
static constexpr float kEps = 1e-5f;
static constexpr int   kRB  = 512;   // reduction blocks
static constexpr int   kDB  = 50;    // trsm diagonal block size (800 = 16 * 50)

typedef unsigned short u16;
typedef __attribute__((ext_vector_type(8))) short short8;
typedef __attribute__((ext_vector_type(4))) float f32x4;

__device__ __forceinline__ u16 f2bf(float v){
  __hip_bfloat16 b = __float2bfloat16(v);
  return *reinterpret_cast<u16*>(&b);
}
__device__ __forceinline__ float bf2f(u16 h){
  unsigned int u = ((unsigned int)h) << 16;
  float f; __builtin_memcpy(&f, &u, 4);
  return f;
}

enum { EPI_NONE=0, EPI_BIAS=1, EPI_SCALE=4, EPI_ACC=6 };

// ---------------------------------------------------------------- fp32 GEMM
// C[M,N] = A * B, row strides lda/ldb/ldc.
// TRIUA: A[m,kglob]==0 for kglob<m (exact); TRIUB: B[kglob,n]==0 for kglob>n.
// kstep!=0: K-split — blockIdx.z is a K-chunk; kbase=z*kstep; A/B pre-offset
// via sA/sB; triangular clips in global coords. EPI_ACC: atomic C += scale*v,
// scale *= sqrt(sqrt(scalp[0])) if scalp given; skip blocks return early.
template<bool TRANSA, bool TRIUA, bool TRIUB, int EPI>
__global__ __launch_bounds__(256)
void gemm_kernel(const float* __restrict__ A, int lda,
                 const float* __restrict__ B, int ldb,
                 float* __restrict__ C, int ldc,
                 int M, int Ncl, int K,
                 long sA, long sB, long sC, float scale,
                 const float* __restrict__ bias, int kstep,
                 const double* __restrict__ scalp)
{
  constexpr int TM=64, TN=64, TK=16;
  A += (long)blockIdx.z * sA;
  B += (long)blockIdx.z * sB;
  C += (long)blockIdx.z * sC;
  __shared__ float As[TK][TM+4];
  __shared__ float Bs[TK][TN+4];
  const int tid = threadIdx.x;
  const int tn4 = (tid & 15)*4, tm4 = (tid >> 4)*4;
  const int m0 = blockIdx.x * TM, n0 = blockIdx.y * TN;
  float acc[4][4] = {};
  const int kbase = kstep ? (int)blockIdx.z * kstep : 0;
  int k0 = TRIUA ? max(m0 - kbase, 0) : 0;
  int kEnd = TRIUB ? min(K, n0 + TN - kbase) : K;
  const bool skip = (k0 >= kEnd);
  if (skip && EPI == EPI_ACC) return;
  if (!skip) {
    for (; k0 < kEnd; k0 += TK) {
      #pragma unroll
      for (int u=0; u<4; ++u) {
        int idx = tid + 256*u;
        if (!TRANSA) {
          int m = idx >> 4, ka = idx & 15;
          int gm = m0+m, gk = k0+ka;
          As[ka][m] = (gm < M && gk < K) ? A[(long)gm*lda + gk] : 0.f;
        } else {
          int ka = idx >> 6, m = idx & 63;
          int gm = m0+m, gk = k0+ka;
          As[ka][m] = (gm < M && gk < K) ? A[(long)gk*lda + gm] : 0.f;
        }
        int kb = idx >> 6, nb = idx & 63;
        int gk = k0+kb, gn = n0+nb;
        Bs[kb][nb] = (gk < K && gn < Ncl) ? B[(long)gk*ldb + gn] : 0.f;
      }
      __syncthreads();
      #pragma unroll
      for (int kk=0; kk<TK; ++kk) {
        float a[4], b[4];
        #pragma unroll
        for (int u=0;u<4;++u){ a[u]=As[kk][tm4+u]; b[u]=Bs[kk][tn4+u]; }
        #pragma unroll
        for (int i=0;i<4;++i)
          #pragma unroll
          for (int j=0;j<4;++j)
            acc[i][j] = fmaf(a[i], b[j], acc[i][j]);
      }
      __syncthreads();
    }
  }
  float sc = scale;
  if (EPI == EPI_ACC && scalp) sc *= (float)sqrt(sqrt(scalp[0]));
  #pragma unroll
  for (int i=0;i<4;++i) {
    int gm = m0 + tm4 + i;
    if (gm >= M) continue;
    #pragma unroll
    for (int j=0;j<4;++j) {
      int gn = n0 + tn4 + j;
      if (gn >= Ncl) continue;
      float v = acc[i][j];
      long off = (long)gm*ldc + gn;
      if (EPI == EPI_BIAS)       C[off] = v + bias[gn];
      else if (EPI == EPI_SCALE) C[off] = scale*v;
      else if (EPI == EPI_ACC)   unsafeAtomicAdd(&C[off], sc*v);
      else                       C[off] = v;
    }
  }
}

template<bool TRANSA, bool TRIUA, bool TRIUB, int EPI>
static inline void launch_gemm(hipStream_t st,
                               const float* A, int lda, const float* B, int ldb,
                               float* C, int ldc, int M, int Ncl, int K, int batch,
                               long sA, long sB, long sC, float scale,
                               const float* bias = nullptr, int kstep = 0,
                               const double* scalp = nullptr)
{
  dim3 grid((M+63)/64, (Ncl+63)/64, batch);
  gemm_kernel<TRANSA,TRIUA,TRIUB,EPI><<<grid, 256, 0, st>>>(
      A,lda,B,ldb,C,ldc,M,Ncl,K,sA,sB,sC,scale,bias,kstep,scalp);
}

// ---------------------------------------------------------------- split-bf16 MFMA GEMM (powers)
// v = (Ah+Al)[kN,kN] @ ((Bth+Btl)[kN,kN])^T dropping lo*lo  (~fp32 accuracy)
// psq += p0*v; qsq += p1*v; Oh/Ol = hi/lo split of v. A and B^T upper-tri.
__global__ __launch_bounds__(256)
void bgemm2_kernel(const u16* __restrict__ Ah, const u16* __restrict__ Al,
                   const u16* __restrict__ Bh, const u16* __restrict__ Bl,
                   float* __restrict__ C, float* __restrict__ C2,
                   u16* __restrict__ Oh, u16* __restrict__ Ol,
                   float p0, float p1)
{
  constexpr int TM=64, TN=64, BK=32;
  __shared__ u16 Ash[TM][40], Asl[TM][40], Bsh[TN][40], Bsl[TN][40];
  const int tid = threadIdx.x;
  const int m0 = blockIdx.x*TM, n0 = blockIdx.y*TN;
  const int w = tid>>6, lane = tid&63;
  const int wm = (w&1)*32, wn = (w>>1)*32;
  const int quad = lane>>4, lm = lane&15;
  f32x4 acc00={}, acc01={}, acc10={}, acc11={};
  const bool skip = (m0 > n0 + TN - 1);
  int k0 = m0;
  const int kEnd = min(kN, n0+TN);
  const int ar = tid>>2, ac = (tid&3)*8;
  if (!skip){
    for (; k0 < kEnd; k0 += BK){
      uint4 avh={0,0,0,0}, avl={0,0,0,0}, bvh={0,0,0,0}, bvl={0,0,0,0};
      int gk = k0 + ac;
      if (m0+ar < kN && gk < kN){
        avh = *(const uint4*)(Ah + (long)(m0+ar)*kN + gk);
        avl = *(const uint4*)(Al + (long)(m0+ar)*kN + gk);
      }
      if (n0+ar < kN && gk < kN){
        bvh = *(const uint4*)(Bh + (long)(n0+ar)*kN + gk);
        bvl = *(const uint4*)(Bl + (long)(n0+ar)*kN + gk);
      }
      __syncthreads();
      *(uint4*)&Ash[ar][ac] = avh; *(uint4*)&Asl[ar][ac] = avl;
      *(uint4*)&Bsh[ar][ac] = bvh; *(uint4*)&Bsl[ar][ac] = bvl;
      __syncthreads();
      short8 a0h = *(const short8*)&Ash[wm+lm][quad*8];
      short8 a1h = *(const short8*)&Ash[wm+16+lm][quad*8];
      short8 a0l = *(const short8*)&Asl[wm+lm][quad*8];
      short8 a1l = *(const short8*)&Asl[wm+16+lm][quad*8];
      short8 b0h = *(const short8*)&Bsh[wn+lm][quad*8];
      short8 b1h = *(const short8*)&Bsh[wn+16+lm][quad*8];
      short8 b0l = *(const short8*)&Bsl[wn+lm][quad*8];
      short8 b1l = *(const short8*)&Bsl[wn+16+lm][quad*8];
      acc00 = __builtin_amdgcn_mfma_f32_16x16x32_bf16(a0h,b0h,acc00,0,0,0);
      acc00 = __builtin_amdgcn_mfma_f32_16x16x32_bf16(a0h,b0l,acc00,0,0,0);
      acc00 = __builtin_amdgcn_mfma_f32_16x16x32_bf16(a0l,b0h,acc00,0,0,0);
      acc01 = __builtin_amdgcn_mfma_f32_16x16x32_bf16(a0h,b1h,acc01,0,0,0);
      acc01 = __builtin_amdgcn_mfma_f32_16x16x32_bf16(a0h,b1l,acc01,0,0,0);
      acc01 = __builtin_amdgcn_mfma_f32_16x16x32_bf16(a0l,b1h,acc01,0,0,0);
      acc10 = __builtin_amdgcn_mfma_f32_16x16x32_bf16(a1h,b0h,acc10,0,0,0);
      acc10 = __builtin_amdgcn_mfma_f32_16x16x32_bf16(a1h,b0l,acc10,0,0,0);
      acc10 = __builtin_amdgcn_mfma_f32_16x16x32_bf16(a1l,b0h,acc10,0,0,0);
      acc11 = __builtin_amdgcn_mfma_f32_16x16x32_bf16(a1h,b1h,acc11,0,0,0);
      acc11 = __builtin_amdgcn_mfma_f32_16x16x32_bf16(a1h,b1l,acc11,0,0,0);
      acc11 = __builtin_amdgcn_mfma_f32_16x16x32_bf16(a1l,b1h,acc11,0,0,0);
    }
  }
  f32x4 accs[2][2] = {{acc00, acc01},{acc10, acc11}};
  #pragma unroll
  for (int ti=0; ti<2; ++ti){
    #pragma unroll
    for (int tj=0; tj<2; ++tj){
      #pragma unroll
      for (int r=0; r<4; ++r){
        int gm = m0 + wm + ti*16 + quad*4 + r;
        int gn = n0 + wn + tj*16 + lm;
        if (gm >= kN || gn >= kN) continue;
        float v = accs[ti][tj][r];
        long off = (long)gm*kN + gn;
        C[off]  += p0*v;
        C2[off] += p1*v;
        u16 h = f2bf(v);
        Oh[off] = h;
        Ol[off] = f2bf(v - bf2f(h));
      }
    }
  }
}

// ---- transpose fp32 -> bf16 hi/lo: dst[c][r]; square kN
__global__ __launch_bounds__(256)
void transpose_bf_kernel(const float* __restrict__ src,
                         u16* __restrict__ dh, u16* __restrict__ dl)
{
  __shared__ float t[32][33];
  int r0 = blockIdx.y*32, c0 = blockIdx.x*32;
  int tr = threadIdx.x>>5, tc = threadIdx.x&31;
  for (int i=tr; i<32; i+=8){
    t[i][tc] = src[(long)(r0+i)*kN + c0+tc];
  }
  __syncthreads();
  for (int i=tr; i<32; i+=8){
    int c = c0+i, r = r0+tc;
    float v = t[tc][i];
    u16 h = f2bf(v);
    dh[(long)c*kN + r] = h;
    dl[(long)c*kN + r] = f2bf(v - bf2f(h));
  }
}

// ---------------------------------------------------------------- mask staircase kernels
// g[e][d] = max{s : edge (s,d) of type e, d' <= d}  (two stages)
__global__ void edge_gmax_kernel(const int* __restrict__ e0, const int* __restrict__ e1,
                                 const int* __restrict__ e2, const int* __restrict__ e3,
                                 int* __restrict__ g){
  const int* eis[4] = {e0,e1,e2,e3};
  const int e = blockIdx.y;
  const int* ei = eis[e];
  int j = blockIdx.x*256 + threadIdx.x;
  if (j >= kNE) return;
  int s = ei[j], d = ei[kNE + j];
  atomicMax(&g[e*kN + d], s);
}

// prefix-max g; h[e][d] = min{n : g[e][n] >= d} (kN if none)
__global__ __launch_bounds__(256)
void scan_gh_kernel(int* __restrict__ g, int* __restrict__ h){
  __shared__ int gs[kN];
  const int e = blockIdx.x;
  for (int i = threadIdx.x; i < kN; i += 256) gs[i] = g[e*kN + i];
  __syncthreads();
  if (threadIdx.x == 0){
    int m = -1;
    for (int i = 0; i < kN; ++i){ m = max(m, gs[i]); gs[i] = m; }
  }
  __syncthreads();
  for (int i = threadIdx.x; i < kN; i += 256) g[e*kN + i] = gs[i];
  for (int d = threadIdx.x; d < kN; d += 256){
    int lo = 0, hi = kN;
    while (lo < hi){ int mid = (lo+hi)>>1; if (gs[mid] >= d) hi = mid; else lo = mid+1; }
    h[e*kN + d] = lo;
  }
}

// in-place scans over Y planes: z<4 -> prefix over n (plane z); z>=4 -> suffix (plane z)
__global__ __launch_bounds__(256)
void scan_msg_kernel(float* __restrict__ Y){
  const int plane = blockIdx.x;          // 0..7
  const int f = threadIdx.x;
  if (f >= kH) return;
  float* P = Y + (long)plane*kNH + f;
  float acc = 0.f;
  if (plane < 4){
    for (int n = 0; n < kN; n += 4){
      float v0 = P[(long)(n+0)*kH], v1 = P[(long)(n+1)*kH];
      float v2 = P[(long)(n+2)*kH], v3 = P[(long)(n+3)*kH];
      acc += v0; P[(long)(n+0)*kH] = acc;
      acc += v1; P[(long)(n+1)*kH] = acc;
      acc += v2; P[(long)(n+2)*kH] = acc;
      acc += v3; P[(long)(n+3)*kH] = acc;
    }
  } else {
    for (int n = kN-1; n >= 0; n -= 4){
      float v0 = P[(long)(n-0)*kH], v1 = P[(long)(n-1)*kH];
      float v2 = P[(long)(n-2)*kH], v3 = P[(long)(n-3)*kH];
      acc += v0; P[(long)(n-0)*kH] = acc;
      acc += v1; P[(long)(n-1)*kH] = acc;
      acc += v2; P[(long)(n-2)*kH] = acc;
      acc += v3; P[(long)(n-3)*kH] = acc;
    }
  }
}

// tnh[n,f] += 0.5*sum_e [ prefixYin[e][g(n)][f] + suffixYout[e][h(n)][f] ]
__global__ __launch_bounds__(256)
void gather_dense_kernel(const float* __restrict__ Y, const int* __restrict__ g,
                         const int* __restrict__ h, float* __restrict__ tnh){
  long idx = (long)blockIdx.x*256 + threadIdx.x;
  if (idx >= kNH) return;
  int n = (int)(idx / kH), f = (int)(idx % kH);
  float v = 0.f;
  #pragma unroll
  for (int e = 0; e < 4; ++e){
    int gi = g[e*kN + n];
    if (gi >= 0) v += Y[(long)e*kNH + (long)gi*kH + f];
    int hi = h[e*kN + n];
    if (hi < kN) v += Y[(long)(4+e)*kNH + (long)hi*kH + f];
  }
  tnh[idx] += 0.5f*v;
}

// ---------------------------------------------------------------- small kernels
__global__ void combine_root_kernel(const float* __restrict__ Y, const float* __restrict__ b,
                                    float* __restrict__ out){
  long idx = (long)blockIdx.x*256 + threadIdx.x;
  if (idx >= kNH) return;
  int f = (int)(idx % kH);
  float v = 0.f;
  #pragma unroll
  for (int e=0;e<4;++e) {
    v += Y[(long)(8+e)*kNH + idx];
    v += (1.f-kAl)*b[(0*4+e)*kH + f] + kAl*b[(1*4+e)*kH + f] + b[(2*4+e)*kH + f];
  }
  out[idx] = v;
}

__global__ __launch_bounds__(256)
void scatter_kernel(const int* __restrict__ e0, const int* __restrict__ e1,
                    const int* __restrict__ e2, const int* __restrict__ e3,
                    const float* __restrict__ Y, float* __restrict__ out){
  const int* eis[4] = {e0,e1,e2,e3};
  const int e = blockIdx.y;
  const int* ei = eis[e];
  long idx = (long)blockIdx.x*256 + threadIdx.x;
  if (idx >= (long)kNE*kH) return;
  int j = (int)(idx / kH), f = (int)(idx % kH);
  int s = ei[j], d = ei[kNE + j];
  float m_in  = Y[((long)e*kN + s)*kH + f];
  float m_out = Y[((long)(4+e)*kN + d)*kH + f];
  unsafeAtomicAdd(&out[(long)d*kH + f], (1.f-kAl)*m_in);
  unsafeAtomicAdd(&out[(long)s*kH + f], kAl*m_out);
}

__global__ __launch_bounds__(256)
void reduce2_part_kernel(const float* __restrict__ x, long n, double* __restrict__ part){
  __shared__ double ss[256], qq[256];
  double s=0.0, q=0.0;
  for (long i = (long)blockIdx.x*256 + threadIdx.x; i < n; i += (long)gridDim.x*256){
    double v = x[i]; s += v; q += v*v;
  }
  ss[threadIdx.x]=s; qq[threadIdx.x]=q;
  __syncthreads();
  for (int h=128; h>0; h>>=1){
    if ((int)threadIdx.x < h){ ss[threadIdx.x]+=ss[threadIdx.x+h]; qq[threadIdx.x]+=qq[threadIdx.x+h]; }
    __syncthreads();
  }
  if (threadIdx.x==0){ part[2*blockIdx.x]=ss[0]; part[2*blockIdx.x+1]=qq[0]; }
}

__global__ __launch_bounds__(256)
void reduce2_fin_kernel(const double* __restrict__ part, int nb, double* __restrict__ out){
  __shared__ double ss[256], qq[256];
  double s=0.0, q=0.0;
  for (int i=threadIdx.x; i<nb; i+=256){ s += part[2*i]; q += part[2*i+1]; }
  ss[threadIdx.x]=s; qq[threadIdx.x]=q;
  __syncthreads();
  for (int h=128; h>0; h>>=1){
    if ((int)threadIdx.x < h){ ss[threadIdx.x]+=ss[threadIdx.x+h]; qq[threadIdx.x]+=qq[threadIdx.x+h]; }
    __syncthreads();
  }
  if (threadIdx.x==0){ out[0]=ss[0]; out[1]=qq[0]; }
}

__global__ void apply_ln_kernel(const float* __restrict__ x, float* __restrict__ y,
                                const float* __restrict__ ln, const double* __restrict__ sc){
  long idx = (long)blockIdx.x*256 + threadIdx.x;
  if (idx >= kNH) return;
  int f = (int)(idx % kH);
  double mu  = sc[0] / (double)kNH;
  double var = sc[1] / (double)kNH - mu*mu;
  float rs = rsqrtf((float)var + kEps);
  y[idx] = (x[idx] - (float)mu) * rs * ln[f] + ln[kH + f];
}

__global__ __launch_bounds__(256)
void pair_kernel(const float* __restrict__ z, const float* __restrict__ linW,
                 const float* __restrict__ linb, float* __restrict__ tri){
  __shared__ float zi[16][201], zj[16][201], w[208];
  const int i0 = blockIdx.y*16, j0 = blockIdx.x*16;
  const int tid = threadIdx.x;
  const int ti = tid >> 4, tj = tid & 15;
  const int i = i0+ti, j = j0+tj;
  if (i0 > j0 + 15) { tri[(long)i*kN + j] = 0.f; return; }
  for (int idx = tid; idx < 16*kH; idx += 256){
    int r = idx / kH, c = idx % kH;
    zi[r][c] = z[(long)(i0+r)*kH + c];
    zj[r][c] = z[(long)(j0+r)*kH + c];
  }
  if (tid < kH) w[tid] = linW[tid];
  __syncthreads();
  float g = 0.f;
  if (i <= j){
    float s = linb[0];
    #pragma unroll 4
    for (int k=0;k<kH;++k){ float d = zi[ti][k]-zj[tj][k]; s = fmaf(d*d, w[k], s); }
    g = 1.f/(1.f + expf(-s));
  }
  tri[(long)i*kN + j] = g;
}

__global__ void init_pade_kernel(const float* __restrict__ tri, float* __restrict__ papp,
                                 u16* __restrict__ papp_h, u16* __restrict__ papp_l,
                                 float* __restrict__ psq, float* __restrict__ qsq,
                                 const double* __restrict__ frob2,
                                 float P0, float P1, float Q0, float Q1){
  int idx = blockIdx.x*256 + threadIdx.x;
  if (idx >= (int)kNN) return;
  int i = idx / kN, j = idx % kN;
  float rn = (float)(1.0 / sqrt(frob2[0]));
  float eye = (i==j) ? 1.f : 0.f;
  float pa = eye - tri[idx]*rn;
  papp[idx] = pa;
  u16 h = f2bf(pa);
  papp_h[idx] = h;
  papp_l[idx] = f2bf(pa - bf2f(h));
  psq[idx] = P0*eye + P1*pa;
  qsq[idx] = Q0*eye + Q1*pa;
}

// ---- invert the 16 diagonal 50x50 upper-tri blocks of U into W (W pre-zeroed)
__global__ __launch_bounds__(64)
void invdiag_kernel(const float* __restrict__ U, float* __restrict__ W){
  __shared__ float Us[kDB][kDB+1];
  __shared__ float Xs[kDB][kDB+1];
  const int base = blockIdx.x * kDB;
  const int tid = threadIdx.x;
  for (int idx = tid; idx < kDB*kDB; idx += 64){
    int r = idx / kDB, c = idx % kDB;
    Us[r][c] = U[(long)(base+r)*kN + base + c];
  }
  __syncthreads();
  const int c = tid;
  for (int i = kDB-1; i >= 0; --i){
    if (c < kDB){
      float x;
      if (c < i) x = 0.f;
      else {
        float s = 0.f;
        for (int k = i+1; k < kDB; ++k) s = fmaf(Us[i][k], Xs[k][c], s);
        x = (((c==i)?1.f:0.f) - s) / Us[i][i];
      }
      Xs[i][c] = x;
    }
    __syncthreads();
  }
  for (int idx = tid; idx < kDB*kDB; idx += 64){
    int r = idx / kDB, cc = idx % kDB;
    W[(long)(base+r)*kN + base + cc] = Xs[r][cc];
  }
}

__global__ __launch_bounds__(256)
void pool_head_kernel(const float* __restrict__ z2, const float* __restrict__ W,
                      const float* __restrict__ b, float* __restrict__ out){
  __shared__ float x2[kH];
  __shared__ float lg[kNC];
  int t = threadIdx.x;
  if (t < kH){
    float s = 0.f;
    for (int n = 0; n < kN; ++n) s += z2[(long)n*kH + t];
    float v = s * (1.f/(float)kN);
    x2[t] = v;
    out[t] = v;
  }
  __syncthreads();
  if (t < kNC){
    float s = b[t];
    for (int f = 0; f < kH; ++f) s = fmaf(x2[f], W[f*kNC + t], s);
    lg[t] = s;
  }
  __syncthreads();
  if (t == 0){
    float m = -1e30f;
    for (int c=0;c<kNC;++c) m = fmaxf(m, lg[c]);
    float se = 0.f;
    for (int c=0;c<kNC;++c) se += expf(lg[c]-m);
    float lse = m + logf(se);
    for (int c=0;c<kNC;++c) out[kH + c] = lg[c]-lse;
  }
}

// ---------------------------------------------------------------- host: Pade [5/5] of sqrt(1-x)
static void pade_coeffs(float* P, float* Q){
  double b[11]; b[0] = 1.0;
  for (int k=1;k<11;++k) b[k] = b[k-1]*(0.5-(k-1))/k;
  double c[11];
  for (int k=0;k<11;++k) c[k] = b[k]*((k&1)?-1.0:1.0);
  double A[5][5], rhs[5];
  for (int i=0;i<5;++i){ for (int j=0;j<5;++j) A[i][j] = c[5+i-j]; rhs[i] = -c[6+i]; }
  for (int col=0; col<5; ++col){
    int p = col;
    for (int r=col+1;r<5;++r) if (fabs(A[r][col]) > fabs(A[p][col])) p = r;
    if (p != col){
      for (int j=0;j<5;++j){ double t=A[col][j]; A[col][j]=A[p][j]; A[p][j]=t; }
      double t=rhs[col]; rhs[col]=rhs[p]; rhs[p]=t;
    }
    for (int r=col+1;r<5;++r){
      double f = A[r][col]/A[col][col];
      for (int j=col;j<5;++j) A[r][j] -= f*A[col][j];
      rhs[r] -= f*rhs[col];
    }
  }
  double q[6]; q[0] = 1.0;
  for (int r=4;r>=0;--r){
    double s = rhs[r];
    for (int j=r+1;j<5;++j) s -= A[r][j]*q[1+j];
    q[1+r] = s/A[r][r];
  }
  double p[6];
  for (int k=0;k<6;++k){
    double s = 0.0; int jm = k<5?k:5;
    for (int j=0;j<=jm;++j) s += q[j]*c[k-j];
    p[k] = s;
  }
  for (int k=0;k<6;++k){ P[k]=(float)p[k]; Q[k]=(float)q[k]; }
}

// ---------------------------------------------------------------- launch
extern "C" void kernel_launch(void* const* d_in, const int* in_sizes, int n_in,
                              void* d_out, int out_size, void* d_ws, size_t ws_size,
                              hipStream_t stream)
{
  const float* x_note = (const float*)d_in[0];
  const float* embW   = (const float*)d_in[1];
  const float* embB   = (const float*)d_in[2];
  const float* g1w1   = (const float*)d_in[3];
  const float* g1b1   = (const float*)d_in[4];
  const float* g1w2   = (const float*)d_in[5];
  const float* g1b2   = (const float*)d_in[6];
  const float* g1ln   = (const float*)d_in[7];
  const float* g2w1   = (const float*)d_in[8];
  const float* g2b1   = (const float*)d_in[9];
  const float* g2w2   = (const float*)d_in[10];
  const float* g2b2   = (const float*)d_in[11];
  const float* g2ln   = (const float*)d_in[12];
  const float* linW   = (const float*)d_in[13];
  const float* linb   = (const float*)d_in[14];
  const float* clfW   = (const float*)d_in[15];
  const float* clfb   = (const float*)d_in[16];
  const int*  e0     = (const int*)d_in[17];
  const int*  e1     = (const int*)d_in[18];
  const int*  e2     = (const int*)d_in[19];
  const int*  e3     = (const int*)d_in[20];
  float* out = (float*)d_out;

  // fp32 region (float offsets); header: scald @0, partd @512B (8 KB)
  constexpr long o_h0   = 2176;
  constexpr long o_h1   = o_h0   + (long)kN*kE;
  constexpr long o_h2   = o_h1   + (long)kN*kE;
  constexpr long o_tnh  = o_h2   + (long)kN*kE;
  constexpr long o_zmid = o_tnh  + kNH;
  constexpr long o_z0   = o_zmid + kNH;
  constexpr long o_z1   = o_z0   + kNH;
  constexpr long o_z2   = o_z1   + kNH;
  constexpr long o_big  = o_z2   + kNH;             // 4*kNN floats: Y planes / power bf16 scratch
  constexpr long o_tri  = o_big  + 4*kNN;           // pair out / merge scratch
  constexpr long o_papp = o_tri  + kNN;
  constexpr long o_winv = o_papp + kNN;
  constexpr long o_psq  = o_winv + kNN;
  constexpr long o_qsq  = o_psq  + kNN;
  constexpr long o_g    = o_qsq  + kNN;             // int g[4][kN]
  constexpr long o_hh   = o_g    + 4*kN;            // int h[4][kN]
  constexpr long o_end  = o_hh   + 4*kN;

  if (ws_size < (size_t)o_end*sizeof(float) || out_size < 215 + 2*(int)kNN || n_in < 21){
    fprintf(stderr, "kernel_launch guard: ws=%zu need=%zu out=%d need=%d n_in=%d\n",
            ws_size, (size_t)o_end*sizeof(float), out_size, (int)(215+2*kNN), n_in);
    hipMemsetAsync(d_out, 0, (size_t)out_size*sizeof(float), stream);
    return;
  }

  float* ws = (float*)d_ws;
  double* scald = (double*)d_ws;
  double* partd = (double*)((char*)d_ws + 512);
  float *h0=ws+o_h0, *h1=ws+o_h1, *h2=ws+o_h2, *tnh=ws+o_tnh,
        *zmid=ws+o_zmid, *z0=ws+o_z0, *z1=ws+o_z1, *z2=ws+o_z2, *big=ws+o_big,
        *tri=ws+o_tri, *papp=ws+o_papp, *winv=ws+o_winv, *psq=ws+o_psq, *qsq=ws+o_qsq;
  int* gArr = (int*)(ws + o_g);
  int* hArr = (int*)(ws + o_hh);
  // power-phase split scratch aliased inside big (8 u16 planes = 4*kNN floats)
  u16* papp_h = (u16*)big;
  u16* papp_l = papp_h + kNN;
  u16* pT_h   = papp_l + kNN;
  u16* pT_l   = pT_h + kNN;
  u16* pwA_h  = pT_l + kNN;
  u16* pwA_l  = pwA_h + kNN;
  u16* pwB_h  = pwA_l + kNN;
  u16* pwB_l  = pwB_h + kNN;

  float P[6], Q[6];
  pade_coeffs(P, Q);

  auto eg = [](long n){ return dim3((unsigned)((n+255)/256)); };

  auto reduce2 = [&](const float* src, long n, double* dst){
    reduce2_part_kernel<<<kRB,256,0,stream>>>(src, n, partd);
    reduce2_fin_kernel<<<1,256,0,stream>>>(partd, kRB, dst);
  };
  auto do_ln = [&](const float* src, float* dst, const float* lnp){
    reduce2(src, kNH, scald);
    apply_ln_kernel<<<eg(kNH),256,0,stream>>>(src, dst, lnp, scald);
  };
  auto sparse_layer = [&](const float* hin, int K, const float* W, const float* b,
                          const float* lnp, float* zout){
    launch_gemm<false,false,false,EPI_NONE>(stream, hin, K, W, kH, big, kH, kN, kH, K, 12,
                                            0, (long)K*kH, kNH, 0.f);
    combine_root_kernel<<<eg(kNH),256,0,stream>>>(big, b, tnh);
    scatter_kernel<<<dim3((unsigned)(((long)kNE*kH+255)/256),4),256,0,stream>>>(e0,e1,e2,e3, big, tnh);
    do_ln(tnh, zout, lnp);
  };
  auto dense_layer = [&](const float* hin, int K, const float* W, const float* b,
                         const float* lnp, float* zout){
    launch_gemm<false,false,false,EPI_NONE>(stream, hin, K, W, kH, big, kH, kN, kH, K, 12,
                                            0, (long)K*kH, kNH, 0.f);
    combine_root_kernel<<<eg(kNH),256,0,stream>>>(big, b, tnh);
    scan_msg_kernel<<<8,256,0,stream>>>(big);          // in-place prefix/suffix on planes 0-7
    gather_dense_kernel<<<eg(kNH),256,0,stream>>>(big, gArr, hArr, tnh);
    do_ln(tnh, zout, lnp);
  };
  auto blocked_trsm = [&](float* SoutDst){
    hipMemsetAsync(winv, 0, (size_t)kNN*sizeof(float), stream);
    invdiag_kernel<<<dim3(kN/kDB),64,0,stream>>>(qsq, winv);
    for (int s = kDB; s < kN; s *= 2){
      int npairs = kN / (2*s);
      long step = (long)2*s*kN + 2*s;
      launch_gemm<false,false,true,EPI_NONE>(stream,
          qsq + s, kN, winv + (long)s*kN + s, kN, tri, s,
          s, s, s, npairs, step, step, (long)s*s, 0.f);
      launch_gemm<false,true,false,EPI_SCALE>(stream,
          winv, kN, tri, s, winv + s, kN,
          s, s, s, npairs, step, (long)s*s, step, -1.f);
    }
    // S = (winv @ psq) * sqrt(normA) atomically into d_out region (pre-zeroed),
    // K-split into 4 chunks of 200 for parallelism.
    launch_gemm<false,true,true,EPI_ACC>(stream,
        winv, kN, psq, kN, SoutDst, kN, kN, kN, 200, 4,
        200 /*sA col off*/, (long)200*kN /*sB row off*/, 0, 1.f,
        nullptr, 200 /*kstep*/, scald+3);
  };
  auto run_pair_mpa = [&](const float* z, float* SoutDst){
    pair_kernel<<<dim3(50,50),256,0,stream>>>(z, linW, linb, tri);
    reduce2(tri, kNN, scald+2);                                // scald[3] = ||A||_F^2
    init_pade_kernel<<<eg(kNN),256,0,stream>>>(tri, papp, papp_h, papp_l, psq, qsq, scald+3,
                                               P[0],P[1],Q[0],Q[1]);
    transpose_bf_kernel<<<dim3(25,25),256,0,stream>>>(papp, pT_h, pT_l);
    dim3 g13(13,13,1);
    bgemm2_kernel<<<g13,256,0,stream>>>(papp_h,papp_l, pT_h,pT_l, psq,qsq, pwA_h,pwA_l, P[2],Q[2]);
    bgemm2_kernel<<<g13,256,0,stream>>>(pwA_h,pwA_l,  pT_h,pT_l, psq,qsq, pwB_h,pwB_l, P[3],Q[3]);
    bgemm2_kernel<<<g13,256,0,stream>>>(pwB_h,pwB_l,  pT_h,pT_l, psq,qsq, pwA_h,pwA_l, P[4],Q[4]);
    bgemm2_kernel<<<g13,256,0,stream>>>(pwA_h,pwA_l,  pT_h,pT_l, psq,qsq, pwB_h,pwB_l, P[5],Q[5]);
    blocked_trsm(SoutDst);
  };
  // h_out = S @ h_in, K-split into 4 chunks (S upper-tri, fp32, atomic acc)
  auto s_times_h = [&](const float* Sf, const float* hin, float* hout){
    hipMemsetAsync(hout, 0, (size_t)kN*kE*sizeof(float), stream);
    launch_gemm<false,true,false,EPI_ACC>(stream,
        Sf, kN, hin, kE, hout, kE, kN, kE, 200, 4,
        200, (long)200*kE, 0, 1.f, nullptr, 200);
  };

  float* S1f = out + 215;
  float* S2f = out + 215 + kNN;

  // ---- once: zero S output regions (atomic-accumulated), build staircase g/h
  hipMemsetAsync(S1f, 0, (size_t)(2*kNN)*sizeof(float), stream);
  hipMemsetAsync(gArr, 0xFF, (size_t)(4*kN)*sizeof(int), stream);   // -1
  edge_gmax_kernel<<<dim3((kNE+255)/256,4),256,0,stream>>>(e0,e1,e2,e3, gArr);
  scan_gh_kernel<<<4,256,0,stream>>>(gArr, hArr);

  // ---- embed
  launch_gemm<false,false,false,EPI_BIAS>(stream, x_note, kF, embW, kE, h0, kE, kN, kE, kF, 1,
                                          0,0,0, 0.f, embB);

  // ---- GNN1 (sparse)
  sparse_layer(h0,  kE, g1w1, g1b1, g1ln,        zmid);
  sparse_layer(zmid,kH, g1w2, g1b2, g1ln + 2*kH, z0);

  // ---- S1
  run_pair_mpa(z0, S1f);

  // ---- h1 = S1 @ h0
  s_times_h(S1f, h0, h1);

  // ---- GNN2 #1 (dense; mask1 == staircase(g,h))
  dense_layer(h1,  kE, g2w1, g2b1, g2ln,        zmid);
  dense_layer(zmid,kH, g2w2, g2b2, g2ln + 2*kH, z1);

  // ---- S2
  run_pair_mpa(z1, S2f);

  // ---- h2 = S2 @ h1
  s_times_h(S2f, h1, h2);

  // ---- GNN2 #2 (dense; mask2 == mask1 — same staircase)
  dense_layer(h2,  kE, g2w1, g2b1, g2ln,        zmid);
  dense_layer(zmid,kH, g2w2, g2b2, g2ln + 2*kH, z2);

  // ---- pool + classifier + log_softmax
  pool_head_kernel<<<dim3(1),256,0,stream>>>(z2, clfW, clfb, out);
}

// Round 9
// 1594.021 us; speedup vs baseline: 3.1112x; 1.0018x over previous
//
#include <hip/hip_runtime.h>
#include <hip/hip_bf16.h>
#include <math.h>
#include <stdio.h>

static constexpr int   kN  = 800;    // nodes
static constexpr int   kF  = 111;    // input features
static constexpr int   kE  = 32;     // embed dim
static constexpr int   kH  = 200;    // hidden
static constexpr int   kNC = 15;     // classes
static constexpr int   kNE = 8000;   // edges per type
static constexpr long  kNN = (long)kN*kN;   // 640000
static constexpr long  kNH = (long)kN*kH;   // 160000
static constexpr float kAl  = 0.5f;  // ALPHA
static constexpr float kEps = 1e-5f;
static constexpr int   kRB  = 64;    // reduction blocks
static constexpr int   kDB  = 50;    // trsm diagonal block size (800 = 16 * 50)

typedef unsigned short u16;
typedef __attribute__((ext_vector_type(8))) short short8;
typedef __attribute__((ext_vector_type(4))) float f32x4;

__device__ __forceinline__ u16 f2bf(float v){
  __hip_bfloat16 b = __float2bfloat16(v);
  return *reinterpret_cast<u16*>(&b);
}
__device__ __forceinline__ float bf2f(u16 h){
  unsigned int u = ((unsigned int)h) << 16;
  float f; __builtin_memcpy(&f, &u, 4);
  return f;
}

enum { EPI_NONE=0, EPI_BIAS=1, EPI_SCALE=4, EPI_ACC=6 };

// ---------------------------------------------------------------- fp32 GEMM
// C[M,N] = A * B, row strides lda/ldb/ldc.
// TRIUA: A[m,kglob]==0 for kglob<m (exact); TRIUB: B[kglob,n]==0 for kglob>n.
// kstep!=0: K-split — blockIdx.z is a K-chunk; kbase=z*kstep; A/B pre-offset
// via sA/sB; triangular clips in global coords. EPI_ACC: atomic C += scale*v,
// scale *= sqrt(sqrt(scalp[0])) if scalp given; skip blocks return early.
template<bool TRANSA, bool TRIUA, bool TRIUB, int EPI>
__global__ __launch_bounds__(256)
void gemm_kernel(const float* __restrict__ A, int lda,
                 const float* __restrict__ B, int ldb,
                 float* __restrict__ C, int ldc,
                 int M, int Ncl, int K,
                 long sA, long sB, long sC, float scale,
                 const float* __restrict__ bias, int kstep,
                 const double* __restrict__ scalp)
{
  constexpr int TM=64, TN=64, TK=16;
  A += (long)blockIdx.z * sA;
  B += (long)blockIdx.z * sB;
  C += (long)blockIdx.z * sC;
  __shared__ float As[TK][TM+4];
  __shared__ float Bs[TK][TN+4];
  const int tid = threadIdx.x;
  const int tn4 = (tid & 15)*4, tm4 = (tid >> 4)*4;
  const int m0 = blockIdx.x * TM, n0 = blockIdx.y * TN;
  float acc[4][4] = {};
  const int kbase = kstep ? (int)blockIdx.z * kstep : 0;
  int k0 = TRIUA ? max(m0 - kbase, 0) : 0;
  int kEnd = TRIUB ? min(K, n0 + TN - kbase) : K;
  const bool skip = (k0 >= kEnd);
  if (skip && EPI == EPI_ACC) return;
  if (!skip) {
    for (; k0 < kEnd; k0 += TK) {
      #pragma unroll
      for (int u=0; u<4; ++u) {
        int idx = tid + 256*u;
        if (!TRANSA) {
          int m = idx >> 4, ka = idx & 15;
          int gm = m0+m, gk = k0+ka;
          As[ka][m] = (gm < M && gk < K) ? A[(long)gm*lda + gk] : 0.f;
        } else {
          int ka = idx >> 6, m = idx & 63;
          int gm = m0+m, gk = k0+ka;
          As[ka][m] = (gm < M && gk < K) ? A[(long)gk*lda + gm] : 0.f;
        }
        int kb = idx >> 6, nb = idx & 63;
        int gk = k0+kb, gn = n0+nb;
        Bs[kb][nb] = (gk < K && gn < Ncl) ? B[(long)gk*ldb + gn] : 0.f;
      }
      __syncthreads();
      #pragma unroll
      for (int kk=0; kk<TK; ++kk) {
        float a[4], b[4];
        #pragma unroll
        for (int u=0;u<4;++u){ a[u]=As[kk][tm4+u]; b[u]=Bs[kk][tn4+u]; }
        #pragma unroll
        for (int i=0;i<4;++i)
          #pragma unroll
          for (int j=0;j<4;++j)
            acc[i][j] = fmaf(a[i], b[j], acc[i][j]);
      }
      __syncthreads();
    }
  }
  float sc = scale;
  if (EPI == EPI_ACC && scalp) sc *= (float)sqrt(sqrt(scalp[0]));
  #pragma unroll
  for (int i=0;i<4;++i) {
    int gm = m0 + tm4 + i;
    if (gm >= M) continue;
    #pragma unroll
    for (int j=0;j<4;++j) {
      int gn = n0 + tn4 + j;
      if (gn >= Ncl) continue;
      float v = acc[i][j];
      long off = (long)gm*ldc + gn;
      if (EPI == EPI_BIAS)       C[off] = v + bias[gn];
      else if (EPI == EPI_SCALE) C[off] = scale*v;
      else if (EPI == EPI_ACC)   unsafeAtomicAdd(&C[off], sc*v);
      else                       C[off] = v;
    }
  }
}

template<bool TRANSA, bool TRIUA, bool TRIUB, int EPI>
static inline void launch_gemm(hipStream_t st,
                               const float* A, int lda, const float* B, int ldb,
                               float* C, int ldc, int M, int Ncl, int K, int batch,
                               long sA, long sB, long sC, float scale,
                               const float* bias = nullptr, int kstep = 0,
                               const double* scalp = nullptr)
{
  dim3 grid((M+63)/64, (Ncl+63)/64, batch);
  gemm_kernel<TRANSA,TRIUA,TRIUB,EPI><<<grid, 256, 0, st>>>(
      A,lda,B,ldb,C,ldc,M,Ncl,K,sA,sB,sC,scale,bias,kstep,scalp);
}

// ---------------------------------------------------------------- split-bf16 MFMA GEMM (powers)
// v = (Ah+Al)[kN,kN] @ ((Bth+Btl)[kN,kN])^T dropping lo*lo  (~fp32 accuracy)
// psq += p0*v; qsq += p1*v; Oh/Ol = hi/lo split of v. A and B^T upper-tri.
__global__ __launch_bounds__(256)
void bgemm2_kernel(const u16* __restrict__ Ah, const u16* __restrict__ Al,
                   const u16* __restrict__ Bh, const u16* __restrict__ Bl,
                   float* __restrict__ C, float* __restrict__ C2,
                   u16* __restrict__ Oh, u16* __restrict__ Ol,
                   float p0, float p1)
{
  constexpr int TM=64, TN=64, BK=32;
  __shared__ u16 Ash[TM][40], Asl[TM][40], Bsh[TN][40], Bsl[TN][40];
  const int tid = threadIdx.x;
  const int m0 = blockIdx.x*TM, n0 = blockIdx.y*TN;
  const int w = tid>>6, lane = tid&63;
  const int wm = (w&1)*32, wn = (w>>1)*32;
  const int quad = lane>>4, lm = lane&15;
  f32x4 acc00={}, acc01={}, acc10={}, acc11={};
  const bool skip = (m0 > n0 + TN - 1);
  int k0 = m0;
  const int kEnd = min(kN, n0+TN);
  const int ar = tid>>2, ac = (tid&3)*8;
  if (!skip){
    for (; k0 < kEnd; k0 += BK){
      uint4 avh={0,0,0,0}, avl={0,0,0,0}, bvh={0,0,0,0}, bvl={0,0,0,0};
      int gk = k0 + ac;
      if (m0+ar < kN && gk < kN){
        avh = *(const uint4*)(Ah + (long)(m0+ar)*kN + gk);
        avl = *(const uint4*)(Al + (long)(m0+ar)*kN + gk);
      }
      if (n0+ar < kN && gk < kN){
        bvh = *(const uint4*)(Bh + (long)(n0+ar)*kN + gk);
        bvl = *(const uint4*)(Bl + (long)(n0+ar)*kN + gk);
      }
      __syncthreads();
      *(uint4*)&Ash[ar][ac] = avh; *(uint4*)&Asl[ar][ac] = avl;
      *(uint4*)&Bsh[ar][ac] = bvh; *(uint4*)&Bsl[ar][ac] = bvl;
      __syncthreads();
      short8 a0h = *(const short8*)&Ash[wm+lm][quad*8];
      short8 a1h = *(const short8*)&Ash[wm+16+lm][quad*8];
      short8 a0l = *(const short8*)&Asl[wm+lm][quad*8];
      short8 a1l = *(const short8*)&Asl[wm+16+lm][quad*8];
      short8 b0h = *(const short8*)&Bsh[wn+lm][quad*8];
      short8 b1h = *(const short8*)&Bsh[wn+16+lm][quad*8];
      short8 b0l = *(const short8*)&Bsl[wn+lm][quad*8];
      short8 b1l = *(const short8*)&Bsl[wn+16+lm][quad*8];
      acc00 = __builtin_amdgcn_mfma_f32_16x16x32_bf16(a0h,b0h,acc00,0,0,0);
      acc00 = __builtin_amdgcn_mfma_f32_16x16x32_bf16(a0h,b0l,acc00,0,0,0);
      acc00 = __builtin_amdgcn_mfma_f32_16x16x32_bf16(a0l,b0h,acc00,0,0,0);
      acc01 = __builtin_amdgcn_mfma_f32_16x16x32_bf16(a0h,b1h,acc01,0,0,0);
      acc01 = __builtin_amdgcn_mfma_f32_16x16x32_bf16(a0h,b1l,acc01,0,0,0);
      acc01 = __builtin_amdgcn_mfma_f32_16x16x32_bf16(a0l,b1h,acc01,0,0,0);
      acc10 = __builtin_amdgcn_mfma_f32_16x16x32_bf16(a1h,b0h,acc10,0,0,0);
      acc10 = __builtin_amdgcn_mfma_f32_16x16x32_bf16(a1h,b0l,acc10,0,0,0);
      acc10 = __builtin_amdgcn_mfma_f32_16x16x32_bf16(a1l,b0h,acc10,0,0,0);
      acc11 = __builtin_amdgcn_mfma_f32_16x16x32_bf16(a1h,b1h,acc11,0,0,0);
      acc11 = __builtin_amdgcn_mfma_f32_16x16x32_bf16(a1h,b1l,acc11,0,0,0);
      acc11 = __builtin_amdgcn_mfma_f32_16x16x32_bf16(a1l,b1h,acc11,0,0,0);
    }
  }
  f32x4 accs[2][2] = {{acc00, acc01},{acc10, acc11}};
  #pragma unroll
  for (int ti=0; ti<2; ++ti){
    #pragma unroll
    for (int tj=0; tj<2; ++tj){
      #pragma unroll
      for (int r=0; r<4; ++r){
        int gm = m0 + wm + ti*16 + quad*4 + r;
        int gn = n0 + wn + tj*16 + lm;
        if (gm >= kN || gn >= kN) continue;
        float v = accs[ti][tj][r];
        long off = (long)gm*kN + gn;
        C[off]  += p0*v;
        C2[off] += p1*v;
        u16 h = f2bf(v);
        Oh[off] = h;
        Ol[off] = f2bf(v - bf2f(h));
      }
    }
  }
}

// ---- transposed pade init: dst[c][r] = hi/lo split of (I - tri/normA)[r][c]
__global__ __launch_bounds__(256)
void transpose_pade_kernel(const float* __restrict__ tri, const double* __restrict__ frob2,
                           u16* __restrict__ dh, u16* __restrict__ dl)
{
  __shared__ float t[32][33];
  const float rn = (float)(1.0 / sqrt(frob2[0]));
  int r0 = blockIdx.y*32, c0 = blockIdx.x*32;
  int tr = threadIdx.x>>5, tc = threadIdx.x&31;
  for (int i=tr; i<32; i+=8){
    int r = r0+i, c = c0+tc;
    float eye = (r==c) ? 1.f : 0.f;
    t[i][tc] = eye - tri[(long)r*kN + c]*rn;
  }
  __syncthreads();
  for (int i=tr; i<32; i+=8){
    int c = c0+i, r = r0+tc;
    float v = t[tc][i];
    u16 h = f2bf(v);
    dh[(long)c*kN + r] = h;
    dl[(long)c*kN + r] = f2bf(v - bf2f(h));
  }
}

// ---------------------------------------------------------------- mask staircase kernels
__global__ void edge_gmax_kernel(const int* __restrict__ e0, const int* __restrict__ e1,
                                 const int* __restrict__ e2, const int* __restrict__ e3,
                                 int* __restrict__ g){
  const int* eis[4] = {e0,e1,e2,e3};
  const int e = blockIdx.y;
  const int* ei = eis[e];
  int j = blockIdx.x*256 + threadIdx.x;
  if (j >= kNE) return;
  int s = ei[j], d = ei[kNE + j];
  atomicMax(&g[e*kN + d], s);
}

__global__ __launch_bounds__(256)
void scan_gh_kernel(int* __restrict__ g, int* __restrict__ h){
  __shared__ int gs[kN];
  const int e = blockIdx.x;
  for (int i = threadIdx.x; i < kN; i += 256) gs[i] = g[e*kN + i];
  __syncthreads();
  if (threadIdx.x == 0){
    int m = -1;
    for (int i = 0; i < kN; ++i){ m = max(m, gs[i]); gs[i] = m; }
  }
  __syncthreads();
  for (int i = threadIdx.x; i < kN; i += 256) g[e*kN + i] = gs[i];
  for (int d = threadIdx.x; d < kN; d += 256){
    int lo = 0, hi = kN;
    while (lo < hi){ int mid = (lo+hi)>>1; if (gs[mid] >= d) hi = mid; else lo = mid+1; }
    h[e*kN + d] = lo;
  }
}

// in-place scans over Y planes: z<4 -> prefix over n; z>=4 -> suffix
__global__ __launch_bounds__(256)
void scan_msg_kernel(float* __restrict__ Y){
  const int plane = blockIdx.x;          // 0..7
  const int f = threadIdx.x;
  if (f >= kH) return;
  float* P = Y + (long)plane*kNH + f;
  float acc = 0.f;
  if (plane < 4){
    for (int n = 0; n < kN; n += 4){
      float v0 = P[(long)(n+0)*kH], v1 = P[(long)(n+1)*kH];
      float v2 = P[(long)(n+2)*kH], v3 = P[(long)(n+3)*kH];
      acc += v0; P[(long)(n+0)*kH] = acc;
      acc += v1; P[(long)(n+1)*kH] = acc;
      acc += v2; P[(long)(n+2)*kH] = acc;
      acc += v3; P[(long)(n+3)*kH] = acc;
    }
  } else {
    for (int n = kN-1; n >= 0; n -= 4){
      float v0 = P[(long)(n-0)*kH], v1 = P[(long)(n-1)*kH];
      float v2 = P[(long)(n-2)*kH], v3 = P[(long)(n-3)*kH];
      acc += v0; P[(long)(n-0)*kH] = acc;
      acc += v1; P[(long)(n-1)*kH] = acc;
      acc += v2; P[(long)(n-2)*kH] = acc;
      acc += v3; P[(long)(n-3)*kH] = acc;
    }
  }
}

__global__ __launch_bounds__(256)
void gather_dense_kernel(const float* __restrict__ Y, const int* __restrict__ g,
                         const int* __restrict__ h, float* __restrict__ tnh){
  long idx = (long)blockIdx.x*256 + threadIdx.x;
  if (idx >= kNH) return;
  int n = (int)(idx / kH), f = (int)(idx % kH);
  float v = 0.f;
  #pragma unroll
  for (int e = 0; e < 4; ++e){
    int gi = g[e*kN + n];
    if (gi >= 0) v += Y[(long)e*kNH + (long)gi*kH + f];
    int hi = h[e*kN + n];
    if (hi < kN) v += Y[(long)(4+e)*kNH + (long)hi*kH + f];
  }
  tnh[idx] += 0.5f*v;
}

// ---------------------------------------------------------------- small kernels
__global__ void combine_root_kernel(const float* __restrict__ Y, const float* __restrict__ b,
                                    float* __restrict__ out){
  long idx = (long)blockIdx.x*256 + threadIdx.x;
  if (idx >= kNH) return;
  int f = (int)(idx % kH);
  float v = 0.f;
  #pragma unroll
  for (int e=0;e<4;++e) {
    v += Y[(long)(8+e)*kNH + idx];
    v += (1.f-kAl)*b[(0*4+e)*kH + f] + kAl*b[(1*4+e)*kH + f] + b[(2*4+e)*kH + f];
  }
  out[idx] = v;
}

__global__ __launch_bounds__(256)
void scatter_kernel(const int* __restrict__ e0, const int* __restrict__ e1,
                    const int* __restrict__ e2, const int* __restrict__ e3,
                    const float* __restrict__ Y, float* __restrict__ out){
  const int* eis[4] = {e0,e1,e2,e3};
  const int e = blockIdx.y;
  const int* ei = eis[e];
  long idx = (long)blockIdx.x*256 + threadIdx.x;
  if (idx >= (long)kNE*kH) return;
  int j = (int)(idx / kH), f = (int)(idx % kH);
  int s = ei[j], d = ei[kNE + j];
  float m_in  = Y[((long)e*kN + s)*kH + f];
  float m_out = Y[((long)(4+e)*kN + d)*kH + f];
  unsafeAtomicAdd(&out[(long)d*kH + f], (1.f-kAl)*m_in);
  unsafeAtomicAdd(&out[(long)s*kH + f], kAl*m_out);
}

// (sum, sumsq) partials — kRB blocks
__global__ __launch_bounds__(256)
void reduce2_part_kernel(const float* __restrict__ x, long n, double* __restrict__ part){
  __shared__ double ss[256], qq[256];
  double s=0.0, q=0.0;
  for (long i = (long)blockIdx.x*256 + threadIdx.x; i < n; i += (long)gridDim.x*256){
    double v = x[i]; s += v; q += v*v;
  }
  ss[threadIdx.x]=s; qq[threadIdx.x]=q;
  __syncthreads();
  for (int h=128; h>0; h>>=1){
    if ((int)threadIdx.x < h){ ss[threadIdx.x]+=ss[threadIdx.x+h]; qq[threadIdx.x]+=qq[threadIdx.x+h]; }
    __syncthreads();
  }
  if (threadIdx.x==0){ part[2*blockIdx.x]=ss[0]; part[2*blockIdx.x+1]=qq[0]; }
}

// graph layernorm with inline final reduction of the kRB partials
__global__ __launch_bounds__(256)
void apply_ln_kernel(const float* __restrict__ x, float* __restrict__ y,
                     const float* __restrict__ ln, const double* __restrict__ part){
  __shared__ double ss[kRB], qq[kRB];
  int t = threadIdx.x;
  if (t < kRB){ ss[t] = part[2*t]; qq[t] = part[2*t+1]; }
  __syncthreads();
  for (int h=kRB/2; h>0; h>>=1){
    if (t < h){ ss[t]+=ss[t+h]; qq[t]+=qq[t+h]; }
    __syncthreads();
  }
  long idx = (long)blockIdx.x*256 + t;
  if (idx >= kNH) return;
  double mu  = ss[0] / (double)kNH;
  double var = qq[0] / (double)kNH - mu*mu;
  float rs = rsqrtf((float)var + kEps);
  int f = (int)(idx % kH);
  y[idx] = (x[idx] - (float)mu) * rs * ln[f] + ln[kH + f];
}

// pair + fused frobenius sumsq (atomic f64 into frob2; zero it first!)
__global__ __launch_bounds__(256)
void pair_kernel(const float* __restrict__ z, const float* __restrict__ linW,
                 const float* __restrict__ linb, float* __restrict__ tri,
                 double* __restrict__ frob2){
  __shared__ float zi[16][201], zj[16][201], w[208];
  __shared__ float red[256];
  const int i0 = blockIdx.y*16, j0 = blockIdx.x*16;
  const int tid = threadIdx.x;
  const int ti = tid >> 4, tj = tid & 15;
  const int i = i0+ti, j = j0+tj;
  if (i0 > j0 + 15) { tri[(long)i*kN + j] = 0.f; return; }
  for (int idx = tid; idx < 16*kH; idx += 256){
    int r = idx / kH, c = idx % kH;
    zi[r][c] = z[(long)(i0+r)*kH + c];
    zj[r][c] = z[(long)(j0+r)*kH + c];
  }
  if (tid < kH) w[tid] = linW[tid];
  __syncthreads();
  float g = 0.f;
  if (i <= j){
    float s = linb[0];
    #pragma unroll 4
    for (int k=0;k<kH;++k){ float d = zi[ti][k]-zj[tj][k]; s = fmaf(d*d, w[k], s); }
    g = 1.f/(1.f + expf(-s));
  }
  tri[(long)i*kN + j] = g;
  red[tid] = g*g;
  __syncthreads();
  for (int h=128; h>0; h>>=1){
    if (tid < h) red[tid] += red[tid+h];
    __syncthreads();
  }
  if (tid == 0) unsafeAtomicAdd(frob2, (double)red[0]);
}

__global__ void init_pade_kernel(const float* __restrict__ tri,
                                 u16* __restrict__ papp_h, u16* __restrict__ papp_l,
                                 float* __restrict__ psq, float* __restrict__ qsq,
                                 const double* __restrict__ frob2,
                                 float P0, float P1, float Q0, float Q1){
  int idx = blockIdx.x*256 + threadIdx.x;
  if (idx >= (int)kNN) return;
  int i = idx / kN, j = idx % kN;
  float rn = (float)(1.0 / sqrt(frob2[0]));
  float eye = (i==j) ? 1.f : 0.f;
  float pa = eye - tri[idx]*rn;
  u16 h = f2bf(pa);
  papp_h[idx] = h;
  papp_l[idx] = f2bf(pa - bf2f(h));
  psq[idx] = P0*eye + P1*pa;
  qsq[idx] = Q0*eye + Q1*pa;
}

// ---- invert the 16 diagonal 50x50 upper-tri blocks of U into W (W pre-zeroed)
__global__ __launch_bounds__(64)
void invdiag_kernel(const float* __restrict__ U, float* __restrict__ W){
  __shared__ float Us[kDB][kDB+1];
  __shared__ float Xs[kDB][kDB+1];
  const int base = blockIdx.x * kDB;
  const int tid = threadIdx.x;
  for (int idx = tid; idx < kDB*kDB; idx += 64){
    int r = idx / kDB, c = idx % kDB;
    Us[r][c] = U[(long)(base+r)*kN + base + c];
  }
  __syncthreads();
  const int c = tid;
  for (int i = kDB-1; i >= 0; --i){
    if (c < kDB){
      float x;
      if (c < i) x = 0.f;
      else {
        float s = 0.f;
        for (int k = i+1; k < kDB; ++k) s = fmaf(Us[i][k], Xs[k][c], s);
        x = (((c==i)?1.f:0.f) - s) / Us[i][i];
      }
      Xs[i][c] = x;
    }
    __syncthreads();
  }
  for (int idx = tid; idx < kDB*kDB; idx += 64){
    int r = idx / kDB, cc = idx % kDB;
    W[(long)(base+r)*kN + base + cc] = Xs[r][cc];
  }
}

// ---- fused merge for level S: one block per pair.
// W[top,bot] = -Wtop @ (U_tb @ Wbot); all S x S at global stride kN.
template<int S>
__global__ __launch_bounds__(256)
void merge_fused_kernel(const float* __restrict__ U, float* __restrict__ W){
  __shared__ float Us[S][S+1];   // Utb, later reused as Wtop
  __shared__ float Wb[S][S+1];   // Wbot
  __shared__ float T[S][S+1];
  const long base = (long)blockIdx.x * (2*S) * (kN+1);
  const int tid = threadIdx.x;
  for (int idx = tid; idx < S*S; idx += 256){
    int r = idx / S, c = idx % S;
    Us[r][c] = U[base + (long)r*kN + S + c];
    Wb[r][c] = W[base + (long)(S+r)*kN + S + c];
  }
  __syncthreads();
  for (int idx = tid; idx < S*S; idx += 256){
    int r = idx / S, c = idx % S;
    float s = 0.f;
    for (int k = 0; k <= c; ++k) s = fmaf(Us[r][k], Wb[k][c], s);  // Wbot upper-tri
    T[r][c] = s;
  }
  __syncthreads();
  for (int idx = tid; idx < S*S; idx += 256){
    int r = idx / S, c = idx % S;
    Us[r][c] = W[base + (long)r*kN + c];   // Wtop
  }
  __syncthreads();
  for (int idx = tid; idx < S*S; idx += 256){
    int r = idx / S, c = idx % S;
    float s = 0.f;
    for (int k = r; k < S; ++k) s = fmaf(Us[r][k], T[k][c], s);    // Wtop upper-tri
    W[base + (long)r*kN + S + c] = -s;
  }
}

__global__ __launch_bounds__(256)
void pool_head_kernel(const float* __restrict__ z2, const float* __restrict__ W,
                      const float* __restrict__ b, float* __restrict__ out){
  __shared__ float x2[kH];
  __shared__ float lg[kNC];
  int t = threadIdx.x;
  if (t < kH){
    float s = 0.f;
    for (int n = 0; n < kN; ++n) s += z2[(long)n*kH + t];
    float v = s * (1.f/(float)kN);
    x2[t] = v;
    out[t] = v;
  }
  __syncthreads();
  if (t < kNC){
    float s = b[t];
    for (int f = 0; f < kH; ++f) s = fmaf(x2[f], W[f*kNC + t], s);
    lg[t] = s;
  }
  __syncthreads();
  if (t == 0){
    float m = -1e30f;
    for (int c=0;c<kNC;++c) m = fmaxf(m, lg[c]);
    float se = 0.f;
    for (int c=0;c<kNC;++c) se += expf(lg[c]-m);
    float lse = m + logf(se);
    for (int c=0;c<kNC;++c) out[kH + c] = lg[c]-lse;
  }
}

// ---------------------------------------------------------------- host: Pade [5/5] of sqrt(1-x)
static void pade_coeffs(float* P, float* Q){
  double b[11]; b[0] = 1.0;
  for (int k=1;k<11;++k) b[k] = b[k-1]*(0.5-(k-1))/k;
  double c[11];
  for (int k=0;k<11;++k) c[k] = b[k]*((k&1)?-1.0:1.0);
  double A[5][5], rhs[5];
  for (int i=0;i<5;++i){ for (int j=0;j<5;++j) A[i][j] = c[5+i-j]; rhs[i] = -c[6+i]; }
  for (int col=0; col<5; ++col){
    int p = col;
    for (int r=col+1;r<5;++r) if (fabs(A[r][col]) > fabs(A[p][col])) p = r;
    if (p != col){
      for (int j=0;j<5;++j){ double t=A[col][j]; A[col][j]=A[p][j]; A[p][j]=t; }
      double t=rhs[col]; rhs[col]=rhs[p]; rhs[p]=t;
    }
    for (int r=col+1;r<5;++r){
      double f = A[r][col]/A[col][col];
      for (int j=col;j<5;++j) A[r][j] -= f*A[col][j];
      rhs[r] -= f*rhs[col];
    }
  }
  double q[6]; q[0] = 1.0;
  for (int r=4;r>=0;--r){
    double s = rhs[r];
    for (int j=r+1;j<5;++j) s -= A[r][j]*q[1+j];
    q[1+r] = s/A[r][r];
  }
  double p[6];
  for (int k=0;k<6;++k){
    double s = 0.0; int jm = k<5?k:5;
    for (int j=0;j<=jm;++j) s += q[j]*c[k-j];
    p[k] = s;
  }
  for (int k=0;k<6;++k){ P[k]=(float)p[k]; Q[k]=(float)q[k]; }
}

// ---------------------------------------------------------------- launch
extern "C" void kernel_launch(void* const* d_in, const int* in_sizes, int n_in,
                              void* d_out, int out_size, void* d_ws, size_t ws_size,
                              hipStream_t stream)
{
  const float* x_note = (const float*)d_in[0];
  const float* embW   = (const float*)d_in[1];
  const float* embB   = (const float*)d_in[2];
  const float* g1w1   = (const float*)d_in[3];
  const float* g1b1   = (const float*)d_in[4];
  const float* g1w2   = (const float*)d_in[5];
  const float* g1b2   = (const float*)d_in[6];
  const float* g1ln   = (const float*)d_in[7];
  const float* g2w1   = (const float*)d_in[8];
  const float* g2b1   = (const float*)d_in[9];
  const float* g2w2   = (const float*)d_in[10];
  const float* g2b2   = (const float*)d_in[11];
  const float* g2ln   = (const float*)d_in[12];
  const float* linW   = (const float*)d_in[13];
  const float* linb   = (const float*)d_in[14];
  const float* clfW   = (const float*)d_in[15];
  const float* clfb   = (const float*)d_in[16];
  const int*  e0     = (const int*)d_in[17];
  const int*  e1     = (const int*)d_in[18];
  const int*  e2     = (const int*)d_in[19];
  const int*  e3     = (const int*)d_in[20];
  float* out = (float*)d_out;

  // fp32 region (float offsets); header: scald @0, partd @512B
  constexpr long o_h0   = 2176;
  constexpr long o_h1   = o_h0   + (long)kN*kE;
  constexpr long o_h2   = o_h1   + (long)kN*kE;
  constexpr long o_tnh  = o_h2   + (long)kN*kE;
  constexpr long o_zmid = o_tnh  + kNH;
  constexpr long o_z0   = o_zmid + kNH;
  constexpr long o_z1   = o_z0   + kNH;
  constexpr long o_z2   = o_z1   + kNH;
  constexpr long o_big  = o_z2   + kNH;             // 4*kNN floats: Y planes / power bf16 scratch
  constexpr long o_tri  = o_big  + 4*kNN;           // pair out / merge scratch
  constexpr long o_papp = o_tri  + kNN;             // (spare)
  constexpr long o_winv = o_papp + kNN;
  constexpr long o_psq  = o_winv + kNN;
  constexpr long o_qsq  = o_psq  + kNN;
  constexpr long o_g    = o_qsq  + kNN;             // int g[4][kN]
  constexpr long o_hh   = o_g    + 4*kN;            // int h[4][kN]
  constexpr long o_end  = o_hh   + 4*kN;

  if (ws_size < (size_t)o_end*sizeof(float) || out_size < 215 + 2*(int)kNN || n_in < 21){
    fprintf(stderr, "kernel_launch guard: ws=%zu need=%zu out=%d need=%d n_in=%d\n",
            ws_size, (size_t)o_end*sizeof(float), out_size, (int)(215+2*kNN), n_in);
    hipMemsetAsync(d_out, 0, (size_t)out_size*sizeof(float), stream);
    return;
  }

  float* ws = (float*)d_ws;
  double* scald = (double*)d_ws;
  double* partd = (double*)((char*)d_ws + 512);
  float *h0=ws+o_h0, *h1=ws+o_h1, *h2=ws+o_h2, *tnh=ws+o_tnh,
        *zmid=ws+o_zmid, *z0=ws+o_z0, *z1=ws+o_z1, *z2=ws+o_z2, *big=ws+o_big,
        *tri=ws+o_tri, *winv=ws+o_winv, *psq=ws+o_psq, *qsq=ws+o_qsq;
  int* gArr = (int*)(ws + o_g);
  int* hArr = (int*)(ws + o_hh);
  // power-phase split scratch aliased inside big (8 u16 planes = 4*kNN floats)
  u16* papp_h = (u16*)big;
  u16* papp_l = papp_h + kNN;
  u16* pT_h   = papp_l + kNN;
  u16* pT_l   = pT_h + kNN;
  u16* pwA_h  = pT_l + kNN;
  u16* pwA_l  = pwA_h + kNN;
  u16* pwB_h  = pwA_l + kNN;
  u16* pwB_l  = pwB_h + kNN;

  float P[6], Q[6];
  pade_coeffs(P, Q);

  auto eg = [](long n){ return dim3((unsigned)((n+255)/256)); };

  auto do_ln = [&](const float* src, float* dst, const float* lnp){
    reduce2_part_kernel<<<kRB,256,0,stream>>>(src, kNH, partd);
    apply_ln_kernel<<<eg(kNH),256,0,stream>>>(src, dst, lnp, partd);
  };
  auto sparse_layer = [&](const float* hin, int K, const float* W, const float* b,
                          const float* lnp, float* zout){
    launch_gemm<false,false,false,EPI_NONE>(stream, hin, K, W, kH, big, kH, kN, kH, K, 12,
                                            0, (long)K*kH, kNH, 0.f);
    combine_root_kernel<<<eg(kNH),256,0,stream>>>(big, b, tnh);
    scatter_kernel<<<dim3((unsigned)(((long)kNE*kH+255)/256),4),256,0,stream>>>(e0,e1,e2,e3, big, tnh);
    do_ln(tnh, zout, lnp);
  };
  auto dense_layer = [&](const float* hin, int K, const float* W, const float* b,
                         const float* lnp, float* zout){
    launch_gemm<false,false,false,EPI_NONE>(stream, hin, K, W, kH, big, kH, kN, kH, K, 12,
                                            0, (long)K*kH, kNH, 0.f);
    combine_root_kernel<<<eg(kNH),256,0,stream>>>(big, b, tnh);
    scan_msg_kernel<<<8,256,0,stream>>>(big);
    gather_dense_kernel<<<eg(kNH),256,0,stream>>>(big, gArr, hArr, tnh);
    do_ln(tnh, zout, lnp);
  };
  auto blocked_trsm = [&](float* SoutDst){
    hipMemsetAsync(winv, 0, (size_t)kNN*sizeof(float), stream);
    invdiag_kernel<<<dim3(kN/kDB),64,0,stream>>>(qsq, winv);
    merge_fused_kernel<50><<<dim3(kN/100),256,0,stream>>>(qsq, winv);   // level s=50
    for (int s = 100; s < kN; s *= 2){
      int npairs = kN / (2*s);
      long step = (long)2*s*kN + 2*s;
      launch_gemm<false,false,true,EPI_NONE>(stream,
          qsq + s, kN, winv + (long)s*kN + s, kN, tri, s,
          s, s, s, npairs, step, step, (long)s*s, 0.f);
      launch_gemm<false,true,false,EPI_SCALE>(stream,
          winv, kN, tri, s, winv + s, kN,
          s, s, s, npairs, step, (long)s*s, step, -1.f);
    }
    // S = (winv @ psq) * sqrt(normA) atomically into d_out region (pre-zeroed),
    // K-split into 8 chunks of 100 for parallelism.
    launch_gemm<false,true,true,EPI_ACC>(stream,
        winv, kN, psq, kN, SoutDst, kN, kN, kN, 100, 8,
        100, (long)100*kN, 0, 1.f, nullptr, 100, scald+3);
  };
  auto run_pair_mpa = [&](const float* z, float* SoutDst){
    hipMemsetAsync((char*)d_ws + 24, 0, 8, stream);            // scald[3] = 0
    pair_kernel<<<dim3(50,50),256,0,stream>>>(z, linW, linb, tri, scald+3);
    init_pade_kernel<<<eg(kNN),256,0,stream>>>(tri, papp_h, papp_l, psq, qsq, scald+3,
                                               P[0],P[1],Q[0],Q[1]);
    transpose_pade_kernel<<<dim3(25,25),256,0,stream>>>(tri, scald+3, pT_h, pT_l);
    dim3 g13(13,13,1);
    bgemm2_kernel<<<g13,256,0,stream>>>(papp_h,papp_l, pT_h,pT_l, psq,qsq, pwA_h,pwA_l, P[2],Q[2]);
    bgemm2_kernel<<<g13,256,0,stream>>>(pwA_h,pwA_l,  pT_h,pT_l, psq,qsq, pwB_h,pwB_l, P[3],Q[3]);
    bgemm2_kernel<<<g13,256,0,stream>>>(pwB_h,pwB_l,  pT_h,pT_l, psq,qsq, pwA_h,pwA_l, P[4],Q[4]);
    bgemm2_kernel<<<g13,256,0,stream>>>(pwA_h,pwA_l,  pT_h,pT_l, psq,qsq, pwB_h,pwB_l, P[5],Q[5]);
    blocked_trsm(SoutDst);
  };
  // h_out = S @ h_in, K-split into 8 chunks (S upper-tri, fp32, atomic acc)
  auto s_times_h = [&](const float* Sf, const float* hin, float* hout){
    hipMemsetAsync(hout, 0, (size_t)kN*kE*sizeof(float), stream);
    launch_gemm<false,true,false,EPI_ACC>(stream,
        Sf, kN, hin, kE, hout, kE, kN, kE, 100, 8,
        100, (long)100*kE, 0, 1.f, nullptr, 100);
  };

  float* S1f = out + 215;
  float* S2f = out + 215 + kNN;

  // ---- once: zero S output regions, build staircase g/h
  hipMemsetAsync(S1f, 0, (size_t)(2*kNN)*sizeof(float), stream);
  hipMemsetAsync(gArr, 0xFF, (size_t)(4*kN)*sizeof(int), stream);   // -1
  edge_gmax_kernel<<<dim3((kNE+255)/256,4),256,0,stream>>>(e0,e1,e2,e3, gArr);
  scan_gh_kernel<<<4,256,0,stream>>>(gArr, hArr);

  // ---- embed
  launch_gemm<false,false,false,EPI_BIAS>(stream, x_note, kF, embW, kE, h0, kE, kN, kE, kF, 1,
                                          0,0,0, 0.f, embB);

  // ---- GNN1 (sparse)
  sparse_layer(h0,  kE, g1w1, g1b1, g1ln,        zmid);
  sparse_layer(zmid,kH, g1w2, g1b2, g1ln + 2*kH, z0);

  // ---- S1
  run_pair_mpa(z0, S1f);

  // ---- h1 = S1 @ h0
  s_times_h(S1f, h0, h1);

  // ---- GNN2 #1 (dense; mask1 == staircase(g,h))
  dense_layer(h1,  kE, g2w1, g2b1, g2ln,        zmid);
  dense_layer(zmid,kH, g2w2, g2b2, g2ln + 2*kH, z1);

  // ---- S2
  run_pair_mpa(z1, S2f);

  // ---- h2 = S2 @ h1
  s_times_h(S2f, h1, h2);

  // ---- GNN2 #2 (dense; mask2 == mask1 — same staircase)
  dense_layer(h2,  kE, g2w1, g2b1, g2ln,        zmid);
  dense_layer(zmid,kH, g2w2, g2b2, g2ln + 2*kH, z2);

  // ---- pool + classifier + log_softmax
  pool_head_kernel<<<dim3(1),256,0,stream>>>(z2, clfW, clfb, out);
}

// Round 10
// 1588.110 us; speedup vs baseline: 3.1227x; 1.0037x over previous
//
#include <hip/hip_runtime.h>
#include <hip/hip_bf16.h>
#include <math.h>
#include <stdio.h>

static constexpr int   kN  = 800;    // nodes
static constexpr int   kF  = 111;    // input features
static constexpr int   kE  = 32;     // embed dim
static constexpr int   kH  = 200;    // hidden
static constexpr int   kNC = 15;     // classes
static constexpr int   kNE = 8000;   // edges per type
static constexpr long  kNN = (long)kN*kN;   // 640000
static constexpr long  kNH = (long)kN*kH;   // 160000
static constexpr float kAl  = 0.5f;  // ALPHA
static constexpr float kEps = 1e-5f;
static constexpr int   kRB  = 64;    // reduction blocks
static constexpr int   kDB  = 50;    // trsm diagonal block size (800 = 16 * 50)

typedef unsigned short u16;
typedef __attribute__((ext_vector_type(8))) short short8;
typedef __attribute__((ext_vector_type(4))) float f32x4;

__device__ __forceinline__ u16 f2bf(float v){
  __hip_bfloat16 b = __float2bfloat16(v);
  return *reinterpret_cast<u16*>(&b);
}
__device__ __forceinline__ float bf2f(u16 h){
  unsigned int u = ((unsigned int)h) << 16;
  float f; __builtin_memcpy(&f, &u, 4);
  return f;
}

enum { EPI_NONE=0, EPI_BIAS=1, EPI_SCALE=4, EPI_ACC=6 };

// ---------------------------------------------------------------- fp32 GEMM
// C[M,N] = A * B, row strides lda/ldb/ldc.
// TRIUA: A[m,kglob]==0 for kglob<m (exact); TRIUB: B[kglob,n]==0 for kglob>n.
// kstep!=0: K-split — blockIdx.z is a K-chunk; kbase=z*kstep; A/B pre-offset
// via sA/sB; triangular clips in global coords. EPI_ACC: atomic C += scale*v,
// scale *= sqrt(sqrt(scalp[0])) if scalp given; skip blocks return early.
template<bool TRANSA, bool TRIUA, bool TRIUB, int EPI>
__global__ __launch_bounds__(256)
void gemm_kernel(const float* __restrict__ A, int lda,
                 const float* __restrict__ B, int ldb,
                 float* __restrict__ C, int ldc,
                 int M, int Ncl, int K,
                 long sA, long sB, long sC, float scale,
                 const float* __restrict__ bias, int kstep,
                 const double* __restrict__ scalp)
{
  constexpr int TM=64, TN=64, TK=16;
  A += (long)blockIdx.z * sA;
  B += (long)blockIdx.z * sB;
  C += (long)blockIdx.z * sC;
  __shared__ float As[TK][TM+4];
  __shared__ float Bs[TK][TN+4];
  const int tid = threadIdx.x;
  const int tn4 = (tid & 15)*4, tm4 = (tid >> 4)*4;
  const int m0 = blockIdx.x * TM, n0 = blockIdx.y * TN;
  float acc[4][4] = {};
  const int kbase = kstep ? (int)blockIdx.z * kstep : 0;
  int k0 = TRIUA ? max(m0 - kbase, 0) : 0;
  int kEnd = TRIUB ? min(K, n0 + TN - kbase) : K;
  const bool skip = (k0 >= kEnd);
  if (skip && EPI == EPI_ACC) return;
  if (!skip) {
    for (; k0 < kEnd; k0 += TK) {
      #pragma unroll
      for (int u=0; u<4; ++u) {
        int idx = tid + 256*u;
        if (!TRANSA) {
          int m = idx >> 4, ka = idx & 15;
          int gm = m0+m, gk = k0+ka;
          As[ka][m] = (gm < M && gk < K) ? A[(long)gm*lda + gk] : 0.f;
        } else {
          int ka = idx >> 6, m = idx & 63;
          int gm = m0+m, gk = k0+ka;
          As[ka][m] = (gm < M && gk < K) ? A[(long)gk*lda + gm] : 0.f;
        }
        int kb = idx >> 6, nb = idx & 63;
        int gk = k0+kb, gn = n0+nb;
        Bs[kb][nb] = (gk < K && gn < Ncl) ? B[(long)gk*ldb + gn] : 0.f;
      }
      __syncthreads();
      #pragma unroll
      for (int kk=0; kk<TK; ++kk) {
        float a[4], b[4];
        #pragma unroll
        for (int u=0;u<4;++u){ a[u]=As[kk][tm4+u]; b[u]=Bs[kk][tn4+u]; }
        #pragma unroll
        for (int i=0;i<4;++i)
          #pragma unroll
          for (int j=0;j<4;++j)
            acc[i][j] = fmaf(a[i], b[j], acc[i][j]);
      }
      __syncthreads();
    }
  }
  float sc = scale;
  if (EPI == EPI_ACC && scalp) sc *= (float)sqrt(sqrt(scalp[0]));
  #pragma unroll
  for (int i=0;i<4;++i) {
    int gm = m0 + tm4 + i;
    if (gm >= M) continue;
    #pragma unroll
    for (int j=0;j<4;++j) {
      int gn = n0 + tn4 + j;
      if (gn >= Ncl) continue;
      float v = acc[i][j];
      long off = (long)gm*ldc + gn;
      if (EPI == EPI_BIAS)       C[off] = v + bias[gn];
      else if (EPI == EPI_SCALE) C[off] = scale*v;
      else if (EPI == EPI_ACC)   unsafeAtomicAdd(&C[off], sc*v);
      else                       C[off] = v;
    }
  }
}

template<bool TRANSA, bool TRIUA, bool TRIUB, int EPI>
static inline void launch_gemm(hipStream_t st,
                               const float* A, int lda, const float* B, int ldb,
                               float* C, int ldc, int M, int Ncl, int K, int batch,
                               long sA, long sB, long sC, float scale,
                               const float* bias = nullptr, int kstep = 0,
                               const double* scalp = nullptr)
{
  dim3 grid((M+63)/64, (Ncl+63)/64, batch);
  gemm_kernel<TRANSA,TRIUA,TRIUB,EPI><<<grid, 256, 0, st>>>(
      A,lda,B,ldb,C,ldc,M,Ncl,K,sA,sB,sC,scale,bias,kstep,scalp);
}

// ---------------------------------------------------------------- split-bf16 MFMA GEMM (powers)
// v = (Ah+Al)[kN,kN] @ ((Bth+Btl)[kN,kN])^T dropping lo*lo  (~fp32 accuracy)
// psq += p0*v; qsq += p1*v; Oh/Ol = hi/lo split of v. A and B^T upper-tri.
__global__ __launch_bounds__(256)
void bgemm2_kernel(const u16* __restrict__ Ah, const u16* __restrict__ Al,
                   const u16* __restrict__ Bh, const u16* __restrict__ Bl,
                   float* __restrict__ C, float* __restrict__ C2,
                   u16* __restrict__ Oh, u16* __restrict__ Ol,
                   float p0, float p1)
{
  constexpr int TM=64, TN=64, BK=32;
  __shared__ u16 Ash[TM][40], Asl[TM][40], Bsh[TN][40], Bsl[TN][40];
  const int tid = threadIdx.x;
  const int m0 = blockIdx.x*TM, n0 = blockIdx.y*TN;
  const int w = tid>>6, lane = tid&63;
  const int wm = (w&1)*32, wn = (w>>1)*32;
  const int quad = lane>>4, lm = lane&15;
  f32x4 acc00={}, acc01={}, acc10={}, acc11={};
  const bool skip = (m0 > n0 + TN - 1);
  int k0 = m0;
  const int kEnd = min(kN, n0+TN);
  const int ar = tid>>2, ac = (tid&3)*8;
  if (!skip){
    for (; k0 < kEnd; k0 += BK){
      uint4 avh={0,0,0,0}, avl={0,0,0,0}, bvh={0,0,0,0}, bvl={0,0,0,0};
      int gk = k0 + ac;
      if (m0+ar < kN && gk < kN){
        avh = *(const uint4*)(Ah + (long)(m0+ar)*kN + gk);
        avl = *(const uint4*)(Al + (long)(m0+ar)*kN + gk);
      }
      if (n0+ar < kN && gk < kN){
        bvh = *(const uint4*)(Bh + (long)(n0+ar)*kN + gk);
        bvl = *(const uint4*)(Bl + (long)(n0+ar)*kN + gk);
      }
      __syncthreads();
      *(uint4*)&Ash[ar][ac] = avh; *(uint4*)&Asl[ar][ac] = avl;
      *(uint4*)&Bsh[ar][ac] = bvh; *(uint4*)&Bsl[ar][ac] = bvl;
      __syncthreads();
      short8 a0h = *(const short8*)&Ash[wm+lm][quad*8];
      short8 a1h = *(const short8*)&Ash[wm+16+lm][quad*8];
      short8 a0l = *(const short8*)&Asl[wm+lm][quad*8];
      short8 a1l = *(const short8*)&Asl[wm+16+lm][quad*8];
      short8 b0h = *(const short8*)&Bsh[wn+lm][quad*8];
      short8 b1h = *(const short8*)&Bsh[wn+16+lm][quad*8];
      short8 b0l = *(const short8*)&Bsl[wn+lm][quad*8];
      short8 b1l = *(const short8*)&Bsl[wn+16+lm][quad*8];
      acc00 = __builtin_amdgcn_mfma_f32_16x16x32_bf16(a0h,b0h,acc00,0,0,0);
      acc00 = __builtin_amdgcn_mfma_f32_16x16x32_bf16(a0h,b0l,acc00,0,0,0);
      acc00 = __builtin_amdgcn_mfma_f32_16x16x32_bf16(a0l,b0h,acc00,0,0,0);
      acc01 = __builtin_amdgcn_mfma_f32_16x16x32_bf16(a0h,b1h,acc01,0,0,0);
      acc01 = __builtin_amdgcn_mfma_f32_16x16x32_bf16(a0h,b1l,acc01,0,0,0);
      acc01 = __builtin_amdgcn_mfma_f32_16x16x32_bf16(a0l,b1h,acc01,0,0,0);
      acc10 = __builtin_amdgcn_mfma_f32_16x16x32_bf16(a1h,b0h,acc10,0,0,0);
      acc10 = __builtin_amdgcn_mfma_f32_16x16x32_bf16(a1h,b0l,acc10,0,0,0);
      acc10 = __builtin_amdgcn_mfma_f32_16x16x32_bf16(a1l,b0h,acc10,0,0,0);
      acc11 = __builtin_amdgcn_mfma_f32_16x16x32_bf16(a1h,b1h,acc11,0,0,0);
      acc11 = __builtin_amdgcn_mfma_f32_16x16x32_bf16(a1h,b1l,acc11,0,0,0);
      acc11 = __builtin_amdgcn_mfma_f32_16x16x32_bf16(a1l,b1h,acc11,0,0,0);
    }
  }
  f32x4 accs[2][2] = {{acc00, acc01},{acc10, acc11}};
  #pragma unroll
  for (int ti=0; ti<2; ++ti){
    #pragma unroll
    for (int tj=0; tj<2; ++tj){
      #pragma unroll
      for (int r=0; r<4; ++r){
        int gm = m0 + wm + ti*16 + quad*4 + r;
        int gn = n0 + wn + tj*16 + lm;
        if (gm >= kN || gn >= kN) continue;
        float v = accs[ti][tj][r];
        long off = (long)gm*kN + gn;
        C[off]  += p0*v;
        C2[off] += p1*v;
        u16 h = f2bf(v);
        Oh[off] = h;
        Ol[off] = f2bf(v - bf2f(h));
      }
    }
  }
}

// ---- transposed pade init: dst[c][r] = hi/lo split of (I - tri/normA)[r][c]
__global__ __launch_bounds__(256)
void transpose_pade_kernel(const float* __restrict__ tri, const double* __restrict__ frob2,
                           u16* __restrict__ dh, u16* __restrict__ dl)
{
  __shared__ float t[32][33];
  const float rn = (float)(1.0 / sqrt(frob2[0]));
  int r0 = blockIdx.y*32, c0 = blockIdx.x*32;
  int tr = threadIdx.x>>5, tc = threadIdx.x&31;
  for (int i=tr; i<32; i+=8){
    int r = r0+i, c = c0+tc;
    float eye = (r==c) ? 1.f : 0.f;
    t[i][tc] = eye - tri[(long)r*kN + c]*rn;
  }
  __syncthreads();
  for (int i=tr; i<32; i+=8){
    int c = c0+i, r = r0+tc;
    float v = t[tc][i];
    u16 h = f2bf(v);
    dh[(long)c*kN + r] = h;
    dl[(long)c*kN + r] = f2bf(v - bf2f(h));
  }
}

// ---- stream S = Sacc * sqrt(normA) into d_out (PCIe-resident) — single pass,
// non-temporal stores, touch d_out exactly once.
__global__ __launch_bounds__(256)
void copy_scale_kernel(const float* __restrict__ src, const double* __restrict__ frob2,
                       float* __restrict__ dst)
{
  const float fac = (float)sqrt(sqrt(frob2[0]));
  long i = (long)blockIdx.x*256 + threadIdx.x;
  if (i < kNN) __builtin_nontemporal_store(src[i]*fac, &dst[i]);
}

// ---------------------------------------------------------------- mask staircase kernels
__global__ void edge_gmax_kernel(const int* __restrict__ e0, const int* __restrict__ e1,
                                 const int* __restrict__ e2, const int* __restrict__ e3,
                                 int* __restrict__ g){
  const int* eis[4] = {e0,e1,e2,e3};
  const int e = blockIdx.y;
  const int* ei = eis[e];
  int j = blockIdx.x*256 + threadIdx.x;
  if (j >= kNE) return;
  int s = ei[j], d = ei[kNE + j];
  atomicMax(&g[e*kN + d], s);
}

__global__ __launch_bounds__(256)
void scan_gh_kernel(int* __restrict__ g, int* __restrict__ h){
  __shared__ int gs[kN];
  const int e = blockIdx.x;
  for (int i = threadIdx.x; i < kN; i += 256) gs[i] = g[e*kN + i];
  __syncthreads();
  if (threadIdx.x == 0){
    int m = -1;
    for (int i = 0; i < kN; ++i){ m = max(m, gs[i]); gs[i] = m; }
  }
  __syncthreads();
  for (int i = threadIdx.x; i < kN; i += 256) g[e*kN + i] = gs[i];
  for (int d = threadIdx.x; d < kN; d += 256){
    int lo = 0, hi = kN;
    while (lo < hi){ int mid = (lo+hi)>>1; if (gs[mid] >= d) hi = mid; else lo = mid+1; }
    h[e*kN + d] = lo;
  }
}

// in-place scans over Y planes: z<4 -> prefix over n; z>=4 -> suffix
__global__ __launch_bounds__(256)
void scan_msg_kernel(float* __restrict__ Y){
  const int plane = blockIdx.x;          // 0..7
  const int f = threadIdx.x;
  if (f >= kH) return;
  float* P = Y + (long)plane*kNH + f;
  float acc = 0.f;
  if (plane < 4){
    for (int n = 0; n < kN; n += 4){
      float v0 = P[(long)(n+0)*kH], v1 = P[(long)(n+1)*kH];
      float v2 = P[(long)(n+2)*kH], v3 = P[(long)(n+3)*kH];
      acc += v0; P[(long)(n+0)*kH] = acc;
      acc += v1; P[(long)(n+1)*kH] = acc;
      acc += v2; P[(long)(n+2)*kH] = acc;
      acc += v3; P[(long)(n+3)*kH] = acc;
    }
  } else {
    for (int n = kN-1; n >= 0; n -= 4){
      float v0 = P[(long)(n-0)*kH], v1 = P[(long)(n-1)*kH];
      float v2 = P[(long)(n-2)*kH], v3 = P[(long)(n-3)*kH];
      acc += v0; P[(long)(n-0)*kH] = acc;
      acc += v1; P[(long)(n-1)*kH] = acc;
      acc += v2; P[(long)(n-2)*kH] = acc;
      acc += v3; P[(long)(n-3)*kH] = acc;
    }
  }
}

__global__ __launch_bounds__(256)
void gather_dense_kernel(const float* __restrict__ Y, const int* __restrict__ g,
                         const int* __restrict__ h, float* __restrict__ tnh){
  long idx = (long)blockIdx.x*256 + threadIdx.x;
  if (idx >= kNH) return;
  int n = (int)(idx / kH), f = (int)(idx % kH);
  float v = 0.f;
  #pragma unroll
  for (int e = 0; e < 4; ++e){
    int gi = g[e*kN + n];
    if (gi >= 0) v += Y[(long)e*kNH + (long)gi*kH + f];
    int hi = h[e*kN + n];
    if (hi < kN) v += Y[(long)(4+e)*kNH + (long)hi*kH + f];
  }
  tnh[idx] += 0.5f*v;
}

// ---------------------------------------------------------------- small kernels
__global__ void combine_root_kernel(const float* __restrict__ Y, const float* __restrict__ b,
                                    float* __restrict__ out){
  long idx = (long)blockIdx.x*256 + threadIdx.x;
  if (idx >= kNH) return;
  int f = (int)(idx % kH);
  float v = 0.f;
  #pragma unroll
  for (int e=0;e<4;++e) {
    v += Y[(long)(8+e)*kNH + idx];
    v += (1.f-kAl)*b[(0*4+e)*kH + f] + kAl*b[(1*4+e)*kH + f] + b[(2*4+e)*kH + f];
  }
  out[idx] = v;
}

__global__ __launch_bounds__(256)
void scatter_kernel(const int* __restrict__ e0, const int* __restrict__ e1,
                    const int* __restrict__ e2, const int* __restrict__ e3,
                    const float* __restrict__ Y, float* __restrict__ out){
  const int* eis[4] = {e0,e1,e2,e3};
  const int e = blockIdx.y;
  const int* ei = eis[e];
  long idx = (long)blockIdx.x*256 + threadIdx.x;
  if (idx >= (long)kNE*kH) return;
  int j = (int)(idx / kH), f = (int)(idx % kH);
  int s = ei[j], d = ei[kNE + j];
  float m_in  = Y[((long)e*kN + s)*kH + f];
  float m_out = Y[((long)(4+e)*kN + d)*kH + f];
  unsafeAtomicAdd(&out[(long)d*kH + f], (1.f-kAl)*m_in);
  unsafeAtomicAdd(&out[(long)s*kH + f], kAl*m_out);
}

// (sum, sumsq) partials — kRB blocks
__global__ __launch_bounds__(256)
void reduce2_part_kernel(const float* __restrict__ x, long n, double* __restrict__ part){
  __shared__ double ss[256], qq[256];
  double s=0.0, q=0.0;
  for (long i = (long)blockIdx.x*256 + threadIdx.x; i < n; i += (long)gridDim.x*256){
    double v = x[i]; s += v; q += v*v;
  }
  ss[threadIdx.x]=s; qq[threadIdx.x]=q;
  __syncthreads();
  for (int h=128; h>0; h>>=1){
    if ((int)threadIdx.x < h){ ss[threadIdx.x]+=ss[threadIdx.x+h]; qq[threadIdx.x]+=qq[threadIdx.x+h]; }
    __syncthreads();
  }
  if (threadIdx.x==0){ part[2*blockIdx.x]=ss[0]; part[2*blockIdx.x+1]=qq[0]; }
}

// graph layernorm with inline final reduction of the kRB partials
__global__ __launch_bounds__(256)
void apply_ln_kernel(const float* __restrict__ x, float* __restrict__ y,
                     const float* __restrict__ ln, const double* __restrict__ part){
  __shared__ double ss[kRB], qq[kRB];
  int t = threadIdx.x;
  if (t < kRB){ ss[t] = part[2*t]; qq[t] = part[2*t+1]; }
  __syncthreads();
  for (int h=kRB/2; h>0; h>>=1){
    if (t < h){ ss[t]+=ss[t+h]; qq[t]+=qq[t+h]; }
    __syncthreads();
  }
  long idx = (long)blockIdx.x*256 + t;
  if (idx >= kNH) return;
  double mu  = ss[0] / (double)kNH;
  double var = qq[0] / (double)kNH - mu*mu;
  float rs = rsqrtf((float)var + kEps);
  int f = (int)(idx % kH);
  y[idx] = (x[idx] - (float)mu) * rs * ln[f] + ln[kH + f];
}

// pair + fused frobenius sumsq (atomic f64 into frob2; zero it first!)
__global__ __launch_bounds__(256)
void pair_kernel(const float* __restrict__ z, const float* __restrict__ linW,
                 const float* __restrict__ linb, float* __restrict__ tri,
                 double* __restrict__ frob2){
  __shared__ float zi[16][201], zj[16][201], w[208];
  __shared__ float red[256];
  const int i0 = blockIdx.y*16, j0 = blockIdx.x*16;
  const int tid = threadIdx.x;
  const int ti = tid >> 4, tj = tid & 15;
  const int i = i0+ti, j = j0+tj;
  if (i0 > j0 + 15) { tri[(long)i*kN + j] = 0.f; return; }
  for (int idx = tid; idx < 16*kH; idx += 256){
    int r = idx / kH, c = idx % kH;
    zi[r][c] = z[(long)(i0+r)*kH + c];
    zj[r][c] = z[(long)(j0+r)*kH + c];
  }
  if (tid < kH) w[tid] = linW[tid];
  __syncthreads();
  float g = 0.f;
  if (i <= j){
    float s = linb[0];
    #pragma unroll 4
    for (int k=0;k<kH;++k){ float d = zi[ti][k]-zj[tj][k]; s = fmaf(d*d, w[k], s); }
    g = 1.f/(1.f + expf(-s));
  }
  tri[(long)i*kN + j] = g;
  red[tid] = g*g;
  __syncthreads();
  for (int h=128; h>0; h>>=1){
    if (tid < h) red[tid] += red[tid+h];
    __syncthreads();
  }
  if (tid == 0) unsafeAtomicAdd(frob2, (double)red[0]);
}

__global__ void init_pade_kernel(const float* __restrict__ tri,
                                 u16* __restrict__ papp_h, u16* __restrict__ papp_l,
                                 float* __restrict__ psq, float* __restrict__ qsq,
                                 const double* __restrict__ frob2,
                                 float P0, float P1, float Q0, float Q1){
  int idx = blockIdx.x*256 + threadIdx.x;
  if (idx >= (int)kNN) return;
  int i = idx / kN, j = idx % kN;
  float rn = (float)(1.0 / sqrt(frob2[0]));
  float eye = (i==j) ? 1.f : 0.f;
  float pa = eye - tri[idx]*rn;
  u16 h = f2bf(pa);
  papp_h[idx] = h;
  papp_l[idx] = f2bf(pa - bf2f(h));
  psq[idx] = P0*eye + P1*pa;
  qsq[idx] = Q0*eye + Q1*pa;
}

// ---- invert the 16 diagonal 50x50 upper-tri blocks of U into W (W pre-zeroed)
__global__ __launch_bounds__(64)
void invdiag_kernel(const float* __restrict__ U, float* __restrict__ W){
  __shared__ float Us[kDB][kDB+1];
  __shared__ float Xs[kDB][kDB+1];
  const int base = blockIdx.x * kDB;
  const int tid = threadIdx.x;
  for (int idx = tid; idx < kDB*kDB; idx += 64){
    int r = idx / kDB, c = idx % kDB;
    Us[r][c] = U[(long)(base+r)*kN + base + c];
  }
  __syncthreads();
  const int c = tid;
  for (int i = kDB-1; i >= 0; --i){
    if (c < kDB){
      float x;
      if (c < i) x = 0.f;
      else {
        float s = 0.f;
        for (int k = i+1; k < kDB; ++k) s = fmaf(Us[i][k], Xs[k][c], s);
        x = (((c==i)?1.f:0.f) - s) / Us[i][i];
      }
      Xs[i][c] = x;
    }
    __syncthreads();
  }
  for (int idx = tid; idx < kDB*kDB; idx += 64){
    int r = idx / kDB, cc = idx % kDB;
    W[(long)(base+r)*kN + base + cc] = Xs[r][cc];
  }
}

// ---- fused merge for level S: one block per pair.
// W[top,bot] = -Wtop @ (U_tb @ Wbot); all S x S at global stride kN.
template<int S>
__global__ __launch_bounds__(256)
void merge_fused_kernel(const float* __restrict__ U, float* __restrict__ W){
  __shared__ float Us[S][S+1];   // Utb, later reused as Wtop
  __shared__ float Wb[S][S+1];   // Wbot
  __shared__ float T[S][S+1];
  const long base = (long)blockIdx.x * (2*S) * (kN+1);
  const int tid = threadIdx.x;
  for (int idx = tid; idx < S*S; idx += 256){
    int r = idx / S, c = idx % S;
    Us[r][c] = U[base + (long)r*kN + S + c];
    Wb[r][c] = W[base + (long)(S+r)*kN + S + c];
  }
  __syncthreads();
  for (int idx = tid; idx < S*S; idx += 256){
    int r = idx / S, c = idx % S;
    float s = 0.f;
    for (int k = 0; k <= c; ++k) s = fmaf(Us[r][k], Wb[k][c], s);  // Wbot upper-tri
    T[r][c] = s;
  }
  __syncthreads();
  for (int idx = tid; idx < S*S; idx += 256){
    int r = idx / S, c = idx % S;
    Us[r][c] = W[base + (long)r*kN + c];   // Wtop
  }
  __syncthreads();
  for (int idx = tid; idx < S*S; idx += 256){
    int r = idx / S, c = idx % S;
    float s = 0.f;
    for (int k = r; k < S; ++k) s = fmaf(Us[r][k], T[k][c], s);    // Wtop upper-tri
    W[base + (long)r*kN + S + c] = -s;
  }
}

__global__ __launch_bounds__(256)
void pool_head_kernel(const float* __restrict__ z2, const float* __restrict__ W,
                      const float* __restrict__ b, float* __restrict__ out){
  __shared__ float x2[kH];
  __shared__ float lg[kNC];
  int t = threadIdx.x;
  if (t < kH){
    float s = 0.f;
    for (int n = 0; n < kN; ++n) s += z2[(long)n*kH + t];
    float v = s * (1.f/(float)kN);
    x2[t] = v;
    out[t] = v;
  }
  __syncthreads();
  if (t < kNC){
    float s = b[t];
    for (int f = 0; f < kH; ++f) s = fmaf(x2[f], W[f*kNC + t], s);
    lg[t] = s;
  }
  __syncthreads();
  if (t == 0){
    float m = -1e30f;
    for (int c=0;c<kNC;++c) m = fmaxf(m, lg[c]);
    float se = 0.f;
    for (int c=0;c<kNC;++c) se += expf(lg[c]-m);
    float lse = m + logf(se);
    for (int c=0;c<kNC;++c) out[kH + c] = lg[c]-lse;
  }
}

// ---------------------------------------------------------------- host: Pade [5/5] of sqrt(1-x)
static void pade_coeffs(float* P, float* Q){
  double b[11]; b[0] = 1.0;
  for (int k=1;k<11;++k) b[k] = b[k-1]*(0.5-(k-1))/k;
  double c[11];
  for (int k=0;k<11;++k) c[k] = b[k]*((k&1)?-1.0:1.0);
  double A[5][5], rhs[5];
  for (int i=0;i<5;++i){ for (int j=0;j<5;++j) A[i][j] = c[5+i-j]; rhs[i] = -c[6+i]; }
  for (int col=0; col<5; ++col){
    int p = col;
    for (int r=col+1;r<5;++r) if (fabs(A[r][col]) > fabs(A[p][col])) p = r;
    if (p != col){
      for (int j=0;j<5;++j){ double t=A[col][j]; A[col][j]=A[p][j]; A[p][j]=t; }
      double t=rhs[col]; rhs[col]=rhs[p]; rhs[p]=t;
    }
    for (int r=col+1;r<5;++r){
      double f = A[r][col]/A[col][col];
      for (int j=col;j<5;++j) A[r][j] -= f*A[col][j];
      rhs[r] -= f*rhs[col];
    }
  }
  double q[6]; q[0] = 1.0;
  for (int r=4;r>=0;--r){
    double s = rhs[r];
    for (int j=r+1;j<5;++j) s -= A[r][j]*q[1+j];
    q[1+r] = s/A[r][r];
  }
  double p[6];
  for (int k=0;k<6;++k){
    double s = 0.0; int jm = k<5?k:5;
    for (int j=0;j<=jm;++j) s += q[j]*c[k-j];
    p[k] = s;
  }
  for (int k=0;k<6;++k){ P[k]=(float)p[k]; Q[k]=(float)q[k]; }
}

// ---------------------------------------------------------------- launch
extern "C" void kernel_launch(void* const* d_in, const int* in_sizes, int n_in,
                              void* d_out, int out_size, void* d_ws, size_t ws_size,
                              hipStream_t stream)
{
  const float* x_note = (const float*)d_in[0];
  const float* embW   = (const float*)d_in[1];
  const float* embB   = (const float*)d_in[2];
  const float* g1w1   = (const float*)d_in[3];
  const float* g1b1   = (const float*)d_in[4];
  const float* g1w2   = (const float*)d_in[5];
  const float* g1b2   = (const float*)d_in[6];
  const float* g1ln   = (const float*)d_in[7];
  const float* g2w1   = (const float*)d_in[8];
  const float* g2b1   = (const float*)d_in[9];
  const float* g2w2   = (const float*)d_in[10];
  const float* g2b2   = (const float*)d_in[11];
  const float* g2ln   = (const float*)d_in[12];
  const float* linW   = (const float*)d_in[13];
  const float* linb   = (const float*)d_in[14];
  const float* clfW   = (const float*)d_in[15];
  const float* clfb   = (const float*)d_in[16];
  const int*  e0     = (const int*)d_in[17];
  const int*  e1     = (const int*)d_in[18];
  const int*  e2     = (const int*)d_in[19];
  const int*  e3     = (const int*)d_in[20];
  float* out = (float*)d_out;

  // fp32 region (float offsets); header: scald @0, partd @512B
  constexpr long o_h0   = 2176;
  constexpr long o_h1   = o_h0   + (long)kN*kE;
  constexpr long o_h2   = o_h1   + (long)kN*kE;
  constexpr long o_tnh  = o_h2   + (long)kN*kE;
  constexpr long o_zmid = o_tnh  + kNH;
  constexpr long o_z0   = o_zmid + kNH;
  constexpr long o_z1   = o_z0   + kNH;
  constexpr long o_z2   = o_z1   + kNH;
  constexpr long o_big  = o_z2   + kNH;             // 4*kNN floats: Y planes / power bf16 scratch
  constexpr long o_tri  = o_big  + 4*kNN;           // pair out / merge scratch
  constexpr long o_sacc = o_tri  + kNN;             // S accumulator (HBM)
  constexpr long o_winv = o_sacc + kNN;
  constexpr long o_psq  = o_winv + kNN;
  constexpr long o_qsq  = o_psq  + kNN;
  constexpr long o_g    = o_qsq  + kNN;             // int g[4][kN]
  constexpr long o_hh   = o_g    + 4*kN;            // int h[4][kN]
  constexpr long o_end  = o_hh   + 4*kN;

  if (ws_size < (size_t)o_end*sizeof(float) || out_size < 215 + 2*(int)kNN || n_in < 21){
    fprintf(stderr, "kernel_launch guard: ws=%zu need=%zu out=%d need=%d n_in=%d\n",
            ws_size, (size_t)o_end*sizeof(float), out_size, (int)(215+2*kNN), n_in);
    hipMemsetAsync(d_out, 0, (size_t)out_size*sizeof(float), stream);
    return;
  }

  float* ws = (float*)d_ws;
  double* scald = (double*)d_ws;
  double* partd = (double*)((char*)d_ws + 512);
  float *h0=ws+o_h0, *h1=ws+o_h1, *h2=ws+o_h2, *tnh=ws+o_tnh,
        *zmid=ws+o_zmid, *z0=ws+o_z0, *z1=ws+o_z1, *z2=ws+o_z2, *big=ws+o_big,
        *tri=ws+o_tri, *Sacc=ws+o_sacc, *winv=ws+o_winv, *psq=ws+o_psq, *qsq=ws+o_qsq;
  int* gArr = (int*)(ws + o_g);
  int* hArr = (int*)(ws + o_hh);
  // power-phase split scratch aliased inside big (8 u16 planes = 4*kNN floats)
  u16* papp_h = (u16*)big;
  u16* papp_l = papp_h + kNN;
  u16* pT_h   = papp_l + kNN;
  u16* pT_l   = pT_h + kNN;
  u16* pwA_h  = pT_l + kNN;
  u16* pwA_l  = pwA_h + kNN;
  u16* pwB_h  = pwA_l + kNN;
  u16* pwB_l  = pwB_h + kNN;

  float P[6], Q[6];
  pade_coeffs(P, Q);

  auto eg = [](long n){ return dim3((unsigned)((n+255)/256)); };

  auto do_ln = [&](const float* src, float* dst, const float* lnp){
    reduce2_part_kernel<<<kRB,256,0,stream>>>(src, kNH, partd);
    apply_ln_kernel<<<eg(kNH),256,0,stream>>>(src, dst, lnp, partd);
  };
  auto sparse_layer = [&](const float* hin, int K, const float* W, const float* b,
                          const float* lnp, float* zout){
    launch_gemm<false,false,false,EPI_NONE>(stream, hin, K, W, kH, big, kH, kN, kH, K, 12,
                                            0, (long)K*kH, kNH, 0.f);
    combine_root_kernel<<<eg(kNH),256,0,stream>>>(big, b, tnh);
    scatter_kernel<<<dim3((unsigned)(((long)kNE*kH+255)/256),4),256,0,stream>>>(e0,e1,e2,e3, big, tnh);
    do_ln(tnh, zout, lnp);
  };
  auto dense_layer = [&](const float* hin, int K, const float* W, const float* b,
                         const float* lnp, float* zout){
    launch_gemm<false,false,false,EPI_NONE>(stream, hin, K, W, kH, big, kH, kN, kH, K, 12,
                                            0, (long)K*kH, kNH, 0.f);
    combine_root_kernel<<<eg(kNH),256,0,stream>>>(big, b, tnh);
    scan_msg_kernel<<<8,256,0,stream>>>(big);
    gather_dense_kernel<<<eg(kNH),256,0,stream>>>(big, gArr, hArr, tnh);
    do_ln(tnh, zout, lnp);
  };
  auto blocked_trsm = [&](){
    hipMemsetAsync(winv, 0, (size_t)kNN*sizeof(float), stream);
    invdiag_kernel<<<dim3(kN/kDB),64,0,stream>>>(qsq, winv);
    merge_fused_kernel<50><<<dim3(kN/100),256,0,stream>>>(qsq, winv);   // level s=50
    for (int s = 100; s < kN; s *= 2){
      int npairs = kN / (2*s);
      long step = (long)2*s*kN + 2*s;
      launch_gemm<false,false,true,EPI_NONE>(stream,
          qsq + s, kN, winv + (long)s*kN + s, kN, tri, s,
          s, s, s, npairs, step, step, (long)s*s, 0.f);
      launch_gemm<false,true,false,EPI_SCALE>(stream,
          winv, kN, tri, s, winv + s, kN,
          s, s, s, npairs, step, (long)s*s, step, -1.f);
    }
    // Sacc = winv @ psq (unscaled), atomic fp32 into HBM workspace, 8 K-chunks
    hipMemsetAsync(Sacc, 0, (size_t)kNN*sizeof(float), stream);
    launch_gemm<false,true,true,EPI_ACC>(stream,
        winv, kN, psq, kN, Sacc, kN, kN, kN, 100, 8,
        100, (long)100*kN, 0, 1.f, nullptr, 100);
  };
  auto run_pair_mpa = [&](const float* z, float* SoutDst){
    hipMemsetAsync((char*)d_ws + 24, 0, 8, stream);            // scald[3] = 0
    pair_kernel<<<dim3(50,50),256,0,stream>>>(z, linW, linb, tri, scald+3);
    init_pade_kernel<<<eg(kNN),256,0,stream>>>(tri, papp_h, papp_l, psq, qsq, scald+3,
                                               P[0],P[1],Q[0],Q[1]);
    transpose_pade_kernel<<<dim3(25,25),256,0,stream>>>(tri, scald+3, pT_h, pT_l);
    dim3 g13(13,13,1);
    bgemm2_kernel<<<g13,256,0,stream>>>(papp_h,papp_l, pT_h,pT_l, psq,qsq, pwA_h,pwA_l, P[2],Q[2]);
    bgemm2_kernel<<<g13,256,0,stream>>>(pwA_h,pwA_l,  pT_h,pT_l, psq,qsq, pwB_h,pwB_l, P[3],Q[3]);
    bgemm2_kernel<<<g13,256,0,stream>>>(pwB_h,pwB_l,  pT_h,pT_l, psq,qsq, pwA_h,pwA_l, P[4],Q[4]);
    bgemm2_kernel<<<g13,256,0,stream>>>(pwA_h,pwA_l,  pT_h,pT_l, psq,qsq, pwB_h,pwB_l, P[5],Q[5]);
    blocked_trsm();
    // single streaming pass into the PCIe-resident output region
    copy_scale_kernel<<<eg(kNN),256,0,stream>>>(Sacc, scald+3, SoutDst);
  };
  // h_out = (Sacc * fac) @ h_in = fac * (Sacc @ h_in); Sacc in ws, scale via scalp
  auto s_times_h = [&](const float* hin, float* hout){
    hipMemsetAsync(hout, 0, (size_t)kN*kE*sizeof(float), stream);
    launch_gemm<false,true,false,EPI_ACC>(stream,
        Sacc, kN, hin, kE, hout, kE, kN, kE, 100, 8,
        100, (long)100*kE, 0, 1.f, nullptr, 100, scald+3);
  };

  float* S1f = out + 215;
  float* S2f = out + 215 + kNN;

  // ---- once: build staircase g/h (no d_out memset — copy_scale writes every elem)
  hipMemsetAsync(gArr, 0xFF, (size_t)(4*kN)*sizeof(int), stream);   // -1
  edge_gmax_kernel<<<dim3((kNE+255)/256,4),256,0,stream>>>(e0,e1,e2,e3, gArr);
  scan_gh_kernel<<<4,256,0,stream>>>(gArr, hArr);

  // ---- embed
  launch_gemm<false,false,false,EPI_BIAS>(stream, x_note, kF, embW, kE, h0, kE, kN, kE, kF, 1,
                                          0,0,0, 0.f, embB);

  // ---- GNN1 (sparse)
  sparse_layer(h0,  kE, g1w1, g1b1, g1ln,        zmid);
  sparse_layer(zmid,kH, g1w2, g1b2, g1ln + 2*kH, z0);

  // ---- S1 (Sacc holds unscaled S1 until s_times_h below)
  run_pair_mpa(z0, S1f);

  // ---- h1 = S1 @ h0   (reads Sacc from ws; scale folded via scald+3)
  s_times_h(h0, h1);

  // ---- GNN2 #1 (dense; mask1 == staircase(g,h))
  dense_layer(h1,  kE, g2w1, g2b1, g2ln,        zmid);
  dense_layer(zmid,kH, g2w2, g2b2, g2ln + 2*kH, z1);

  // ---- S2
  run_pair_mpa(z1, S2f);

  // ---- h2 = S2 @ h1
  s_times_h(h1, h2);

  // ---- GNN2 #2 (dense; mask2 == mask1 — same staircase)
  dense_layer(h2,  kE, g2w1, g2b1, g2ln,        zmid);
  dense_layer(zmid,kH, g2w2, g2b2, g2ln + 2*kH, z2);

  // ---- pool + classifier + log_softmax
  pool_head_kernel<<<dim3(1),256,0,stream>>>(z2, clfW, clfb, out);
}

// Round 11
// 1532.072 us; speedup vs baseline: 3.2370x; 1.0366x over previous
//
#include <hip/hip_runtime.h>
#include <hip/hip_bf16.h>
#include <math.h>
#include <stdio.h>

static constexpr int   kN  = 800;    // nodes
static constexpr int   kF  = 111;    // input features
static constexpr int   kE  = 32;     // embed dim
static constexpr int   kH  = 200;    // hidden
static constexpr int   kNC = 15;     // classes
static constexpr int   kNE = 8000;   // edges per type
static constexpr long  kNN = (long)kN*kN;   // 640000
static constexpr long  kNH = (long)kN*kH;   // 160000
static constexpr float kAl  = 0.5f;  // ALPHA
static constexpr float kEps = 1e-5f;
static constexpr int   kRB  = 64;    // reduction blocks (sparse path)
static constexpr int   kGB  = (int)((kNH+255)/256);  // gather blocks = 625
static constexpr int   kDB  = 50;    // trsm diagonal block size (800 = 16 * 50)

typedef unsigned short u16;
typedef __attribute__((ext_vector_type(8))) short short8;
typedef __attribute__((ext_vector_type(4))) float f32x4;

__device__ __forceinline__ u16 f2bf(float v){
  __hip_bfloat16 b = __float2bfloat16(v);
  return *reinterpret_cast<u16*>(&b);
}
__device__ __forceinline__ float bf2f(u16 h){
  unsigned int u = ((unsigned int)h) << 16;
  float f; __builtin_memcpy(&f, &u, 4);
  return f;
}

enum { EPI_NONE=0, EPI_BIAS=1, EPI_SCALE=4, EPI_ACC=6 };

// ---------------------------------------------------------------- fp32 GEMM
// C[M,N] = A * B, row strides lda/ldb/ldc.
// TRIUA: A[m,kglob]==0 for kglob<m; TRIUB: B[kglob,n]==0 for kglob>n (exact).
// kstep!=0: K-split — blockIdx.z is a K-chunk; kbase=z*kstep; A/B pre-offset
// via sA/sB; triangular clips in global coords. EPI_ACC: atomic C += scale*v,
// scale *= sqrt(sqrt(scalp[0])) if scalp given; skip blocks return early.
template<bool TRANSA, bool TRIUA, bool TRIUB, int EPI>
__global__ __launch_bounds__(256)
void gemm_kernel(const float* __restrict__ A, int lda,
                 const float* __restrict__ B, int ldb,
                 float* __restrict__ C, int ldc,
                 int M, int Ncl, int K,
                 long sA, long sB, long sC, float scale,
                 const float* __restrict__ bias, int kstep,
                 const double* __restrict__ scalp)
{
  constexpr int TM=64, TN=64, TK=16;
  A += (long)blockIdx.z * sA;
  B += (long)blockIdx.z * sB;
  C += (long)blockIdx.z * sC;
  __shared__ float As[TK][TM+4];
  __shared__ float Bs[TK][TN+4];
  const int tid = threadIdx.x;
  const int tn4 = (tid & 15)*4, tm4 = (tid >> 4)*4;
  const int m0 = blockIdx.x * TM, n0 = blockIdx.y * TN;
  float acc[4][4] = {};
  const int kbase = kstep ? (int)blockIdx.z * kstep : 0;
  int k0 = TRIUA ? max(m0 - kbase, 0) : 0;
  int kEnd = TRIUB ? min(K, n0 + TN - kbase) : K;
  const bool skip = (k0 >= kEnd);
  if (skip && EPI == EPI_ACC) return;
  if (!skip) {
    for (; k0 < kEnd; k0 += TK) {
      #pragma unroll
      for (int u=0; u<4; ++u) {
        int idx = tid + 256*u;
        if (!TRANSA) {
          int m = idx >> 4, ka = idx & 15;
          int gm = m0+m, gk = k0+ka;
          As[ka][m] = (gm < M && gk < K) ? A[(long)gm*lda + gk] : 0.f;
        } else {
          int ka = idx >> 6, m = idx & 63;
          int gm = m0+m, gk = k0+ka;
          As[ka][m] = (gm < M && gk < K) ? A[(long)gk*lda + gm] : 0.f;
        }
        int kb = idx >> 6, nb = idx & 63;
        int gk = k0+kb, gn = n0+nb;
        Bs[kb][nb] = (gk < K && gn < Ncl) ? B[(long)gk*ldb + gn] : 0.f;
      }
      __syncthreads();
      #pragma unroll
      for (int kk=0; kk<TK; ++kk) {
        float a[4], b[4];
        #pragma unroll
        for (int u=0;u<4;++u){ a[u]=As[kk][tm4+u]; b[u]=Bs[kk][tn4+u]; }
        #pragma unroll
        for (int i=0;i<4;++i)
          #pragma unroll
          for (int j=0;j<4;++j)
            acc[i][j] = fmaf(a[i], b[j], acc[i][j]);
      }
      __syncthreads();
    }
  }
  float sc = scale;
  if (EPI == EPI_ACC && scalp) sc *= (float)sqrt(sqrt(scalp[0]));
  #pragma unroll
  for (int i=0;i<4;++i) {
    int gm = m0 + tm4 + i;
    if (gm >= M) continue;
    #pragma unroll
    for (int j=0;j<4;++j) {
      int gn = n0 + tn4 + j;
      if (gn >= Ncl) continue;
      float v = acc[i][j];
      long off = (long)gm*ldc + gn;
      if (EPI == EPI_BIAS)       C[off] = v + bias[gn];
      else if (EPI == EPI_SCALE) C[off] = scale*v;
      else if (EPI == EPI_ACC)   unsafeAtomicAdd(&C[off], sc*v);
      else                       C[off] = v;
    }
  }
}

template<bool TRANSA, bool TRIUA, bool TRIUB, int EPI>
static inline void launch_gemm(hipStream_t st,
                               const float* A, int lda, const float* B, int ldb,
                               float* C, int ldc, int M, int Ncl, int K, int batch,
                               long sA, long sB, long sC, float scale,
                               const float* bias = nullptr, int kstep = 0,
                               const double* scalp = nullptr)
{
  dim3 grid((M+63)/64, (Ncl+63)/64, batch);
  gemm_kernel<TRANSA,TRIUA,TRIUB,EPI><<<grid, 256, 0, st>>>(
      A,lda,B,ldb,C,ldc,M,Ncl,K,sA,sB,sC,scale,bias,kstep,scalp);
}

// ---------------------------------------------------------------- split-bf16 MFMA GEMM (powers)
// v = (Ah+Al) @ (Bth+Btl)^T dropping lo*lo (~fp32). psq += p0*v; qsq += p1*v;
// Oh/Ol = hi/lo split of v. A and B^T upper-tri (exact zeros preserved).
__global__ __launch_bounds__(256)
void bgemm2_kernel(const u16* __restrict__ Ah, const u16* __restrict__ Al,
                   const u16* __restrict__ Bh, const u16* __restrict__ Bl,
                   float* __restrict__ C, float* __restrict__ C2,
                   u16* __restrict__ Oh, u16* __restrict__ Ol,
                   float p0, float p1)
{
  constexpr int TM=64, TN=64, BK=32;
  __shared__ u16 Ash[TM][40], Asl[TM][40], Bsh[TN][40], Bsl[TN][40];
  const int tid = threadIdx.x;
  const int m0 = blockIdx.x*TM, n0 = blockIdx.y*TN;
  const int w = tid>>6, lane = tid&63;
  const int wm = (w&1)*32, wn = (w>>1)*32;
  const int quad = lane>>4, lm = lane&15;
  f32x4 acc00={}, acc01={}, acc10={}, acc11={};
  const bool skip = (m0 > n0 + TN - 1);
  int k0 = m0;
  const int kEnd = min(kN, n0+TN);
  const int ar = tid>>2, ac = (tid&3)*8;
  if (!skip){
    for (; k0 < kEnd; k0 += BK){
      uint4 avh={0,0,0,0}, avl={0,0,0,0}, bvh={0,0,0,0}, bvl={0,0,0,0};
      int gk = k0 + ac;
      if (m0+ar < kN && gk < kN){
        avh = *(const uint4*)(Ah + (long)(m0+ar)*kN + gk);
        avl = *(const uint4*)(Al + (long)(m0+ar)*kN + gk);
      }
      if (n0+ar < kN && gk < kN){
        bvh = *(const uint4*)(Bh + (long)(n0+ar)*kN + gk);
        bvl = *(const uint4*)(Bl + (long)(n0+ar)*kN + gk);
      }
      __syncthreads();
      *(uint4*)&Ash[ar][ac] = avh; *(uint4*)&Asl[ar][ac] = avl;
      *(uint4*)&Bsh[ar][ac] = bvh; *(uint4*)&Bsl[ar][ac] = bvl;
      __syncthreads();
      short8 a0h = *(const short8*)&Ash[wm+lm][quad*8];
      short8 a1h = *(const short8*)&Ash[wm+16+lm][quad*8];
      short8 a0l = *(const short8*)&Asl[wm+lm][quad*8];
      short8 a1l = *(const short8*)&Asl[wm+16+lm][quad*8];
      short8 b0h = *(const short8*)&Bsh[wn+lm][quad*8];
      short8 b1h = *(const short8*)&Bsh[wn+16+lm][quad*8];
      short8 b0l = *(const short8*)&Bsl[wn+lm][quad*8];
      short8 b1l = *(const short8*)&Bsl[wn+16+lm][quad*8];
      acc00 = __builtin_amdgcn_mfma_f32_16x16x32_bf16(a0h,b0h,acc00,0,0,0);
      acc00 = __builtin_amdgcn_mfma_f32_16x16x32_bf16(a0h,b0l,acc00,0,0,0);
      acc00 = __builtin_amdgcn_mfma_f32_16x16x32_bf16(a0l,b0h,acc00,0,0,0);
      acc01 = __builtin_amdgcn_mfma_f32_16x16x32_bf16(a0h,b1h,acc01,0,0,0);
      acc01 = __builtin_amdgcn_mfma_f32_16x16x32_bf16(a0h,b1l,acc01,0,0,0);
      acc01 = __builtin_amdgcn_mfma_f32_16x16x32_bf16(a0l,b1h,acc01,0,0,0);
      acc10 = __builtin_amdgcn_mfma_f32_16x16x32_bf16(a1h,b0h,acc10,0,0,0);
      acc10 = __builtin_amdgcn_mfma_f32_16x16x32_bf16(a1h,b0l,acc10,0,0,0);
      acc10 = __builtin_amdgcn_mfma_f32_16x16x32_bf16(a1l,b0h,acc10,0,0,0);
      acc11 = __builtin_amdgcn_mfma_f32_16x16x32_bf16(a1h,b1h,acc11,0,0,0);
      acc11 = __builtin_amdgcn_mfma_f32_16x16x32_bf16(a1h,b1l,acc11,0,0,0);
      acc11 = __builtin_amdgcn_mfma_f32_16x16x32_bf16(a1l,b1h,acc11,0,0,0);
    }
  }
  f32x4 accs[2][2] = {{acc00, acc01},{acc10, acc11}};
  #pragma unroll
  for (int ti=0; ti<2; ++ti){
    #pragma unroll
    for (int tj=0; tj<2; ++tj){
      #pragma unroll
      for (int r=0; r<4; ++r){
        int gm = m0 + wm + ti*16 + quad*4 + r;
        int gn = n0 + wn + tj*16 + lm;
        if (gm >= kN || gn >= kN) continue;
        float v = accs[ti][tj][r];
        long off = (long)gm*kN + gn;
        C[off]  += p0*v;
        C2[off] += p1*v;
        u16 h = f2bf(v);
        Oh[off] = h;
        Ol[off] = f2bf(v - bf2f(h));
      }
    }
  }
}

// ---- transposed pade init: dst[c][r] = hi/lo split of (I - tri/normA)[r][c]
__global__ __launch_bounds__(256)
void transpose_pade_kernel(const float* __restrict__ tri, const double* __restrict__ frob2,
                           u16* __restrict__ dh, u16* __restrict__ dl)
{
  __shared__ float t[32][33];
  const float rn = (float)(1.0 / sqrt(frob2[0]));
  int r0 = blockIdx.y*32, c0 = blockIdx.x*32;
  int tr = threadIdx.x>>5, tc = threadIdx.x&31;
  for (int i=tr; i<32; i+=8){
    int r = r0+i, c = c0+tc;
    float eye = (r==c) ? 1.f : 0.f;
    t[i][tc] = eye - tri[(long)r*kN + c]*rn;
  }
  __syncthreads();
  for (int i=tr; i<32; i+=8){
    int c = c0+i, r = r0+tc;
    float v = t[tc][i];
    u16 h = f2bf(v);
    dh[(long)c*kN + r] = h;
    dl[(long)c*kN + r] = f2bf(v - bf2f(h));
  }
}

// ---- stream S = Sacc * sqrt(normA) into d_out — single pass, non-temporal
__global__ __launch_bounds__(256)
void copy_scale_kernel(const float* __restrict__ src, const double* __restrict__ frob2,
                       float* __restrict__ dst)
{
  const float fac = (float)sqrt(sqrt(frob2[0]));
  long i = (long)blockIdx.x*256 + threadIdx.x;
  if (i < kNN) __builtin_nontemporal_store(src[i]*fac, &dst[i]);
}

// ---------------------------------------------------------------- mask staircase kernels
__global__ void edge_gmax_kernel(const int* __restrict__ e0, const int* __restrict__ e1,
                                 const int* __restrict__ e2, const int* __restrict__ e3,
                                 int* __restrict__ g){
  const int* eis[4] = {e0,e1,e2,e3};
  const int e = blockIdx.y;
  const int* ei = eis[e];
  int j = blockIdx.x*256 + threadIdx.x;
  if (j >= kNE) return;
  int s = ei[j], d = ei[kNE + j];
  atomicMax(&g[e*kN + d], s);
}

__global__ __launch_bounds__(256)
void scan_gh_kernel(int* __restrict__ g, int* __restrict__ h){
  __shared__ int gs[kN];
  const int e = blockIdx.x;
  for (int i = threadIdx.x; i < kN; i += 256) gs[i] = g[e*kN + i];
  __syncthreads();
  if (threadIdx.x == 0){
    int m = -1;
    for (int i = 0; i < kN; ++i){ m = max(m, gs[i]); gs[i] = m; }
  }
  __syncthreads();
  for (int i = threadIdx.x; i < kN; i += 256) g[e*kN + i] = gs[i];
  for (int d = threadIdx.x; d < kN; d += 256){
    int lo = 0, hi = kN;
    while (lo < hi){ int mid = (lo+hi)>>1; if (gs[mid] >= d) hi = mid; else lo = mid+1; }
    h[e*kN + d] = lo;
  }
}

// in-place scans over Y planes: z<4 -> prefix over n; z>=4 -> suffix
__global__ __launch_bounds__(256)
void scan_msg_kernel(float* __restrict__ Y){
  const int plane = blockIdx.x;          // 0..7
  const int f = threadIdx.x;
  if (f >= kH) return;
  float* P = Y + (long)plane*kNH + f;
  float acc = 0.f;
  if (plane < 4){
    for (int n = 0; n < kN; n += 4){
      float v0 = P[(long)(n+0)*kH], v1 = P[(long)(n+1)*kH];
      float v2 = P[(long)(n+2)*kH], v3 = P[(long)(n+3)*kH];
      acc += v0; P[(long)(n+0)*kH] = acc;
      acc += v1; P[(long)(n+1)*kH] = acc;
      acc += v2; P[(long)(n+2)*kH] = acc;
      acc += v3; P[(long)(n+3)*kH] = acc;
    }
  } else {
    for (int n = kN-1; n >= 0; n -= 4){
      float v0 = P[(long)(n-0)*kH], v1 = P[(long)(n-1)*kH];
      float v2 = P[(long)(n-2)*kH], v3 = P[(long)(n-3)*kH];
      acc += v0; P[(long)(n-0)*kH] = acc;
      acc += v1; P[(long)(n-1)*kH] = acc;
      acc += v2; P[(long)(n-2)*kH] = acc;
      acc += v3; P[(long)(n-3)*kH] = acc;
    }
  }
}

// gather + fused LN partials: tnh[n,f] += 0.5*sum_e[...]; part[b]=(sum,sumsq)
__global__ __launch_bounds__(256)
void gather_dense_kernel(const float* __restrict__ Y, const int* __restrict__ g,
                         const int* __restrict__ h, float* __restrict__ tnh,
                         double* __restrict__ part){
  __shared__ double ss[256], qq[256];
  long idx = (long)blockIdx.x*256 + threadIdx.x;
  double s = 0.0, q = 0.0;
  if (idx < kNH){
    int n = (int)(idx / kH), f = (int)(idx % kH);
    float v = 0.f;
    #pragma unroll
    for (int e = 0; e < 4; ++e){
      int gi = g[e*kN + n];
      if (gi >= 0) v += Y[(long)e*kNH + (long)gi*kH + f];
      int hi = h[e*kN + n];
      if (hi < kN) v += Y[(long)(4+e)*kNH + (long)hi*kH + f];
    }
    float t = tnh[idx] + 0.5f*v;
    tnh[idx] = t;
    s = t; q = (double)t*t;
  }
  ss[threadIdx.x]=s; qq[threadIdx.x]=q;
  __syncthreads();
  for (int hh=128; hh>0; hh>>=1){
    if ((int)threadIdx.x < hh){ ss[threadIdx.x]+=ss[threadIdx.x+hh]; qq[threadIdx.x]+=qq[threadIdx.x+hh]; }
    __syncthreads();
  }
  if (threadIdx.x==0){ part[2*blockIdx.x]=ss[0]; part[2*blockIdx.x+1]=qq[0]; }
}

// ---------------------------------------------------------------- small kernels
// Wr = sum_e W[2,e]  (root weight pre-sum);  bsum[f] = sum_e((1-a)b0+a b1+b2)
__global__ void sum_root_kernel(const float* __restrict__ W, const float* __restrict__ b,
                                int K, float* __restrict__ Wr, float* __restrict__ bsum){
  int idx = blockIdx.x*256 + threadIdx.x;
  int tot = K*kH;
  if (idx < tot){
    float v = 0.f;
    #pragma unroll
    for (int e=0;e<4;++e) v += W[(long)(8+e)*tot + idx];
    Wr[idx] = v;
  }
  if (idx < kH){
    float v = 0.f;
    #pragma unroll
    for (int e=0;e<4;++e)
      v += (1.f-kAl)*b[(0*4+e)*kH + idx] + kAl*b[(1*4+e)*kH + idx] + b[(2*4+e)*kH + idx];
    bsum[idx] = v;
  }
}

__global__ __launch_bounds__(256)
void scatter_kernel(const int* __restrict__ e0, const int* __restrict__ e1,
                    const int* __restrict__ e2, const int* __restrict__ e3,
                    const float* __restrict__ Y, float* __restrict__ out){
  const int* eis[4] = {e0,e1,e2,e3};
  const int e = blockIdx.y;
  const int* ei = eis[e];
  long idx = (long)blockIdx.x*256 + threadIdx.x;
  if (idx >= (long)kNE*kH) return;
  int j = (int)(idx / kH), f = (int)(idx % kH);
  int s = ei[j], d = ei[kNE + j];
  float m_in  = Y[((long)e*kN + s)*kH + f];
  float m_out = Y[((long)(4+e)*kN + d)*kH + f];
  unsafeAtomicAdd(&out[(long)d*kH + f], (1.f-kAl)*m_in);
  unsafeAtomicAdd(&out[(long)s*kH + f], kAl*m_out);
}

// (sum, sumsq) partials — kRB blocks (sparse path)
__global__ __launch_bounds__(256)
void reduce2_part_kernel(const float* __restrict__ x, long n, double* __restrict__ part){
  __shared__ double ss[256], qq[256];
  double s=0.0, q=0.0;
  for (long i = (long)blockIdx.x*256 + threadIdx.x; i < n; i += (long)gridDim.x*256){
    double v = x[i]; s += v; q += v*v;
  }
  ss[threadIdx.x]=s; qq[threadIdx.x]=q;
  __syncthreads();
  for (int h=128; h>0; h>>=1){
    if ((int)threadIdx.x < h){ ss[threadIdx.x]+=ss[threadIdx.x+h]; qq[threadIdx.x]+=qq[threadIdx.x+h]; }
    __syncthreads();
  }
  if (threadIdx.x==0){ part[2*blockIdx.x]=ss[0]; part[2*blockIdx.x+1]=qq[0]; }
}

// graph layernorm with inline final reduction of nb partials
__global__ __launch_bounds__(256)
void apply_ln_kernel(const float* __restrict__ x, float* __restrict__ y,
                     const float* __restrict__ ln, const double* __restrict__ part, int nb){
  __shared__ double ss[256], qq[256];
  int t = threadIdx.x;
  double s=0.0, q=0.0;
  for (int i=t; i<nb; i+=256){ s += part[2*i]; q += part[2*i+1]; }
  ss[t]=s; qq[t]=q;
  __syncthreads();
  for (int h=128; h>0; h>>=1){
    if (t < h){ ss[t]+=ss[t+h]; qq[t]+=qq[t+h]; }
    __syncthreads();
  }
  long idx = (long)blockIdx.x*256 + t;
  if (idx >= kNH) return;
  double mu  = ss[0] / (double)kNH;
  double var = qq[0] / (double)kNH - mu*mu;
  float rs = rsqrtf((float)var + kEps);
  int f = (int)(idx % kH);
  y[idx] = (x[idx] - (float)mu) * rs * ln[f] + ln[kH + f];
}

// pair + fused frobenius sumsq (atomic f64 into frob2; zero it first!)
__global__ __launch_bounds__(256)
void pair_kernel(const float* __restrict__ z, const float* __restrict__ linW,
                 const float* __restrict__ linb, float* __restrict__ tri,
                 double* __restrict__ frob2){
  __shared__ float zi[16][201], zj[16][201], w[208];
  __shared__ float red[256];
  const int i0 = blockIdx.y*16, j0 = blockIdx.x*16;
  const int tid = threadIdx.x;
  const int ti = tid >> 4, tj = tid & 15;
  const int i = i0+ti, j = j0+tj;
  if (i0 > j0 + 15) { tri[(long)i*kN + j] = 0.f; return; }
  for (int idx = tid; idx < 16*kH; idx += 256){
    int r = idx / kH, c = idx % kH;
    zi[r][c] = z[(long)(i0+r)*kH + c];
    zj[r][c] = z[(long)(j0+r)*kH + c];
  }
  if (tid < kH) w[tid] = linW[tid];
  __syncthreads();
  float g = 0.f;
  if (i <= j){
    float s = linb[0];
    #pragma unroll 4
    for (int k=0;k<kH;++k){ float d = zi[ti][k]-zj[tj][k]; s = fmaf(d*d, w[k], s); }
    g = 1.f/(1.f + expf(-s));
  }
  tri[(long)i*kN + j] = g;
  red[tid] = g*g;
  __syncthreads();
  for (int h=128; h>0; h>>=1){
    if (tid < h) red[tid] += red[tid+h];
    __syncthreads();
  }
  if (tid == 0) unsafeAtomicAdd(frob2, (double)red[0]);
}

__global__ void init_pade_kernel(const float* __restrict__ tri,
                                 u16* __restrict__ papp_h, u16* __restrict__ papp_l,
                                 float* __restrict__ psq, float* __restrict__ qsq,
                                 const double* __restrict__ frob2,
                                 float P0, float P1, float Q0, float Q1){
  int idx = blockIdx.x*256 + threadIdx.x;
  if (idx >= (int)kNN) return;
  int i = idx / kN, j = idx % kN;
  float rn = (float)(1.0 / sqrt(frob2[0]));
  float eye = (i==j) ? 1.f : 0.f;
  float pa = eye - tri[idx]*rn;
  u16 h = f2bf(pa);
  papp_h[idx] = h;
  papp_l[idx] = f2bf(pa - bf2f(h));
  psq[idx] = P0*eye + P1*pa;
  qsq[idx] = Q0*eye + Q1*pa;
}

// ---- invert the 16 diagonal 50x50 upper-tri blocks of U into W (W pre-zeroed)
__global__ __launch_bounds__(64)
void invdiag_kernel(const float* __restrict__ U, float* __restrict__ W){
  __shared__ float Us[kDB][kDB+1];
  __shared__ float Xs[kDB][kDB+1];
  const int base = blockIdx.x * kDB;
  const int tid = threadIdx.x;
  for (int idx = tid; idx < kDB*kDB; idx += 64){
    int r = idx / kDB, c = idx % kDB;
    Us[r][c] = U[(long)(base+r)*kN + base + c];
  }
  __syncthreads();
  const int c = tid;
  for (int i = kDB-1; i >= 0; --i){
    if (c < kDB){
      float x;
      if (c < i) x = 0.f;
      else {
        float s = 0.f;
        for (int k = i+1; k < kDB; ++k) s = fmaf(Us[i][k], Xs[k][c], s);
        x = (((c==i)?1.f:0.f) - s) / Us[i][i];
      }
      Xs[i][c] = x;
    }
    __syncthreads();
  }
  for (int idx = tid; idx < kDB*kDB; idx += 64){
    int r = idx / kDB, cc = idx % kDB;
    W[(long)(base+r)*kN + base + cc] = Xs[r][cc];
  }
}

// ---- fused merge for level S: one block per pair.
// W[top,bot] = -Wtop @ (U_tb @ Wbot); all S x S at global stride kN.
template<int S>
__global__ __launch_bounds__(256)
void merge_fused_kernel(const float* __restrict__ U, float* __restrict__ W){
  __shared__ float Us[S][S+1];   // Utb, later reused as Wtop
  __shared__ float Wb[S][S+1];   // Wbot
  __shared__ float T[S][S+1];
  const long base = (long)blockIdx.x * (2*S) * (kN+1);
  const int tid = threadIdx.x;
  for (int idx = tid; idx < S*S; idx += 256){
    int r = idx / S, c = idx % S;
    Us[r][c] = U[base + (long)r*kN + S + c];
    Wb[r][c] = W[base + (long)(S+r)*kN + S + c];
  }
  __syncthreads();
  for (int idx = tid; idx < S*S; idx += 256){
    int r = idx / S, c = idx % S;
    float s = 0.f;
    for (int k = 0; k <= c; ++k) s = fmaf(Us[r][k], Wb[k][c], s);  // Wbot upper-tri
    T[r][c] = s;
  }
  __syncthreads();
  for (int idx = tid; idx < S*S; idx += 256){
    int r = idx / S, c = idx % S;
    Us[r][c] = W[base + (long)r*kN + c];   // Wtop
  }
  __syncthreads();
  for (int idx = tid; idx < S*S; idx += 256){
    int r = idx / S, c = idx % S;
    float s = 0.f;
    for (int k = r; k < S; ++k) s = fmaf(Us[r][k], T[k][c], s);    // Wtop upper-tri
    W[base + (long)r*kN + S + c] = -s;
  }
}

__global__ __launch_bounds__(256)
void pool_head_kernel(const float* __restrict__ z2, const float* __restrict__ W,
                      const float* __restrict__ b, float* __restrict__ out){
  __shared__ float x2[kH];
  __shared__ float lg[kNC];
  int t = threadIdx.x;
  if (t < kH){
    float s = 0.f;
    for (int n = 0; n < kN; ++n) s += z2[(long)n*kH + t];
    float v = s * (1.f/(float)kN);
    x2[t] = v;
    out[t] = v;
  }
  __syncthreads();
  if (t < kNC){
    float s = b[t];
    for (int f = 0; f < kH; ++f) s = fmaf(x2[f], W[f*kNC + t], s);
    lg[t] = s;
  }
  __syncthreads();
  if (t == 0){
    float m = -1e30f;
    for (int c=0;c<kNC;++c) m = fmaxf(m, lg[c]);
    float se = 0.f;
    for (int c=0;c<kNC;++c) se += expf(lg[c]-m);
    float lse = m + logf(se);
    for (int c=0;c<kNC;++c) out[kH + c] = lg[c]-lse;
  }
}

// ---------------------------------------------------------------- host: Pade [5/5] of sqrt(1-x)
static void pade_coeffs(float* P, float* Q){
  double b[11]; b[0] = 1.0;
  for (int k=1;k<11;++k) b[k] = b[k-1]*(0.5-(k-1))/k;
  double c[11];
  for (int k=0;k<11;++k) c[k] = b[k]*((k&1)?-1.0:1.0);
  double A[5][5], rhs[5];
  for (int i=0;i<5;++i){ for (int j=0;j<5;++j) A[i][j] = c[5+i-j]; rhs[i] = -c[6+i]; }
  for (int col=0; col<5; ++col){
    int p = col;
    for (int r=col+1;r<5;++r) if (fabs(A[r][col]) > fabs(A[p][col])) p = r;
    if (p != col){
      for (int j=0;j<5;++j){ double t=A[col][j]; A[col][j]=A[p][j]; A[p][j]=t; }
      double t=rhs[col]; rhs[col]=rhs[p]; rhs[p]=t;
    }
    for (int r=col+1;r<5;++r){
      double f = A[r][col]/A[col][col];
      for (int j=col;j<5;++j) A[r][j] -= f*A[col][j];
      rhs[r] -= f*rhs[col];
    }
  }
  double q[6]; q[0] = 1.0;
  for (int r=4;r>=0;--r){
    double s = rhs[r];
    for (int j=r+1;j<5;++j) s -= A[r][j]*q[1+j];
    q[1+r] = s/A[r][r];
  }
  double p[6];
  for (int k=0;k<6;++k){
    double s = 0.0; int jm = k<5?k:5;
    for (int j=0;j<=jm;++j) s += q[j]*c[k-j];
    p[k] = s;
  }
  for (int k=0;k<6;++k){ P[k]=(float)p[k]; Q[k]=(float)q[k]; }
}

// ---------------------------------------------------------------- launch
extern "C" void kernel_launch(void* const* d_in, const int* in_sizes, int n_in,
                              void* d_out, int out_size, void* d_ws, size_t ws_size,
                              hipStream_t stream)
{
  const float* x_note = (const float*)d_in[0];
  const float* embW   = (const float*)d_in[1];
  const float* embB   = (const float*)d_in[2];
  const float* g1w1   = (const float*)d_in[3];
  const float* g1b1   = (const float*)d_in[4];
  const float* g1w2   = (const float*)d_in[5];
  const float* g1b2   = (const float*)d_in[6];
  const float* g1ln   = (const float*)d_in[7];
  const float* g2w1   = (const float*)d_in[8];
  const float* g2b1   = (const float*)d_in[9];
  const float* g2w2   = (const float*)d_in[10];
  const float* g2b2   = (const float*)d_in[11];
  const float* g2ln   = (const float*)d_in[12];
  const float* linW   = (const float*)d_in[13];
  const float* linb   = (const float*)d_in[14];
  const float* clfW   = (const float*)d_in[15];
  const float* clfb   = (const float*)d_in[16];
  const int*  e0     = (const int*)d_in[17];
  const int*  e1     = (const int*)d_in[18];
  const int*  e2     = (const int*)d_in[19];
  const int*  e3     = (const int*)d_in[20];
  float* out = (float*)d_out;

  // header: scald @0 (32B), partd @512B (room for 992 pairs)
  constexpr long o_h0   = 4096;
  constexpr long o_h1   = o_h0   + (long)kN*kE;
  constexpr long o_h2   = o_h1   + (long)kN*kE;
  constexpr long o_tnh  = o_h2   + (long)kN*kE;
  constexpr long o_zmid = o_tnh  + kNH;
  constexpr long o_z0   = o_zmid + kNH;
  constexpr long o_z1   = o_z0   + kNH;
  constexpr long o_z2   = o_z1   + kNH;
  constexpr long o_big  = o_z2   + kNH;             // 4*kNN floats: Y planes / power bf16 scratch
  constexpr long o_tri  = o_big  + 4*kNN;           // pair out / merge scratch
  constexpr long o_sacc = o_tri  + kNN;             // S accumulator (HBM)
  constexpr long o_winv = o_sacc + kNN;
  constexpr long o_psq  = o_winv + kNN;
  constexpr long o_qsq  = o_psq  + kNN;
  constexpr long o_g    = o_qsq  + kNN;             // int g[4][kN]
  constexpr long o_hh   = o_g    + 4*kN;            // int h[4][kN]
  constexpr long o_wr1  = o_hh   + 4*kN;            // root sums
  constexpr long o_wr2  = o_wr1  + (long)kE*kH;
  constexpr long o_wr3  = o_wr2  + (long)kH*kH;
  constexpr long o_wr4  = o_wr3  + (long)kE*kH;
  constexpr long o_bs   = o_wr4  + (long)kH*kH;     // 4 x kH bias sums
  constexpr long o_end  = o_bs   + 4*kH;

  if (ws_size < (size_t)o_end*sizeof(float) || out_size < 215 + 2*(int)kNN || n_in < 21){
    fprintf(stderr, "kernel_launch guard: ws=%zu need=%zu out=%d need=%d n_in=%d\n",
            ws_size, (size_t)o_end*sizeof(float), out_size, (int)(215+2*kNN), n_in);
    hipMemsetAsync(d_out, 0, (size_t)out_size*sizeof(float), stream);
    return;
  }

  float* ws = (float*)d_ws;
  double* scald = (double*)d_ws;
  double* partd = (double*)((char*)d_ws + 512);
  float *h0=ws+o_h0, *h1=ws+o_h1, *h2=ws+o_h2, *tnh=ws+o_tnh,
        *zmid=ws+o_zmid, *z0=ws+o_z0, *z1=ws+o_z1, *z2=ws+o_z2, *big=ws+o_big,
        *tri=ws+o_tri, *Sacc=ws+o_sacc, *winv=ws+o_winv, *psq=ws+o_psq, *qsq=ws+o_qsq;
  int* gArr = (int*)(ws + o_g);
  int* hArr = (int*)(ws + o_hh);
  float *wr1=ws+o_wr1, *wr2=ws+o_wr2, *wr3=ws+o_wr3, *wr4=ws+o_wr4, *bs=ws+o_bs;
  // power-phase split scratch aliased inside big (8 u16 planes = 4*kNN floats)
  u16* papp_h = (u16*)big;
  u16* papp_l = papp_h + kNN;
  u16* pT_h   = papp_l + kNN;
  u16* pT_l   = pT_h + kNN;
  u16* pwA_h  = pT_l + kNN;
  u16* pwA_l  = pwA_h + kNN;
  u16* pwB_h  = pwA_l + kNN;
  u16* pwB_l  = pwB_h + kNN;

  float P[6], Q[6];
  pade_coeffs(P, Q);

  auto eg = [](long n){ return dim3((unsigned)((n+255)/256)); };

  // layer: messages (batch 8) -> big[0..7]; root+bias (batch 1) -> tnh
  auto layer_pre = [&](const float* hin, int K, const float* W, const float* Wr,
                       const float* bsum){
    launch_gemm<false,false,false,EPI_NONE>(stream, hin, K, W, kH, big, kH, kN, kH, K, 8,
                                            0, (long)K*kH, kNH, 0.f);
    launch_gemm<false,false,false,EPI_BIAS>(stream, hin, K, Wr, kH, tnh, kH, kN, kH, K, 1,
                                            0,0,0, 0.f, bsum);
  };
  auto sparse_layer = [&](const float* hin, int K, const float* W, const float* Wr,
                          const float* bsum, const float* lnp, float* zout){
    layer_pre(hin, K, W, Wr, bsum);
    scatter_kernel<<<dim3((unsigned)(((long)kNE*kH+255)/256),4),256,0,stream>>>(e0,e1,e2,e3, big, tnh);
    reduce2_part_kernel<<<kRB,256,0,stream>>>(tnh, kNH, partd);
    apply_ln_kernel<<<eg(kNH),256,0,stream>>>(tnh, zout, lnp, partd, kRB);
  };
  auto dense_layer = [&](const float* hin, int K, const float* W, const float* Wr,
                         const float* bsum, const float* lnp, float* zout){
    layer_pre(hin, K, W, Wr, bsum);
    scan_msg_kernel<<<8,256,0,stream>>>(big);
    gather_dense_kernel<<<kGB,256,0,stream>>>(big, gArr, hArr, tnh, partd);
    apply_ln_kernel<<<eg(kNH),256,0,stream>>>(tnh, zout, lnp, partd, kGB);
  };
  auto blocked_trsm = [&](){
    hipMemsetAsync(winv, 0, (size_t)kNN*sizeof(float), stream);
    invdiag_kernel<<<dim3(kN/kDB),64,0,stream>>>(qsq, winv);
    merge_fused_kernel<50><<<dim3(kN/100),256,0,stream>>>(qsq, winv);   // level s=50
    {   // level s=100 (4 pairs)
      int s = 100, npairs = 4;
      long step = (long)2*s*kN + 2*s;
      launch_gemm<false,false,true,EPI_NONE>(stream,
          qsq + s, kN, winv + (long)s*kN + s, kN, tri, s,
          s, s, s, npairs, step, step, (long)s*s, 0.f);
      launch_gemm<false,true,false,EPI_SCALE>(stream,
          winv, kN, tri, s, winv + s, kN,
          s, s, s, npairs, step, (long)s*s, step, -1.f);
    }
    {   // level s=200 (2 pairs)
      int s = 200, npairs = 2;
      long step = (long)2*s*kN + 2*s;
      launch_gemm<false,false,true,EPI_NONE>(stream,
          qsq + s, kN, winv + (long)s*kN + s, kN, tri, s,
          s, s, s, npairs, step, step, (long)s*s, 0.f);
      launch_gemm<false,true,false,EPI_SCALE>(stream,
          winv, kN, tri, s, winv + s, kN,
          s, s, s, npairs, step, (long)s*s, step, -1.f);
    }
    {   // level s=400 (1 pair) — K-split x4, atomic ACC
      hipMemsetAsync(tri, 0, (size_t)400*400*sizeof(float), stream);
      // T = qsq[0:400,400:800] @ Winv[400:,400:]  (B upper-tri, local coords)
      launch_gemm<false,false,true,EPI_ACC>(stream,
          qsq + 400, kN, winv + (long)400*kN + 400, kN, tri, 400,
          400, 400, 100, 4, 100, (long)100*kN, 0, 1.f, nullptr, 100);
      // Winv[0:400,400:800] = -Wtop @ T   (A upper-tri; dest is pristine zero)
      launch_gemm<false,true,false,EPI_ACC>(stream,
          winv, kN, tri, 400, winv + 400, kN,
          400, 400, 100, 4, 100, (long)100*400, 0, -1.f, nullptr, 100);
    }
    // Sacc = winv @ psq (unscaled), atomic fp32, 8 K-chunks
    hipMemsetAsync(Sacc, 0, (size_t)kNN*sizeof(float), stream);
    launch_gemm<false,true,true,EPI_ACC>(stream,
        winv, kN, psq, kN, Sacc, kN, kN, kN, 100, 8,
        100, (long)100*kN, 0, 1.f, nullptr, 100);
  };
  auto run_pair_mpa = [&](const float* z, float* SoutDst){
    hipMemsetAsync((char*)d_ws + 24, 0, 8, stream);            // scald[3] = 0
    pair_kernel<<<dim3(50,50),256,0,stream>>>(z, linW, linb, tri, scald+3);
    init_pade_kernel<<<eg(kNN),256,0,stream>>>(tri, papp_h, papp_l, psq, qsq, scald+3,
                                               P[0],P[1],Q[0],Q[1]);
    transpose_pade_kernel<<<dim3(25,25),256,0,stream>>>(tri, scald+3, pT_h, pT_l);
    dim3 g13(13,13,1);
    bgemm2_kernel<<<g13,256,0,stream>>>(papp_h,papp_l, pT_h,pT_l, psq,qsq, pwA_h,pwA_l, P[2],Q[2]);
    bgemm2_kernel<<<g13,256,0,stream>>>(pwA_h,pwA_l,  pT_h,pT_l, psq,qsq, pwB_h,pwB_l, P[3],Q[3]);
    bgemm2_kernel<<<g13,256,0,stream>>>(pwB_h,pwB_l,  pT_h,pT_l, psq,qsq, pwA_h,pwA_l, P[4],Q[4]);
    bgemm2_kernel<<<g13,256,0,stream>>>(pwA_h,pwA_l,  pT_h,pT_l, psq,qsq, pwB_h,pwB_l, P[5],Q[5]);
    blocked_trsm();
    copy_scale_kernel<<<eg(kNN),256,0,stream>>>(Sacc, scald+3, SoutDst);
  };
  auto s_times_h = [&](const float* hin, float* hout){
    hipMemsetAsync(hout, 0, (size_t)kN*kE*sizeof(float), stream);
    launch_gemm<false,true,false,EPI_ACC>(stream,
        Sacc, kN, hin, kE, hout, kE, kN, kE, 100, 8,
        100, (long)100*kE, 0, 1.f, nullptr, 100, scald+3);
  };

  float* S1f = out + 215;
  float* S2f = out + 215 + kNN;

  // ---- once: staircase g/h + root-weight/bias pre-sums
  hipMemsetAsync(gArr, 0xFF, (size_t)(4*kN)*sizeof(int), stream);   // -1
  edge_gmax_kernel<<<dim3((kNE+255)/256,4),256,0,stream>>>(e0,e1,e2,e3, gArr);
  scan_gh_kernel<<<4,256,0,stream>>>(gArr, hArr);
  sum_root_kernel<<<eg((long)kE*kH),256,0,stream>>>(g1w1, g1b1, kE, wr1, bs);
  sum_root_kernel<<<eg((long)kH*kH),256,0,stream>>>(g1w2, g1b2, kH, wr2, bs+kH);
  sum_root_kernel<<<eg((long)kE*kH),256,0,stream>>>(g2w1, g2b1, kE, wr3, bs+2*kH);
  sum_root_kernel<<<eg((long)kH*kH),256,0,stream>>>(g2w2, g2b2, kH, wr4, bs+3*kH);

  // ---- embed
  launch_gemm<false,false,false,EPI_BIAS>(stream, x_note, kF, embW, kE, h0, kE, kN, kE, kF, 1,
                                          0,0,0, 0.f, embB);

  // ---- GNN1 (sparse)
  sparse_layer(h0,  kE, g1w1, wr1, bs,      g1ln,        zmid);
  sparse_layer(zmid,kH, g1w2, wr2, bs+kH,   g1ln + 2*kH, z0);

  // ---- S1 (Sacc holds unscaled S1 until s_times_h)
  run_pair_mpa(z0, S1f);

  // ---- h1 = S1 @ h0
  s_times_h(h0, h1);

  // ---- GNN2 #1 (dense; mask1 == staircase(g,h))
  dense_layer(h1,  kE, g2w1, wr3, bs+2*kH, g2ln,        zmid);
  dense_layer(zmid,kH, g2w2, wr4, bs+3*kH, g2ln + 2*kH, z1);

  // ---- S2
  run_pair_mpa(z1, S2f);

  // ---- h2 = S2 @ h1
  s_times_h(h1, h2);

  // ---- GNN2 #2 (dense; mask2 == mask1)
  dense_layer(h2,  kE, g2w1, wr3, bs+2*kH, g2ln,        zmid);
  dense_layer(zmid,kH, g2w2, wr4, bs+3*kH, g2ln + 2*kH, z2);

  // ---- pool + classifier + log_softmax
  pool_head_kernel<<<dim3(1),256,0,stream>>>(z2, clfW, clfb, out);
}

// Round 12
// 1512.493 us; speedup vs baseline: 3.2789x; 1.0129x over previous
//
#include <hip/hip_runtime.h>
#include <hip/hip_bf16.h>
#include <math.h>
#include <stdio.h>

static constexpr int   kN  = 800;    // nodes
static constexpr int   kF  = 111;    // input features
static constexpr int   kE  = 32;     // embed dim
static constexpr int   kH  = 200;    // hidden
static constexpr int   kNC = 15;     // classes
static constexpr int   kNE = 8000;   // edges per type
static constexpr long  kNN = (long)kN*kN;   // 640000
static constexpr long  kNH = (long)kN*kH;   // 160000
static constexpr float kAl  = 0.5f;  // ALPHA
static constexpr float kEps = 1e-5f;
static constexpr int   kGB  = (int)((kNH+255)/256);  // gather blocks = 625
static constexpr int   kDB  = 50;    // trsm diagonal block size (800 = 16 * 50)

typedef unsigned short u16;
typedef __attribute__((ext_vector_type(8))) short short8;
typedef __attribute__((ext_vector_type(4))) float f32x4;

__device__ __forceinline__ u16 f2bf(float v){
  __hip_bfloat16 b = __float2bfloat16(v);
  return *reinterpret_cast<u16*>(&b);
}
__device__ __forceinline__ float bf2f(u16 h){
  unsigned int u = ((unsigned int)h) << 16;
  float f; __builtin_memcpy(&f, &u, 4);
  return f;
}

enum { EPI_NONE=0, EPI_BIAS=1, EPI_SCALE=4, EPI_ACC=6 };

// ---------------------------------------------------------------- fp32 GEMM
// C[M,N] = A * B, row strides lda/ldb/ldc.
// TRIUA: A[m,kglob]==0 for kglob<m; TRIUB: B[kglob,n]==0 for kglob>n (exact).
// kstep!=0: K-split; EPI_ACC: atomic C += scale*v (scale *= sqrt(sqrt(scalp[0]))
// if scalp given); skip blocks return early.
template<bool TRANSA, bool TRIUA, bool TRIUB, int EPI>
__global__ __launch_bounds__(256)
void gemm_kernel(const float* __restrict__ A, int lda,
                 const float* __restrict__ B, int ldb,
                 float* __restrict__ C, int ldc,
                 int M, int Ncl, int K,
                 long sA, long sB, long sC, float scale,
                 const float* __restrict__ bias, int kstep,
                 const double* __restrict__ scalp)
{
  constexpr int TM=64, TN=64, TK=16;
  A += (long)blockIdx.z * sA;
  B += (long)blockIdx.z * sB;
  C += (long)blockIdx.z * sC;
  __shared__ float As[TK][TM+4];
  __shared__ float Bs[TK][TN+4];
  const int tid = threadIdx.x;
  const int tn4 = (tid & 15)*4, tm4 = (tid >> 4)*4;
  const int m0 = blockIdx.x * TM, n0 = blockIdx.y * TN;
  float acc[4][4] = {};
  const int kbase = kstep ? (int)blockIdx.z * kstep : 0;
  int k0 = TRIUA ? max(m0 - kbase, 0) : 0;
  int kEnd = TRIUB ? min(K, n0 + TN - kbase) : K;
  const bool skip = (k0 >= kEnd);
  if (skip && EPI == EPI_ACC) return;
  if (!skip) {
    for (; k0 < kEnd; k0 += TK) {
      #pragma unroll
      for (int u=0; u<4; ++u) {
        int idx = tid + 256*u;
        if (!TRANSA) {
          int m = idx >> 4, ka = idx & 15;
          int gm = m0+m, gk = k0+ka;
          As[ka][m] = (gm < M && gk < K) ? A[(long)gm*lda + gk] : 0.f;
        } else {
          int ka = idx >> 6, m = idx & 63;
          int gm = m0+m, gk = k0+ka;
          As[ka][m] = (gm < M && gk < K) ? A[(long)gk*lda + gm] : 0.f;
        }
        int kb = idx >> 6, nb = idx & 63;
        int gk = k0+kb, gn = n0+nb;
        Bs[kb][nb] = (gk < K && gn < Ncl) ? B[(long)gk*ldb + gn] : 0.f;
      }
      __syncthreads();
      #pragma unroll
      for (int kk=0; kk<TK; ++kk) {
        float a[4], b[4];
        #pragma unroll
        for (int u=0;u<4;++u){ a[u]=As[kk][tm4+u]; b[u]=Bs[kk][tn4+u]; }
        #pragma unroll
        for (int i=0;i<4;++i)
          #pragma unroll
          for (int j=0;j<4;++j)
            acc[i][j] = fmaf(a[i], b[j], acc[i][j]);
      }
      __syncthreads();
    }
  }
  float sc = scale;
  if (EPI == EPI_ACC && scalp) sc *= (float)sqrt(sqrt(scalp[0]));
  #pragma unroll
  for (int i=0;i<4;++i) {
    int gm = m0 + tm4 + i;
    if (gm >= M) continue;
    #pragma unroll
    for (int j=0;j<4;++j) {
      int gn = n0 + tn4 + j;
      if (gn >= Ncl) continue;
      float v = acc[i][j];
      long off = (long)gm*ldc + gn;
      if (EPI == EPI_BIAS)       C[off] = v + bias[gn];
      else if (EPI == EPI_SCALE) C[off] = scale*v;
      else if (EPI == EPI_ACC)   unsafeAtomicAdd(&C[off], sc*v);
      else                       C[off] = v;
    }
  }
}

template<bool TRANSA, bool TRIUA, bool TRIUB, int EPI>
static inline void launch_gemm(hipStream_t st,
                               const float* A, int lda, const float* B, int ldb,
                               float* C, int ldc, int M, int Ncl, int K, int batch,
                               long sA, long sB, long sC, float scale,
                               const float* bias = nullptr, int kstep = 0,
                               const double* scalp = nullptr)
{
  dim3 grid((M+63)/64, (Ncl+63)/64, batch);
  gemm_kernel<TRANSA,TRIUA,TRIUB,EPI><<<grid, 256, 0, st>>>(
      A,lda,B,ldb,C,ldc,M,Ncl,K,sA,sB,sC,scale,bias,kstep,scalp);
}

// ---------------------------------------------------------------- split-bf16 MFMA GEMM (powers)
__global__ __launch_bounds__(256)
void bgemm2_kernel(const u16* __restrict__ Ah, const u16* __restrict__ Al,
                   const u16* __restrict__ Bh, const u16* __restrict__ Bl,
                   float* __restrict__ C, float* __restrict__ C2,
                   u16* __restrict__ Oh, u16* __restrict__ Ol,
                   float p0, float p1)
{
  constexpr int TM=64, TN=64, BK=32;
  __shared__ u16 Ash[TM][40], Asl[TM][40], Bsh[TN][40], Bsl[TN][40];
  const int tid = threadIdx.x;
  const int m0 = blockIdx.x*TM, n0 = blockIdx.y*TN;
  const int w = tid>>6, lane = tid&63;
  const int wm = (w&1)*32, wn = (w>>1)*32;
  const int quad = lane>>4, lm = lane&15;
  f32x4 acc00={}, acc01={}, acc10={}, acc11={};
  const bool skip = (m0 > n0 + TN - 1);
  int k0 = m0;
  const int kEnd = min(kN, n0+TN);
  const int ar = tid>>2, ac = (tid&3)*8;
  if (!skip){
    for (; k0 < kEnd; k0 += BK){
      uint4 avh={0,0,0,0}, avl={0,0,0,0}, bvh={0,0,0,0}, bvl={0,0,0,0};
      int gk = k0 + ac;
      if (m0+ar < kN && gk < kN){
        avh = *(const uint4*)(Ah + (long)(m0+ar)*kN + gk);
        avl = *(const uint4*)(Al + (long)(m0+ar)*kN + gk);
      }
      if (n0+ar < kN && gk < kN){
        bvh = *(const uint4*)(Bh + (long)(n0+ar)*kN + gk);
        bvl = *(const uint4*)(Bl + (long)(n0+ar)*kN + gk);
      }
      __syncthreads();
      *(uint4*)&Ash[ar][ac] = avh; *(uint4*)&Asl[ar][ac] = avl;
      *(uint4*)&Bsh[ar][ac] = bvh; *(uint4*)&Bsl[ar][ac] = bvl;
      __syncthreads();
      short8 a0h = *(const short8*)&Ash[wm+lm][quad*8];
      short8 a1h = *(const short8*)&Ash[wm+16+lm][quad*8];
      short8 a0l = *(const short8*)&Asl[wm+lm][quad*8];
      short8 a1l = *(const short8*)&Asl[wm+16+lm][quad*8];
      short8 b0h = *(const short8*)&Bsh[wn+lm][quad*8];
      short8 b1h = *(const short8*)&Bsh[wn+16+lm][quad*8];
      short8 b0l = *(const short8*)&Bsl[wn+lm][quad*8];
      short8 b1l = *(const short8*)&Bsl[wn+16+lm][quad*8];
      acc00 = __builtin_amdgcn_mfma_f32_16x16x32_bf16(a0h,b0h,acc00,0,0,0);
      acc00 = __builtin_amdgcn_mfma_f32_16x16x32_bf16(a0h,b0l,acc00,0,0,0);
      acc00 = __builtin_amdgcn_mfma_f32_16x16x32_bf16(a0l,b0h,acc00,0,0,0);
      acc01 = __builtin_amdgcn_mfma_f32_16x16x32_bf16(a0h,b1h,acc01,0,0,0);
      acc01 = __builtin_amdgcn_mfma_f32_16x16x32_bf16(a0h,b1l,acc01,0,0,0);
      acc01 = __builtin_amdgcn_mfma_f32_16x16x32_bf16(a0l,b1h,acc01,0,0,0);
      acc10 = __builtin_amdgcn_mfma_f32_16x16x32_bf16(a1h,b0h,acc10,0,0,0);
      acc10 = __builtin_amdgcn_mfma_f32_16x16x32_bf16(a1h,b0l,acc10,0,0,0);
      acc10 = __builtin_amdgcn_mfma_f32_16x16x32_bf16(a1l,b0h,acc10,0,0,0);
      acc11 = __builtin_amdgcn_mfma_f32_16x16x32_bf16(a1h,b1h,acc11,0,0,0);
      acc11 = __builtin_amdgcn_mfma_f32_16x16x32_bf16(a1h,b1l,acc11,0,0,0);
      acc11 = __builtin_amdgcn_mfma_f32_16x16x32_bf16(a1l,b1h,acc11,0,0,0);
    }
  }
  f32x4 accs[2][2] = {{acc00, acc01},{acc10, acc11}};
  #pragma unroll
  for (int ti=0; ti<2; ++ti){
    #pragma unroll
    for (int tj=0; tj<2; ++tj){
      #pragma unroll
      for (int r=0; r<4; ++r){
        int gm = m0 + wm + ti*16 + quad*4 + r;
        int gn = n0 + wn + tj*16 + lm;
        if (gm >= kN || gn >= kN) continue;
        float v = accs[ti][tj][r];
        long off = (long)gm*kN + gn;
        C[off]  += p0*v;
        C2[off] += p1*v;
        u16 h = f2bf(v);
        Oh[off] = h;
        Ol[off] = f2bf(v - bf2f(h));
      }
    }
  }
}

// ---- transposed pade init: dst[c][r] = hi/lo split of (I - tri/normA)[r][c]
__global__ __launch_bounds__(256)
void transpose_pade_kernel(const float* __restrict__ tri, const double* __restrict__ frob2,
                           u16* __restrict__ dh, u16* __restrict__ dl)
{
  __shared__ float t[32][33];
  const float rn = (float)(1.0 / sqrt(frob2[0]));
  int r0 = blockIdx.y*32, c0 = blockIdx.x*32;
  int tr = threadIdx.x>>5, tc = threadIdx.x&31;
  for (int i=tr; i<32; i+=8){
    int r = r0+i, c = c0+tc;
    float eye = (r==c) ? 1.f : 0.f;
    t[i][tc] = eye - tri[(long)r*kN + c]*rn;
  }
  __syncthreads();
  for (int i=tr; i<32; i+=8){
    int c = c0+i, r = r0+tc;
    float v = t[tc][i];
    u16 h = f2bf(v);
    dh[(long)c*kN + r] = h;
    dl[(long)c*kN + r] = f2bf(v - bf2f(h));
  }
}

// ---- stream S = Sacc * sqrt(normA) into d_out — single pass, non-temporal
__global__ __launch_bounds__(256)
void copy_scale_kernel(const float* __restrict__ src, const double* __restrict__ frob2,
                       float* __restrict__ dst)
{
  const float fac = (float)sqrt(sqrt(frob2[0]));
  long i = (long)blockIdx.x*256 + threadIdx.x;
  if (i < kNN) __builtin_nontemporal_store(src[i]*fac, &dst[i]);
}

// ---------------------------------------------------------------- CSR build (8 lists: in[e], out[e])
__global__ void edge_count_kernel(const int* __restrict__ e0, const int* __restrict__ e1,
                                  const int* __restrict__ e2, const int* __restrict__ e3,
                                  int* __restrict__ cnt){
  const int* eis[4] = {e0,e1,e2,e3};
  const int e = blockIdx.y;
  const int* ei = eis[e];
  int j = blockIdx.x*256 + threadIdx.x;
  if (j >= kNE) return;
  int s = ei[j], d = ei[kNE + j];
  atomicAdd(&cnt[e*kN + d], 1);         // in-list of d
  atomicAdd(&cnt[(4+e)*kN + s], 1);     // out-list of s
}

// serial prefix per list -> offs (kN+1), copy to cur
__global__ void csr_scan_kernel(const int* __restrict__ cnt, int* __restrict__ offs,
                                int* __restrict__ cur){
  const int l = blockIdx.x;             // 0..7
  if (threadIdx.x != 0) return;
  int acc = 0;
  for (int i = 0; i < kN; ++i){
    offs[l*(kN+1) + i] = acc;
    cur[l*kN + i] = acc;
    acc += cnt[l*kN + i];
  }
  offs[l*(kN+1) + kN] = acc;
}

__global__ void edge_fill_kernel(const int* __restrict__ e0, const int* __restrict__ e1,
                                 const int* __restrict__ e2, const int* __restrict__ e3,
                                 int* __restrict__ cur, int* __restrict__ adj){
  const int* eis[4] = {e0,e1,e2,e3};
  const int e = blockIdx.y;
  const int* ei = eis[e];
  int j = blockIdx.x*256 + threadIdx.x;
  if (j >= kNE) return;
  int s = ei[j], d = ei[kNE + j];
  int p = atomicAdd(&cur[e*kN + d], 1);
  adj[(long)e*kNE + p] = s;
  int q = atomicAdd(&cur[(4+e)*kN + s], 1);
  adj[(long)(4+e)*kNE + q] = d;
}

// CSR gather for sparse layers: one block per node; fused LN partials.
// tnh[n,f] += 0.5 * [ sum_e sum_{s in in[e][n]} Y[e][s][f]
//                   + sum_e sum_{d in out[e][n]} Y[4+e][d][f] ]
__global__ __launch_bounds__(256)
void gather_sparse_kernel(const float* __restrict__ Y, const int* __restrict__ offs,
                          const int* __restrict__ adj, float* __restrict__ tnh,
                          double* __restrict__ part){
  __shared__ double ss[256], qq[256];
  const int n = blockIdx.x;
  const int f = threadIdx.x;
  double sp = 0.0, qp = 0.0;
  float acc = 0.f;
  if (f < kH){
    #pragma unroll
    for (int l = 0; l < 8; ++l){
      const float* Yp = Y + (long)l*kNH;
      int b = offs[l*(kN+1) + n], e2 = offs[l*(kN+1) + n + 1];
      for (int idx = b; idx < e2; ++idx){
        int m = adj[(long)l*kNE + idx];
        acc += Yp[(long)m*kH + f];
      }
    }
    float t = tnh[(long)n*kH + f] + 0.5f*acc;
    tnh[(long)n*kH + f] = t;
    sp = t; qp = (double)t*t;
  }
  ss[threadIdx.x]=sp; qq[threadIdx.x]=qp;
  __syncthreads();
  for (int hh=128; hh>0; hh>>=1){
    if ((int)threadIdx.x < hh){ ss[threadIdx.x]+=ss[threadIdx.x+hh]; qq[threadIdx.x]+=qq[threadIdx.x+hh]; }
    __syncthreads();
  }
  if (threadIdx.x==0){ part[2*blockIdx.x]=ss[0]; part[2*blockIdx.x+1]=qq[0]; }
}

// ---------------------------------------------------------------- mask staircase kernels
__global__ void edge_gmax_kernel(const int* __restrict__ e0, const int* __restrict__ e1,
                                 const int* __restrict__ e2, const int* __restrict__ e3,
                                 int* __restrict__ g){
  const int* eis[4] = {e0,e1,e2,e3};
  const int e = blockIdx.y;
  const int* ei = eis[e];
  int j = blockIdx.x*256 + threadIdx.x;
  if (j >= kNE) return;
  int s = ei[j], d = ei[kNE + j];
  atomicMax(&g[e*kN + d], s);
}

__global__ __launch_bounds__(256)
void scan_gh_kernel(int* __restrict__ g, int* __restrict__ h){
  __shared__ int gs[kN];
  const int e = blockIdx.x;
  for (int i = threadIdx.x; i < kN; i += 256) gs[i] = g[e*kN + i];
  __syncthreads();
  if (threadIdx.x == 0){
    int m = -1;
    for (int i = 0; i < kN; ++i){ m = max(m, gs[i]); gs[i] = m; }
  }
  __syncthreads();
  for (int i = threadIdx.x; i < kN; i += 256) g[e*kN + i] = gs[i];
  for (int d = threadIdx.x; d < kN; d += 256){
    int lo = 0, hi = kN;
    while (lo < hi){ int mid = (lo+hi)>>1; if (gs[mid] >= d) hi = mid; else lo = mid+1; }
    h[e*kN + d] = lo;
  }
}

// in-place scans over Y planes: z<4 -> prefix over n; z>=4 -> suffix
__global__ __launch_bounds__(256)
void scan_msg_kernel(float* __restrict__ Y){
  const int plane = blockIdx.x;          // 0..7
  const int f = threadIdx.x;
  if (f >= kH) return;
  float* P = Y + (long)plane*kNH + f;
  float acc = 0.f;
  if (plane < 4){
    for (int n = 0; n < kN; n += 4){
      float v0 = P[(long)(n+0)*kH], v1 = P[(long)(n+1)*kH];
      float v2 = P[(long)(n+2)*kH], v3 = P[(long)(n+3)*kH];
      acc += v0; P[(long)(n+0)*kH] = acc;
      acc += v1; P[(long)(n+1)*kH] = acc;
      acc += v2; P[(long)(n+2)*kH] = acc;
      acc += v3; P[(long)(n+3)*kH] = acc;
    }
  } else {
    for (int n = kN-1; n >= 0; n -= 4){
      float v0 = P[(long)(n-0)*kH], v1 = P[(long)(n-1)*kH];
      float v2 = P[(long)(n-2)*kH], v3 = P[(long)(n-3)*kH];
      acc += v0; P[(long)(n-0)*kH] = acc;
      acc += v1; P[(long)(n-1)*kH] = acc;
      acc += v2; P[(long)(n-2)*kH] = acc;
      acc += v3; P[(long)(n-3)*kH] = acc;
    }
  }
}

// gather + fused LN partials (dense staircase)
__global__ __launch_bounds__(256)
void gather_dense_kernel(const float* __restrict__ Y, const int* __restrict__ g,
                         const int* __restrict__ h, float* __restrict__ tnh,
                         double* __restrict__ part){
  __shared__ double ss[256], qq[256];
  long idx = (long)blockIdx.x*256 + threadIdx.x;
  double s = 0.0, q = 0.0;
  if (idx < kNH){
    int n = (int)(idx / kH), f = (int)(idx % kH);
    float v = 0.f;
    #pragma unroll
    for (int e = 0; e < 4; ++e){
      int gi = g[e*kN + n];
      if (gi >= 0) v += Y[(long)e*kNH + (long)gi*kH + f];
      int hi = h[e*kN + n];
      if (hi < kN) v += Y[(long)(4+e)*kNH + (long)hi*kH + f];
    }
    float t = tnh[idx] + 0.5f*v;
    tnh[idx] = t;
    s = t; q = (double)t*t;
  }
  ss[threadIdx.x]=s; qq[threadIdx.x]=q;
  __syncthreads();
  for (int hh=128; hh>0; hh>>=1){
    if ((int)threadIdx.x < hh){ ss[threadIdx.x]+=ss[threadIdx.x+hh]; qq[threadIdx.x]+=qq[threadIdx.x+hh]; }
    __syncthreads();
  }
  if (threadIdx.x==0){ part[2*blockIdx.x]=ss[0]; part[2*blockIdx.x+1]=qq[0]; }
}

// ---------------------------------------------------------------- small kernels
// Wr = sum_e W[2,e];  bsum[f] = sum_e((1-a)b0+a b1+b2)
__global__ void sum_root_kernel(const float* __restrict__ W, const float* __restrict__ b,
                                int K, float* __restrict__ Wr, float* __restrict__ bsum){
  int idx = blockIdx.x*256 + threadIdx.x;
  int tot = K*kH;
  if (idx < tot){
    float v = 0.f;
    #pragma unroll
    for (int e=0;e<4;++e) v += W[(long)(8+e)*tot + idx];
    Wr[idx] = v;
  }
  if (idx < kH){
    float v = 0.f;
    #pragma unroll
    for (int e=0;e<4;++e)
      v += (1.f-kAl)*b[(0*4+e)*kH + idx] + kAl*b[(1*4+e)*kH + idx] + b[(2*4+e)*kH + idx];
    bsum[idx] = v;
  }
}

// graph layernorm with inline final reduction of nb partials
__global__ __launch_bounds__(256)
void apply_ln_kernel(const float* __restrict__ x, float* __restrict__ y,
                     const float* __restrict__ ln, const double* __restrict__ part, int nb){
  __shared__ double ss[256], qq[256];
  int t = threadIdx.x;
  double s=0.0, q=0.0;
  for (int i=t; i<nb; i+=256){ s += part[2*i]; q += part[2*i+1]; }
  ss[t]=s; qq[t]=q;
  __syncthreads();
  for (int h=128; h>0; h>>=1){
    if (t < h){ ss[t]+=ss[t+h]; qq[t]+=qq[t+h]; }
    __syncthreads();
  }
  long idx = (long)blockIdx.x*256 + t;
  if (idx >= kNH) return;
  double mu  = ss[0] / (double)kNH;
  double var = qq[0] / (double)kNH - mu*mu;
  float rs = rsqrtf((float)var + kEps);
  int f = (int)(idx % kH);
  y[idx] = (x[idx] - (float)mu) * rs * ln[f] + ln[kH + f];
}

// pair + fused frobenius sumsq (atomic f64 into frob2; zero it first!)
__global__ __launch_bounds__(256)
void pair_kernel(const float* __restrict__ z, const float* __restrict__ linW,
                 const float* __restrict__ linb, float* __restrict__ tri,
                 double* __restrict__ frob2){
  __shared__ float zi[16][201], zj[16][201], w[208];
  __shared__ float red[256];
  const int i0 = blockIdx.y*16, j0 = blockIdx.x*16;
  const int tid = threadIdx.x;
  const int ti = tid >> 4, tj = tid & 15;
  const int i = i0+ti, j = j0+tj;
  if (i0 > j0 + 15) { tri[(long)i*kN + j] = 0.f; return; }
  for (int idx = tid; idx < 16*kH; idx += 256){
    int r = idx / kH, c = idx % kH;
    zi[r][c] = z[(long)(i0+r)*kH + c];
    zj[r][c] = z[(long)(j0+r)*kH + c];
  }
  if (tid < kH) w[tid] = linW[tid];
  __syncthreads();
  float g = 0.f;
  if (i <= j){
    float s = linb[0];
    #pragma unroll 4
    for (int k=0;k<kH;++k){ float d = zi[ti][k]-zj[tj][k]; s = fmaf(d*d, w[k], s); }
    g = 1.f/(1.f + expf(-s));
  }
  tri[(long)i*kN + j] = g;
  red[tid] = g*g;
  __syncthreads();
  for (int h=128; h>0; h>>=1){
    if (tid < h) red[tid] += red[tid+h];
    __syncthreads();
  }
  if (tid == 0) unsafeAtomicAdd(frob2, (double)red[0]);
}

__global__ void init_pade_kernel(const float* __restrict__ tri,
                                 u16* __restrict__ papp_h, u16* __restrict__ papp_l,
                                 float* __restrict__ psq, float* __restrict__ qsq,
                                 const double* __restrict__ frob2,
                                 float P0, float P1, float Q0, float Q1){
  int idx = blockIdx.x*256 + threadIdx.x;
  if (idx >= (int)kNN) return;
  int i = idx / kN, j = idx % kN;
  float rn = (float)(1.0 / sqrt(frob2[0]));
  float eye = (i==j) ? 1.f : 0.f;
  float pa = eye - tri[idx]*rn;
  u16 h = f2bf(pa);
  papp_h[idx] = h;
  papp_l[idx] = f2bf(pa - bf2f(h));
  psq[idx] = P0*eye + P1*pa;
  qsq[idx] = Q0*eye + Q1*pa;
}

// ---- invert the 16 diagonal 50x50 upper-tri blocks of U into W (W pre-zeroed)
__global__ __launch_bounds__(64)
void invdiag_kernel(const float* __restrict__ U, float* __restrict__ W){
  __shared__ float Us[kDB][kDB+1];
  __shared__ float Xs[kDB][kDB+1];
  const int base = blockIdx.x * kDB;
  const int tid = threadIdx.x;
  for (int idx = tid; idx < kDB*kDB; idx += 64){
    int r = idx / kDB, c = idx % kDB;
    Us[r][c] = U[(long)(base+r)*kN + base + c];
  }
  __syncthreads();
  const int c = tid;
  for (int i = kDB-1; i >= 0; --i){
    if (c < kDB){
      float x;
      if (c < i) x = 0.f;
      else {
        float s = 0.f;
        for (int k = i+1; k < kDB; ++k) s = fmaf(Us[i][k], Xs[k][c], s);
        x = (((c==i)?1.f:0.f) - s) / Us[i][i];
      }
      Xs[i][c] = x;
    }
    __syncthreads();
  }
  for (int idx = tid; idx < kDB*kDB; idx += 64){
    int r = idx / kDB, cc = idx % kDB;
    W[(long)(base+r)*kN + base + cc] = Xs[r][cc];
  }
}

// ---- fused merge for level S: one block per pair.
template<int S>
__global__ __launch_bounds__(256)
void merge_fused_kernel(const float* __restrict__ U, float* __restrict__ W){
  __shared__ float Us[S][S+1];
  __shared__ float Wb[S][S+1];
  __shared__ float T[S][S+1];
  const long base = (long)blockIdx.x * (2*S) * (kN+1);
  const int tid = threadIdx.x;
  for (int idx = tid; idx < S*S; idx += 256){
    int r = idx / S, c = idx % S;
    Us[r][c] = U[base + (long)r*kN + S + c];
    Wb[r][c] = W[base + (long)(S+r)*kN + S + c];
  }
  __syncthreads();
  for (int idx = tid; idx < S*S; idx += 256){
    int r = idx / S, c = idx % S;
    float s = 0.f;
    for (int k = 0; k <= c; ++k) s = fmaf(Us[r][k], Wb[k][c], s);
    T[r][c] = s;
  }
  __syncthreads();
  for (int idx = tid; idx < S*S; idx += 256){
    int r = idx / S, c = idx % S;
    Us[r][c] = W[base + (long)r*kN + c];
  }
  __syncthreads();
  for (int idx = tid; idx < S*S; idx += 256){
    int r = idx / S, c = idx % S;
    float s = 0.f;
    for (int k = r; k < S; ++k) s = fmaf(Us[r][k], T[k][c], s);
    W[base + (long)r*kN + S + c] = -s;
  }
}

__global__ __launch_bounds__(256)
void pool_head_kernel(const float* __restrict__ z2, const float* __restrict__ W,
                      const float* __restrict__ b, float* __restrict__ out){
  __shared__ float x2[kH];
  __shared__ float lg[kNC];
  int t = threadIdx.x;
  if (t < kH){
    float s = 0.f;
    for (int n = 0; n < kN; ++n) s += z2[(long)n*kH + t];
    float v = s * (1.f/(float)kN);
    x2[t] = v;
    out[t] = v;
  }
  __syncthreads();
  if (t < kNC){
    float s = b[t];
    for (int f = 0; f < kH; ++f) s = fmaf(x2[f], W[f*kNC + t], s);
    lg[t] = s;
  }
  __syncthreads();
  if (t == 0){
    float m = -1e30f;
    for (int c=0;c<kNC;++c) m = fmaxf(m, lg[c]);
    float se = 0.f;
    for (int c=0;c<kNC;++c) se += expf(lg[c]-m);
    float lse = m + logf(se);
    for (int c=0;c<kNC;++c) out[kH + c] = lg[c]-lse;
  }
}

// ---------------------------------------------------------------- host: Pade [5/5] of sqrt(1-x)
static void pade_coeffs(float* P, float* Q){
  double b[11]; b[0] = 1.0;
  for (int k=1;k<11;++k) b[k] = b[k-1]*(0.5-(k-1))/k;
  double c[11];
  for (int k=0;k<11;++k) c[k] = b[k]*((k&1)?-1.0:1.0);
  double A[5][5], rhs[5];
  for (int i=0;i<5;++i){ for (int j=0;j<5;++j) A[i][j] = c[5+i-j]; rhs[i] = -c[6+i]; }
  for (int col=0; col<5; ++col){
    int p = col;
    for (int r=col+1;r<5;++r) if (fabs(A[r][col]) > fabs(A[p][col])) p = r;
    if (p != col){
      for (int j=0;j<5;++j){ double t=A[col][j]; A[col][j]=A[p][j]; A[p][j]=t; }
      double t=rhs[col]; rhs[col]=rhs[p]; rhs[p]=t;
    }
    for (int r=col+1;r<5;++r){
      double f = A[r][col]/A[col][col];
      for (int j=col;j<5;++j) A[r][j] -= f*A[col][j];
      rhs[r] -= f*rhs[col];
    }
  }
  double q[6]; q[0] = 1.0;
  for (int r=4;r>=0;--r){
    double s = rhs[r];
    for (int j=r+1;j<5;++j) s -= A[r][j]*q[1+j];
    q[1+r] = s/A[r][r];
  }
  double p[6];
  for (int k=0;k<6;++k){
    double s = 0.0; int jm = k<5?k:5;
    for (int j=0;j<=jm;++j) s += q[j]*c[k-j];
    p[k] = s;
  }
  for (int k=0;k<6;++k){ P[k]=(float)p[k]; Q[k]=(float)q[k]; }
}

// ---------------------------------------------------------------- launch
extern "C" void kernel_launch(void* const* d_in, const int* in_sizes, int n_in,
                              void* d_out, int out_size, void* d_ws, size_t ws_size,
                              hipStream_t stream)
{
  const float* x_note = (const float*)d_in[0];
  const float* embW   = (const float*)d_in[1];
  const float* embB   = (const float*)d_in[2];
  const float* g1w1   = (const float*)d_in[3];
  const float* g1b1   = (const float*)d_in[4];
  const float* g1w2   = (const float*)d_in[5];
  const float* g1b2   = (const float*)d_in[6];
  const float* g1ln   = (const float*)d_in[7];
  const float* g2w1   = (const float*)d_in[8];
  const float* g2b1   = (const float*)d_in[9];
  const float* g2w2   = (const float*)d_in[10];
  const float* g2b2   = (const float*)d_in[11];
  const float* g2ln   = (const float*)d_in[12];
  const float* linW   = (const float*)d_in[13];
  const float* linb   = (const float*)d_in[14];
  const float* clfW   = (const float*)d_in[15];
  const float* clfb   = (const float*)d_in[16];
  const int*  e0     = (const int*)d_in[17];
  const int*  e1     = (const int*)d_in[18];
  const int*  e2     = (const int*)d_in[19];
  const int*  e3     = (const int*)d_in[20];
  float* out = (float*)d_out;

  // header: scald @0 (32B), partd @512B (room for 800 pairs = 12.8 KB)
  constexpr long o_h0   = 4096;
  constexpr long o_h1   = o_h0   + (long)kN*kE;
  constexpr long o_h2   = o_h1   + (long)kN*kE;
  constexpr long o_tnh  = o_h2   + (long)kN*kE;
  constexpr long o_zmid = o_tnh  + kNH;
  constexpr long o_z0   = o_zmid + kNH;
  constexpr long o_z1   = o_z0   + kNH;
  constexpr long o_z2   = o_z1   + kNH;
  constexpr long o_big  = o_z2   + kNH;             // 4*kNN floats
  constexpr long o_tri  = o_big  + 4*kNN;
  constexpr long o_sacc = o_tri  + kNN;
  constexpr long o_winv = o_sacc + kNN;
  constexpr long o_psq  = o_winv + kNN;
  constexpr long o_qsq  = o_psq  + kNN;
  constexpr long o_g    = o_qsq  + kNN;             // int g[4][kN]
  constexpr long o_hh   = o_g    + 4*kN;            // int h[4][kN]
  constexpr long o_wr1  = o_hh   + 4*kN;
  constexpr long o_wr2  = o_wr1  + (long)kE*kH;
  constexpr long o_wr3  = o_wr2  + (long)kH*kH;
  constexpr long o_wr4  = o_wr3  + (long)kE*kH;
  constexpr long o_bs   = o_wr4  + (long)kH*kH;     // 4 x kH bias sums
  constexpr long o_cnt  = o_bs   + 4*kH;            // int cnt[8][kN]
  constexpr long o_offs = o_cnt  + 8*kN;            // int offs[8][kN+1]
  constexpr long o_cur  = o_offs + 8*(kN+1);        // int cur[8][kN]
  constexpr long o_adj  = o_cur  + 8*kN;            // int adj[8][kNE]
  constexpr long o_end  = o_adj  + 8*(long)kNE;

  if (ws_size < (size_t)o_end*sizeof(float) || out_size < 215 + 2*(int)kNN || n_in < 21){
    fprintf(stderr, "kernel_launch guard: ws=%zu need=%zu out=%d need=%d n_in=%d\n",
            ws_size, (size_t)o_end*sizeof(float), out_size, (int)(215+2*kNN), n_in);
    hipMemsetAsync(d_out, 0, (size_t)out_size*sizeof(float), stream);
    return;
  }

  float* ws = (float*)d_ws;
  double* scald = (double*)d_ws;
  double* partd = (double*)((char*)d_ws + 512);
  float *h0=ws+o_h0, *h1=ws+o_h1, *h2=ws+o_h2, *tnh=ws+o_tnh,
        *zmid=ws+o_zmid, *z0=ws+o_z0, *z1=ws+o_z1, *z2=ws+o_z2, *big=ws+o_big,
        *tri=ws+o_tri, *Sacc=ws+o_sacc, *winv=ws+o_winv, *psq=ws+o_psq, *qsq=ws+o_qsq;
  int* gArr = (int*)(ws + o_g);
  int* hArr = (int*)(ws + o_hh);
  float *wr1=ws+o_wr1, *wr2=ws+o_wr2, *wr3=ws+o_wr3, *wr4=ws+o_wr4, *bs=ws+o_bs;
  int* cntA = (int*)(ws + o_cnt);
  int* offsA= (int*)(ws + o_offs);
  int* curA = (int*)(ws + o_cur);
  int* adjA = (int*)(ws + o_adj);
  // power-phase split scratch aliased inside big (8 u16 planes = 4*kNN floats)
  u16* papp_h = (u16*)big;
  u16* papp_l = papp_h + kNN;
  u16* pT_h   = papp_l + kNN;
  u16* pT_l   = pT_h + kNN;
  u16* pwA_h  = pT_l + kNN;
  u16* pwA_l  = pwA_h + kNN;
  u16* pwB_h  = pwA_l + kNN;
  u16* pwB_l  = pwB_h + kNN;

  float P[6], Q[6];
  pade_coeffs(P, Q);

  auto eg = [](long n){ return dim3((unsigned)((n+255)/256)); };

  auto layer_pre = [&](const float* hin, int K, const float* W, const float* Wr,
                       const float* bsum){
    launch_gemm<false,false,false,EPI_NONE>(stream, hin, K, W, kH, big, kH, kN, kH, K, 8,
                                            0, (long)K*kH, kNH, 0.f);
    launch_gemm<false,false,false,EPI_BIAS>(stream, hin, K, Wr, kH, tnh, kH, kN, kH, K, 1,
                                            0,0,0, 0.f, bsum);
  };
  auto sparse_layer = [&](const float* hin, int K, const float* W, const float* Wr,
                          const float* bsum, const float* lnp, float* zout){
    layer_pre(hin, K, W, Wr, bsum);
    gather_sparse_kernel<<<dim3(kN),256,0,stream>>>(big, offsA, adjA, tnh, partd);
    apply_ln_kernel<<<eg(kNH),256,0,stream>>>(tnh, zout, lnp, partd, kN);
  };
  auto dense_layer = [&](const float* hin, int K, const float* W, const float* Wr,
                         const float* bsum, const float* lnp, float* zout){
    layer_pre(hin, K, W, Wr, bsum);
    scan_msg_kernel<<<8,256,0,stream>>>(big);
    gather_dense_kernel<<<kGB,256,0,stream>>>(big, gArr, hArr, tnh, partd);
    apply_ln_kernel<<<eg(kNH),256,0,stream>>>(tnh, zout, lnp, partd, kGB);
  };
  auto blocked_trsm = [&](){
    hipMemsetAsync(winv, 0, (size_t)kNN*sizeof(float), stream);
    invdiag_kernel<<<dim3(kN/kDB),64,0,stream>>>(qsq, winv);
    merge_fused_kernel<50><<<dim3(kN/100),256,0,stream>>>(qsq, winv);
    {   // level s=100 (4 pairs)
      int s = 100, npairs = 4;
      long step = (long)2*s*kN + 2*s;
      launch_gemm<false,false,true,EPI_NONE>(stream,
          qsq + s, kN, winv + (long)s*kN + s, kN, tri, s,
          s, s, s, npairs, step, step, (long)s*s, 0.f);
      launch_gemm<false,true,false,EPI_SCALE>(stream,
          winv, kN, tri, s, winv + s, kN,
          s, s, s, npairs, step, (long)s*s, step, -1.f);
    }
    {   // level s=200 (2 pairs)
      int s = 200, npairs = 2;
      long step = (long)2*s*kN + 2*s;
      launch_gemm<false,false,true,EPI_NONE>(stream,
          qsq + s, kN, winv + (long)s*kN + s, kN, tri, s,
          s, s, s, npairs, step, step, (long)s*s, 0.f);
      launch_gemm<false,true,false,EPI_SCALE>(stream,
          winv, kN, tri, s, winv + s, kN,
          s, s, s, npairs, step, (long)s*s, step, -1.f);
    }
    {   // level s=400 (1 pair) — K-split x4, atomic ACC
      hipMemsetAsync(tri, 0, (size_t)400*400*sizeof(float), stream);
      launch_gemm<false,false,true,EPI_ACC>(stream,
          qsq + 400, kN, winv + (long)400*kN + 400, kN, tri, 400,
          400, 400, 100, 4, 100, (long)100*kN, 0, 1.f, nullptr, 100);
      launch_gemm<false,true,false,EPI_ACC>(stream,
          winv, kN, tri, 400, winv + 400, kN,
          400, 400, 100, 4, 100, (long)100*400, 0, -1.f, nullptr, 100);
    }
    hipMemsetAsync(Sacc, 0, (size_t)kNN*sizeof(float), stream);
    launch_gemm<false,true,true,EPI_ACC>(stream,
        winv, kN, psq, kN, Sacc, kN, kN, kN, 100, 8,
        100, (long)100*kN, 0, 1.f, nullptr, 100);
  };
  auto run_pair_mpa = [&](const float* z, float* SoutDst){
    hipMemsetAsync((char*)d_ws + 24, 0, 8, stream);            // scald[3] = 0
    pair_kernel<<<dim3(50,50),256,0,stream>>>(z, linW, linb, tri, scald+3);
    init_pade_kernel<<<eg(kNN),256,0,stream>>>(tri, papp_h, papp_l, psq, qsq, scald+3,
                                               P[0],P[1],Q[0],Q[1]);
    transpose_pade_kernel<<<dim3(25,25),256,0,stream>>>(tri, scald+3, pT_h, pT_l);
    dim3 g13(13,13,1);
    bgemm2_kernel<<<g13,256,0,stream>>>(papp_h,papp_l, pT_h,pT_l, psq,qsq, pwA_h,pwA_l, P[2],Q[2]);
    bgemm2_kernel<<<g13,256,0,stream>>>(pwA_h,pwA_l,  pT_h,pT_l, psq,qsq, pwB_h,pwB_l, P[3],Q[3]);
    bgemm2_kernel<<<g13,256,0,stream>>>(pwB_h,pwB_l,  pT_h,pT_l, psq,qsq, pwA_h,pwA_l, P[4],Q[4]);
    bgemm2_kernel<<<g13,256,0,stream>>>(pwA_h,pwA_l,  pT_h,pT_l, psq,qsq, pwB_h,pwB_l, P[5],Q[5]);
    blocked_trsm();
    copy_scale_kernel<<<eg(kNN),256,0,stream>>>(Sacc, scald+3, SoutDst);
  };
  auto s_times_h = [&](const float* hin, float* hout){
    hipMemsetAsync(hout, 0, (size_t)kN*kE*sizeof(float), stream);
    launch_gemm<false,true,false,EPI_ACC>(stream,
        Sacc, kN, hin, kE, hout, kE, kN, kE, 100, 8,
        100, (long)100*kE, 0, 1.f, nullptr, 100, scald+3);
  };

  float* S1f = out + 215;
  float* S2f = out + 215 + kNN;

  // ---- once: staircase g/h, CSR build, root-weight/bias pre-sums
  hipMemsetAsync(gArr, 0xFF, (size_t)(4*kN)*sizeof(int), stream);   // -1
  edge_gmax_kernel<<<dim3((kNE+255)/256,4),256,0,stream>>>(e0,e1,e2,e3, gArr);
  scan_gh_kernel<<<4,256,0,stream>>>(gArr, hArr);
  hipMemsetAsync(cntA, 0, (size_t)(8*kN)*sizeof(int), stream);
  edge_count_kernel<<<dim3((kNE+255)/256,4),256,0,stream>>>(e0,e1,e2,e3, cntA);
  csr_scan_kernel<<<8,64,0,stream>>>(cntA, offsA, curA);
  edge_fill_kernel<<<dim3((kNE+255)/256,4),256,0,stream>>>(e0,e1,e2,e3, curA, adjA);
  sum_root_kernel<<<eg((long)kE*kH),256,0,stream>>>(g1w1, g1b1, kE, wr1, bs);
  sum_root_kernel<<<eg((long)kH*kH),256,0,stream>>>(g1w2, g1b2, kH, wr2, bs+kH);
  sum_root_kernel<<<eg((long)kE*kH),256,0,stream>>>(g2w1, g2b1, kE, wr3, bs+2*kH);
  sum_root_kernel<<<eg((long)kH*kH),256,0,stream>>>(g2w2, g2b2, kH, wr4, bs+3*kH);

  // ---- embed
  launch_gemm<false,false,false,EPI_BIAS>(stream, x_note, kF, embW, kE, h0, kE, kN, kE, kF, 1,
                                          0,0,0, 0.f, embB);

  // ---- GNN1 (sparse, CSR gather)
  sparse_layer(h0,  kE, g1w1, wr1, bs,      g1ln,        zmid);
  sparse_layer(zmid,kH, g1w2, wr2, bs+kH,   g1ln + 2*kH, z0);

  // ---- S1 (Sacc holds unscaled S1 until s_times_h)
  run_pair_mpa(z0, S1f);

  // ---- h1 = S1 @ h0
  s_times_h(h0, h1);

  // ---- GNN2 #1 (dense; mask1 == staircase(g,h))
  dense_layer(h1,  kE, g2w1, wr3, bs+2*kH, g2ln,        zmid);
  dense_layer(zmid,kH, g2w2, wr4, bs+3*kH, g2ln + 2*kH, z1);

  // ---- S2
  run_pair_mpa(z1, S2f);

  // ---- h2 = S2 @ h1
  s_times_h(h1, h2);

  // ---- GNN2 #2 (dense; mask2 == mask1)
  dense_layer(h2,  kE, g2w1, wr3, bs+2*kH, g2ln,        zmid);
  dense_layer(zmid,kH, g2w2, wr4, bs+3*kH, g2ln + 2*kH, z2);

  // ---- pool + classifier + log_softmax
  pool_head_kernel<<<dim3(1),256,0,stream>>>(z2, clfW, clfb, out);
}

// Round 13
// 1190.993 us; speedup vs baseline: 4.1640x; 1.2699x over previous
//
#include <hip/hip_runtime.h>
#include <hip/hip_bf16.h>
#include <math.h>
#include <stdio.h>

static constexpr int   kN  = 800;    // nodes
static constexpr int   kF  = 111;    // input features
static constexpr int   kE  = 32;     // embed dim
static constexpr int   kH  = 200;    // hidden
static constexpr int   kNC = 15;     // classes
static constexpr int   kNE = 8000;   // edges per type
static constexpr long  kNN = (long)kN*kN;   // 640000
static constexpr long  kNH = (long)kN*kH;   // 160000
static constexpr float kAl  = 0.5f;  // ALPHA
static constexpr float kEps = 1e-5f;
static constexpr int   kGB  = (int)((kNH+255)/256);  // gather blocks = 625
static constexpr int   kDB  = 50;    // trsm diagonal block size (800 = 16 * 50)

typedef unsigned short u16;
typedef __attribute__((ext_vector_type(8))) short short8;
typedef __attribute__((ext_vector_type(4))) float f32x4;

__device__ __forceinline__ u16 f2bf(float v){
  __hip_bfloat16 b = __float2bfloat16(v);
  return *reinterpret_cast<u16*>(&b);
}
__device__ __forceinline__ float bf2f(u16 h){
  unsigned int u = ((unsigned int)h) << 16;
  float f; __builtin_memcpy(&f, &u, 4);
  return f;
}

enum { EPI_NONE=0, EPI_BIAS=1, EPI_SCALE=4, EPI_ACC=6 };

// ---------------------------------------------------------------- fp32 GEMM (software-pipelined)
// C[M,N] = A * B, row strides lda/ldb/ldc.
// TRIUA: A[m,kglob]==0 for kglob<m; TRIUB: B[kglob,n]==0 for kglob>n (exact).
// kstep!=0: K-split; EPI_ACC: atomic C += scale*v (scale *= sqrt(sqrt(scalp[0]))
// if scalp given); skip blocks return early.
template<bool TRANSA, bool TRIUA, bool TRIUB, int EPI>
__global__ __launch_bounds__(256)
void gemm_kernel(const float* __restrict__ A, int lda,
                 const float* __restrict__ B, int ldb,
                 float* __restrict__ C, int ldc,
                 int M, int Ncl, int K,
                 long sA, long sB, long sC, float scale,
                 const float* __restrict__ bias, int kstep,
                 const double* __restrict__ scalp)
{
  constexpr int TM=64, TN=64, TK=16;
  A += (long)blockIdx.z * sA;
  B += (long)blockIdx.z * sB;
  C += (long)blockIdx.z * sC;
  __shared__ float As[TK][TM+4];
  __shared__ float Bs[TK][TN+4];
  const int tid = threadIdx.x;
  const int tn4 = (tid & 15)*4, tm4 = (tid >> 4)*4;
  const int m0 = blockIdx.x * TM, n0 = blockIdx.y * TN;
  float acc[4][4] = {};
  const int kbase = kstep ? (int)blockIdx.z * kstep : 0;
  int k0 = TRIUA ? max(m0 - kbase, 0) : 0;
  int kEnd = TRIUB ? min(K, n0 + TN - kbase) : K;
  const bool skip = (k0 >= kEnd);
  if (skip && EPI == EPI_ACC) return;
  if (!skip) {
    float ar[4], br[4];
    auto loadT = [&](int kk0, float* arr, float* brr){
      #pragma unroll
      for (int u=0; u<4; ++u){
        int idx = tid + 256*u;
        float av;
        if (!TRANSA) {
          int m = idx >> 4, ka = idx & 15;
          int gm = m0+m, gk = kk0+ka;
          av = (gm < M && gk < K) ? A[(long)gm*lda + gk] : 0.f;
        } else {
          int ka = idx >> 6, m = idx & 63;
          int gm = m0+m, gk = kk0+ka;
          av = (gm < M && gk < K) ? A[(long)gk*lda + gm] : 0.f;
        }
        int kb = idx >> 6, nb = idx & 63;
        int gk = kk0+kb, gn = n0+nb;
        arr[u] = av;
        brr[u] = (gk < K && gn < Ncl) ? B[(long)gk*ldb + gn] : 0.f;
      }
    };
    auto storeT = [&](const float* arr, const float* brr){
      #pragma unroll
      for (int u=0; u<4; ++u){
        int idx = tid + 256*u;
        if (!TRANSA){ int m = idx>>4, ka = idx&15; As[ka][m] = arr[u]; }
        else        { int ka = idx>>6, m = idx&63; As[ka][m] = arr[u]; }
        int kb = idx>>6, nb = idx&63;
        Bs[kb][nb] = brr[u];
      }
    };
    loadT(k0, ar, br);
    for (;;){
      __syncthreads();          // WAR: previous iteration's LDS readers done
      storeT(ar, br);
      __syncthreads();
      int kn = k0 + TK;
      bool more = kn < kEnd;
      if (more) loadT(kn, ar, br);   // prefetch overlaps compute below
      #pragma unroll
      for (int kk=0; kk<TK; ++kk) {
        float a[4], b[4];
        #pragma unroll
        for (int u=0;u<4;++u){ a[u]=As[kk][tm4+u]; b[u]=Bs[kk][tn4+u]; }
        #pragma unroll
        for (int i=0;i<4;++i)
          #pragma unroll
          for (int j=0;j<4;++j)
            acc[i][j] = fmaf(a[i], b[j], acc[i][j]);
      }
      if (!more) break;
      k0 = kn;
    }
  }
  float sc = scale;
  if (EPI == EPI_ACC && scalp) sc *= (float)sqrt(sqrt(scalp[0]));
  #pragma unroll
  for (int i=0;i<4;++i) {
    int gm = m0 + tm4 + i;
    if (gm >= M) continue;
    #pragma unroll
    for (int j=0;j<4;++j) {
      int gn = n0 + tn4 + j;
      if (gn >= Ncl) continue;
      float v = acc[i][j];
      long off = (long)gm*ldc + gn;
      if (EPI == EPI_BIAS)       C[off] = v + bias[gn];
      else if (EPI == EPI_SCALE) C[off] = scale*v;
      else if (EPI == EPI_ACC)   unsafeAtomicAdd(&C[off], sc*v);
      else                       C[off] = v;
    }
  }
}

template<bool TRANSA, bool TRIUA, bool TRIUB, int EPI>
static inline void launch_gemm(hipStream_t st,
                               const float* A, int lda, const float* B, int ldb,
                               float* C, int ldc, int M, int Ncl, int K, int batch,
                               long sA, long sB, long sC, float scale,
                               const float* bias = nullptr, int kstep = 0,
                               const double* scalp = nullptr)
{
  dim3 grid((M+63)/64, (Ncl+63)/64, batch);
  gemm_kernel<TRANSA,TRIUA,TRIUB,EPI><<<grid, 256, 0, st>>>(
      A,lda,B,ldb,C,ldc,M,Ncl,K,sA,sB,sC,scale,bias,kstep,scalp);
}

// ---------------------------------------------------------------- split-bf16 MFMA GEMM (powers, pipelined)
__global__ __launch_bounds__(256)
void bgemm2_kernel(const u16* __restrict__ Ah, const u16* __restrict__ Al,
                   const u16* __restrict__ Bh, const u16* __restrict__ Bl,
                   float* __restrict__ C, float* __restrict__ C2,
                   u16* __restrict__ Oh, u16* __restrict__ Ol,
                   float p0, float p1)
{
  constexpr int TM=64, TN=64, BK=32;
  __shared__ u16 Ash[TM][40], Asl[TM][40], Bsh[TN][40], Bsl[TN][40];
  const int tid = threadIdx.x;
  const int m0 = blockIdx.x*TM, n0 = blockIdx.y*TN;
  const int w = tid>>6, lane = tid&63;
  const int wm = (w&1)*32, wn = (w>>1)*32;
  const int quad = lane>>4, lm = lane&15;
  f32x4 acc00={}, acc01={}, acc10={}, acc11={};
  const bool skip = (m0 > n0 + TN - 1);
  int k0 = m0;
  const int kEnd = min(kN, n0+TN);
  const int ar = tid>>2, ac = (tid&3)*8;
  if (!skip){
    uint4 avh, avl, bvh, bvl;
    auto loadT = [&](int kk0){
      avh = {0,0,0,0}; avl = {0,0,0,0}; bvh = {0,0,0,0}; bvl = {0,0,0,0};
      int gk = kk0 + ac;
      if (m0+ar < kN && gk < kN){
        avh = *(const uint4*)(Ah + (long)(m0+ar)*kN + gk);
        avl = *(const uint4*)(Al + (long)(m0+ar)*kN + gk);
      }
      if (n0+ar < kN && gk < kN){
        bvh = *(const uint4*)(Bh + (long)(n0+ar)*kN + gk);
        bvl = *(const uint4*)(Bl + (long)(n0+ar)*kN + gk);
      }
    };
    loadT(k0);
    for (;;){
      __syncthreads();
      *(uint4*)&Ash[ar][ac] = avh; *(uint4*)&Asl[ar][ac] = avl;
      *(uint4*)&Bsh[ar][ac] = bvh; *(uint4*)&Bsl[ar][ac] = bvl;
      __syncthreads();
      int kn = k0 + BK;
      bool more = kn < kEnd;
      if (more) loadT(kn);               // prefetch overlaps MFMAs below
      short8 a0h = *(const short8*)&Ash[wm+lm][quad*8];
      short8 a1h = *(const short8*)&Ash[wm+16+lm][quad*8];
      short8 a0l = *(const short8*)&Asl[wm+lm][quad*8];
      short8 a1l = *(const short8*)&Asl[wm+16+lm][quad*8];
      short8 b0h = *(const short8*)&Bsh[wn+lm][quad*8];
      short8 b1h = *(const short8*)&Bsh[wn+16+lm][quad*8];
      short8 b0l = *(const short8*)&Bsl[wn+lm][quad*8];
      short8 b1l = *(const short8*)&Bsl[wn+16+lm][quad*8];
      acc00 = __builtin_amdgcn_mfma_f32_16x16x32_bf16(a0h,b0h,acc00,0,0,0);
      acc00 = __builtin_amdgcn_mfma_f32_16x16x32_bf16(a0h,b0l,acc00,0,0,0);
      acc00 = __builtin_amdgcn_mfma_f32_16x16x32_bf16(a0l,b0h,acc00,0,0,0);
      acc01 = __builtin_amdgcn_mfma_f32_16x16x32_bf16(a0h,b1h,acc01,0,0,0);
      acc01 = __builtin_amdgcn_mfma_f32_16x16x32_bf16(a0h,b1l,acc01,0,0,0);
      acc01 = __builtin_amdgcn_mfma_f32_16x16x32_bf16(a0l,b1h,acc01,0,0,0);
      acc10 = __builtin_amdgcn_mfma_f32_16x16x32_bf16(a1h,b0h,acc10,0,0,0);
      acc10 = __builtin_amdgcn_mfma_f32_16x16x32_bf16(a1h,b0l,acc10,0,0,0);
      acc10 = __builtin_amdgcn_mfma_f32_16x16x32_bf16(a1l,b0h,acc10,0,0,0);
      acc11 = __builtin_amdgcn_mfma_f32_16x16x32_bf16(a1h,b1h,acc11,0,0,0);
      acc11 = __builtin_amdgcn_mfma_f32_16x16x32_bf16(a1h,b1l,acc11,0,0,0);
      acc11 = __builtin_amdgcn_mfma_f32_16x16x32_bf16(a1l,b1h,acc11,0,0,0);
      if (!more) break;
      k0 = kn;
    }
  }
  f32x4 accs[2][2] = {{acc00, acc01},{acc10, acc11}};
  #pragma unroll
  for (int ti=0; ti<2; ++ti){
    #pragma unroll
    for (int tj=0; tj<2; ++tj){
      #pragma unroll
      for (int r=0; r<4; ++r){
        int gm = m0 + wm + ti*16 + quad*4 + r;
        int gn = n0 + wn + tj*16 + lm;
        if (gm >= kN || gn >= kN) continue;
        float v = accs[ti][tj][r];
        long off = (long)gm*kN + gn;
        C[off]  += p0*v;
        C2[off] += p1*v;
        u16 h = f2bf(v);
        Oh[off] = h;
        Ol[off] = f2bf(v - bf2f(h));
      }
    }
  }
}

// ---- transposed pade init: dst[c][r] = hi/lo split of (I - tri/normA)[r][c]
__global__ __launch_bounds__(256)
void transpose_pade_kernel(const float* __restrict__ tri, const double* __restrict__ frob2,
                           u16* __restrict__ dh, u16* __restrict__ dl)
{
  __shared__ float t[32][33];
  const float rn = (float)(1.0 / sqrt(frob2[0]));
  int r0 = blockIdx.y*32, c0 = blockIdx.x*32;
  int tr = threadIdx.x>>5, tc = threadIdx.x&31;
  for (int i=tr; i<32; i+=8){
    int r = r0+i, c = c0+tc;
    float eye = (r==c) ? 1.f : 0.f;
    t[i][tc] = eye - tri[(long)r*kN + c]*rn;
  }
  __syncthreads();
  for (int i=tr; i<32; i+=8){
    int c = c0+i, r = r0+tc;
    float v = t[tc][i];
    u16 h = f2bf(v);
    dh[(long)c*kN + r] = h;
    dl[(long)c*kN + r] = f2bf(v - bf2f(h));
  }
}

// ---- stream S = Sacc * sqrt(normA) into d_out — single pass, non-temporal
__global__ __launch_bounds__(256)
void copy_scale_kernel(const float* __restrict__ src, const double* __restrict__ frob2,
                       float* __restrict__ dst)
{
  const float fac = (float)sqrt(sqrt(frob2[0]));
  long i = (long)blockIdx.x*256 + threadIdx.x;
  if (i < kNN) __builtin_nontemporal_store(src[i]*fac, &dst[i]);
}

// ---------------------------------------------------------------- CSR build (8 lists: in[e], out[e])
__global__ void edge_count_kernel(const int* __restrict__ e0, const int* __restrict__ e1,
                                  const int* __restrict__ e2, const int* __restrict__ e3,
                                  int* __restrict__ cnt){
  const int* eis[4] = {e0,e1,e2,e3};
  const int e = blockIdx.y;
  const int* ei = eis[e];
  int j = blockIdx.x*256 + threadIdx.x;
  if (j >= kNE) return;
  int s = ei[j], d = ei[kNE + j];
  atomicAdd(&cnt[e*kN + d], 1);
  atomicAdd(&cnt[(4+e)*kN + s], 1);
}

__global__ void csr_scan_kernel(const int* __restrict__ cnt, int* __restrict__ offs,
                                int* __restrict__ cur){
  const int l = blockIdx.x;
  if (threadIdx.x != 0) return;
  int acc = 0;
  for (int i = 0; i < kN; ++i){
    offs[l*(kN+1) + i] = acc;
    cur[l*kN + i] = acc;
    acc += cnt[l*kN + i];
  }
  offs[l*(kN+1) + kN] = acc;
}

__global__ void edge_fill_kernel(const int* __restrict__ e0, const int* __restrict__ e1,
                                 const int* __restrict__ e2, const int* __restrict__ e3,
                                 int* __restrict__ cur, int* __restrict__ adj){
  const int* eis[4] = {e0,e1,e2,e3};
  const int e = blockIdx.y;
  const int* ei = eis[e];
  int j = blockIdx.x*256 + threadIdx.x;
  if (j >= kNE) return;
  int s = ei[j], d = ei[kNE + j];
  int p = atomicAdd(&cur[e*kN + d], 1);
  adj[(long)e*kNE + p] = s;
  int q = atomicAdd(&cur[(4+e)*kN + s], 1);
  adj[(long)(4+e)*kNE + q] = d;
}

// CSR gather (sparse layers) + fused LN partials
__global__ __launch_bounds__(256)
void gather_sparse_kernel(const float* __restrict__ Y, const int* __restrict__ offs,
                          const int* __restrict__ adj, float* __restrict__ tnh,
                          double* __restrict__ part){
  __shared__ double ss[256], qq[256];
  const int n = blockIdx.x;
  const int f = threadIdx.x;
  double sp = 0.0, qp = 0.0;
  float acc = 0.f;
  if (f < kH){
    #pragma unroll
    for (int l = 0; l < 8; ++l){
      const float* Yp = Y + (long)l*kNH;
      int b = offs[l*(kN+1) + n], e2 = offs[l*(kN+1) + n + 1];
      for (int idx = b; idx < e2; ++idx){
        int m = adj[(long)l*kNE + idx];
        acc += Yp[(long)m*kH + f];
      }
    }
    float t = tnh[(long)n*kH + f] + 0.5f*acc;
    tnh[(long)n*kH + f] = t;
    sp = t; qp = (double)t*t;
  }
  ss[threadIdx.x]=sp; qq[threadIdx.x]=qp;
  __syncthreads();
  for (int hh=128; hh>0; hh>>=1){
    if ((int)threadIdx.x < hh){ ss[threadIdx.x]+=ss[threadIdx.x+hh]; qq[threadIdx.x]+=qq[threadIdx.x+hh]; }
    __syncthreads();
  }
  if (threadIdx.x==0){ part[2*blockIdx.x]=ss[0]; part[2*blockIdx.x+1]=qq[0]; }
}

// ---------------------------------------------------------------- mask staircase kernels
__global__ void edge_gmax_kernel(const int* __restrict__ e0, const int* __restrict__ e1,
                                 const int* __restrict__ e2, const int* __restrict__ e3,
                                 int* __restrict__ g){
  const int* eis[4] = {e0,e1,e2,e3};
  const int e = blockIdx.y;
  const int* ei = eis[e];
  int j = blockIdx.x*256 + threadIdx.x;
  if (j >= kNE) return;
  int s = ei[j], d = ei[kNE + j];
  atomicMax(&g[e*kN + d], s);
}

__global__ __launch_bounds__(256)
void scan_gh_kernel(int* __restrict__ g, int* __restrict__ h){
  __shared__ int gs[kN];
  const int e = blockIdx.x;
  for (int i = threadIdx.x; i < kN; i += 256) gs[i] = g[e*kN + i];
  __syncthreads();
  if (threadIdx.x == 0){
    int m = -1;
    for (int i = 0; i < kN; ++i){ m = max(m, gs[i]); gs[i] = m; }
  }
  __syncthreads();
  for (int i = threadIdx.x; i < kN; i += 256) g[e*kN + i] = gs[i];
  for (int d = threadIdx.x; d < kN; d += 256){
    int lo = 0, hi = kN;
    while (lo < hi){ int mid = (lo+hi)>>1; if (gs[mid] >= d) hi = mid; else lo = mid+1; }
    h[e*kN + d] = lo;
  }
}

// in-place scans over Y planes: z<4 -> prefix over n; z>=4 -> suffix
__global__ __launch_bounds__(256)
void scan_msg_kernel(float* __restrict__ Y){
  const int plane = blockIdx.x;
  const int f = threadIdx.x;
  if (f >= kH) return;
  float* P = Y + (long)plane*kNH + f;
  float acc = 0.f;
  if (plane < 4){
    for (int n = 0; n < kN; n += 4){
      float v0 = P[(long)(n+0)*kH], v1 = P[(long)(n+1)*kH];
      float v2 = P[(long)(n+2)*kH], v3 = P[(long)(n+3)*kH];
      acc += v0; P[(long)(n+0)*kH] = acc;
      acc += v1; P[(long)(n+1)*kH] = acc;
      acc += v2; P[(long)(n+2)*kH] = acc;
      acc += v3; P[(long)(n+3)*kH] = acc;
    }
  } else {
    for (int n = kN-1; n >= 0; n -= 4){
      float v0 = P[(long)(n-0)*kH], v1 = P[(long)(n-1)*kH];
      float v2 = P[(long)(n-2)*kH], v3 = P[(long)(n-3)*kH];
      acc += v0; P[(long)(n-0)*kH] = acc;
      acc += v1; P[(long)(n-1)*kH] = acc;
      acc += v2; P[(long)(n-2)*kH] = acc;
      acc += v3; P[(long)(n-3)*kH] = acc;
    }
  }
}

// gather + fused LN partials (dense staircase)
__global__ __launch_bounds__(256)
void gather_dense_kernel(const float* __restrict__ Y, const int* __restrict__ g,
                         const int* __restrict__ h, float* __restrict__ tnh,
                         double* __restrict__ part){
  __shared__ double ss[256], qq[256];
  long idx = (long)blockIdx.x*256 + threadIdx.x;
  double s = 0.0, q = 0.0;
  if (idx < kNH){
    int n = (int)(idx / kH), f = (int)(idx % kH);
    float v = 0.f;
    #pragma unroll
    for (int e = 0; e < 4; ++e){
      int gi = g[e*kN + n];
      if (gi >= 0) v += Y[(long)e*kNH + (long)gi*kH + f];
      int hi = h[e*kN + n];
      if (hi < kN) v += Y[(long)(4+e)*kNH + (long)hi*kH + f];
    }
    float t = tnh[idx] + 0.5f*v;
    tnh[idx] = t;
    s = t; q = (double)t*t;
  }
  ss[threadIdx.x]=s; qq[threadIdx.x]=q;
  __syncthreads();
  for (int hh=128; hh>0; hh>>=1){
    if ((int)threadIdx.x < hh){ ss[threadIdx.x]+=ss[threadIdx.x+hh]; qq[threadIdx.x]+=qq[threadIdx.x+hh]; }
    __syncthreads();
  }
  if (threadIdx.x==0){ part[2*blockIdx.x]=ss[0]; part[2*blockIdx.x+1]=qq[0]; }
}

// ---------------------------------------------------------------- small kernels
__global__ void sum_root_kernel(const float* __restrict__ W, const float* __restrict__ b,
                                int K, float* __restrict__ Wr, float* __restrict__ bsum){
  int idx = blockIdx.x*256 + threadIdx.x;
  int tot = K*kH;
  if (idx < tot){
    float v = 0.f;
    #pragma unroll
    for (int e=0;e<4;++e) v += W[(long)(8+e)*tot + idx];
    Wr[idx] = v;
  }
  if (idx < kH){
    float v = 0.f;
    #pragma unroll
    for (int e=0;e<4;++e)
      v += (1.f-kAl)*b[(0*4+e)*kH + idx] + kAl*b[(1*4+e)*kH + idx] + b[(2*4+e)*kH + idx];
    bsum[idx] = v;
  }
}

// graph layernorm with inline final reduction of nb partials
__global__ __launch_bounds__(256)
void apply_ln_kernel(const float* __restrict__ x, float* __restrict__ y,
                     const float* __restrict__ ln, const double* __restrict__ part, int nb){
  __shared__ double ss[256], qq[256];
  int t = threadIdx.x;
  double s=0.0, q=0.0;
  for (int i=t; i<nb; i+=256){ s += part[2*i]; q += part[2*i+1]; }
  ss[t]=s; qq[t]=q;
  __syncthreads();
  for (int h=128; h>0; h>>=1){
    if (t < h){ ss[t]+=ss[t+h]; qq[t]+=qq[t+h]; }
    __syncthreads();
  }
  long idx = (long)blockIdx.x*256 + t;
  if (idx >= kNH) return;
  double mu  = ss[0] / (double)kNH;
  double var = qq[0] / (double)kNH - mu*mu;
  float rs = rsqrtf((float)var + kEps);
  int f = (int)(idx % kH);
  y[idx] = (x[idx] - (float)mu) * rs * ln[f] + ln[kH + f];
}

// pair + fused frobenius sumsq (atomic f64 into frob2; zero it first!)
__global__ __launch_bounds__(256)
void pair_kernel(const float* __restrict__ z, const float* __restrict__ linW,
                 const float* __restrict__ linb, float* __restrict__ tri,
                 double* __restrict__ frob2){
  __shared__ float zi[16][201], zj[16][201], w[208];
  __shared__ float red[256];
  const int i0 = blockIdx.y*16, j0 = blockIdx.x*16;
  const int tid = threadIdx.x;
  const int ti = tid >> 4, tj = tid & 15;
  const int i = i0+ti, j = j0+tj;
  if (i0 > j0 + 15) { tri[(long)i*kN + j] = 0.f; return; }
  for (int idx = tid; idx < 16*kH; idx += 256){
    int r = idx / kH, c = idx % kH;
    zi[r][c] = z[(long)(i0+r)*kH + c];
    zj[r][c] = z[(long)(j0+r)*kH + c];
  }
  if (tid < kH) w[tid] = linW[tid];
  __syncthreads();
  float g = 0.f;
  if (i <= j){
    float s = linb[0];
    #pragma unroll 4
    for (int k=0;k<kH;++k){ float d = zi[ti][k]-zj[tj][k]; s = fmaf(d*d, w[k], s); }
    g = 1.f/(1.f + expf(-s));
  }
  tri[(long)i*kN + j] = g;
  red[tid] = g*g;
  __syncthreads();
  for (int h=128; h>0; h>>=1){
    if (tid < h) red[tid] += red[tid+h];
    __syncthreads();
  }
  if (tid == 0) unsafeAtomicAdd(frob2, (double)red[0]);
}

__global__ void init_pade_kernel(const float* __restrict__ tri,
                                 u16* __restrict__ papp_h, u16* __restrict__ papp_l,
                                 float* __restrict__ psq, float* __restrict__ qsq,
                                 const double* __restrict__ frob2,
                                 float P0, float P1, float Q0, float Q1){
  int idx = blockIdx.x*256 + threadIdx.x;
  if (idx >= (int)kNN) return;
  int i = idx / kN, j = idx % kN;
  float rn = (float)(1.0 / sqrt(frob2[0]));
  float eye = (i==j) ? 1.f : 0.f;
  float pa = eye - tri[idx]*rn;
  u16 h = f2bf(pa);
  papp_h[idx] = h;
  papp_l[idx] = f2bf(pa - bf2f(h));
  psq[idx] = P0*eye + P1*pa;
  qsq[idx] = Q0*eye + Q1*pa;
}

// ---- invert the 16 diagonal 50x50 upper-tri blocks of U into W (W pre-zeroed)
__global__ __launch_bounds__(64)
void invdiag_kernel(const float* __restrict__ U, float* __restrict__ W){
  __shared__ float Us[kDB][kDB+1];
  __shared__ float Xs[kDB][kDB+1];
  const int base = blockIdx.x * kDB;
  const int tid = threadIdx.x;
  for (int idx = tid; idx < kDB*kDB; idx += 64){
    int r = idx / kDB, c = idx % kDB;
    Us[r][c] = U[(long)(base+r)*kN + base + c];
  }
  __syncthreads();
  const int c = tid;
  for (int i = kDB-1; i >= 0; --i){
    if (c < kDB){
      float x;
      if (c < i) x = 0.f;
      else {
        float s = 0.f;
        for (int k = i+1; k < kDB; ++k) s = fmaf(Us[i][k], Xs[k][c], s);
        x = (((c==i)?1.f:0.f) - s) / Us[i][i];
      }
      Xs[i][c] = x;
    }
    __syncthreads();
  }
  for (int idx = tid; idx < kDB*kDB; idx += 64){
    int r = idx / kDB, cc = idx % kDB;
    W[(long)(base+r)*kN + base + cc] = Xs[r][cc];
  }
}

// ---- fused merge for level S: one block per pair.
template<int S>
__global__ __launch_bounds__(256)
void merge_fused_kernel(const float* __restrict__ U, float* __restrict__ W){
  __shared__ float Us[S][S+1];
  __shared__ float Wb[S][S+1];
  __shared__ float T[S][S+1];
  const long base = (long)blockIdx.x * (2*S) * (kN+1);
  const int tid = threadIdx.x;
  for (int idx = tid; idx < S*S; idx += 256){
    int r = idx / S, c = idx % S;
    Us[r][c] = U[base + (long)r*kN + S + c];
    Wb[r][c] = W[base + (long)(S+r)*kN + S + c];
  }
  __syncthreads();
  for (int idx = tid; idx < S*S; idx += 256){
    int r = idx / S, c = idx % S;
    float s = 0.f;
    for (int k = 0; k <= c; ++k) s = fmaf(Us[r][k], Wb[k][c], s);
    T[r][c] = s;
  }
  __syncthreads();
  for (int idx = tid; idx < S*S; idx += 256){
    int r = idx / S, c = idx % S;
    Us[r][c] = W[base + (long)r*kN + c];
  }
  __syncthreads();
  for (int idx = tid; idx < S*S; idx += 256){
    int r = idx / S, c = idx % S;
    float s = 0.f;
    for (int k = r; k < S; ++k) s = fmaf(Us[r][k], T[k][c], s);
    W[base + (long)r*kN + S + c] = -s;
  }
}

__global__ __launch_bounds__(256)
void pool_head_kernel(const float* __restrict__ z2, const float* __restrict__ W,
                      const float* __restrict__ b, float* __restrict__ out){
  __shared__ float x2[kH];
  __shared__ float lg[kNC];
  int t = threadIdx.x;
  if (t < kH){
    float s = 0.f;
    for (int n = 0; n < kN; ++n) s += z2[(long)n*kH + t];
    float v = s * (1.f/(float)kN);
    x2[t] = v;
    out[t] = v;
  }
  __syncthreads();
  if (t < kNC){
    float s = b[t];
    for (int f = 0; f < kH; ++f) s = fmaf(x2[f], W[f*kNC + t], s);
    lg[t] = s;
  }
  __syncthreads();
  if (t == 0){
    float m = -1e30f;
    for (int c=0;c<kNC;++c) m = fmaxf(m, lg[c]);
    float se = 0.f;
    for (int c=0;c<kNC;++c) se += expf(lg[c]-m);
    float lse = m + logf(se);
    for (int c=0;c<kNC;++c) out[kH + c] = lg[c]-lse;
  }
}

// ---------------------------------------------------------------- host: Pade [5/5] of sqrt(1-x)
static void pade_coeffs(float* P, float* Q){
  double b[11]; b[0] = 1.0;
  for (int k=1;k<11;++k) b[k] = b[k-1]*(0.5-(k-1))/k;
  double c[11];
  for (int k=0;k<11;++k) c[k] = b[k]*((k&1)?-1.0:1.0);
  double A[5][5], rhs[5];
  for (int i=0;i<5;++i){ for (int j=0;j<5;++j) A[i][j] = c[5+i-j]; rhs[i] = -c[6+i]; }
  for (int col=0; col<5; ++col){
    int p = col;
    for (int r=col+1;r<5;++r) if (fabs(A[r][col]) > fabs(A[p][col])) p = r;
    if (p != col){
      for (int j=0;j<5;++j){ double t=A[col][j]; A[col][j]=A[p][j]; A[p][j]=t; }
      double t=rhs[col]; rhs[col]=rhs[p]; rhs[p]=t;
    }
    for (int r=col+1;r<5;++r){
      double f = A[r][col]/A[col][col];
      for (int j=col;j<5;++j) A[r][j] -= f*A[col][j];
      rhs[r] -= f*rhs[col];
    }
  }
  double q[6]; q[0] = 1.0;
  for (int r=4;r>=0;--r){
    double s = rhs[r];
    for (int j=r+1;j<5;++j) s -= A[r][j]*q[1+j];
    q[1+r] = s/A[r][r];
  }
  double p[6];
  for (int k=0;k<6;++k){
    double s = 0.0; int jm = k<5?k:5;
    for (int j=0;j<=jm;++j) s += q[j]*c[k-j];
    p[k] = s;
  }
  for (int k=0;k<6;++k){ P[k]=(float)p[k]; Q[k]=(float)q[k]; }
}

// ---------------------------------------------------------------- launch
extern "C" void kernel_launch(void* const* d_in, const int* in_sizes, int n_in,
                              void* d_out, int out_size, void* d_ws, size_t ws_size,
                              hipStream_t stream)
{
  const float* x_note = (const float*)d_in[0];
  const float* embW   = (const float*)d_in[1];
  const float* embB   = (const float*)d_in[2];
  const float* g1w1   = (const float*)d_in[3];
  const float* g1b1   = (const float*)d_in[4];
  const float* g1w2   = (const float*)d_in[5];
  const float* g1b2   = (const float*)d_in[6];
  const float* g1ln   = (const float*)d_in[7];
  const float* g2w1   = (const float*)d_in[8];
  const float* g2b1   = (const float*)d_in[9];
  const float* g2w2   = (const float*)d_in[10];
  const float* g2b2   = (const float*)d_in[11];
  const float* g2ln   = (const float*)d_in[12];
  const float* linW   = (const float*)d_in[13];
  const float* linb   = (const float*)d_in[14];
  const float* clfW   = (const float*)d_in[15];
  const float* clfb   = (const float*)d_in[16];
  const int*  e0     = (const int*)d_in[17];
  const int*  e1     = (const int*)d_in[18];
  const int*  e2     = (const int*)d_in[19];
  const int*  e3     = (const int*)d_in[20];
  float* out = (float*)d_out;

  // header: scald @0 (32B), partd @512B
  constexpr long o_h0   = 4096;
  constexpr long o_h1   = o_h0   + (long)kN*kE;
  constexpr long o_h2   = o_h1   + (long)kN*kE;
  constexpr long o_tnh  = o_h2   + (long)kN*kE;
  constexpr long o_zmid = o_tnh  + kNH;
  constexpr long o_z0   = o_zmid + kNH;
  constexpr long o_z1   = o_z0   + kNH;
  constexpr long o_z2   = o_z1   + kNH;
  constexpr long o_big  = o_z2   + kNH;
  constexpr long o_tri  = o_big  + 4*kNN;
  constexpr long o_sacc = o_tri  + kNN;
  constexpr long o_winv = o_sacc + kNN;
  constexpr long o_psq  = o_winv + kNN;
  constexpr long o_qsq  = o_psq  + kNN;
  constexpr long o_g    = o_qsq  + kNN;
  constexpr long o_hh   = o_g    + 4*kN;
  constexpr long o_wr1  = o_hh   + 4*kN;
  constexpr long o_wr2  = o_wr1  + (long)kE*kH;
  constexpr long o_wr3  = o_wr2  + (long)kH*kH;
  constexpr long o_wr4  = o_wr3  + (long)kE*kH;
  constexpr long o_bs   = o_wr4  + (long)kH*kH;
  constexpr long o_cnt  = o_bs   + 4*kH;
  constexpr long o_offs = o_cnt  + 8*kN;
  constexpr long o_cur  = o_offs + 8*(kN+1);
  constexpr long o_adj  = o_cur  + 8*kN;
  constexpr long o_end  = o_adj  + 8*(long)kNE;

  if (ws_size < (size_t)o_end*sizeof(float) || out_size < 215 + 2*(int)kNN || n_in < 21){
    fprintf(stderr, "kernel_launch guard: ws=%zu need=%zu out=%d need=%d n_in=%d\n",
            ws_size, (size_t)o_end*sizeof(float), out_size, (int)(215+2*kNN), n_in);
    hipMemsetAsync(d_out, 0, (size_t)out_size*sizeof(float), stream);
    return;
  }

  float* ws = (float*)d_ws;
  double* scald = (double*)d_ws;
  double* partd = (double*)((char*)d_ws + 512);
  float *h0=ws+o_h0, *h1=ws+o_h1, *h2=ws+o_h2, *tnh=ws+o_tnh,
        *zmid=ws+o_zmid, *z0=ws+o_z0, *z1=ws+o_z1, *z2=ws+o_z2, *big=ws+o_big,
        *tri=ws+o_tri, *Sacc=ws+o_sacc, *winv=ws+o_winv, *psq=ws+o_psq, *qsq=ws+o_qsq;
  int* gArr = (int*)(ws + o_g);
  int* hArr = (int*)(ws + o_hh);
  float *wr1=ws+o_wr1, *wr2=ws+o_wr2, *wr3=ws+o_wr3, *wr4=ws+o_wr4, *bs=ws+o_bs;
  int* cntA = (int*)(ws + o_cnt);
  int* offsA= (int*)(ws + o_offs);
  int* curA = (int*)(ws + o_cur);
  int* adjA = (int*)(ws + o_adj);
  u16* papp_h = (u16*)big;
  u16* papp_l = papp_h + kNN;
  u16* pT_h   = papp_l + kNN;
  u16* pT_l   = pT_h + kNN;
  u16* pwA_h  = pT_l + kNN;
  u16* pwA_l  = pwA_h + kNN;
  u16* pwB_h  = pwA_l + kNN;
  u16* pwB_l  = pwB_h + kNN;

  float P[6], Q[6];
  pade_coeffs(P, Q);

  auto eg = [](long n){ return dim3((unsigned)((n+255)/256)); };

  auto layer_pre = [&](const float* hin, int K, const float* W, const float* Wr,
                       const float* bsum){
    launch_gemm<false,false,false,EPI_NONE>(stream, hin, K, W, kH, big, kH, kN, kH, K, 8,
                                            0, (long)K*kH, kNH, 0.f);
    launch_gemm<false,false,false,EPI_BIAS>(stream, hin, K, Wr, kH, tnh, kH, kN, kH, K, 1,
                                            0,0,0, 0.f, bsum);
  };
  auto sparse_layer = [&](const float* hin, int K, const float* W, const float* Wr,
                          const float* bsum, const float* lnp, float* zout){
    layer_pre(hin, K, W, Wr, bsum);
    gather_sparse_kernel<<<dim3(kN),256,0,stream>>>(big, offsA, adjA, tnh, partd);
    apply_ln_kernel<<<eg(kNH),256,0,stream>>>(tnh, zout, lnp, partd, kN);
  };
  auto dense_layer = [&](const float* hin, int K, const float* W, const float* Wr,
                         const float* bsum, const float* lnp, float* zout){
    layer_pre(hin, K, W, Wr, bsum);
    scan_msg_kernel<<<8,256,0,stream>>>(big);
    gather_dense_kernel<<<kGB,256,0,stream>>>(big, gArr, hArr, tnh, partd);
    apply_ln_kernel<<<eg(kNH),256,0,stream>>>(tnh, zout, lnp, partd, kGB);
  };
  auto blocked_trsm = [&](){
    hipMemsetAsync(winv, 0, (size_t)kNN*sizeof(float), stream);
    invdiag_kernel<<<dim3(kN/kDB),64,0,stream>>>(qsq, winv);
    merge_fused_kernel<50><<<dim3(kN/100),256,0,stream>>>(qsq, winv);
    {   // level s=100 (4 pairs)
      int s = 100, npairs = 4;
      long step = (long)2*s*kN + 2*s;
      launch_gemm<false,false,true,EPI_NONE>(stream,
          qsq + s, kN, winv + (long)s*kN + s, kN, tri, s,
          s, s, s, npairs, step, step, (long)s*s, 0.f);
      launch_gemm<false,true,false,EPI_SCALE>(stream,
          winv, kN, tri, s, winv + s, kN,
          s, s, s, npairs, step, (long)s*s, step, -1.f);
    }
    {   // level s=200 (2 pairs)
      int s = 200, npairs = 2;
      long step = (long)2*s*kN + 2*s;
      launch_gemm<false,false,true,EPI_NONE>(stream,
          qsq + s, kN, winv + (long)s*kN + s, kN, tri, s,
          s, s, s, npairs, step, step, (long)s*s, 0.f);
      launch_gemm<false,true,false,EPI_SCALE>(stream,
          winv, kN, tri, s, winv + s, kN,
          s, s, s, npairs, step, (long)s*s, step, -1.f);
    }
    {   // level s=400 (1 pair) — K-split x4, atomic ACC
      hipMemsetAsync(tri, 0, (size_t)400*400*sizeof(float), stream);
      launch_gemm<false,false,true,EPI_ACC>(stream,
          qsq + 400, kN, winv + (long)400*kN + 400, kN, tri, 400,
          400, 400, 100, 4, 100, (long)100*kN, 0, 1.f, nullptr, 100);
      launch_gemm<false,true,false,EPI_ACC>(stream,
          winv, kN, tri, 400, winv + 400, kN,
          400, 400, 100, 4, 100, (long)100*400, 0, -1.f, nullptr, 100);
    }
    hipMemsetAsync(Sacc, 0, (size_t)kNN*sizeof(float), stream);
    launch_gemm<false,true,true,EPI_ACC>(stream,
        winv, kN, psq, kN, Sacc, kN, kN, kN, 100, 8,
        100, (long)100*kN, 0, 1.f, nullptr, 100);
  };
  auto run_pair_mpa = [&](const float* z, float* SoutDst){
    hipMemsetAsync((char*)d_ws + 24, 0, 8, stream);            // scald[3] = 0
    pair_kernel<<<dim3(50,50),256,0,stream>>>(z, linW, linb, tri, scald+3);
    init_pade_kernel<<<eg(kNN),256,0,stream>>>(tri, papp_h, papp_l, psq, qsq, scald+3,
                                               P[0],P[1],Q[0],Q[1]);
    transpose_pade_kernel<<<dim3(25,25),256,0,stream>>>(tri, scald+3, pT_h, pT_l);
    dim3 g13(13,13,1);
    bgemm2_kernel<<<g13,256,0,stream>>>(papp_h,papp_l, pT_h,pT_l, psq,qsq, pwA_h,pwA_l, P[2],Q[2]);
    bgemm2_kernel<<<g13,256,0,stream>>>(pwA_h,pwA_l,  pT_h,pT_l, psq,qsq, pwB_h,pwB_l, P[3],Q[3]);
    bgemm2_kernel<<<g13,256,0,stream>>>(pwB_h,pwB_l,  pT_h,pT_l, psq,qsq, pwA_h,pwA_l, P[4],Q[4]);
    bgemm2_kernel<<<g13,256,0,stream>>>(pwA_h,pwA_l,  pT_h,pT_l, psq,qsq, pwB_h,pwB_l, P[5],Q[5]);
    blocked_trsm();
    copy_scale_kernel<<<eg(kNN),256,0,stream>>>(Sacc, scald+3, SoutDst);
  };
  auto s_times_h = [&](const float* hin, float* hout){
    hipMemsetAsync(hout, 0, (size_t)kN*kE*sizeof(float), stream);
    launch_gemm<false,true,false,EPI_ACC>(stream,
        Sacc, kN, hin, kE, hout, kE, kN, kE, 100, 8,
        100, (long)100*kE, 0, 1.f, nullptr, 100, scald+3);
  };

  float* S1f = out + 215;
  float* S2f = out + 215 + kNN;

  // ---- once: staircase g/h, CSR build, root-weight/bias pre-sums
  hipMemsetAsync(gArr, 0xFF, (size_t)(4*kN)*sizeof(int), stream);   // -1
  edge_gmax_kernel<<<dim3((kNE+255)/256,4),256,0,stream>>>(e0,e1,e2,e3, gArr);
  scan_gh_kernel<<<4,256,0,stream>>>(gArr, hArr);
  hipMemsetAsync(cntA, 0, (size_t)(8*kN)*sizeof(int), stream);
  edge_count_kernel<<<dim3((kNE+255)/256,4),256,0,stream>>>(e0,e1,e2,e3, cntA);
  csr_scan_kernel<<<8,64,0,stream>>>(cntA, offsA, curA);
  edge_fill_kernel<<<dim3((kNE+255)/256,4),256,0,stream>>>(e0,e1,e2,e3, curA, adjA);
  sum_root_kernel<<<eg((long)kE*kH),256,0,stream>>>(g1w1, g1b1, kE, wr1, bs);
  sum_root_kernel<<<eg((long)kH*kH),256,0,stream>>>(g1w2, g1b2, kH, wr2, bs+kH);
  sum_root_kernel<<<eg((long)kE*kH),256,0,stream>>>(g2w1, g2b1, kE, wr3, bs+2*kH);
  sum_root_kernel<<<eg((long)kH*kH),256,0,stream>>>(g2w2, g2b2, kH, wr4, bs+3*kH);

  // ---- embed
  launch_gemm<false,false,false,EPI_BIAS>(stream, x_note, kF, embW, kE, h0, kE, kN, kE, kF, 1,
                                          0,0,0, 0.f, embB);

  // ---- GNN1 (sparse, CSR gather)
  sparse_layer(h0,  kE, g1w1, wr1, bs,      g1ln,        zmid);
  sparse_layer(zmid,kH, g1w2, wr2, bs+kH,   g1ln + 2*kH, z0);

  // ---- S1 (Sacc holds unscaled S1 until s_times_h)
  run_pair_mpa(z0, S1f);

  // ---- h1 = S1 @ h0
  s_times_h(h0, h1);

  // ---- GNN2 #1 (dense; mask1 == staircase(g,h))
  dense_layer(h1,  kE, g2w1, wr3, bs+2*kH, g2ln,        zmid);
  dense_layer(zmid,kH, g2w2, wr4, bs+3*kH, g2ln + 2*kH, z1);

  // ---- S2
  run_pair_mpa(z1, S2f);

  // ---- h2 = S2 @ h1
  s_times_h(h1, h2);

  // ---- GNN2 #2 (dense; mask2 == mask1)
  dense_layer(h2,  kE, g2w1, wr3, bs+2*kH, g2ln,        zmid);
  dense_layer(zmid,kH, g2w2, wr4, bs+3*kH, g2ln + 2*kH, z2);

  // ---- pool + classifier + log_softmax
  pool_head_kernel<<<dim3(1),256,0,stream>>>(z2, clfW, clfb, out);
}

// Round 14
// 1136.250 us; speedup vs baseline: 4.3646x; 1.0482x over previous
//
#include <hip/hip_runtime.h>
#include <hip/hip_bf16.h>
#include <math.h>
#include <stdio.h>

static constexpr int   kN  = 800;    // nodes
static constexpr int   kF  = 111;    // input features
static constexpr int   kE  = 32;     // embed dim
static constexpr int   kH  = 200;    // hidden
static constexpr int   kNC = 15;     // classes
static constexpr int   kNE = 8000;   // edges per type
static constexpr long  kNN = (long)kN*kN;   // 640000
static constexpr long  kNH = (long)kN*kH;   // 160000
static constexpr float kAl  = 0.5f;  // ALPHA
static constexpr float kEps = 1e-5f;
static constexpr int   kGB  = (int)((kNH+255)/256);  // gather blocks = 625
static constexpr int   kDB  = 50;    // trsm diagonal block size

typedef unsigned short u16;
typedef __attribute__((ext_vector_type(8))) short short8;
typedef __attribute__((ext_vector_type(4))) float f32x4;

__device__ __forceinline__ u16 f2bf(float v){
  __hip_bfloat16 b = __float2bfloat16(v);
  return *reinterpret_cast<u16*>(&b);
}
__device__ __forceinline__ float bf2f(u16 h){
  unsigned int u = ((unsigned int)h) << 16;
  float f; __builtin_memcpy(&f, &u, 4);
  return f;
}

enum { EPI_NONE=0, EPI_BIAS=1, EPI_SCALE=4, EPI_ACC=6 };

// ---------------------------------------------------------------- fp32 GEMM (software-pipelined)
template<bool TRANSA, bool TRIUA, bool TRIUB, int EPI>
__global__ __launch_bounds__(256)
void gemm_kernel(const float* __restrict__ A, int lda,
                 const float* __restrict__ B, int ldb,
                 float* __restrict__ C, int ldc,
                 int M, int Ncl, int K,
                 long sA, long sB, long sC, float scale,
                 const float* __restrict__ bias, int kstep,
                 const double* __restrict__ scalp)
{
  constexpr int TM=64, TN=64, TK=16;
  A += (long)blockIdx.z * sA;
  B += (long)blockIdx.z * sB;
  C += (long)blockIdx.z * sC;
  __shared__ float As[TK][TM+4];
  __shared__ float Bs[TK][TN+4];
  const int tid = threadIdx.x;
  const int tn4 = (tid & 15)*4, tm4 = (tid >> 4)*4;
  const int m0 = blockIdx.x * TM, n0 = blockIdx.y * TN;
  float acc[4][4] = {};
  const int kbase = kstep ? (int)blockIdx.z * kstep : 0;
  int k0 = TRIUA ? max(m0 - kbase, 0) : 0;
  int kEnd = TRIUB ? min(K, n0 + TN - kbase) : K;
  const bool skip = (k0 >= kEnd);
  if (skip && EPI == EPI_ACC) return;
  if (!skip) {
    float ar[4], br[4];
    auto loadT = [&](int kk0, float* arr, float* brr){
      #pragma unroll
      for (int u=0; u<4; ++u){
        int idx = tid + 256*u;
        float av;
        if (!TRANSA) {
          int m = idx >> 4, ka = idx & 15;
          int gm = m0+m, gk = kk0+ka;
          av = (gm < M && gk < K) ? A[(long)gm*lda + gk] : 0.f;
        } else {
          int ka = idx >> 6, m = idx & 63;
          int gm = m0+m, gk = kk0+ka;
          av = (gm < M && gk < K) ? A[(long)gk*lda + gm] : 0.f;
        }
        int kb = idx >> 6, nb = idx & 63;
        int gk = kk0+kb, gn = n0+nb;
        arr[u] = av;
        brr[u] = (gk < K && gn < Ncl) ? B[(long)gk*ldb + gn] : 0.f;
      }
    };
    auto storeT = [&](const float* arr, const float* brr){
      #pragma unroll
      for (int u=0; u<4; ++u){
        int idx = tid + 256*u;
        if (!TRANSA){ int m = idx>>4, ka = idx&15; As[ka][m] = arr[u]; }
        else        { int ka = idx>>6, m = idx&63; As[ka][m] = arr[u]; }
        int kb = idx>>6, nb = idx&63;
        Bs[kb][nb] = brr[u];
      }
    };
    loadT(k0, ar, br);
    for (;;){
      __syncthreads();
      storeT(ar, br);
      __syncthreads();
      int kn = k0 + TK;
      bool more = kn < kEnd;
      if (more) loadT(kn, ar, br);
      #pragma unroll
      for (int kk=0; kk<TK; ++kk) {
        float a[4], b[4];
        #pragma unroll
        for (int u=0;u<4;++u){ a[u]=As[kk][tm4+u]; b[u]=Bs[kk][tn4+u]; }
        #pragma unroll
        for (int i=0;i<4;++i)
          #pragma unroll
          for (int j=0;j<4;++j)
            acc[i][j] = fmaf(a[i], b[j], acc[i][j]);
      }
      if (!more) break;
      k0 = kn;
    }
  }
  float sc = scale;
  if (EPI == EPI_ACC && scalp) sc *= (float)sqrt(sqrt(scalp[0]));
  #pragma unroll
  for (int i=0;i<4;++i) {
    int gm = m0 + tm4 + i;
    if (gm >= M) continue;
    #pragma unroll
    for (int j=0;j<4;++j) {
      int gn = n0 + tn4 + j;
      if (gn >= Ncl) continue;
      float v = acc[i][j];
      long off = (long)gm*ldc + gn;
      if (EPI == EPI_BIAS)       C[off] = v + bias[gn];
      else if (EPI == EPI_SCALE) C[off] = scale*v;
      else if (EPI == EPI_ACC)   unsafeAtomicAdd(&C[off], sc*v);
      else                       C[off] = v;
    }
  }
}

template<bool TRANSA, bool TRIUA, bool TRIUB, int EPI>
static inline void launch_gemm(hipStream_t st,
                               const float* A, int lda, const float* B, int ldb,
                               float* C, int ldc, int M, int Ncl, int K, int batch,
                               long sA, long sB, long sC, float scale,
                               const float* bias = nullptr, int kstep = 0,
                               const double* scalp = nullptr)
{
  dim3 grid((M+63)/64, (Ncl+63)/64, batch);
  gemm_kernel<TRANSA,TRIUA,TRIUB,EPI><<<grid, 256, 0, st>>>(
      A,lda,B,ldb,C,ldc,M,Ncl,K,sA,sB,sC,scale,bias,kstep,scalp);
}

// ---------------------------------------------------------------- split-bf16 MFMA GEMM (powers, pipelined)
__global__ __launch_bounds__(256)
void bgemm2_kernel(const u16* __restrict__ Ah, const u16* __restrict__ Al,
                   const u16* __restrict__ Bh, const u16* __restrict__ Bl,
                   float* __restrict__ C, float* __restrict__ C2,
                   u16* __restrict__ Oh, u16* __restrict__ Ol,
                   float p0, float p1)
{
  constexpr int TM=64, TN=64, BK=32;
  __shared__ u16 Ash[TM][40], Asl[TM][40], Bsh[TN][40], Bsl[TN][40];
  const int tid = threadIdx.x;
  const int m0 = blockIdx.x*TM, n0 = blockIdx.y*TN;
  const int w = tid>>6, lane = tid&63;
  const int wm = (w&1)*32, wn = (w>>1)*32;
  const int quad = lane>>4, lm = lane&15;
  f32x4 acc00={}, acc01={}, acc10={}, acc11={};
  const bool skip = (m0 > n0 + TN - 1);
  int k0 = m0;
  const int kEnd = min(kN, n0+TN);
  const int ar = tid>>2, ac = (tid&3)*8;
  if (!skip){
    uint4 avh, avl, bvh, bvl;
    auto loadT = [&](int kk0){
      avh = {0,0,0,0}; avl = {0,0,0,0}; bvh = {0,0,0,0}; bvl = {0,0,0,0};
      int gk = kk0 + ac;
      if (m0+ar < kN && gk < kN){
        avh = *(const uint4*)(Ah + (long)(m0+ar)*kN + gk);
        avl = *(const uint4*)(Al + (long)(m0+ar)*kN + gk);
      }
      if (n0+ar < kN && gk < kN){
        bvh = *(const uint4*)(Bh + (long)(n0+ar)*kN + gk);
        bvl = *(const uint4*)(Bl + (long)(n0+ar)*kN + gk);
      }
    };
    loadT(k0);
    for (;;){
      __syncthreads();
      *(uint4*)&Ash[ar][ac] = avh; *(uint4*)&Asl[ar][ac] = avl;
      *(uint4*)&Bsh[ar][ac] = bvh; *(uint4*)&Bsl[ar][ac] = bvl;
      __syncthreads();
      int kn = k0 + BK;
      bool more = kn < kEnd;
      if (more) loadT(kn);
      short8 a0h = *(const short8*)&Ash[wm+lm][quad*8];
      short8 a1h = *(const short8*)&Ash[wm+16+lm][quad*8];
      short8 a0l = *(const short8*)&Asl[wm+lm][quad*8];
      short8 a1l = *(const short8*)&Asl[wm+16+lm][quad*8];
      short8 b0h = *(const short8*)&Bsh[wn+lm][quad*8];
      short8 b1h = *(const short8*)&Bsh[wn+16+lm][quad*8];
      short8 b0l = *(const short8*)&Bsl[wn+lm][quad*8];
      short8 b1l = *(const short8*)&Bsl[wn+16+lm][quad*8];
      acc00 = __builtin_amdgcn_mfma_f32_16x16x32_bf16(a0h,b0h,acc00,0,0,0);
      acc00 = __builtin_amdgcn_mfma_f32_16x16x32_bf16(a0h,b0l,acc00,0,0,0);
      acc00 = __builtin_amdgcn_mfma_f32_16x16x32_bf16(a0l,b0h,acc00,0,0,0);
      acc01 = __builtin_amdgcn_mfma_f32_16x16x32_bf16(a0h,b1h,acc01,0,0,0);
      acc01 = __builtin_amdgcn_mfma_f32_16x16x32_bf16(a0h,b1l,acc01,0,0,0);
      acc01 = __builtin_amdgcn_mfma_f32_16x16x32_bf16(a0l,b1h,acc01,0,0,0);
      acc10 = __builtin_amdgcn_mfma_f32_16x16x32_bf16(a1h,b0h,acc10,0,0,0);
      acc10 = __builtin_amdgcn_mfma_f32_16x16x32_bf16(a1h,b0l,acc10,0,0,0);
      acc10 = __builtin_amdgcn_mfma_f32_16x16x32_bf16(a1l,b0h,acc10,0,0,0);
      acc11 = __builtin_amdgcn_mfma_f32_16x16x32_bf16(a1h,b1h,acc11,0,0,0);
      acc11 = __builtin_amdgcn_mfma_f32_16x16x32_bf16(a1h,b1l,acc11,0,0,0);
      acc11 = __builtin_amdgcn_mfma_f32_16x16x32_bf16(a1l,b1h,acc11,0,0,0);
      if (!more) break;
      k0 = kn;
    }
  }
  f32x4 accs[2][2] = {{acc00, acc01},{acc10, acc11}};
  #pragma unroll
  for (int ti=0; ti<2; ++ti){
    #pragma unroll
    for (int tj=0; tj<2; ++tj){
      #pragma unroll
      for (int r=0; r<4; ++r){
        int gm = m0 + wm + ti*16 + quad*4 + r;
        int gn = n0 + wn + tj*16 + lm;
        if (gm >= kN || gn >= kN) continue;
        float v = accs[ti][tj][r];
        long off = (long)gm*kN + gn;
        C[off]  += p0*v;
        C2[off] += p1*v;
        u16 h = f2bf(v);
        Oh[off] = h;
        Ol[off] = f2bf(v - bf2f(h));
      }
    }
  }
}

// ---- fused pade init: papp hi/lo (straight + transposed), psq, qsq — one read of tri
__global__ __launch_bounds__(256)
void pade_both_kernel(const float* __restrict__ tri, const double* __restrict__ frob2,
                      u16* __restrict__ ph, u16* __restrict__ pl,
                      u16* __restrict__ th, u16* __restrict__ tl,
                      float* __restrict__ psq, float* __restrict__ qsq,
                      float P0, float P1, float Q0, float Q1)
{
  __shared__ float t[32][33];
  const float rn = (float)(1.0 / sqrt(frob2[0]));
  int r0 = blockIdx.y*32, c0 = blockIdx.x*32;
  int tr = threadIdx.x>>5, tc = threadIdx.x&31;
  for (int i=tr; i<32; i+=8){
    int r = r0+i, c = c0+tc;
    float eye = (r==c) ? 1.f : 0.f;
    float pa = eye - tri[(long)r*kN + c]*rn;
    t[i][tc] = pa;
    long off = (long)r*kN + c;
    psq[off] = P0*eye + P1*pa;
    qsq[off] = Q0*eye + Q1*pa;
    u16 h = f2bf(pa);
    ph[off] = h;
    pl[off] = f2bf(pa - bf2f(h));
  }
  __syncthreads();
  for (int i=tr; i<32; i+=8){
    int c = c0+i, r = r0+tc;
    float v = t[tc][i];
    u16 h = f2bf(v);
    th[(long)c*kN + r] = h;
    tl[(long)c*kN + r] = f2bf(v - bf2f(h));
  }
}

// ---- stream S = Sacc * sqrt(normA) into d_out
__global__ __launch_bounds__(256)
void copy_scale_kernel(const float* __restrict__ src, const double* __restrict__ frob2,
                       float* __restrict__ dst)
{
  const float fac = (float)sqrt(sqrt(frob2[0]));
  long i = (long)blockIdx.x*256 + threadIdx.x;
  if (i < kNN) __builtin_nontemporal_store(src[i]*fac, &dst[i]);
}

// ---------------------------------------------------------------- CSR build (8 lists)
__global__ void edge_count_kernel(const int* __restrict__ e0, const int* __restrict__ e1,
                                  const int* __restrict__ e2, const int* __restrict__ e3,
                                  int* __restrict__ cnt){
  const int* eis[4] = {e0,e1,e2,e3};
  const int e = blockIdx.y;
  const int* ei = eis[e];
  int j = blockIdx.x*256 + threadIdx.x;
  if (j >= kNE) return;
  int s = ei[j], d = ei[kNE + j];
  atomicAdd(&cnt[e*kN + d], 1);
  atomicAdd(&cnt[(4+e)*kN + s], 1);
}

__global__ void csr_scan_kernel(const int* __restrict__ cnt, int* __restrict__ offs,
                                int* __restrict__ cur){
  const int l = blockIdx.x;
  if (threadIdx.x != 0) return;
  int acc = 0;
  for (int i = 0; i < kN; ++i){
    offs[l*(kN+1) + i] = acc;
    cur[l*kN + i] = acc;
    acc += cnt[l*kN + i];
  }
  offs[l*(kN+1) + kN] = acc;
}

__global__ void edge_fill_kernel(const int* __restrict__ e0, const int* __restrict__ e1,
                                 const int* __restrict__ e2, const int* __restrict__ e3,
                                 int* __restrict__ cur, int* __restrict__ adj){
  const int* eis[4] = {e0,e1,e2,e3};
  const int e = blockIdx.y;
  const int* ei = eis[e];
  int j = blockIdx.x*256 + threadIdx.x;
  if (j >= kNE) return;
  int s = ei[j], d = ei[kNE + j];
  int p = atomicAdd(&cur[e*kN + d], 1);
  adj[(long)e*kNE + p] = s;
  int q = atomicAdd(&cur[(4+e)*kN + s], 1);
  adj[(long)(4+e)*kNE + q] = d;
}

// CSR gather (sparse): t = Y[8] + bsum + 0.5*msgs; pure store + LN partials
__global__ __launch_bounds__(256)
void gather_sparse_kernel(const float* __restrict__ Y, const int* __restrict__ offs,
                          const int* __restrict__ adj, const float* __restrict__ bsum,
                          float* __restrict__ tnh, double* __restrict__ part){
  __shared__ double ss[256], qq[256];
  const int n = blockIdx.x;
  const int f = threadIdx.x;
  double sp = 0.0, qp = 0.0;
  float acc = 0.f;
  if (f < kH){
    #pragma unroll
    for (int l = 0; l < 8; ++l){
      const float* Yp = Y + (long)l*kNH;
      int b = offs[l*(kN+1) + n], e2 = offs[l*(kN+1) + n + 1];
      for (int idx = b; idx < e2; ++idx){
        int m = adj[(long)l*kNE + idx];
        acc += Yp[(long)m*kH + f];
      }
    }
    float t = Y[(long)8*kNH + (long)n*kH + f] + bsum[f] + 0.5f*acc;
    tnh[(long)n*kH + f] = t;
    sp = t; qp = (double)t*t;
  }
  ss[threadIdx.x]=sp; qq[threadIdx.x]=qp;
  __syncthreads();
  for (int hh=128; hh>0; hh>>=1){
    if ((int)threadIdx.x < hh){ ss[threadIdx.x]+=ss[threadIdx.x+hh]; qq[threadIdx.x]+=qq[threadIdx.x+hh]; }
    __syncthreads();
  }
  if (threadIdx.x==0){ part[2*blockIdx.x]=ss[0]; part[2*blockIdx.x+1]=qq[0]; }
}

// ---------------------------------------------------------------- mask staircase kernels
__global__ void edge_gmax_kernel(const int* __restrict__ e0, const int* __restrict__ e1,
                                 const int* __restrict__ e2, const int* __restrict__ e3,
                                 int* __restrict__ g){
  const int* eis[4] = {e0,e1,e2,e3};
  const int e = blockIdx.y;
  const int* ei = eis[e];
  int j = blockIdx.x*256 + threadIdx.x;
  if (j >= kNE) return;
  int s = ei[j], d = ei[kNE + j];
  atomicMax(&g[e*kN + d], s);
}

__global__ __launch_bounds__(256)
void scan_gh_kernel(int* __restrict__ g, int* __restrict__ h){
  __shared__ int gs[kN];
  const int e = blockIdx.x;
  for (int i = threadIdx.x; i < kN; i += 256) gs[i] = g[e*kN + i];
  __syncthreads();
  if (threadIdx.x == 0){
    int m = -1;
    for (int i = 0; i < kN; ++i){ m = max(m, gs[i]); gs[i] = m; }
  }
  __syncthreads();
  for (int i = threadIdx.x; i < kN; i += 256) g[e*kN + i] = gs[i];
  for (int d = threadIdx.x; d < kN; d += 256){
    int lo = 0, hi = kN;
    while (lo < hi){ int mid = (lo+hi)>>1; if (gs[mid] >= d) hi = mid; else lo = mid+1; }
    h[e*kN + d] = lo;
  }
}

// in-place scans over Y planes: z<4 prefix; z>=4 suffix
__global__ __launch_bounds__(256)
void scan_msg_kernel(float* __restrict__ Y){
  const int plane = blockIdx.x;
  const int f = threadIdx.x;
  if (f >= kH) return;
  float* P = Y + (long)plane*kNH + f;
  float acc = 0.f;
  if (plane < 4){
    for (int n = 0; n < kN; n += 4){
      float v0 = P[(long)(n+0)*kH], v1 = P[(long)(n+1)*kH];
      float v2 = P[(long)(n+2)*kH], v3 = P[(long)(n+3)*kH];
      acc += v0; P[(long)(n+0)*kH] = acc;
      acc += v1; P[(long)(n+1)*kH] = acc;
      acc += v2; P[(long)(n+2)*kH] = acc;
      acc += v3; P[(long)(n+3)*kH] = acc;
    }
  } else {
    for (int n = kN-1; n >= 0; n -= 4){
      float v0 = P[(long)(n-0)*kH], v1 = P[(long)(n-1)*kH];
      float v2 = P[(long)(n-2)*kH], v3 = P[(long)(n-3)*kH];
      acc += v0; P[(long)(n-0)*kH] = acc;
      acc += v1; P[(long)(n-1)*kH] = acc;
      acc += v2; P[(long)(n-2)*kH] = acc;
      acc += v3; P[(long)(n-3)*kH] = acc;
    }
  }
}

// dense gather: t = Y[8] + bsum + 0.5*(staircase sums); pure store + LN partials
__global__ __launch_bounds__(256)
void gather_dense_kernel(const float* __restrict__ Y, const int* __restrict__ g,
                         const int* __restrict__ h, const float* __restrict__ bsum,
                         float* __restrict__ tnh, double* __restrict__ part){
  __shared__ double ss[256], qq[256];
  long idx = (long)blockIdx.x*256 + threadIdx.x;
  double s = 0.0, q = 0.0;
  if (idx < kNH){
    int n = (int)(idx / kH), f = (int)(idx % kH);
    float v = 0.f;
    #pragma unroll
    for (int e = 0; e < 4; ++e){
      int gi = g[e*kN + n];
      if (gi >= 0) v += Y[(long)e*kNH + (long)gi*kH + f];
      int hi = h[e*kN + n];
      if (hi < kN) v += Y[(long)(4+e)*kNH + (long)hi*kH + f];
    }
    float t = Y[(long)8*kNH + idx] + bsum[f] + 0.5f*v;
    tnh[idx] = t;
    s = t; q = (double)t*t;
  }
  ss[threadIdx.x]=s; qq[threadIdx.x]=q;
  __syncthreads();
  for (int hh=128; hh>0; hh>>=1){
    if ((int)threadIdx.x < hh){ ss[threadIdx.x]+=ss[threadIdx.x+hh]; qq[threadIdx.x]+=qq[threadIdx.x+hh]; }
    __syncthreads();
  }
  if (threadIdx.x==0){ part[2*blockIdx.x]=ss[0]; part[2*blockIdx.x+1]=qq[0]; }
}

// ---------------------------------------------------------------- small kernels
// Wr = sum_e W[2,e] (written into wcat tail); bsum = bias sums
__global__ void sum_root_kernel(const float* __restrict__ W, const float* __restrict__ b,
                                int K, float* __restrict__ Wr, float* __restrict__ bsum){
  int idx = blockIdx.x*256 + threadIdx.x;
  int tot = K*kH;
  if (idx < tot){
    float v = 0.f;
    #pragma unroll
    for (int e=0;e<4;++e) v += W[(long)(8+e)*tot + idx];
    Wr[idx] = v;
  }
  if (idx < kH){
    float v = 0.f;
    #pragma unroll
    for (int e=0;e<4;++e)
      v += (1.f-kAl)*b[(0*4+e)*kH + idx] + kAl*b[(1*4+e)*kH + idx] + b[(2*4+e)*kH + idx];
    bsum[idx] = v;
  }
}

// graph layernorm with inline final reduction of nb partials
__global__ __launch_bounds__(256)
void apply_ln_kernel(const float* __restrict__ x, float* __restrict__ y,
                     const float* __restrict__ ln, const double* __restrict__ part, int nb){
  __shared__ double ss[256], qq[256];
  int t = threadIdx.x;
  double s=0.0, q=0.0;
  for (int i=t; i<nb; i+=256){ s += part[2*i]; q += part[2*i+1]; }
  ss[t]=s; qq[t]=q;
  __syncthreads();
  for (int h=128; h>0; h>>=1){
    if (t < h){ ss[t]+=ss[t+h]; qq[t]+=qq[t+h]; }
    __syncthreads();
  }
  long idx = (long)blockIdx.x*256 + t;
  if (idx >= kNH) return;
  double mu  = ss[0] / (double)kNH;
  double var = qq[0] / (double)kNH - mu*mu;
  float rs = rsqrtf((float)var + kEps);
  int f = (int)(idx % kH);
  y[idx] = (x[idx] - (float)mu) * rs * ln[f] + ln[kH + f];
}

// pair + inline LN of raw z + fused frobenius sumsq
__global__ __launch_bounds__(256)
void pair_kernel(const float* __restrict__ zraw, const double* __restrict__ part, int nb,
                 const float* __restrict__ ln,
                 const float* __restrict__ linW, const float* __restrict__ linb,
                 float* __restrict__ tri, double* __restrict__ frob2){
  __shared__ float zi[16][201], zj[16][201], w[208], lw[208], lb[208];
  __shared__ float red[256];
  __shared__ double sred[256], qred[256];
  const int i0 = blockIdx.y*16, j0 = blockIdx.x*16;
  const int tid = threadIdx.x;
  const int ti = tid >> 4, tj = tid & 15;
  const int i = i0+ti, j = j0+tj;
  if (i0 > j0 + 15) { tri[(long)i*kN + j] = 0.f; return; }
  // LN stats from partials
  double s=0.0, q=0.0;
  for (int ii=tid; ii<nb; ii+=256){ s += part[2*ii]; q += part[2*ii+1]; }
  sred[tid]=s; qred[tid]=q;
  __syncthreads();
  for (int hh=128; hh>0; hh>>=1){
    if (tid < hh){ sred[tid]+=sred[tid+hh]; qred[tid]+=qred[tid+hh]; }
    __syncthreads();
  }
  const float mu = (float)(sred[0] / (double)kNH);
  const float rs = rsqrtf((float)(qred[0]/(double)kNH - (sred[0]/(double)kNH)*(sred[0]/(double)kNH)) + kEps);
  if (tid < kH){ w[tid] = linW[tid]; lw[tid] = ln[tid]; lb[tid] = ln[kH + tid]; }
  __syncthreads();
  for (int idx = tid; idx < 16*kH; idx += 256){
    int r = idx / kH, c = idx % kH;
    float sc = rs*lw[c], of = lb[c];
    zi[r][c] = (zraw[(long)(i0+r)*kH + c] - mu)*sc + of;
    zj[r][c] = (zraw[(long)(j0+r)*kH + c] - mu)*sc + of;
  }
  __syncthreads();
  float g = 0.f;
  if (i <= j){
    float sacc = linb[0];
    #pragma unroll 4
    for (int k=0;k<kH;++k){ float d = zi[ti][k]-zj[tj][k]; sacc = fmaf(d*d, w[k], sacc); }
    g = 1.f/(1.f + expf(-sacc));
  }
  tri[(long)i*kN + j] = g;
  red[tid] = g*g;
  __syncthreads();
  for (int hh=128; hh>0; hh>>=1){
    if (tid < hh) red[tid] += red[tid+hh];
    __syncthreads();
  }
  if (tid == 0) unsafeAtomicAdd(frob2, (double)red[0]);
}

// ---- invert the 16 diagonal 50x50 upper-tri blocks of U into W (W pre-zeroed)
__global__ __launch_bounds__(64)
void invdiag_kernel(const float* __restrict__ U, float* __restrict__ W){
  __shared__ float Us[kDB][kDB+1];
  __shared__ float Xs[kDB][kDB+1];
  const int base = blockIdx.x * kDB;
  const int tid = threadIdx.x;
  for (int idx = tid; idx < kDB*kDB; idx += 64){
    int r = idx / kDB, c = idx % kDB;
    Us[r][c] = U[(long)(base+r)*kN + base + c];
  }
  __syncthreads();
  const int c = tid;
  for (int i = kDB-1; i >= 0; --i){
    if (c < kDB){
      float x;
      if (c < i) x = 0.f;
      else {
        float s = 0.f;
        for (int k = i+1; k < kDB; ++k) s = fmaf(Us[i][k], Xs[k][c], s);
        x = (((c==i)?1.f:0.f) - s) / Us[i][i];
      }
      Xs[i][c] = x;
    }
    __syncthreads();
  }
  for (int idx = tid; idx < kDB*kDB; idx += 64){
    int r = idx / kDB, cc = idx % kDB;
    W[(long)(base+r)*kN + base + cc] = Xs[r][cc];
  }
}

// ---- fused merge for level S: one block per pair
template<int S>
__global__ __launch_bounds__(256)
void merge_fused_kernel(const float* __restrict__ U, float* __restrict__ W){
  __shared__ float Us[S][S+1];
  __shared__ float Wb[S][S+1];
  __shared__ float T[S][S+1];
  const long base = (long)blockIdx.x * (2*S) * (kN+1);
  const int tid = threadIdx.x;
  for (int idx = tid; idx < S*S; idx += 256){
    int r = idx / S, c = idx % S;
    Us[r][c] = U[base + (long)r*kN + S + c];
    Wb[r][c] = W[base + (long)(S+r)*kN + S + c];
  }
  __syncthreads();
  for (int idx = tid; idx < S*S; idx += 256){
    int r = idx / S, c = idx % S;
    float s = 0.f;
    for (int k = 0; k <= c; ++k) s = fmaf(Us[r][k], Wb[k][c], s);
    T[r][c] = s;
  }
  __syncthreads();
  for (int idx = tid; idx < S*S; idx += 256){
    int r = idx / S, c = idx % S;
    Us[r][c] = W[base + (long)r*kN + c];
  }
  __syncthreads();
  for (int idx = tid; idx < S*S; idx += 256){
    int r = idx / S, c = idx % S;
    float s = 0.f;
    for (int k = r; k < S; ++k) s = fmaf(Us[r][k], T[k][c], s);
    W[base + (long)r*kN + S + c] = -s;
  }
}

// pool + classifier + log_softmax, with inline LN of raw z2
__global__ __launch_bounds__(256)
void pool_head_kernel(const float* __restrict__ z2raw, const double* __restrict__ part, int nb,
                      const float* __restrict__ ln,
                      const float* __restrict__ W, const float* __restrict__ b,
                      float* __restrict__ out){
  __shared__ double sred[256], qred[256];
  __shared__ float x2[kH];
  __shared__ float lg[kNC];
  int t = threadIdx.x;
  double s=0.0, q=0.0;
  for (int i=t; i<nb; i+=256){ s += part[2*i]; q += part[2*i+1]; }
  sred[t]=s; qred[t]=q;
  __syncthreads();
  for (int hh=128; hh>0; hh>>=1){
    if (t < hh){ sred[t]+=sred[t+hh]; qred[t]+=qred[t+hh]; }
    __syncthreads();
  }
  const float mu = (float)(sred[0] / (double)kNH);
  const float rs = rsqrtf((float)(qred[0]/(double)kNH - (sred[0]/(double)kNH)*(sred[0]/(double)kNH)) + kEps);
  if (t < kH){
    float sc = rs*ln[t], of = ln[kH+t];
    float sum = 0.f;
    for (int n = 0; n < kN; ++n) sum += (z2raw[(long)n*kH + t] - mu)*sc + of;
    float v = sum * (1.f/(float)kN);
    x2[t] = v;
    out[t] = v;
  }
  __syncthreads();
  if (t < kNC){
    float sv = b[t];
    for (int f = 0; f < kH; ++f) sv = fmaf(x2[f], W[f*kNC + t], sv);
    lg[t] = sv;
  }
  __syncthreads();
  if (t == 0){
    float m = -1e30f;
    for (int c=0;c<kNC;++c) m = fmaxf(m, lg[c]);
    float se = 0.f;
    for (int c=0;c<kNC;++c) se += expf(lg[c]-m);
    float lse = m + logf(se);
    for (int c=0;c<kNC;++c) out[kH + c] = lg[c]-lse;
  }
}

// ---------------------------------------------------------------- host: Pade [5/5] of sqrt(1-x)
static void pade_coeffs(float* P, float* Q){
  double b[11]; b[0] = 1.0;
  for (int k=1;k<11;++k) b[k] = b[k-1]*(0.5-(k-1))/k;
  double c[11];
  for (int k=0;k<11;++k) c[k] = b[k]*((k&1)?-1.0:1.0);
  double A[5][5], rhs[5];
  for (int i=0;i<5;++i){ for (int j=0;j<5;++j) A[i][j] = c[5+i-j]; rhs[i] = -c[6+i]; }
  for (int col=0; col<5; ++col){
    int p = col;
    for (int r=col+1;r<5;++r) if (fabs(A[r][col]) > fabs(A[p][col])) p = r;
    if (p != col){
      for (int j=0;j<5;++j){ double t=A[col][j]; A[col][j]=A[p][j]; A[p][j]=t; }
      double t=rhs[col]; rhs[col]=rhs[p]; rhs[p]=t;
    }
    for (int r=col+1;r<5;++r){
      double f = A[r][col]/A[col][col];
      for (int j=col;j<5;++j) A[r][j] -= f*A[col][j];
      rhs[r] -= f*rhs[col];
    }
  }
  double q[6]; q[0] = 1.0;
  for (int r=4;r>=0;--r){
    double s = rhs[r];
    for (int j=r+1;j<5;++j) s -= A[r][j]*q[1+j];
    q[1+r] = s/A[r][r];
  }
  double p[6];
  for (int k=0;k<6;++k){
    double s = 0.0; int jm = k<5?k:5;
    for (int j=0;j<=jm;++j) s += q[j]*c[k-j];
    p[k] = s;
  }
  for (int k=0;k<6;++k){ P[k]=(float)p[k]; Q[k]=(float)q[k]; }
}

// ---------------------------------------------------------------- launch
extern "C" void kernel_launch(void* const* d_in, const int* in_sizes, int n_in,
                              void* d_out, int out_size, void* d_ws, size_t ws_size,
                              hipStream_t stream)
{
  const float* x_note = (const float*)d_in[0];
  const float* embW   = (const float*)d_in[1];
  const float* embB   = (const float*)d_in[2];
  const float* g1w1   = (const float*)d_in[3];
  const float* g1b1   = (const float*)d_in[4];
  const float* g1w2   = (const float*)d_in[5];
  const float* g1b2   = (const float*)d_in[6];
  const float* g1ln   = (const float*)d_in[7];
  const float* g2w1   = (const float*)d_in[8];
  const float* g2b1   = (const float*)d_in[9];
  const float* g2w2   = (const float*)d_in[10];
  const float* g2b2   = (const float*)d_in[11];
  const float* g2ln   = (const float*)d_in[12];
  const float* linW   = (const float*)d_in[13];
  const float* linb   = (const float*)d_in[14];
  const float* clfW   = (const float*)d_in[15];
  const float* clfb   = (const float*)d_in[16];
  const int*  e0     = (const int*)d_in[17];
  const int*  e1     = (const int*)d_in[18];
  const int*  e2     = (const int*)d_in[19];
  const int*  e3     = (const int*)d_in[20];
  float* out = (float*)d_out;

  // header: scald @0 (32B), partd @512B
  constexpr long o_h0   = 4096;
  constexpr long o_h1   = o_h0   + (long)kN*kE;
  constexpr long o_h2   = o_h1   + (long)kN*kE;
  constexpr long o_tnh  = o_h2   + (long)kN*kE;
  constexpr long o_zmid = o_tnh  + kNH;
  constexpr long o_big  = o_zmid + kNH;             // 4*kNN floats (9 Y planes / power scratch)
  constexpr long o_tri  = o_big  + 4*kNN;
  constexpr long o_sacc = o_tri  + kNN;
  constexpr long o_winv = o_sacc + kNN;
  constexpr long o_psq  = o_winv + kNN;
  constexpr long o_qsq  = o_psq  + kNN;
  constexpr long o_g    = o_qsq  + kNN;
  constexpr long o_hh   = o_g    + 4*kN;
  constexpr long o_wc1  = o_hh   + 4*kN;            // wcat: 9 planes each
  constexpr long o_wc2  = o_wc1  + 9L*kE*kH;
  constexpr long o_wc3  = o_wc2  + 9L*kH*kH;
  constexpr long o_wc4  = o_wc3  + 9L*kE*kH;
  constexpr long o_bs   = o_wc4  + 9L*kH*kH;        // 4 x kH bias sums
  constexpr long o_cnt  = o_bs   + 4*kH;
  constexpr long o_offs = o_cnt  + 8*kN;
  constexpr long o_cur  = o_offs + 8*(kN+1);
  constexpr long o_adj  = o_cur  + 8*kN;
  constexpr long o_end  = o_adj  + 8*(long)kNE;

  if (ws_size < (size_t)o_end*sizeof(float) || out_size < 215 + 2*(int)kNN || n_in < 21){
    fprintf(stderr, "kernel_launch guard: ws=%zu need=%zu out=%d need=%d n_in=%d\n",
            ws_size, (size_t)o_end*sizeof(float), out_size, (int)(215+2*kNN), n_in);
    hipMemsetAsync(d_out, 0, (size_t)out_size*sizeof(float), stream);
    return;
  }

  float* ws = (float*)d_ws;
  double* scald = (double*)d_ws;
  double* partd = (double*)((char*)d_ws + 512);
  float *h0=ws+o_h0, *h1=ws+o_h1, *h2=ws+o_h2, *tnh=ws+o_tnh, *zmid=ws+o_zmid,
        *big=ws+o_big, *tri=ws+o_tri, *Sacc=ws+o_sacc, *winv=ws+o_winv,
        *psq=ws+o_psq, *qsq=ws+o_qsq;
  int* gArr = (int*)(ws + o_g);
  int* hArr = (int*)(ws + o_hh);
  float *wc1=ws+o_wc1, *wc2=ws+o_wc2, *wc3=ws+o_wc3, *wc4=ws+o_wc4, *bs=ws+o_bs;
  int* cntA = (int*)(ws + o_cnt);
  int* offsA= (int*)(ws + o_offs);
  int* curA = (int*)(ws + o_cur);
  int* adjA = (int*)(ws + o_adj);
  u16* papp_h = (u16*)big;
  u16* papp_l = papp_h + kNN;
  u16* pT_h   = papp_l + kNN;
  u16* pT_l   = pT_h + kNN;
  u16* pwA_h  = pT_l + kNN;
  u16* pwA_l  = pwA_h + kNN;
  u16* pwB_h  = pwA_l + kNN;
  u16* pwB_l  = pwB_h + kNN;

  float P[6], Q[6];
  pade_coeffs(P, Q);

  auto eg = [](long n){ return dim3((unsigned)((n+255)/256)); };

  // one batch-9 GEMM per layer: planes 0..7 messages, plane 8 root
  auto layer_gemm = [&](const float* hin, int K, const float* wcat){
    launch_gemm<false,false,false,EPI_NONE>(stream, hin, K, wcat, kH, big, kH, kN, kH, K, 9,
                                            0, (long)K*kH, kNH, 0.f);
  };
  auto sparse_layer = [&](const float* hin, int K, const float* wcat, const float* bsum){
    layer_gemm(hin, K, wcat);
    gather_sparse_kernel<<<dim3(kN),256,0,stream>>>(big, offsA, adjA, bsum, tnh, partd);
  };
  auto dense_layer = [&](const float* hin, int K, const float* wcat, const float* bsum){
    layer_gemm(hin, K, wcat);
    scan_msg_kernel<<<8,256,0,stream>>>(big);
    gather_dense_kernel<<<kGB,256,0,stream>>>(big, gArr, hArr, bsum, tnh, partd);
  };
  auto blocked_trsm = [&](){
    hipMemsetAsync(winv, 0, (size_t)kNN*sizeof(float), stream);
    invdiag_kernel<<<dim3(kN/kDB),64,0,stream>>>(qsq, winv);
    merge_fused_kernel<50><<<dim3(kN/100),256,0,stream>>>(qsq, winv);
    {   // level s=100 (4 pairs)
      int s = 100, npairs = 4;
      long step = (long)2*s*kN + 2*s;
      launch_gemm<false,false,true,EPI_NONE>(stream,
          qsq + s, kN, winv + (long)s*kN + s, kN, tri, s,
          s, s, s, npairs, step, step, (long)s*s, 0.f);
      launch_gemm<false,true,false,EPI_SCALE>(stream,
          winv, kN, tri, s, winv + s, kN,
          s, s, s, npairs, step, (long)s*s, step, -1.f);
    }
    {   // level s=200 (2 pairs)
      int s = 200, npairs = 2;
      long step = (long)2*s*kN + 2*s;
      launch_gemm<false,false,true,EPI_NONE>(stream,
          qsq + s, kN, winv + (long)s*kN + s, kN, tri, s,
          s, s, s, npairs, step, step, (long)s*s, 0.f);
      launch_gemm<false,true,false,EPI_SCALE>(stream,
          winv, kN, tri, s, winv + s, kN,
          s, s, s, npairs, step, (long)s*s, step, -1.f);
    }
    {   // level s=400 (1 pair) — K-split x4, atomic ACC
      hipMemsetAsync(tri, 0, (size_t)400*400*sizeof(float), stream);
      launch_gemm<false,false,true,EPI_ACC>(stream,
          qsq + 400, kN, winv + (long)400*kN + 400, kN, tri, 400,
          400, 400, 100, 4, 100, (long)100*kN, 0, 1.f, nullptr, 100);
      launch_gemm<false,true,false,EPI_ACC>(stream,
          winv, kN, tri, 400, winv + 400, kN,
          400, 400, 100, 4, 100, (long)100*400, 0, -1.f, nullptr, 100);
    }
    hipMemsetAsync(Sacc, 0, (size_t)kNN*sizeof(float), stream);
    launch_gemm<false,true,true,EPI_ACC>(stream,
        winv, kN, psq, kN, Sacc, kN, kN, kN, 100, 8,
        100, (long)100*kN, 0, 1.f, nullptr, 100);
  };
  // consumes raw tnh (+partials, nb) with LN fused into pair
  auto run_pair_mpa = [&](int nb, const float* lnp, float* SoutDst){
    hipMemsetAsync((char*)d_ws + 24, 0, 8, stream);            // scald[3] = 0
    pair_kernel<<<dim3(50,50),256,0,stream>>>(tnh, partd, nb, lnp, linW, linb, tri, scald+3);
    pade_both_kernel<<<dim3(25,25),256,0,stream>>>(tri, scald+3, papp_h, papp_l, pT_h, pT_l,
                                                   psq, qsq, P[0],P[1],Q[0],Q[1]);
    dim3 g13(13,13,1);
    bgemm2_kernel<<<g13,256,0,stream>>>(papp_h,papp_l, pT_h,pT_l, psq,qsq, pwA_h,pwA_l, P[2],Q[2]);
    bgemm2_kernel<<<g13,256,0,stream>>>(pwA_h,pwA_l,  pT_h,pT_l, psq,qsq, pwB_h,pwB_l, P[3],Q[3]);
    bgemm2_kernel<<<g13,256,0,stream>>>(pwB_h,pwB_l,  pT_h,pT_l, psq,qsq, pwA_h,pwA_l, P[4],Q[4]);
    bgemm2_kernel<<<g13,256,0,stream>>>(pwA_h,pwA_l,  pT_h,pT_l, psq,qsq, pwB_h,pwB_l, P[5],Q[5]);
    blocked_trsm();
    copy_scale_kernel<<<eg(kNN),256,0,stream>>>(Sacc, scald+3, SoutDst);
  };
  auto s_times_h = [&](const float* hin, float* hout){
    hipMemsetAsync(hout, 0, (size_t)kN*kE*sizeof(float), stream);
    launch_gemm<false,true,false,EPI_ACC>(stream,
        Sacc, kN, hin, kE, hout, kE, kN, kE, 100, 8,
        100, (long)100*kE, 0, 1.f, nullptr, 100, scald+3);
  };

  float* S1f = out + 215;
  float* S2f = out + 215 + kNN;

  // ---- once: staircase g/h, CSR build, wcat (8 message planes + root sum) + bias sums
  hipMemsetAsync(gArr, 0xFF, (size_t)(4*kN)*sizeof(int), stream);
  edge_gmax_kernel<<<dim3((kNE+255)/256,4),256,0,stream>>>(e0,e1,e2,e3, gArr);
  scan_gh_kernel<<<4,256,0,stream>>>(gArr, hArr);
  hipMemsetAsync(cntA, 0, (size_t)(8*kN)*sizeof(int), stream);
  edge_count_kernel<<<dim3((kNE+255)/256,4),256,0,stream>>>(e0,e1,e2,e3, cntA);
  csr_scan_kernel<<<8,64,0,stream>>>(cntA, offsA, curA);
  edge_fill_kernel<<<dim3((kNE+255)/256,4),256,0,stream>>>(e0,e1,e2,e3, curA, adjA);
  hipMemcpyAsync(wc1, g1w1, 8L*kE*kH*sizeof(float), hipMemcpyDeviceToDevice, stream);
  hipMemcpyAsync(wc2, g1w2, 8L*kH*kH*sizeof(float), hipMemcpyDeviceToDevice, stream);
  hipMemcpyAsync(wc3, g2w1, 8L*kE*kH*sizeof(float), hipMemcpyDeviceToDevice, stream);
  hipMemcpyAsync(wc4, g2w2, 8L*kH*kH*sizeof(float), hipMemcpyDeviceToDevice, stream);
  sum_root_kernel<<<eg((long)kE*kH),256,0,stream>>>(g1w1, g1b1, kE, wc1 + 8L*kE*kH, bs);
  sum_root_kernel<<<eg((long)kH*kH),256,0,stream>>>(g1w2, g1b2, kH, wc2 + 8L*kH*kH, bs+kH);
  sum_root_kernel<<<eg((long)kE*kH),256,0,stream>>>(g2w1, g2b1, kE, wc3 + 8L*kE*kH, bs+2*kH);
  sum_root_kernel<<<eg((long)kH*kH),256,0,stream>>>(g2w2, g2b2, kH, wc4 + 8L*kH*kH, bs+3*kH);

  // ---- embed
  launch_gemm<false,false,false,EPI_BIAS>(stream, x_note, kF, embW, kE, h0, kE, kN, kE, kF, 1,
                                          0,0,0, 0.f, embB);

  // ---- GNN1 (sparse, CSR gather); L1 needs LN -> zmid, L2 stays raw for pair
  sparse_layer(h0, kE, wc1, bs);
  apply_ln_kernel<<<eg(kNH),256,0,stream>>>(tnh, zmid, g1ln, partd, kN);
  sparse_layer(zmid, kH, wc2, bs+kH);

  // ---- S1 (pair applies LN(g1ln[1]) to raw tnh)
  run_pair_mpa(kN, g1ln + 2*kH, S1f);

  // ---- h1 = S1 @ h0
  s_times_h(h0, h1);

  // ---- GNN2 #1 (dense)
  dense_layer(h1, kE, wc3, bs+2*kH);
  apply_ln_kernel<<<eg(kNH),256,0,stream>>>(tnh, zmid, g2ln, partd, kGB);
  dense_layer(zmid, kH, wc4, bs+3*kH);

  // ---- S2
  run_pair_mpa(kGB, g2ln + 2*kH, S2f);

  // ---- h2 = S2 @ h1
  s_times_h(h1, h2);

  // ---- GNN2 #2 (dense; mask2 == mask1)
  dense_layer(h2, kE, wc3, bs+2*kH);
  apply_ln_kernel<<<eg(kNH),256,0,stream>>>(tnh, zmid, g2ln, partd, kGB);
  dense_layer(zmid, kH, wc4, bs+3*kH);

  // ---- pool + classifier + log_softmax (LN fused)
  pool_head_kernel<<<dim3(1),256,0,stream>>>(tnh, partd, kGB, g2ln + 2*kH, clfW, clfb, out);
}

// Round 15
// 1121.503 us; speedup vs baseline: 4.4220x; 1.0131x over previous
//
#include <hip/hip_runtime.h>
#include <hip/hip_bf16.h>
#include <math.h>
#include <stdio.h>

static constexpr int   kN  = 800;    // nodes
static constexpr int   kF  = 111;    // input features
static constexpr int   kE  = 32;     // embed dim
static constexpr int   kH  = 200;    // hidden
static constexpr int   kNC = 15;     // classes
static constexpr int   kNE = 8000;   // edges per type
static constexpr long  kNN = (long)kN*kN;   // 640000
static constexpr long  kNH = (long)kN*kH;   // 160000
static constexpr float kAl  = 0.5f;  // ALPHA
static constexpr float kEps = 1e-5f;
static constexpr int   kGB  = (int)((kNH+255)/256);  // gather blocks = 625
static constexpr int   kDB  = 50;    // trsm diagonal block size

typedef unsigned short u16;
typedef __attribute__((ext_vector_type(8))) short short8;
typedef __attribute__((ext_vector_type(4))) float f32x4;

__device__ __forceinline__ u16 f2bf(float v){
  __hip_bfloat16 b = __float2bfloat16(v);
  return *reinterpret_cast<u16*>(&b);
}
__device__ __forceinline__ float bf2f(u16 h){
  unsigned int u = ((unsigned int)h) << 16;
  float f; __builtin_memcpy(&f, &u, 4);
  return f;
}

enum { EPI_NONE=0, EPI_BIAS=1, EPI_SCALE=4, EPI_ACC=6 };

// ---------------------------------------------------------------- fp32 GEMM (software-pipelined)
// LNA: apply graph-LN to A on load: a' = (a - mu)*(rs*lnw[k]) + lnw[kH+k],
// stats reduced from lnpart (lnnb pairs).
template<bool TRANSA, bool TRIUA, bool TRIUB, int EPI, bool LNA>
__global__ __launch_bounds__(256)
void gemm_kernel(const float* __restrict__ A, int lda,
                 const float* __restrict__ B, int ldb,
                 float* __restrict__ C, int ldc,
                 int M, int Ncl, int K,
                 long sA, long sB, long sC, float scale,
                 const float* __restrict__ bias, int kstep,
                 const double* __restrict__ scalp,
                 const float* __restrict__ lnw,
                 const double* __restrict__ lnpart, int lnnb)
{
  constexpr int TM=64, TN=64, TK=16;
  A += (long)blockIdx.z * sA;
  B += (long)blockIdx.z * sB;
  C += (long)blockIdx.z * sC;
  __shared__ float As[TK][TM+4];
  __shared__ float Bs[TK][TN+4];
  const int tid = threadIdx.x;
  const int tn4 = (tid & 15)*4, tm4 = (tid >> 4)*4;
  const int m0 = blockIdx.x * TM, n0 = blockIdx.y * TN;
  float acc[4][4] = {};
  float mu = 0.f, rsf = 1.f;
  if (LNA){
    __shared__ double lnS[256], lnQ[256];
    double s=0.0, q=0.0;
    for (int i=tid; i<lnnb; i+=256){ s += lnpart[2*i]; q += lnpart[2*i+1]; }
    lnS[tid]=s; lnQ[tid]=q;
    __syncthreads();
    for (int h=128; h>0; h>>=1){
      if (tid < h){ lnS[tid]+=lnS[tid+h]; lnQ[tid]+=lnQ[tid+h]; }
      __syncthreads();
    }
    double m = lnS[0]/(double)kNH;
    double var = lnQ[0]/(double)kNH - m*m;
    mu = (float)m;
    rsf = rsqrtf((float)var + kEps);
    __syncthreads();
  }
  const int kbase = kstep ? (int)blockIdx.z * kstep : 0;
  int k0 = TRIUA ? max(m0 - kbase, 0) : 0;
  int kEnd = TRIUB ? min(K, n0 + TN - kbase) : K;
  const bool skip = (k0 >= kEnd);
  if (skip && EPI == EPI_ACC) return;
  if (!skip) {
    float ar[4], br[4];
    auto loadT = [&](int kk0, float* arr, float* brr){
      #pragma unroll
      for (int u=0; u<4; ++u){
        int idx = tid + 256*u;
        float av = 0.f;
        if (!TRANSA) {
          int m = idx >> 4, ka = idx & 15;
          int gm = m0+m, gk = kk0+ka;
          if (gm < M && gk < K){
            av = A[(long)gm*lda + gk];
            if (LNA) av = (av - mu)*(rsf*lnw[gk]) + lnw[kH + gk];
          }
        } else {
          int ka = idx >> 6, m = idx & 63;
          int gm = m0+m, gk = kk0+ka;
          if (gm < M && gk < K){
            av = A[(long)gk*lda + gm];
            if (LNA) av = (av - mu)*(rsf*lnw[gk]) + lnw[kH + gk];
          }
        }
        int kb = idx >> 6, nb = idx & 63;
        int gk = kk0+kb, gn = n0+nb;
        arr[u] = av;
        brr[u] = (gk < K && gn < Ncl) ? B[(long)gk*ldb + gn] : 0.f;
      }
    };
    auto storeT = [&](const float* arr, const float* brr){
      #pragma unroll
      for (int u=0; u<4; ++u){
        int idx = tid + 256*u;
        if (!TRANSA){ int m = idx>>4, ka = idx&15; As[ka][m] = arr[u]; }
        else        { int ka = idx>>6, m = idx&63; As[ka][m] = arr[u]; }
        int kb = idx>>6, nb = idx&63;
        Bs[kb][nb] = brr[u];
      }
    };
    loadT(k0, ar, br);
    for (;;){
      __syncthreads();
      storeT(ar, br);
      __syncthreads();
      int kn = k0 + TK;
      bool more = kn < kEnd;
      if (more) loadT(kn, ar, br);
      #pragma unroll
      for (int kk=0; kk<TK; ++kk) {
        float a[4], b[4];
        #pragma unroll
        for (int u=0;u<4;++u){ a[u]=As[kk][tm4+u]; b[u]=Bs[kk][tn4+u]; }
        #pragma unroll
        for (int i=0;i<4;++i)
          #pragma unroll
          for (int j=0;j<4;++j)
            acc[i][j] = fmaf(a[i], b[j], acc[i][j]);
      }
      if (!more) break;
      k0 = kn;
    }
  }
  float sc = scale;
  if (EPI == EPI_ACC && scalp) sc *= (float)sqrt(sqrt(scalp[0]));
  #pragma unroll
  for (int i=0;i<4;++i) {
    int gm = m0 + tm4 + i;
    if (gm >= M) continue;
    #pragma unroll
    for (int j=0;j<4;++j) {
      int gn = n0 + tn4 + j;
      if (gn >= Ncl) continue;
      float v = acc[i][j];
      long off = (long)gm*ldc + gn;
      if (EPI == EPI_BIAS)       C[off] = v + bias[gn];
      else if (EPI == EPI_SCALE) C[off] = scale*v;
      else if (EPI == EPI_ACC)   unsafeAtomicAdd(&C[off], sc*v);
      else                       C[off] = v;
    }
  }
}

template<bool TRANSA, bool TRIUA, bool TRIUB, int EPI, bool LNA = false>
static inline void launch_gemm(hipStream_t st,
                               const float* A, int lda, const float* B, int ldb,
                               float* C, int ldc, int M, int Ncl, int K, int batch,
                               long sA, long sB, long sC, float scale,
                               const float* bias = nullptr, int kstep = 0,
                               const double* scalp = nullptr,
                               const float* lnw = nullptr,
                               const double* lnpart = nullptr, int lnnb = 0)
{
  dim3 grid((M+63)/64, (Ncl+63)/64, batch);
  gemm_kernel<TRANSA,TRIUA,TRIUB,EPI,LNA><<<grid, 256, 0, st>>>(
      A,lda,B,ldb,C,ldc,M,Ncl,K,sA,sB,sC,scale,bias,kstep,scalp,lnw,lnpart,lnnb);
}

// ---------------------------------------------------------------- split-bf16 MFMA GEMM (powers, pipelined)
__global__ __launch_bounds__(256)
void bgemm2_kernel(const u16* __restrict__ Ah, const u16* __restrict__ Al,
                   const u16* __restrict__ Bh, const u16* __restrict__ Bl,
                   float* __restrict__ C, float* __restrict__ C2,
                   u16* __restrict__ Oh, u16* __restrict__ Ol,
                   float p0, float p1)
{
  constexpr int TM=64, TN=64, BK=32;
  __shared__ u16 Ash[TM][40], Asl[TM][40], Bsh[TN][40], Bsl[TN][40];
  const int tid = threadIdx.x;
  const int m0 = blockIdx.x*TM, n0 = blockIdx.y*TN;
  const int w = tid>>6, lane = tid&63;
  const int wm = (w&1)*32, wn = (w>>1)*32;
  const int quad = lane>>4, lm = lane&15;
  f32x4 acc00={}, acc01={}, acc10={}, acc11={};
  const bool skip = (m0 > n0 + TN - 1);
  int k0 = m0;
  const int kEnd = min(kN, n0+TN);
  const int ar = tid>>2, ac = (tid&3)*8;
  if (!skip){
    uint4 avh, avl, bvh, bvl;
    auto loadT = [&](int kk0){
      avh = {0,0,0,0}; avl = {0,0,0,0}; bvh = {0,0,0,0}; bvl = {0,0,0,0};
      int gk = kk0 + ac;
      if (m0+ar < kN && gk < kN){
        avh = *(const uint4*)(Ah + (long)(m0+ar)*kN + gk);
        avl = *(const uint4*)(Al + (long)(m0+ar)*kN + gk);
      }
      if (n0+ar < kN && gk < kN){
        bvh = *(const uint4*)(Bh + (long)(n0+ar)*kN + gk);
        bvl = *(const uint4*)(Bl + (long)(n0+ar)*kN + gk);
      }
    };
    loadT(k0);
    for (;;){
      __syncthreads();
      *(uint4*)&Ash[ar][ac] = avh; *(uint4*)&Asl[ar][ac] = avl;
      *(uint4*)&Bsh[ar][ac] = bvh; *(uint4*)&Bsl[ar][ac] = bvl;
      __syncthreads();
      int kn = k0 + BK;
      bool more = kn < kEnd;
      if (more) loadT(kn);
      short8 a0h = *(const short8*)&Ash[wm+lm][quad*8];
      short8 a1h = *(const short8*)&Ash[wm+16+lm][quad*8];
      short8 a0l = *(const short8*)&Asl[wm+lm][quad*8];
      short8 a1l = *(const short8*)&Asl[wm+16+lm][quad*8];
      short8 b0h = *(const short8*)&Bsh[wn+lm][quad*8];
      short8 b1h = *(const short8*)&Bsh[wn+16+lm][quad*8];
      short8 b0l = *(const short8*)&Bsl[wn+lm][quad*8];
      short8 b1l = *(const short8*)&Bsl[wn+16+lm][quad*8];
      acc00 = __builtin_amdgcn_mfma_f32_16x16x32_bf16(a0h,b0h,acc00,0,0,0);
      acc00 = __builtin_amdgcn_mfma_f32_16x16x32_bf16(a0h,b0l,acc00,0,0,0);
      acc00 = __builtin_amdgcn_mfma_f32_16x16x32_bf16(a0l,b0h,acc00,0,0,0);
      acc01 = __builtin_amdgcn_mfma_f32_16x16x32_bf16(a0h,b1h,acc01,0,0,0);
      acc01 = __builtin_amdgcn_mfma_f32_16x16x32_bf16(a0h,b1l,acc01,0,0,0);
      acc01 = __builtin_amdgcn_mfma_f32_16x16x32_bf16(a0l,b1h,acc01,0,0,0);
      acc10 = __builtin_amdgcn_mfma_f32_16x16x32_bf16(a1h,b0h,acc10,0,0,0);
      acc10 = __builtin_amdgcn_mfma_f32_16x16x32_bf16(a1h,b0l,acc10,0,0,0);
      acc10 = __builtin_amdgcn_mfma_f32_16x16x32_bf16(a1l,b0h,acc10,0,0,0);
      acc11 = __builtin_amdgcn_mfma_f32_16x16x32_bf16(a1h,b1h,acc11,0,0,0);
      acc11 = __builtin_amdgcn_mfma_f32_16x16x32_bf16(a1h,b1l,acc11,0,0,0);
      acc11 = __builtin_amdgcn_mfma_f32_16x16x32_bf16(a1l,b1h,acc11,0,0,0);
      if (!more) break;
      k0 = kn;
    }
  }
  f32x4 accs[2][2] = {{acc00, acc01},{acc10, acc11}};
  #pragma unroll
  for (int ti=0; ti<2; ++ti){
    #pragma unroll
    for (int tj=0; tj<2; ++tj){
      #pragma unroll
      for (int r=0; r<4; ++r){
        int gm = m0 + wm + ti*16 + quad*4 + r;
        int gn = n0 + wn + tj*16 + lm;
        if (gm >= kN || gn >= kN) continue;
        float v = accs[ti][tj][r];
        long off = (long)gm*kN + gn;
        C[off]  += p0*v;
        C2[off] += p1*v;
        u16 h = f2bf(v);
        Oh[off] = h;
        Ol[off] = f2bf(v - bf2f(h));
      }
    }
  }
}

// ---------------------------------------------------------------- pairwise S via MFMA
// prep: per node n, z = LN(tnh), write hi/lo of (w.*z) and z, and a[n]=sum w z^2
__global__ __launch_bounds__(256)
void ln_pair_prep_kernel(const float* __restrict__ tnh, const double* __restrict__ part,
                         int nb, const float* __restrict__ ln, const float* __restrict__ linW,
                         u16* __restrict__ zwh, u16* __restrict__ zwl,
                         u16* __restrict__ zzh, u16* __restrict__ zzl,
                         float* __restrict__ avec)
{
  __shared__ double ss[256], qq[256];
  __shared__ float ared[256];
  const int n = blockIdx.x, t = threadIdx.x;
  double s=0.0, q=0.0;
  for (int i=t; i<nb; i+=256){ s += part[2*i]; q += part[2*i+1]; }
  ss[t]=s; qq[t]=q;
  __syncthreads();
  for (int h=128; h>0; h>>=1){
    if (t < h){ ss[t]+=ss[t+h]; qq[t]+=qq[t+h]; }
    __syncthreads();
  }
  double m = ss[0]/(double)kNH;
  const float mu = (float)m;
  const float rs = rsqrtf((float)(qq[0]/(double)kNH - m*m) + kEps);
  float acc = 0.f;
  if (t < kH){
    float z = (tnh[(long)n*kH + t] - mu)*(rs*ln[t]) + ln[kH + t];
    float wv = linW[t];
    float zw = wv*z;
    long off = (long)n*kH + t;
    u16 h1 = f2bf(zw);
    zwh[off] = h1; zwl[off] = f2bf(zw - bf2f(h1));
    u16 h2 = f2bf(z);
    zzh[off] = h2; zzl[off] = f2bf(z - bf2f(h2));
    acc = zw*z;
  }
  ared[t] = acc;
  __syncthreads();
  for (int h=128; h>0; h>>=1){
    if (t < h) ared[t] += ared[t+h];
    __syncthreads();
  }
  if (t == 0) avec[n] = ared[0];
}

// tri[i][j] = (i<=j) ? sigmoid(a_i + a_j - 2*G_ij + linb) : 0 ; G = (zw)(z)^T
__global__ __launch_bounds__(256)
void bgemm_pair_kernel(const u16* __restrict__ Ah, const u16* __restrict__ Al,
                       const u16* __restrict__ Bh, const u16* __restrict__ Bl,
                       const float* __restrict__ avec, const float* __restrict__ linb,
                       float* __restrict__ tri, double* __restrict__ frob2)
{
  constexpr int TM=64, TN=64, BK=32, KK=kH;
  __shared__ u16 Ash[TM][40], Asl[TM][40], Bsh[TN][40], Bsl[TN][40];
  __shared__ float red[256];
  const int tid = threadIdx.x;
  const int m0 = blockIdx.x*TM, n0 = blockIdx.y*TN;
  if (m0 > n0 + TN - 1){  // fully-lower block: exact zeros
    for (int idx = tid; idx < TM*TN; idx += 256){
      int r = idx >> 6, c = idx & 63;
      int gm = m0 + r, gn = n0 + c;
      if (gm < kN && gn < kN) tri[(long)gm*kN + gn] = 0.f;
    }
    return;
  }
  const int w = tid>>6, lane = tid&63;
  const int wm = (w&1)*32, wn = (w>>1)*32;
  const int quad = lane>>4, lm = lane&15;
  f32x4 acc00={}, acc01={}, acc10={}, acc11={};
  const int ar = tid>>2, ac = (tid&3)*8;
  for (int k0 = 0; k0 < KK; k0 += BK){
    uint4 avh={0,0,0,0}, avl={0,0,0,0}, bvh={0,0,0,0}, bvl={0,0,0,0};
    int gk = k0 + ac;
    if (m0+ar < kN && gk < KK){
      avh = *(const uint4*)(Ah + (long)(m0+ar)*KK + gk);
      avl = *(const uint4*)(Al + (long)(m0+ar)*KK + gk);
    }
    if (n0+ar < kN && gk < KK){
      bvh = *(const uint4*)(Bh + (long)(n0+ar)*KK + gk);
      bvl = *(const uint4*)(Bl + (long)(n0+ar)*KK + gk);
    }
    __syncthreads();
    *(uint4*)&Ash[ar][ac] = avh; *(uint4*)&Asl[ar][ac] = avl;
    *(uint4*)&Bsh[ar][ac] = bvh; *(uint4*)&Bsl[ar][ac] = bvl;
    __syncthreads();
    short8 a0h = *(const short8*)&Ash[wm+lm][quad*8];
    short8 a1h = *(const short8*)&Ash[wm+16+lm][quad*8];
    short8 a0l = *(const short8*)&Asl[wm+lm][quad*8];
    short8 a1l = *(const short8*)&Asl[wm+16+lm][quad*8];
    short8 b0h = *(const short8*)&Bsh[wn+lm][quad*8];
    short8 b1h = *(const short8*)&Bsh[wn+16+lm][quad*8];
    short8 b0l = *(const short8*)&Bsl[wn+lm][quad*8];
    short8 b1l = *(const short8*)&Bsl[wn+16+lm][quad*8];
    acc00 = __builtin_amdgcn_mfma_f32_16x16x32_bf16(a0h,b0h,acc00,0,0,0);
    acc00 = __builtin_amdgcn_mfma_f32_16x16x32_bf16(a0h,b0l,acc00,0,0,0);
    acc00 = __builtin_amdgcn_mfma_f32_16x16x32_bf16(a0l,b0h,acc00,0,0,0);
    acc01 = __builtin_amdgcn_mfma_f32_16x16x32_bf16(a0h,b1h,acc01,0,0,0);
    acc01 = __builtin_amdgcn_mfma_f32_16x16x32_bf16(a0h,b1l,acc01,0,0,0);
    acc01 = __builtin_amdgcn_mfma_f32_16x16x32_bf16(a0l,b1h,acc01,0,0,0);
    acc10 = __builtin_amdgcn_mfma_f32_16x16x32_bf16(a1h,b0h,acc10,0,0,0);
    acc10 = __builtin_amdgcn_mfma_f32_16x16x32_bf16(a1h,b0l,acc10,0,0,0);
    acc10 = __builtin_amdgcn_mfma_f32_16x16x32_bf16(a1l,b0h,acc10,0,0,0);
    acc11 = __builtin_amdgcn_mfma_f32_16x16x32_bf16(a1h,b1h,acc11,0,0,0);
    acc11 = __builtin_amdgcn_mfma_f32_16x16x32_bf16(a1h,b1l,acc11,0,0,0);
    acc11 = __builtin_amdgcn_mfma_f32_16x16x32_bf16(a1l,b1h,acc11,0,0,0);
  }
  const float lb = linb[0];
  float r2 = 0.f;
  f32x4 accs[2][2] = {{acc00, acc01},{acc10, acc11}};
  #pragma unroll
  for (int ti=0; ti<2; ++ti){
    #pragma unroll
    for (int tj=0; tj<2; ++tj){
      #pragma unroll
      for (int r=0; r<4; ++r){
        int gm = m0 + wm + ti*16 + quad*4 + r;
        int gn = n0 + wn + tj*16 + lm;
        if (gm >= kN || gn >= kN) continue;
        float t = 0.f;
        if (gm <= gn){
          float marg = avec[gm] + avec[gn] - 2.f*accs[ti][tj][r] + lb;
          t = 1.f/(1.f + expf(-marg));
        }
        tri[(long)gm*kN + gn] = t;
        r2 += t*t;
      }
    }
  }
  red[tid] = r2;
  __syncthreads();
  for (int h=128; h>0; h>>=1){
    if (tid < h) red[tid] += red[tid+h];
    __syncthreads();
  }
  if (tid == 0) unsafeAtomicAdd(frob2, (double)red[0]);
}

// ---- fused pade init: papp hi/lo (straight + transposed), psq, qsq
__global__ __launch_bounds__(256)
void pade_both_kernel(const float* __restrict__ tri, const double* __restrict__ frob2,
                      u16* __restrict__ ph, u16* __restrict__ pl,
                      u16* __restrict__ th, u16* __restrict__ tl,
                      float* __restrict__ psq, float* __restrict__ qsq,
                      float P0, float P1, float Q0, float Q1)
{
  __shared__ float t[32][33];
  const float rn = (float)(1.0 / sqrt(frob2[0]));
  int r0 = blockIdx.y*32, c0 = blockIdx.x*32;
  int tr = threadIdx.x>>5, tc = threadIdx.x&31;
  for (int i=tr; i<32; i+=8){
    int r = r0+i, c = c0+tc;
    float eye = (r==c) ? 1.f : 0.f;
    float pa = eye - tri[(long)r*kN + c]*rn;
    t[i][tc] = pa;
    long off = (long)r*kN + c;
    psq[off] = P0*eye + P1*pa;
    qsq[off] = Q0*eye + Q1*pa;
    u16 h = f2bf(pa);
    ph[off] = h;
    pl[off] = f2bf(pa - bf2f(h));
  }
  __syncthreads();
  for (int i=tr; i<32; i+=8){
    int c = c0+i, r = r0+tc;
    float v = t[tc][i];
    u16 h = f2bf(v);
    th[(long)c*kN + r] = h;
    tl[(long)c*kN + r] = f2bf(v - bf2f(h));
  }
}

// ---- stream S = Sacc * sqrt(normA) into d_out
__global__ __launch_bounds__(256)
void copy_scale_kernel(const float* __restrict__ src, const double* __restrict__ frob2,
                       float* __restrict__ dst)
{
  const float fac = (float)sqrt(sqrt(frob2[0]));
  long i = (long)blockIdx.x*256 + threadIdx.x;
  if (i < kNN) __builtin_nontemporal_store(src[i]*fac, &dst[i]);
}

// ---------------------------------------------------------------- CSR build (8 lists)
__global__ void edge_count_kernel(const int* __restrict__ e0, const int* __restrict__ e1,
                                  const int* __restrict__ e2, const int* __restrict__ e3,
                                  int* __restrict__ cnt){
  const int* eis[4] = {e0,e1,e2,e3};
  const int e = blockIdx.y;
  const int* ei = eis[e];
  int j = blockIdx.x*256 + threadIdx.x;
  if (j >= kNE) return;
  int s = ei[j], d = ei[kNE + j];
  atomicAdd(&cnt[e*kN + d], 1);
  atomicAdd(&cnt[(4+e)*kN + s], 1);
}

__global__ void csr_scan_kernel(const int* __restrict__ cnt, int* __restrict__ offs,
                                int* __restrict__ cur){
  const int l = blockIdx.x;
  if (threadIdx.x != 0) return;
  int acc = 0;
  for (int i = 0; i < kN; ++i){
    offs[l*(kN+1) + i] = acc;
    cur[l*kN + i] = acc;
    acc += cnt[l*kN + i];
  }
  offs[l*(kN+1) + kN] = acc;
}

__global__ void edge_fill_kernel(const int* __restrict__ e0, const int* __restrict__ e1,
                                 const int* __restrict__ e2, const int* __restrict__ e3,
                                 int* __restrict__ cur, int* __restrict__ adj){
  const int* eis[4] = {e0,e1,e2,e3};
  const int e = blockIdx.y;
  const int* ei = eis[e];
  int j = blockIdx.x*256 + threadIdx.x;
  if (j >= kNE) return;
  int s = ei[j], d = ei[kNE + j];
  int p = atomicAdd(&cur[e*kN + d], 1);
  adj[(long)e*kNE + p] = s;
  int q = atomicAdd(&cur[(4+e)*kN + s], 1);
  adj[(long)(4+e)*kNE + q] = d;
}

// CSR gather (sparse): t = Y[8] + bsum + 0.5*msgs; pure store + LN partials
__global__ __launch_bounds__(256)
void gather_sparse_kernel(const float* __restrict__ Y, const int* __restrict__ offs,
                          const int* __restrict__ adj, const float* __restrict__ bsum,
                          float* __restrict__ tnh, double* __restrict__ part){
  __shared__ double ss[256], qq[256];
  const int n = blockIdx.x;
  const int f = threadIdx.x;
  double sp = 0.0, qp = 0.0;
  float acc = 0.f;
  if (f < kH){
    #pragma unroll
    for (int l = 0; l < 8; ++l){
      const float* Yp = Y + (long)l*kNH;
      int b = offs[l*(kN+1) + n], e2 = offs[l*(kN+1) + n + 1];
      for (int idx = b; idx < e2; ++idx){
        int m = adj[(long)l*kNE + idx];
        acc += Yp[(long)m*kH + f];
      }
    }
    float t = Y[(long)8*kNH + (long)n*kH + f] + bsum[f] + 0.5f*acc;
    tnh[(long)n*kH + f] = t;
    sp = t; qp = (double)t*t;
  }
  ss[threadIdx.x]=sp; qq[threadIdx.x]=qp;
  __syncthreads();
  for (int hh=128; hh>0; hh>>=1){
    if ((int)threadIdx.x < hh){ ss[threadIdx.x]+=ss[threadIdx.x+hh]; qq[threadIdx.x]+=qq[threadIdx.x+hh]; }
    __syncthreads();
  }
  if (threadIdx.x==0){ part[2*blockIdx.x]=ss[0]; part[2*blockIdx.x+1]=qq[0]; }
}

// ---------------------------------------------------------------- mask staircase kernels
__global__ void edge_gmax_kernel(const int* __restrict__ e0, const int* __restrict__ e1,
                                 const int* __restrict__ e2, const int* __restrict__ e3,
                                 int* __restrict__ g){
  const int* eis[4] = {e0,e1,e2,e3};
  const int e = blockIdx.y;
  const int* ei = eis[e];
  int j = blockIdx.x*256 + threadIdx.x;
  if (j >= kNE) return;
  int s = ei[j], d = ei[kNE + j];
  atomicMax(&g[e*kN + d], s);
}

__global__ __launch_bounds__(256)
void scan_gh_kernel(int* __restrict__ g, int* __restrict__ h){
  __shared__ int gs[kN];
  const int e = blockIdx.x;
  for (int i = threadIdx.x; i < kN; i += 256) gs[i] = g[e*kN + i];
  __syncthreads();
  if (threadIdx.x == 0){
    int m = -1;
    for (int i = 0; i < kN; ++i){ m = max(m, gs[i]); gs[i] = m; }
  }
  __syncthreads();
  for (int i = threadIdx.x; i < kN; i += 256) g[e*kN + i] = gs[i];
  for (int d = threadIdx.x; d < kN; d += 256){
    int lo = 0, hi = kN;
    while (lo < hi){ int mid = (lo+hi)>>1; if (gs[mid] >= d) hi = mid; else lo = mid+1; }
    h[e*kN + d] = lo;
  }
}

// in-place scans over Y planes: z<4 prefix; z>=4 suffix
__global__ __launch_bounds__(256)
void scan_msg_kernel(float* __restrict__ Y){
  const int plane = blockIdx.x;
  const int f = threadIdx.x;
  if (f >= kH) return;
  float* P = Y + (long)plane*kNH + f;
  float acc = 0.f;
  if (plane < 4){
    for (int n = 0; n < kN; n += 4){
      float v0 = P[(long)(n+0)*kH], v1 = P[(long)(n+1)*kH];
      float v2 = P[(long)(n+2)*kH], v3 = P[(long)(n+3)*kH];
      acc += v0; P[(long)(n+0)*kH] = acc;
      acc += v1; P[(long)(n+1)*kH] = acc;
      acc += v2; P[(long)(n+2)*kH] = acc;
      acc += v3; P[(long)(n+3)*kH] = acc;
    }
  } else {
    for (int n = kN-1; n >= 0; n -= 4){
      float v0 = P[(long)(n-0)*kH], v1 = P[(long)(n-1)*kH];
      float v2 = P[(long)(n-2)*kH], v3 = P[(long)(n-3)*kH];
      acc += v0; P[(long)(n-0)*kH] = acc;
      acc += v1; P[(long)(n-1)*kH] = acc;
      acc += v2; P[(long)(n-2)*kH] = acc;
      acc += v3; P[(long)(n-3)*kH] = acc;
    }
  }
}

// dense gather: t = Y[8] + bsum + 0.5*(staircase sums); pure store + LN partials
__global__ __launch_bounds__(256)
void gather_dense_kernel(const float* __restrict__ Y, const int* __restrict__ g,
                         const int* __restrict__ h, const float* __restrict__ bsum,
                         float* __restrict__ tnh, double* __restrict__ part){
  __shared__ double ss[256], qq[256];
  long idx = (long)blockIdx.x*256 + threadIdx.x;
  double s = 0.0, q = 0.0;
  if (idx < kNH){
    int n = (int)(idx / kH), f = (int)(idx % kH);
    float v = 0.f;
    #pragma unroll
    for (int e = 0; e < 4; ++e){
      int gi = g[e*kN + n];
      if (gi >= 0) v += Y[(long)e*kNH + (long)gi*kH + f];
      int hi = h[e*kN + n];
      if (hi < kN) v += Y[(long)(4+e)*kNH + (long)hi*kH + f];
    }
    float t = Y[(long)8*kNH + idx] + bsum[f] + 0.5f*v;
    tnh[idx] = t;
    s = t; q = (double)t*t;
  }
  ss[threadIdx.x]=s; qq[threadIdx.x]=q;
  __syncthreads();
  for (int hh=128; hh>0; hh>>=1){
    if ((int)threadIdx.x < hh){ ss[threadIdx.x]+=ss[threadIdx.x+hh]; qq[threadIdx.x]+=qq[threadIdx.x+hh]; }
    __syncthreads();
  }
  if (threadIdx.x==0){ part[2*blockIdx.x]=ss[0]; part[2*blockIdx.x+1]=qq[0]; }
}

// ---------------------------------------------------------------- small kernels
__global__ void sum_root_kernel(const float* __restrict__ W, const float* __restrict__ b,
                                int K, float* __restrict__ Wr, float* __restrict__ bsum){
  int idx = blockIdx.x*256 + threadIdx.x;
  int tot = K*kH;
  if (idx < tot){
    float v = 0.f;
    #pragma unroll
    for (int e=0;e<4;++e) v += W[(long)(8+e)*tot + idx];
    Wr[idx] = v;
  }
  if (idx < kH){
    float v = 0.f;
    #pragma unroll
    for (int e=0;e<4;++e)
      v += (1.f-kAl)*b[(0*4+e)*kH + idx] + kAl*b[(1*4+e)*kH + idx] + b[(2*4+e)*kH + idx];
    bsum[idx] = v;
  }
}

// ---- invert the 16 diagonal 50x50 upper-tri blocks of U into W (W pre-zeroed)
__global__ __launch_bounds__(64)
void invdiag_kernel(const float* __restrict__ U, float* __restrict__ W){
  __shared__ float Us[kDB][kDB+1];
  __shared__ float Xs[kDB][kDB+1];
  const int base = blockIdx.x * kDB;
  const int tid = threadIdx.x;
  for (int idx = tid; idx < kDB*kDB; idx += 64){
    int r = idx / kDB, c = idx % kDB;
    Us[r][c] = U[(long)(base+r)*kN + base + c];
  }
  __syncthreads();
  const int c = tid;
  for (int i = kDB-1; i >= 0; --i){
    if (c < kDB){
      float x;
      if (c < i) x = 0.f;
      else {
        float s = 0.f;
        for (int k = i+1; k < kDB; ++k) s = fmaf(Us[i][k], Xs[k][c], s);
        x = (((c==i)?1.f:0.f) - s) / Us[i][i];
      }
      Xs[i][c] = x;
    }
    __syncthreads();
  }
  for (int idx = tid; idx < kDB*kDB; idx += 64){
    int r = idx / kDB, cc = idx % kDB;
    W[(long)(base+r)*kN + base + cc] = Xs[r][cc];
  }
}

// ---- fused merge for level S: one block per pair
template<int S>
__global__ __launch_bounds__(256)
void merge_fused_kernel(const float* __restrict__ U, float* __restrict__ W){
  __shared__ float Us[S][S+1];
  __shared__ float Wb[S][S+1];
  __shared__ float T[S][S+1];
  const long base = (long)blockIdx.x * (2*S) * (kN+1);
  const int tid = threadIdx.x;
  for (int idx = tid; idx < S*S; idx += 256){
    int r = idx / S, c = idx % S;
    Us[r][c] = U[base + (long)r*kN + S + c];
    Wb[r][c] = W[base + (long)(S+r)*kN + S + c];
  }
  __syncthreads();
  for (int idx = tid; idx < S*S; idx += 256){
    int r = idx / S, c = idx % S;
    float s = 0.f;
    for (int k = 0; k <= c; ++k) s = fmaf(Us[r][k], Wb[k][c], s);
    T[r][c] = s;
  }
  __syncthreads();
  for (int idx = tid; idx < S*S; idx += 256){
    int r = idx / S, c = idx % S;
    Us[r][c] = W[base + (long)r*kN + c];
  }
  __syncthreads();
  for (int idx = tid; idx < S*S; idx += 256){
    int r = idx / S, c = idx % S;
    float s = 0.f;
    for (int k = r; k < S; ++k) s = fmaf(Us[r][k], T[k][c], s);
    W[base + (long)r*kN + S + c] = -s;
  }
}

// pool + classifier + log_softmax, with inline LN of raw z2
__global__ __launch_bounds__(256)
void pool_head_kernel(const float* __restrict__ z2raw, const double* __restrict__ part, int nb,
                      const float* __restrict__ ln,
                      const float* __restrict__ W, const float* __restrict__ b,
                      float* __restrict__ out){
  __shared__ double sred[256], qred[256];
  __shared__ float x2[kH];
  __shared__ float lg[kNC];
  int t = threadIdx.x;
  double s=0.0, q=0.0;
  for (int i=t; i<nb; i+=256){ s += part[2*i]; q += part[2*i+1]; }
  sred[t]=s; qred[t]=q;
  __syncthreads();
  for (int hh=128; hh>0; hh>>=1){
    if (t < hh){ sred[t]+=sred[t+hh]; qred[t]+=qred[t+hh]; }
    __syncthreads();
  }
  const float mu = (float)(sred[0] / (double)kNH);
  const float rs = rsqrtf((float)(qred[0]/(double)kNH - (sred[0]/(double)kNH)*(sred[0]/(double)kNH)) + kEps);
  if (t < kH){
    float sc = rs*ln[t], of = ln[kH+t];
    float sum = 0.f;
    for (int n = 0; n < kN; ++n) sum += (z2raw[(long)n*kH + t] - mu)*sc + of;
    float v = sum * (1.f/(float)kN);
    x2[t] = v;
    out[t] = v;
  }
  __syncthreads();
  if (t < kNC){
    float sv = b[t];
    for (int f = 0; f < kH; ++f) sv = fmaf(x2[f], W[f*kNC + t], sv);
    lg[t] = sv;
  }
  __syncthreads();
  if (t == 0){
    float m = -1e30f;
    for (int c=0;c<kNC;++c) m = fmaxf(m, lg[c]);
    float se = 0.f;
    for (int c=0;c<kNC;++c) se += expf(lg[c]-m);
    float lse = m + logf(se);
    for (int c=0;c<kNC;++c) out[kH + c] = lg[c]-lse;
  }
}

// ---------------------------------------------------------------- host: Pade [5/5] of sqrt(1-x)
static void pade_coeffs(float* P, float* Q){
  double b[11]; b[0] = 1.0;
  for (int k=1;k<11;++k) b[k] = b[k-1]*(0.5-(k-1))/k;
  double c[11];
  for (int k=0;k<11;++k) c[k] = b[k]*((k&1)?-1.0:1.0);
  double A[5][5], rhs[5];
  for (int i=0;i<5;++i){ for (int j=0;j<5;++j) A[i][j] = c[5+i-j]; rhs[i] = -c[6+i]; }
  for (int col=0; col<5; ++col){
    int p = col;
    for (int r=col+1;r<5;++r) if (fabs(A[r][col]) > fabs(A[p][col])) p = r;
    if (p != col){
      for (int j=0;j<5;++j){ double t=A[col][j]; A[col][j]=A[p][j]; A[p][j]=t; }
      double t=rhs[col]; rhs[col]=rhs[p]; rhs[p]=t;
    }
    for (int r=col+1;r<5;++r){
      double f = A[r][col]/A[col][col];
      for (int j=col;j<5;++j) A[r][j] -= f*A[col][j];
      rhs[r] -= f*rhs[col];
    }
  }
  double q[6]; q[0] = 1.0;
  for (int r=4;r>=0;--r){
    double s = rhs[r];
    for (int j=r+1;j<5;++j) s -= A[r][j]*q[1+j];
    q[1+r] = s/A[r][r];
  }
  double p[6];
  for (int k=0;k<6;++k){
    double s = 0.0; int jm = k<5?k:5;
    for (int j=0;j<=jm;++j) s += q[j]*c[k-j];
    p[k] = s;
  }
  for (int k=0;k<6;++k){ P[k]=(float)p[k]; Q[k]=(float)q[k]; }
}

// ---------------------------------------------------------------- launch
extern "C" void kernel_launch(void* const* d_in, const int* in_sizes, int n_in,
                              void* d_out, int out_size, void* d_ws, size_t ws_size,
                              hipStream_t stream)
{
  const float* x_note = (const float*)d_in[0];
  const float* embW   = (const float*)d_in[1];
  const float* embB   = (const float*)d_in[2];
  const float* g1w1   = (const float*)d_in[3];
  const float* g1b1   = (const float*)d_in[4];
  const float* g1w2   = (const float*)d_in[5];
  const float* g1b2   = (const float*)d_in[6];
  const float* g1ln   = (const float*)d_in[7];
  const float* g2w1   = (const float*)d_in[8];
  const float* g2b1   = (const float*)d_in[9];
  const float* g2w2   = (const float*)d_in[10];
  const float* g2b2   = (const float*)d_in[11];
  const float* g2ln   = (const float*)d_in[12];
  const float* linW   = (const float*)d_in[13];
  const float* linb   = (const float*)d_in[14];
  const float* clfW   = (const float*)d_in[15];
  const float* clfb   = (const float*)d_in[16];
  const int*  e0     = (const int*)d_in[17];
  const int*  e1     = (const int*)d_in[18];
  const int*  e2     = (const int*)d_in[19];
  const int*  e3     = (const int*)d_in[20];
  float* out = (float*)d_out;

  // header: scald @0 (32B), partd @512B
  constexpr long o_h0   = 4096;
  constexpr long o_h1   = o_h0   + (long)kN*kE;
  constexpr long o_h2   = o_h1   + (long)kN*kE;
  constexpr long o_tnh  = o_h2   + (long)kN*kE;
  constexpr long o_pp   = o_tnh  + kNH;             // 4 u16 planes = 2*kNH floats
  constexpr long o_av   = o_pp   + 2*kNH;           // kN floats
  constexpr long o_big  = o_av   + kN;              // 4*kNN floats
  constexpr long o_tri  = o_big  + 4*kNN;
  constexpr long o_sacc = o_tri  + kNN;
  constexpr long o_winv = o_sacc + kNN;
  constexpr long o_psq  = o_winv + kNN;
  constexpr long o_qsq  = o_psq  + kNN;
  constexpr long o_g    = o_qsq  + kNN;
  constexpr long o_hh   = o_g    + 4*kN;
  constexpr long o_wc1  = o_hh   + 4*kN;
  constexpr long o_wc2  = o_wc1  + 9L*kE*kH;
  constexpr long o_wc3  = o_wc2  + 9L*kH*kH;
  constexpr long o_wc4  = o_wc3  + 9L*kE*kH;
  constexpr long o_bs   = o_wc4  + 9L*kH*kH;
  constexpr long o_cnt  = o_bs   + 4*kH;
  constexpr long o_offs = o_cnt  + 8*kN;
  constexpr long o_cur  = o_offs + 8*(kN+1);
  constexpr long o_adj  = o_cur  + 8*kN;
  constexpr long o_end  = o_adj  + 8*(long)kNE;

  if (ws_size < (size_t)o_end*sizeof(float) || out_size < 215 + 2*(int)kNN || n_in < 21){
    fprintf(stderr, "kernel_launch guard: ws=%zu need=%zu out=%d need=%d n_in=%d\n",
            ws_size, (size_t)o_end*sizeof(float), out_size, (int)(215+2*kNN), n_in);
    hipMemsetAsync(d_out, 0, (size_t)out_size*sizeof(float), stream);
    return;
  }

  float* ws = (float*)d_ws;
  double* scald = (double*)d_ws;
  double* partd = (double*)((char*)d_ws + 512);
  float *h0=ws+o_h0, *h1=ws+o_h1, *h2=ws+o_h2, *tnh=ws+o_tnh,
        *big=ws+o_big, *tri=ws+o_tri, *Sacc=ws+o_sacc, *winv=ws+o_winv,
        *psq=ws+o_psq, *qsq=ws+o_qsq;
  u16* zwh = (u16*)(ws + o_pp);
  u16* zwl = zwh + kNH;
  u16* zzh = zwl + kNH;
  u16* zzl = zzh + kNH;
  float* avec = ws + o_av;
  int* gArr = (int*)(ws + o_g);
  int* hArr = (int*)(ws + o_hh);
  float *wc1=ws+o_wc1, *wc2=ws+o_wc2, *wc3=ws+o_wc3, *wc4=ws+o_wc4, *bs=ws+o_bs;
  int* cntA = (int*)(ws + o_cnt);
  int* offsA= (int*)(ws + o_offs);
  int* curA = (int*)(ws + o_cur);
  int* adjA = (int*)(ws + o_adj);
  u16* papp_h = (u16*)big;
  u16* papp_l = papp_h + kNN;
  u16* pT_h   = papp_l + kNN;
  u16* pT_l   = pT_h + kNN;
  u16* pwA_h  = pT_l + kNN;
  u16* pwA_l  = pwA_h + kNN;
  u16* pwB_h  = pwA_l + kNN;
  u16* pwB_l  = pwB_h + kNN;

  float P[6], Q[6];
  pade_coeffs(P, Q);

  auto eg = [](long n){ return dim3((unsigned)((n+255)/256)); };

  // one batch-9 GEMM per layer; lnp!=null -> LN fused into A-load (reads raw tnh)
  auto layer_gemm = [&](const float* hin, int K, const float* wcat,
                        const float* lnp, int nb){
    if (lnp)
      launch_gemm<false,false,false,EPI_NONE,true>(stream, hin, K, wcat, kH, big, kH,
          kN, kH, K, 9, 0, (long)K*kH, kNH, 0.f, nullptr, 0, nullptr, lnp, partd, nb);
    else
      launch_gemm<false,false,false,EPI_NONE>(stream, hin, K, wcat, kH, big, kH,
          kN, kH, K, 9, 0, (long)K*kH, kNH, 0.f);
  };
  auto sparse_layer = [&](const float* hin, int K, const float* wcat, const float* bsum,
                          const float* lnp, int nb){
    layer_gemm(hin, K, wcat, lnp, nb);
    gather_sparse_kernel<<<dim3(kN),256,0,stream>>>(big, offsA, adjA, bsum, tnh, partd);
  };
  auto dense_layer = [&](const float* hin, int K, const float* wcat, const float* bsum,
                         const float* lnp, int nb){
    layer_gemm(hin, K, wcat, lnp, nb);
    scan_msg_kernel<<<8,256,0,stream>>>(big);
    gather_dense_kernel<<<kGB,256,0,stream>>>(big, gArr, hArr, bsum, tnh, partd);
  };
  auto blocked_trsm = [&](){
    hipMemsetAsync(winv, 0, (size_t)kNN*sizeof(float), stream);
    invdiag_kernel<<<dim3(kN/kDB),64,0,stream>>>(qsq, winv);
    merge_fused_kernel<50><<<dim3(kN/100),256,0,stream>>>(qsq, winv);
    {   // level s=100 (4 pairs)
      int s = 100, npairs = 4;
      long step = (long)2*s*kN + 2*s;
      launch_gemm<false,false,true,EPI_NONE>(stream,
          qsq + s, kN, winv + (long)s*kN + s, kN, tri, s,
          s, s, s, npairs, step, step, (long)s*s, 0.f);
      launch_gemm<false,true,false,EPI_SCALE>(stream,
          winv, kN, tri, s, winv + s, kN,
          s, s, s, npairs, step, (long)s*s, step, -1.f);
    }
    {   // level s=200 (2 pairs)
      int s = 200, npairs = 2;
      long step = (long)2*s*kN + 2*s;
      launch_gemm<false,false,true,EPI_NONE>(stream,
          qsq + s, kN, winv + (long)s*kN + s, kN, tri, s,
          s, s, s, npairs, step, step, (long)s*s, 0.f);
      launch_gemm<false,true,false,EPI_SCALE>(stream,
          winv, kN, tri, s, winv + s, kN,
          s, s, s, npairs, step, (long)s*s, step, -1.f);
    }
    {   // level s=400 (1 pair) — K-split x4, atomic ACC
      hipMemsetAsync(tri, 0, (size_t)400*400*sizeof(float), stream);
      launch_gemm<false,false,true,EPI_ACC>(stream,
          qsq + 400, kN, winv + (long)400*kN + 400, kN, tri, 400,
          400, 400, 100, 4, 100, (long)100*kN, 0, 1.f, nullptr, 100);
      launch_gemm<false,true,false,EPI_ACC>(stream,
          winv, kN, tri, 400, winv + 400, kN,
          400, 400, 100, 4, 100, (long)100*400, 0, -1.f, nullptr, 100);
    }
    hipMemsetAsync(Sacc, 0, (size_t)kNN*sizeof(float), stream);
    launch_gemm<false,true,true,EPI_ACC>(stream,
        winv, kN, psq, kN, Sacc, kN, kN, kN, 100, 8,
        100, (long)100*kN, 0, 1.f, nullptr, 100);
  };
  // consumes raw tnh (+partials, nb), LN fused into prep
  auto run_pair_mpa = [&](int nb, const float* lnp, float* SoutDst){
    hipMemsetAsync((char*)d_ws + 24, 0, 8, stream);            // scald[3] = 0
    ln_pair_prep_kernel<<<dim3(kN),256,0,stream>>>(tnh, partd, nb, lnp, linW,
                                                   zwh, zwl, zzh, zzl, avec);
    bgemm_pair_kernel<<<dim3(13,13),256,0,stream>>>(zwh, zwl, zzh, zzl, avec, linb,
                                                    tri, scald+3);
    pade_both_kernel<<<dim3(25,25),256,0,stream>>>(tri, scald+3, papp_h, papp_l, pT_h, pT_l,
                                                   psq, qsq, P[0],P[1],Q[0],Q[1]);
    dim3 g13(13,13,1);
    bgemm2_kernel<<<g13,256,0,stream>>>(papp_h,papp_l, pT_h,pT_l, psq,qsq, pwA_h,pwA_l, P[2],Q[2]);
    bgemm2_kernel<<<g13,256,0,stream>>>(pwA_h,pwA_l,  pT_h,pT_l, psq,qsq, pwB_h,pwB_l, P[3],Q[3]);
    bgemm2_kernel<<<g13,256,0,stream>>>(pwB_h,pwB_l,  pT_h,pT_l, psq,qsq, pwA_h,pwA_l, P[4],Q[4]);
    bgemm2_kernel<<<g13,256,0,stream>>>(pwA_h,pwA_l,  pT_h,pT_l, psq,qsq, pwB_h,pwB_l, P[5],Q[5]);
    blocked_trsm();
    copy_scale_kernel<<<eg(kNN),256,0,stream>>>(Sacc, scald+3, SoutDst);
  };
  auto s_times_h = [&](const float* hin, float* hout){
    hipMemsetAsync(hout, 0, (size_t)kN*kE*sizeof(float), stream);
    launch_gemm<false,true,false,EPI_ACC>(stream,
        Sacc, kN, hin, kE, hout, kE, kN, kE, 100, 8,
        100, (long)100*kE, 0, 1.f, nullptr, 100, scald+3);
  };

  float* S1f = out + 215;
  float* S2f = out + 215 + kNN;

  // ---- once: staircase g/h, CSR build, wcat + bias sums
  hipMemsetAsync(gArr, 0xFF, (size_t)(4*kN)*sizeof(int), stream);
  edge_gmax_kernel<<<dim3((kNE+255)/256,4),256,0,stream>>>(e0,e1,e2,e3, gArr);
  scan_gh_kernel<<<4,256,0,stream>>>(gArr, hArr);
  hipMemsetAsync(cntA, 0, (size_t)(8*kN)*sizeof(int), stream);
  edge_count_kernel<<<dim3((kNE+255)/256,4),256,0,stream>>>(e0,e1,e2,e3, cntA);
  csr_scan_kernel<<<8,64,0,stream>>>(cntA, offsA, curA);
  edge_fill_kernel<<<dim3((kNE+255)/256,4),256,0,stream>>>(e0,e1,e2,e3, curA, adjA);
  hipMemcpyAsync(wc1, g1w1, 8L*kE*kH*sizeof(float), hipMemcpyDeviceToDevice, stream);
  hipMemcpyAsync(wc2, g1w2, 8L*kH*kH*sizeof(float), hipMemcpyDeviceToDevice, stream);
  hipMemcpyAsync(wc3, g2w1, 8L*kE*kH*sizeof(float), hipMemcpyDeviceToDevice, stream);
  hipMemcpyAsync(wc4, g2w2, 8L*kH*kH*sizeof(float), hipMemcpyDeviceToDevice, stream);
  sum_root_kernel<<<eg((long)kE*kH),256,0,stream>>>(g1w1, g1b1, kE, wc1 + 8L*kE*kH, bs);
  sum_root_kernel<<<eg((long)kH*kH),256,0,stream>>>(g1w2, g1b2, kH, wc2 + 8L*kH*kH, bs+kH);
  sum_root_kernel<<<eg((long)kE*kH),256,0,stream>>>(g2w1, g2b1, kE, wc3 + 8L*kE*kH, bs+2*kH);
  sum_root_kernel<<<eg((long)kH*kH),256,0,stream>>>(g2w2, g2b2, kH, wc4 + 8L*kH*kH, bs+3*kH);

  // ---- embed
  launch_gemm<false,false,false,EPI_BIAS>(stream, x_note, kF, embW, kE, h0, kE, kN, kE, kF, 1,
                                          0,0,0, 0.f, embB);

  // ---- GNN1 (sparse); layer 2 reads raw tnh with LN fused into GEMM
  sparse_layer(h0,  kE, wc1, bs,      nullptr, 0);
  sparse_layer(tnh, kH, wc2, bs+kH,   g1ln, kN);

  // ---- S1 (LN(g1ln[1]) fused into pair prep)
  run_pair_mpa(kN, g1ln + 2*kH, S1f);

  // ---- h1 = S1 @ h0
  s_times_h(h0, h1);

  // ---- GNN2 #1 (dense)
  dense_layer(h1,  kE, wc3, bs+2*kH, nullptr, 0);
  dense_layer(tnh, kH, wc4, bs+3*kH, g2ln, kGB);

  // ---- S2
  run_pair_mpa(kGB, g2ln + 2*kH, S2f);

  // ---- h2 = S2 @ h1
  s_times_h(h1, h2);

  // ---- GNN2 #2 (dense; mask2 == mask1)
  dense_layer(h2,  kE, wc3, bs+2*kH, nullptr, 0);
  dense_layer(tnh, kH, wc4, bs+3*kH, g2ln, kGB);

  // ---- pool + classifier + log_softmax (LN fused)
  pool_head_kernel<<<dim3(1),256,0,stream>>>(tnh, partd, kGB, g2ln + 2*kH, clfW, clfb, out);
}